// Round 2
// baseline (1177.614 us; speedup 1.0000x reference)
//
#include <hip/hip_runtime.h>

// ---------------------------------------------------------------------------
// Net_3152505995976: point-cloud classifier forward pass on MI355X.
// Round 2: all-fp32 pipeline (bf16 intermediates removed — they cost 0.15
// absmax through the BN amplification chain).
//   - KNN exact reference distance formula + stable top-k
//   - LAPACK ssyevd replica (fp32) for 3x3 eigh sign/order matching
//   - BN via global stats kernels (double atomics), affine folded on load
//   - l23 is IN-PLACE (stage rows through LDS, sync, write back) -> one
//     84 MB fp32 h buffer, total ws footprint unchanged at ~110.8 MB
//   - DD2 reads fp32 W21 from global (L2-resident), LDS 66 KB -> 2 blk/CU
// ---------------------------------------------------------------------------

#define NEW_SLARTG 1

typedef unsigned short u16;
typedef unsigned int u32;

#define BB 8
#define NNp 2048
#define KKn 20
#define NP 16384      // BB*NNp
#define EE 327680     // NP*KKn

// ---------------- small helpers ----------------
__device__ __forceinline__ u32 fkey(float f) {
  u32 u = __float_as_uint(f);
  return (u & 0x80000000u) ? ~u : (u | 0x80000000u);
}
__device__ __forceinline__ float funkey(u32 k) {
  u32 u = (k & 0x80000000u) ? (k ^ 0x80000000u) : ~k;
  return __uint_as_float(u);
}
__device__ __forceinline__ float f_sign(float a, float b) {
  return (b >= 0.f) ? fabsf(a) : -fabsf(a);
}

// ---------------- LAPACK fp32 replicas ----------------
__device__ float slapy2_(float x, float y) {
#pragma clang fp contract(off)
  float xa = fabsf(x), ya = fabsf(y);
  float w = fmaxf(xa, ya), z = fminf(xa, ya);
  if (z == 0.f) return w;
  float t = z / w;
  return w * sqrtf(1.0f + t * t);
}

__device__ void slartg_(float f, float g, float& c, float& s, float& r) {
#pragma clang fp contract(off)
#if NEW_SLARTG
  const float safmin = 1.17549435e-38f;
  const float safmax = 8.50705917e+37f;
  const float rtmin = 1.08420217e-19f;   // sqrt(safmin)
  const float rtmax = 6.52221171e+18f;   // sqrt(safmax/2)
  float f1 = fabsf(f), g1 = fabsf(g);
  if (g == 0.f) { c = 1.f; s = 0.f; r = f; }
  else if (f == 0.f) { c = 0.f; s = (g >= 0.f) ? 1.f : -1.f; r = g1; }
  else {
    float d;
    if (f1 > rtmin && f1 < rtmax && g1 > rtmin && g1 < rtmax) {
      d = sqrtf(f * f + g * g);
      c = f1 / d;
      r = (f >= 0.f) ? d : -d;
    } else {
      float uu = fminf(safmax, fmaxf(safmin, fmaxf(f1, g1)));
      float fs = f / uu, gs = g / uu;
      d = sqrtf(fs * fs + gs * gs);
      c = fabsf(fs) / d;
      r = ((f >= 0.f) ? d : -d) * uu;
    }
    s = g / r;
  }
#else
  if (g == 0.f) { c = 1.f; s = 0.f; r = f; }
  else if (f == 0.f) { c = 0.f; s = 1.f; r = g; }
  else {
    float f1 = f, g1 = g;
    r = sqrtf(f1 * f1 + g1 * g1);
    c = f1 / r;
    s = g1 / r;
    if (fabsf(f) > fabsf(g) && c < 0.f) { c = -c; s = -s; r = -r; }
  }
#endif
}

__device__ void slaev2_(float a, float b, float c, float& rt1, float& rt2,
                        float& cs1, float& sn1) {
#pragma clang fp contract(off)
  float sm = a + c;
  float df = a - c;
  float adf = fabsf(df);
  float tb = b + b;
  float ab = fabsf(tb);
  float acmx, acmn;
  if (fabsf(a) > fabsf(c)) { acmx = a; acmn = c; } else { acmx = c; acmn = a; }
  float rt;
  if (adf > ab) { float t = ab / adf; rt = adf * sqrtf(1.f + t * t); }
  else if (adf < ab) { float t = adf / ab; rt = ab * sqrtf(1.f + t * t); }
  else { rt = ab * sqrtf(2.f); }
  int sgn1;
  if (sm < 0.f) {
    rt1 = 0.5f * (sm - rt); sgn1 = -1;
    rt2 = (acmx / rt1) * acmn - (b / rt1) * b;
  } else if (sm > 0.f) {
    rt1 = 0.5f * (sm + rt); sgn1 = 1;
    rt2 = (acmx / rt1) * acmn - (b / rt1) * b;
  } else {
    rt1 = 0.5f * rt; rt2 = -0.5f * rt; sgn1 = 1;
  }
  float cs; int sgn2;
  if (df >= 0.f) { cs = df + rt; sgn2 = 1; } else { cs = df - rt; sgn2 = -1; }
  float acs = fabsf(cs);
  if (acs > ab) {
    float ct = -tb / cs;
    sn1 = 1.f / sqrtf(1.f + ct * ct);
    cs1 = ct * sn1;
  } else {
    if (ab == 0.f) { cs1 = 1.f; sn1 = 0.f; }
    else {
      float tn = -cs / tb;
      cs1 = 1.f / sqrtf(1.f + tn * tn);
      sn1 = tn * cs1;
    }
  }
  if (sgn1 == sgn2) { float tn = cs1; cs1 = -sn1; sn1 = tn; }
}

// ssteqr for n=3, compz='I' (z must be identity on entry)
__device__ void ssteqr3_(float* d, float* e, float z[3][3]) {
#pragma clang fp contract(off)
  const float eps = 5.9604645e-08f;
  const float eps2 = 3.5527137e-15f;
  const float safmin = 1.17549435e-38f;
  const int n = 3;
  const int nmaxit = 90;
  int jtot = 0;
  int l1 = 1;

  while (1) {
    if (l1 > n) break;
    if (l1 > 1) e[l1 - 2] = 0.f;
    int m = n;
    if (l1 <= n - 1) {
      for (int mm = l1; mm <= n - 1; ++mm) {
        float tst = fabsf(e[mm - 1]);
        if (tst == 0.f) { m = mm; break; }
        if (tst <= (sqrtf(fabsf(d[mm - 1])) * sqrtf(fabsf(d[mm]))) * eps) {
          e[mm - 1] = 0.f; m = mm; break;
        }
      }
    }
    int l = l1, lsv = l, lend = m, lendsv = lend;
    (void)lsv; (void)lendsv;
    l1 = m + 1;
    if (lend == l) continue;

    float anorm = 0.f;
    for (int i = l; i <= lend; ++i) anorm = fmaxf(anorm, fabsf(d[i - 1]));
    for (int i = l; i <= lend - 1; ++i) anorm = fmaxf(anorm, fabsf(e[i - 1]));
    if (anorm == 0.f) continue;

    if (fabsf(d[lend - 1]) < fabsf(d[l - 1])) { lend = lsv; l = lendsv; }

    if (lend > l) {
      // --- QL iteration ---
      while (1) {
        int m2 = lend;
        if (l != lend) {
          for (int mm = l; mm <= lend - 1; ++mm) {
            float tst = fabsf(e[mm - 1]); tst = tst * tst;
            if (tst <= (eps2 * fabsf(d[mm - 1])) * fabsf(d[mm]) + safmin) { m2 = mm; break; }
          }
        }
        if (m2 < lend) e[m2 - 1] = 0.f;
        float p = d[l - 1];
        if (m2 == l) {
          d[l - 1] = p; l += 1;
          if (l <= lend) continue;
          break;
        }
        if (m2 == l + 1) {
          float rt1, rt2, cc, ss;
          slaev2_(d[l - 1], e[l - 1], d[l], rt1, rt2, cc, ss);
          for (int i = 0; i < 3; ++i) {
            float temp = z[i][l];
            z[i][l] = cc * temp - ss * z[i][l - 1];
            z[i][l - 1] = ss * temp + cc * z[i][l - 1];
          }
          d[l - 1] = rt1; d[l] = rt2; e[l - 1] = 0.f;
          l += 2;
          if (l <= lend) continue;
          break;
        }
        if (jtot == nmaxit) break;
        jtot++;
        float g = (d[l] - p) / (2.f * e[l - 1]);
        float r = slapy2_(g, 1.f);
        g = d[m2 - 1] - p + (e[l - 1] / (g + f_sign(r, g)));
        float s = 1.f, c = 1.f;
        p = 0.f;
        float csv[2], snv[2];
        for (int i = m2 - 1; i >= l; --i) {
          float f = s * e[i - 1];
          float b = c * e[i - 1];
          slartg_(g, f, c, s, r);
          if (i != m2 - 1) e[i] = r;
          g = d[i] - p;
          r = (d[i - 1] - g) * s + (2.f * c) * b;
          p = s * r;
          d[i] = g + p;
          g = c * r - b;
          csv[i - l] = c; snv[i - l] = -s;
        }
        int cnt = m2 - l;
        for (int j = cnt; j >= 1; --j) {       // slasr 'R','V','B'
          float cj = csv[j - 1], sj = snv[j - 1];
          int c0 = (l - 1) + (j - 1);
          for (int i = 0; i < 3; ++i) {
            float temp = z[i][c0 + 1];
            z[i][c0 + 1] = cj * temp - sj * z[i][c0];
            z[i][c0] = sj * temp + cj * z[i][c0];
          }
        }
        d[l - 1] = d[l - 1] - p;
        e[l - 1] = g;
      }
    } else {
      // --- QR iteration ---
      while (1) {
        int m2 = lend;
        if (l != lend) {
          for (int mm = l; mm >= lend + 1; --mm) {
            float tst = fabsf(e[mm - 2]); tst = tst * tst;
            if (tst <= (eps2 * fabsf(d[mm - 1])) * fabsf(d[mm - 2]) + safmin) { m2 = mm; break; }
          }
        }
        if (m2 > lend) e[m2 - 2] = 0.f;
        float p = d[l - 1];
        if (m2 == l) {
          d[l - 1] = p; l -= 1;
          if (l >= lend) continue;
          break;
        }
        if (m2 == l - 1) {
          float rt1, rt2, cc, ss;
          slaev2_(d[l - 2], e[l - 2], d[l - 1], rt1, rt2, cc, ss);
          for (int i = 0; i < 3; ++i) {
            float temp = z[i][l - 1];
            z[i][l - 1] = cc * temp - ss * z[i][l - 2];
            z[i][l - 2] = ss * temp + cc * z[i][l - 2];
          }
          d[l - 2] = rt1; d[l - 1] = rt2; e[l - 2] = 0.f;
          l -= 2;
          if (l >= lend) continue;
          break;
        }
        if (jtot == nmaxit) break;
        jtot++;
        float g = (d[l - 2] - p) / (2.f * e[l - 2]);
        float r = slapy2_(g, 1.f);
        g = d[m2 - 1] - p + (e[l - 2] / (g + f_sign(r, g)));
        float s = 1.f, c = 1.f;
        p = 0.f;
        float csv[2], snv[2];
        for (int i = m2; i <= l - 1; ++i) {
          float f = s * e[i - 1];
          float b = c * e[i - 1];
          slartg_(g, f, c, s, r);
          if (i != m2) e[i - 2] = r;
          g = d[i - 1] - p;
          r = (d[i] - g) * s + (2.f * c) * b;
          p = s * r;
          d[i - 1] = g + p;
          g = c * r - b;
          csv[i - m2] = c; snv[i - m2] = s;
        }
        int cnt = l - m2;
        for (int j = 1; j <= cnt; ++j) {       // slasr 'R','V','F'
          float cj = csv[j - 1], sj = snv[j - 1];
          int c0 = (m2 - 1) + (j - 1);
          for (int i = 0; i < 3; ++i) {
            float temp = z[i][c0 + 1];
            z[i][c0 + 1] = cj * temp - sj * z[i][c0];
            z[i][c0] = sj * temp + cj * z[i][c0];
          }
        }
        d[l - 1] = d[l - 1] - p;
        e[l - 2] = g;
      }
    }
  }

  // selection sort ascending, swap eigenvector columns (LAPACK exact)
  for (int ii = 2; ii <= n; ++ii) {
    int i = ii - 1, k = i;
    float p = d[i - 1];
    for (int j = ii; j <= n; ++j)
      if (d[j - 1] < p) { k = j; p = d[j - 1]; }
    if (k != i) {
      d[k - 1] = d[i - 1]; d[i - 1] = p;
      for (int r2 = 0; r2 < 3; ++r2) {
        float t = z[r2][i - 1]; z[r2][i - 1] = z[r2][k - 1]; z[r2][k - 1] = t;
      }
    }
  }
}

// full ssyevd replica for 3x3 symmetric (lower entries), eigenvectors only
__device__ void eigh3_(float a00, float a10, float a11, float a20, float a21,
                       float a22, float V[3][3]) {
#pragma clang fp contract(off)
  float d0, d1, d2, e0, e1, tau1 = 0.f, v2 = 0.f;
  {
    float alpha = a10;
    float xnorm = fabsf(a20);
    if (xnorm == 0.f) {
      tau1 = 0.f; v2 = 0.f;
      e0 = alpha; d0 = a00; d1 = a11; d2 = a22; e1 = a21;
    } else {
      float beta = -f_sign(slapy2_(alpha, xnorm), alpha);
      tau1 = (beta - alpha) / beta;
      float inv = 1.0f / (alpha - beta);
      v2 = a20 * inv;
      float y0 = tau1 * a11;
      float y1v = tau1 * a21;
      float temp2 = a21 * v2;
      y0 = y0 + tau1 * temp2;
      y1v = y1v + (tau1 * v2) * a22;
      float dotyv = y0 * 1.f + y1v * v2;
      float al = (-0.5f * tau1) * dotyv;
      float w0 = y0 + al * 1.f;
      float w1 = y1v + al * v2;
      a11 = (a11 + 1.f * (-w0)) + w0 * (-1.f);
      a21 = (a21 + v2 * (-w0)) + w1 * (-1.f);
      a22 = (a22 + v2 * (-w1)) + w1 * (-v2);
      e0 = beta; d0 = a00; d1 = a11; d2 = a22; e1 = a21;
    }
  }
  float dd[3] = { d0, d1, d2 };
  float ee[2] = { e0, e1 };
  float z[3][3] = { {1.f,0.f,0.f},{0.f,1.f,0.f},{0.f,0.f,1.f} };
  ssteqr3_(dd, ee, z);
  if (tau1 != 0.f) {
    for (int j = 0; j < 3; ++j) {
      float wj = z[1][j] * 1.f + z[2][j] * v2;
      float temp = -tau1 * wj;
      z[1][j] = z[1][j] + 1.f * temp;
      z[2][j] = z[2][j] + v2 * temp;
    }
  }
  for (int r = 0; r < 3; ++r)
    for (int cix = 0; cix < 3; ++cix)
      V[r][cix] = z[r][cix];
}

// ---------------- kernels ----------------

__global__ void zero_kernel(u32* p1, int n1, u32* p2, int n2) {
  int t = blockIdx.x * blockDim.x + threadIdx.x;
  if (t < n1) p1[t] = 0u;
  if (t < n2) p2[t] = 0u;
}

// one wave per query point; per-lane sorted top-20 + wave merge
__global__ __launch_bounds__(256) void knn_kernel(const float* __restrict__ pos,
                                                  int* __restrict__ idx) {
#pragma clang fp contract(off)
  int wid = blockIdx.x * 4 + (threadIdx.x >> 6);
  int lane = threadIdx.x & 63;
  int b = wid >> 11;
  int n = wid & 2047;
  const float* pc = pos + (size_t)b * NNp * 3;
  float qx = pc[n * 3 + 0], qy = pc[n * 3 + 1], qz = pc[n * 3 + 2];
  float d2n = (qx * qx + qy * qy) + qz * qz;
  float kd[20]; int ki[20];
#pragma unroll
  for (int j = 0; j < 20; ++j) { kd[j] = __builtin_inff(); ki[j] = 0x7fffffff; }
  for (int m = lane; m < NNp; m += 64) {
    if (m == n) continue;
    float x = pc[m * 3 + 0], y = pc[m * 3 + 1], zc = pc[m * 3 + 2];
    float d2m = (x * x + y * y) + zc * zc;
    float dot = (qx * x + qy * y) + qz * zc;
    float dist = (d2n + d2m) - 2.0f * dot;
    if (dist < kd[19]) {
      kd[19] = dist; ki[19] = m;
#pragma unroll
      for (int j = 19; j > 0; --j) {
        if (kd[j] < kd[j - 1]) {
          float td = kd[j]; kd[j] = kd[j - 1]; kd[j - 1] = td;
          int ti = ki[j]; ki[j] = ki[j - 1]; ki[j - 1] = ti;
        }
      }
    }
  }
  for (int t = 0; t < 20; ++t) {
    float hd = kd[0]; int hi = ki[0];
    float bd = hd; int bi = hi;
#pragma unroll
    for (int off = 32; off; off >>= 1) {
      float od = __shfl_xor(bd, off);
      int oi = __shfl_xor(bi, off);
      if (od < bd || (od == bd && oi < bi)) { bd = od; bi = oi; }
    }
    if (hd == bd && hi == bi) {
#pragma unroll
      for (int j = 0; j < 19; ++j) { kd[j] = kd[j + 1]; ki[j] = ki[j + 1]; }
      kd[19] = __builtin_inff(); ki[19] = 0x7fffffff;
    }
    if (lane == 0) idx[(size_t)wid * 20 + t] = bi;
  }
}

// per-point: covariance, LAPACK-replica eigh, loc = rel @ V
__global__ __launch_bounds__(256) void prep_kernel(const float* __restrict__ pos,
                                                   const int* __restrict__ idx,
                                                   float* __restrict__ loc,
                                                   float* __restrict__ Vout) {
#pragma clang fp contract(off)
  int p = blockIdx.x * 256 + threadIdx.x;
  int b = p >> 11, n = p & 2047;
  const float* pc = pos + (size_t)b * NNp * 3;
  float qx = pc[n * 3 + 0], qy = pc[n * 3 + 1], qz = pc[n * 3 + 2];
  const int* ip = idx + (size_t)p * 20;
  float c00 = 0, c01 = 0, c02 = 0, c11 = 0, c12 = 0, c22 = 0;
  for (int k = 0; k < 20; ++k) {
    int j = ip[k];
    float rx = pc[j * 3 + 0] - qx, ry = pc[j * 3 + 1] - qy, rz = pc[j * 3 + 2] - qz;
    c00 += rx * rx; c01 += rx * ry; c02 += rx * rz;
    c11 += ry * ry; c12 += ry * rz; c22 += rz * rz;
  }
  float Vm[3][3];
  eigh3_(c00, c01, c11, c02, c12, c22, Vm);
  float* vp = Vout + (size_t)p * 9;
  for (int d = 0; d < 3; ++d)
    for (int e = 0; e < 3; ++e) vp[d * 3 + e] = Vm[d][e];
  for (int k = 0; k < 20; ++k) {
    int j = ip[k];
    float rx = pc[j * 3 + 0] - qx, ry = pc[j * 3 + 1] - qy, rz = pc[j * 3 + 2] - qz;
    float l0 = rx * Vm[0][0] + ry * Vm[1][0] + rz * Vm[2][0];
    float l1 = rx * Vm[0][1] + ry * Vm[1][1] + rz * Vm[2][1];
    float l2 = rx * Vm[0][2] + ry * Vm[1][2] + rz * Vm[2][2];
    size_t e = ((size_t)p * 20 + k) * 3;
    loc[e + 0] = l0; loc[e + 1] = l1; loc[e + 2] = l2;
  }
}

// layer1: [E,3]@[3,64]+b, relu, store fp32
__global__ __launch_bounds__(256) void l1_kernel(const float* __restrict__ loc,
                                                 const float* __restrict__ W,
                                                 const float* __restrict__ bias,
                                                 float* __restrict__ h1) {
  __shared__ float sW[192];
  __shared__ float sB[64];
  int t = threadIdx.x;
  if (t < 192) sW[t] = W[t];
  if (t < 64) sB[t] = bias[t];
  __syncthreads();
  size_t e = (size_t)blockIdx.x * 256 + t;
  float x0 = loc[e * 3 + 0], x1 = loc[e * 3 + 1], x2 = loc[e * 3 + 2];
  for (int c0 = 0; c0 < 64; c0 += 4) {
    float4 st;
    st.x = fmaxf(sB[c0 + 0] + x0 * sW[c0 + 0] + x1 * sW[64 + c0 + 0] + x2 * sW[128 + c0 + 0], 0.f);
    st.y = fmaxf(sB[c0 + 1] + x0 * sW[c0 + 1] + x1 * sW[64 + c0 + 1] + x2 * sW[128 + c0 + 1], 0.f);
    st.z = fmaxf(sB[c0 + 2] + x0 * sW[c0 + 2] + x1 * sW[64 + c0 + 2] + x2 * sW[128 + c0 + 2], 0.f);
    st.w = fmaxf(sB[c0 + 3] + x0 * sW[c0 + 3] + x1 * sW[64 + c0 + 3] + x2 * sW[128 + c0 + 3], 0.f);
    *(float4*)&h1[e * 64 + c0] = st;
  }
}

// per-channel sum/sumsq of an fp32 [E,64] buffer -> double atomics
__global__ __launch_bounds__(256) void stats64_kernel(const float* __restrict__ h,
                                                      double* __restrict__ sums) {
  __shared__ float red[512];
  int t = threadIdx.x;
  int c = t & 63, w = t >> 6;
  size_t rbase = (size_t)blockIdx.x * 1280 + w;
  float s = 0.f, q = 0.f;
  for (int r = 0; r < 1280; r += 4) {
    float v = h[(rbase + r) * 64 + c];
    s += v; q += v * v;
  }
  red[t] = s; red[256 + t] = q;
  __syncthreads();
  if (t < 64) {
    float S = red[t] + red[64 + t] + red[128 + t] + red[192 + t];
    float Q = red[256 + t] + red[320 + t] + red[384 + t] + red[448 + t];
    atomicAdd(&sums[t], (double)S);
    atomicAdd(&sums[64 + t], (double)Q);
  }
}

// sums -> per-channel affine (scale, shift) implementing train-mode BN
__global__ void finalize_kernel(const double* __restrict__ sums, int nch,
                                double count, const float* __restrict__ g,
                                const float* __restrict__ be,
                                float* __restrict__ out) {
  int c = blockIdx.x * blockDim.x + threadIdx.x;
  if (c < nch) {
    double m = sums[c] / count;
    double var = sums[nch + c] / count - m * m;
    double inv = 1.0 / sqrt(var + 1e-5);
    double sc = (double)g[c] * inv;
    out[c] = (float)sc;
    out[nch + c] = (float)((double)be[c] - m * sc);
  }
}

// layers 2/3: fp32 [E,64] @ [64,64]+b, relu, IN-PLACE capable (hin==hout):
// rows staged to LDS, synced, then written back. 80 edges x 64 outs / block.
__global__ __launch_bounds__(256) void l23_kernel(const float* __restrict__ hin,
                                                  const float* __restrict__ ss,
                                                  const float* __restrict__ W,
                                                  const float* __restrict__ bias,
                                                  float* __restrict__ hout) {
  __shared__ float xT[64 * 84];
  int t = threadIdx.x;
  size_t e0 = (size_t)blockIdx.x * 80;
  for (int v = t; v < 80 * 64; v += 256) {
    int el = v >> 6, c = v & 63;
    float val = hin[(e0 + el) * 64 + c];
    val = val * ss[c] + ss[64 + c];
    xT[c * 84 + el] = val;
  }
  __syncthreads();
  int og = t & 15, eg = t >> 4;
  int o0 = og * 4, eb = eg * 5;
  float acc[5][4];
#pragma unroll
  for (int a = 0; a < 5; ++a)
#pragma unroll
    for (int o = 0; o < 4; ++o) acc[a][o] = 0.f;
  for (int i = 0; i < 64; ++i) {
    float4 w4 = *(const float4*)&W[i * 64 + o0];
    float xx[5];
#pragma unroll
    for (int a = 0; a < 5; ++a) xx[a] = xT[i * 84 + eb + a];
#pragma unroll
    for (int a = 0; a < 5; ++a) {
      acc[a][0] += xx[a] * w4.x;
      acc[a][1] += xx[a] * w4.y;
      acc[a][2] += xx[a] * w4.z;
      acc[a][3] += xx[a] * w4.w;
    }
  }
  float4 b4 = *(const float4*)&bias[o0];
#pragma unroll
  for (int a = 0; a < 5; ++a) {
    size_t e = e0 + eb + a;
    float4 st;
    st.x = fmaxf(acc[a][0] + b4.x, 0.f);
    st.y = fmaxf(acc[a][1] + b4.y, 0.f);
    st.z = fmaxf(acc[a][2] + b4.z, 0.f);
    st.w = fmaxf(acc[a][3] + b4.w, 0.f);
    *(float4*)&hout[e * 64 + o0] = st;
  }
}

// f3d[p][c][d] = max_k h3n[p,k,c] * loc[p,k,d]
__global__ __launch_bounds__(256) void f3d_kernel(const float* __restrict__ h3,
                                                  const float* __restrict__ ss3,
                                                  const float* __restrict__ loc,
                                                  float* __restrict__ f3d) {
  int t = threadIdx.x;
  int p = blockIdx.x * 4 + (t >> 6);
  int c = t & 63;
  float sc = ss3[c], sh = ss3[64 + c];
  float m0 = -__builtin_inff(), m1 = m0, m2 = m0;
  size_t eb = (size_t)p * 20;
  for (int k = 0; k < 20; ++k) {
    size_t e = eb + k;
    float h = h3[e * 64 + c] * sc + sh;
    float l0 = loc[e * 3 + 0], l1 = loc[e * 3 + 1], l2 = loc[e * 3 + 2];
    m0 = fmaxf(m0, h * l0);
    m1 = fmaxf(m1, h * l1);
    m2 = fmaxf(m2, h * l2);
  }
  size_t o = (size_t)p * 192 + c * 3;
  f3d[o + 0] = m0; f3d[o + 1] = m1; f3d[o + 2] = m2;
}

// DD2: gather f3d[idx], rotate by V, GEMM [80,192]@[192,128]+b (W fp32 from
// global, L2-resident), relu, per-point max over k, stats
__global__ __launch_bounds__(256) void dd2_kernel(const float* __restrict__ f3d,
                                                  const float* __restrict__ Vmat,
                                                  const int* __restrict__ idx,
                                                  const float* __restrict__ W,
                                                  const float* __restrict__ bias,
                                                  float* __restrict__ fdd2,
                                                  double* __restrict__ s4) {
  __shared__ float xT[192 * 84];     // staged X^T [i][edge], reused as zbuf
  __shared__ float sV[36];
  __shared__ float red[256];
  int t = threadIdx.x;
  int p0 = blockIdx.x * 4;
  if (t < 36) sV[t] = Vmat[(size_t)p0 * 9 + t];
  __syncthreads();
  // build X^T
  for (int v = t; v < 80 * 64; v += 256) {
    int el = v >> 6, c = v & 63;
    int pp = el / 20;
    int k = el - pp * 20;
    int pg = p0 + pp;
    int b = pg >> 11;
    int j = idx[(size_t)pg * 20 + k];
    size_t jg = ((size_t)(b << 11) + j) * 192;
    float f0 = f3d[jg + c * 3 + 0];
    float f1 = f3d[jg + c * 3 + 1];
    float f2 = f3d[jg + c * 3 + 2];
    const float* Vp = &sV[pp * 9];
    float x0 = f0 * Vp[0] + f1 * Vp[3] + f2 * Vp[6];
    float x1 = f0 * Vp[1] + f1 * Vp[4] + f2 * Vp[7];
    float x2 = f0 * Vp[2] + f1 * Vp[5] + f2 * Vp[8];
    xT[(c * 3 + 0) * 84 + el] = x0;
    xT[(c * 3 + 1) * 84 + el] = x1;
    xT[(c * 3 + 2) * 84 + el] = x2;
  }
  __syncthreads();
  int og = t & 15, eg = t >> 4;
  int o0 = og * 8, eb = eg * 5;
  float acc[5][8];
#pragma unroll
  for (int a = 0; a < 5; ++a)
#pragma unroll
    for (int o = 0; o < 8; ++o) acc[a][o] = 0.f;
  for (int i = 0; i < 192; ++i) {
    float4 w0 = *(const float4*)&W[i * 128 + o0];
    float4 w1 = *(const float4*)&W[i * 128 + o0 + 4];
    float xx[5];
#pragma unroll
    for (int a = 0; a < 5; ++a) xx[a] = xT[i * 84 + eb + a];
#pragma unroll
    for (int a = 0; a < 5; ++a) {
      acc[a][0] += xx[a] * w0.x;
      acc[a][1] += xx[a] * w0.y;
      acc[a][2] += xx[a] * w0.z;
      acc[a][3] += xx[a] * w0.w;
      acc[a][4] += xx[a] * w1.x;
      acc[a][5] += xx[a] * w1.y;
      acc[a][6] += xx[a] * w1.z;
      acc[a][7] += xx[a] * w1.w;
    }
  }
  __syncthreads();
  // z -> zbuf (reuse xT), relu(acc+bias)
  float* zbuf = xT;   // [80][132]
  float4 bb0 = *(const float4*)&bias[o0];
  float4 bb1 = *(const float4*)&bias[o0 + 4];
#pragma unroll
  for (int a = 0; a < 5; ++a) {
    int el = eb + a;
    float4 s0, s1;
    s0.x = fmaxf(acc[a][0] + bb0.x, 0.f);
    s0.y = fmaxf(acc[a][1] + bb0.y, 0.f);
    s0.z = fmaxf(acc[a][2] + bb0.z, 0.f);
    s0.w = fmaxf(acc[a][3] + bb0.w, 0.f);
    s1.x = fmaxf(acc[a][4] + bb1.x, 0.f);
    s1.y = fmaxf(acc[a][5] + bb1.y, 0.f);
    s1.z = fmaxf(acc[a][6] + bb1.z, 0.f);
    s1.w = fmaxf(acc[a][7] + bb1.w, 0.f);
    *(float4*)&zbuf[el * 132 + o0] = s0;
    *(float4*)&zbuf[el * 132 + o0 + 4] = s1;
  }
  __syncthreads();
  // per-point max over k (raw; BN affine applied later, g>0 so max commutes)
  {
    int pp = t >> 6, oc = t & 63;
#pragma unroll
    for (int oo = 0; oo < 2; ++oo) {
      int o = oc + oo * 64;
      float m = 0.f;
      for (int k = 0; k < 20; ++k)
        m = fmaxf(m, zbuf[(pp * 20 + k) * 132 + o]);
      fdd2[(size_t)(p0 + pp) * 128 + o] = m;
    }
  }
  // stats over all 80x128 z values
  {
    int o = t & 127, half = t >> 7;
    float s = 0.f, q = 0.f;
    for (int el = half * 40; el < half * 40 + 40; ++el) {
      float z = zbuf[el * 132 + o];
      s += z; q += z * z;
    }
    red[t] = s;
    __syncthreads();
    if (t < 128) atomicAdd(&s4[t], (double)(red[t] + red[t + 128]));
    __syncthreads();
    red[t] = q;
    __syncthreads();
    if (t < 128) atomicAdd(&s4[128 + t], (double)(red[t] + red[t + 128]));
  }
}

// y1: normalized fdd2 [16384,128] @ wh1 [128,1024]; max over n per cloud
__global__ __launch_bounds__(128) void y1_kernel(const float* __restrict__ fdd2,
                                                 const float* __restrict__ ss4,
                                                 const float* __restrict__ wh1,
                                                 const float* __restrict__ bh1,
                                                 u32* __restrict__ y1key) {
  __shared__ float sW[128 * 128];
  __shared__ float sx[128];
  int t = threadIdx.x;
  int bid = blockIdx.x;
  int nch = bid & 15, cch = (bid >> 4) & 7, cl = bid >> 7;
  int c0 = cch * 128;
  for (int v = t; v < 128 * 128; v += 128) {
    int i = v >> 7, c = v & 127;
    sW[v] = wh1[(size_t)i * 1024 + c0 + c];
  }
  float sc = ss4[t], sh = ss4[128 + t];
  size_t pbase = (size_t)cl * 2048 + nch * 128;
  float vmax = -__builtin_inff();
  __syncthreads();
  for (int p = 0; p < 128; ++p) {
    sx[t] = fdd2[(pbase + p) * 128 + t] * sc + sh;
    __syncthreads();
    float dot = 0.f;
#pragma unroll 8
    for (int i = 0; i < 128; ++i) dot += sx[i] * sW[i * 128 + t];
    vmax = fmaxf(vmax, dot);
    __syncthreads();
  }
  float val = vmax + bh1[c0 + t];
  atomicMax(&y1key[(size_t)cl * 1024 + c0 + t], fkey(val));
}

// y1 decode + relu + BN over 8 clouds
__global__ void y1bn_kernel(const u32* __restrict__ y1key,
                            const float* __restrict__ g,
                            const float* __restrict__ be,
                            float* __restrict__ y1n) {
  int c = blockIdx.x * 256 + threadIdx.x;
  if (c >= 1024) return;
  float v[8]; double s = 0.0;
#pragma unroll
  for (int b = 0; b < 8; ++b) {
    v[b] = fmaxf(funkey(y1key[b * 1024 + c]), 0.f);
    s += (double)v[b];
  }
  double m = s / 8.0, q = 0.0;
#pragma unroll
  for (int b = 0; b < 8; ++b) { double d = (double)v[b] - m; q += d * d; }
  q /= 8.0;
  double inv = 1.0 / sqrt(q + 1e-5);
  double sg = (double)g[c] * inv;
#pragma unroll
  for (int b = 0; b < 8; ++b)
    y1n[b * 1024 + c] = (float)(((double)v[b] - m) * sg + (double)be[c]);
}

// small dense layer: [8,IN]@[IN,OUT]+b, relu, BN over 8 -> out
__global__ __launch_bounds__(64) void head_kernel(const float* __restrict__ yin,
                                                  const float* __restrict__ W,
                                                  const float* __restrict__ bias,
                                                  const float* __restrict__ g,
                                                  const float* __restrict__ be,
                                                  float* __restrict__ yout,
                                                  int INn, int OUTn) {
  __shared__ float sx[8192];
  int t = threadIdx.x;
  for (int v = t; v < 8 * INn; v += 64) sx[v] = yin[v];
  __syncthreads();
  int o = blockIdx.x * 64 + t;
  if (o >= OUTn) return;
  float acc[8];
#pragma unroll
  for (int b = 0; b < 8; ++b) acc[b] = 0.f;
  for (int i = 0; i < INn; ++i) {
    float w = W[(size_t)i * OUTn + o];
#pragma unroll
    for (int b = 0; b < 8; ++b) acc[b] += sx[b * INn + i] * w;
  }
  float bs = bias[o];
  float v[8]; double s = 0.0;
#pragma unroll
  for (int b = 0; b < 8; ++b) { v[b] = fmaxf(acc[b] + bs, 0.f); s += (double)v[b]; }
  double m = s / 8.0, q = 0.0;
#pragma unroll
  for (int b = 0; b < 8; ++b) { double d = (double)v[b] - m; q += d * d; }
  q /= 8.0;
  double inv = 1.0 / sqrt(q + 1e-5);
  double sg = (double)g[o] * inv;
#pragma unroll
  for (int b = 0; b < 8; ++b)
    yout[(size_t)b * OUTn + o] = (float)(((double)v[b] - m) * sg + (double)be[o]);
}

// final linear [8,265]@[265,40]+b then log_softmax per row
__global__ __launch_bounds__(384) void logits_kernel(const float* __restrict__ y3n,
                                                     const float* __restrict__ W,
                                                     const float* __restrict__ bias,
                                                     float* __restrict__ out) {
  __shared__ float sy[8 * 265];
  __shared__ float slog[320];
  __shared__ float sm[8], sl[8];
  int t = threadIdx.x;
  for (int v = t; v < 8 * 265; v += 384) sy[v] = y3n[v];
  __syncthreads();
  if (t < 320) {
    int b = t / 40, o = t % 40;
    float acc = 0.f;
    for (int i = 0; i < 265; ++i) acc += sy[b * 265 + i] * W[i * 40 + o];
    slog[t] = acc + bias[o];
  }
  __syncthreads();
  if (t < 8) {
    float m = slog[t * 40];
    for (int o = 1; o < 40; ++o) m = fmaxf(m, slog[t * 40 + o]);
    float s = 0.f;
    for (int o = 0; o < 40; ++o) s += expf(slog[t * 40 + o] - m);
    sm[t] = m; sl[t] = logf(s);
  }
  __syncthreads();
  if (t < 320) {
    int b = t / 40;
    out[t] = slog[t] - sm[b] - sl[b];
  }
}

// ---------------- launcher ----------------
extern "C" void kernel_launch(void* const* d_in, const int* in_sizes, int n_in,
                              void* d_out, int out_size, void* d_ws, size_t ws_size,
                              hipStream_t stream) {
  (void)in_sizes; (void)n_in; (void)out_size; (void)ws_size;
  const float* pos  = (const float*)d_in[0];
  const float* w11  = (const float*)d_in[1];
  const float* b11  = (const float*)d_in[2];
  const float* g11  = (const float*)d_in[3];
  const float* be11 = (const float*)d_in[4];
  const float* w12  = (const float*)d_in[5];
  const float* b12  = (const float*)d_in[6];
  const float* g12  = (const float*)d_in[7];
  const float* be12 = (const float*)d_in[8];
  const float* w13  = (const float*)d_in[9];
  const float* b13  = (const float*)d_in[10];
  const float* g13  = (const float*)d_in[11];
  const float* be13 = (const float*)d_in[12];
  const float* w21  = (const float*)d_in[13];
  const float* b21  = (const float*)d_in[14];
  const float* g21  = (const float*)d_in[15];
  const float* be21 = (const float*)d_in[16];
  const float* wh1  = (const float*)d_in[17];
  const float* bh1  = (const float*)d_in[18];
  const float* gh1  = (const float*)d_in[19];
  const float* beh1 = (const float*)d_in[20];
  const float* wh2  = (const float*)d_in[21];
  const float* bh2  = (const float*)d_in[22];
  const float* gh2  = (const float*)d_in[23];
  const float* beh2 = (const float*)d_in[24];
  const float* wh3  = (const float*)d_in[25];
  const float* bh3  = (const float*)d_in[26];
  const float* gh3  = (const float*)d_in[27];
  const float* beh3 = (const float*)d_in[28];
  const float* wh4  = (const float*)d_in[29];
  const float* bh4  = (const float*)d_in[30];

  char* ws = (char*)d_ws;
  int*    idx   = (int*)(ws + 0);                 // 1,310,720 B
  float*  loc   = (float*)(ws + 1310720);         // 3,932,160 B
  float*  V     = (float*)(ws + 5242880);         //   589,824 B
  float*  h     = (float*)(ws + 5832704);         // 83,886,080 B (fp32, reused in-place)
  float*  f3d   = (float*)(ws + 89718784);        // 12,582,912 B
  float*  fdd2  = (float*)(ws + 102301696);       //  8,388,608 B
  u32*    y1k   = (u32*)(ws + 110690304);         //     32,768 B
  float*  y1n   = (float*)(ws + 110723072);       //     32,768 B
  float*  y2n   = (float*)(ws + 110755840);       //     16,384 B
  float*  y3n   = (float*)(ws + 110772224);       //      8,512 B
  double* stats = (double*)(ws + 110780736);      // 640 doubles
  float*  param = (float*)(ws + 110785856);       // 640 floats
  float*  out   = (float*)d_out;

  zero_kernel<<<32, 256, 0, stream>>>((u32*)stats, 1280, y1k, 8192);
  knn_kernel<<<4096, 256, 0, stream>>>(pos, idx);
  prep_kernel<<<64, 256, 0, stream>>>(pos, idx, loc, V);

  l1_kernel<<<1280, 256, 0, stream>>>(loc, w11, b11, h);
  stats64_kernel<<<256, 256, 0, stream>>>(h, stats);
  finalize_kernel<<<1, 256, 0, stream>>>(stats, 64, (double)EE, g11, be11, param);

  l23_kernel<<<4096, 256, 0, stream>>>(h, param, w12, b12, h);          // in-place
  stats64_kernel<<<256, 256, 0, stream>>>(h, stats + 128);
  finalize_kernel<<<1, 256, 0, stream>>>(stats + 128, 64, (double)EE, g12, be12, param + 128);

  l23_kernel<<<4096, 256, 0, stream>>>(h, param + 128, w13, b13, h);    // in-place
  stats64_kernel<<<256, 256, 0, stream>>>(h, stats + 256);
  finalize_kernel<<<1, 256, 0, stream>>>(stats + 256, 64, (double)EE, g13, be13, param + 256);

  f3d_kernel<<<4096, 256, 0, stream>>>(h, param + 256, loc, f3d);
  dd2_kernel<<<4096, 256, 0, stream>>>(f3d, V, idx, w21, b21, fdd2, stats + 384);
  finalize_kernel<<<1, 256, 0, stream>>>(stats + 384, 128, (double)EE, g21, be21, param + 384);

  y1_kernel<<<1024, 128, 0, stream>>>(fdd2, param + 384, wh1, bh1, y1k);
  y1bn_kernel<<<4, 256, 0, stream>>>(y1k, gh1, beh1, y1n);

  head_kernel<<<8, 64, 0, stream>>>(y1n, wh2, bh2, gh2, beh2, y2n, 1024, 512);
  head_kernel<<<5, 64, 0, stream>>>(y2n, wh3, bh3, gh3, beh3, y3n, 512, 265);
  logits_kernel<<<1, 384, 0, stream>>>(y3n, wh4, bh4, out);
}

// Round 3
// 863.672 us; speedup vs baseline: 1.3635x; 1.3635x over previous
//
#include <hip/hip_runtime.h>

// ---------------------------------------------------------------------------
// Net_3152505995976: point-cloud classifier forward pass on MI355X.
// Round 3: y1 GEMM rewrite (408us -> target ~50us).
//   - y1: 64Mx64N register-tiled fp32 GEMM, K=128 staged in LDS (padded 68),
//     4x4 acc/thread, fused max-pool + atomicMax. Dot-product k-order is
//     unchanged (sequential 0..127) -> bit-identical accuracy path.
//   - prep_kernel regridded 64x256 -> 256x64 (was using only 64 CUs).
//   - everything else identical to the passing R2 kernel.
// ---------------------------------------------------------------------------

#define NEW_SLARTG 1

typedef unsigned short u16;
typedef unsigned int u32;

#define BB 8
#define NNp 2048
#define KKn 20
#define NP 16384      // BB*NNp
#define EE 327680     // NP*KKn

// ---------------- small helpers ----------------
__device__ __forceinline__ u32 fkey(float f) {
  u32 u = __float_as_uint(f);
  return (u & 0x80000000u) ? ~u : (u | 0x80000000u);
}
__device__ __forceinline__ float funkey(u32 k) {
  u32 u = (k & 0x80000000u) ? (k ^ 0x80000000u) : ~k;
  return __uint_as_float(u);
}
__device__ __forceinline__ float f_sign(float a, float b) {
  return (b >= 0.f) ? fabsf(a) : -fabsf(a);
}

// ---------------- LAPACK fp32 replicas ----------------
__device__ float slapy2_(float x, float y) {
#pragma clang fp contract(off)
  float xa = fabsf(x), ya = fabsf(y);
  float w = fmaxf(xa, ya), z = fminf(xa, ya);
  if (z == 0.f) return w;
  float t = z / w;
  return w * sqrtf(1.0f + t * t);
}

__device__ void slartg_(float f, float g, float& c, float& s, float& r) {
#pragma clang fp contract(off)
#if NEW_SLARTG
  const float safmin = 1.17549435e-38f;
  const float safmax = 8.50705917e+37f;
  const float rtmin = 1.08420217e-19f;   // sqrt(safmin)
  const float rtmax = 6.52221171e+18f;   // sqrt(safmax/2)
  float f1 = fabsf(f), g1 = fabsf(g);
  if (g == 0.f) { c = 1.f; s = 0.f; r = f; }
  else if (f == 0.f) { c = 0.f; s = (g >= 0.f) ? 1.f : -1.f; r = g1; }
  else {
    float d;
    if (f1 > rtmin && f1 < rtmax && g1 > rtmin && g1 < rtmax) {
      d = sqrtf(f * f + g * g);
      c = f1 / d;
      r = (f >= 0.f) ? d : -d;
    } else {
      float uu = fminf(safmax, fmaxf(safmin, fmaxf(f1, g1)));
      float fs = f / uu, gs = g / uu;
      d = sqrtf(fs * fs + gs * gs);
      c = fabsf(fs) / d;
      r = ((f >= 0.f) ? d : -d) * uu;
    }
    s = g / r;
  }
#else
  if (g == 0.f) { c = 1.f; s = 0.f; r = f; }
  else if (f == 0.f) { c = 0.f; s = 1.f; r = g; }
  else {
    float f1 = f, g1 = g;
    r = sqrtf(f1 * f1 + g1 * g1);
    c = f1 / r;
    s = g1 / r;
    if (fabsf(f) > fabsf(g) && c < 0.f) { c = -c; s = -s; r = -r; }
  }
#endif
}

__device__ void slaev2_(float a, float b, float c, float& rt1, float& rt2,
                        float& cs1, float& sn1) {
#pragma clang fp contract(off)
  float sm = a + c;
  float df = a - c;
  float adf = fabsf(df);
  float tb = b + b;
  float ab = fabsf(tb);
  float acmx, acmn;
  if (fabsf(a) > fabsf(c)) { acmx = a; acmn = c; } else { acmx = c; acmn = a; }
  float rt;
  if (adf > ab) { float t = ab / adf; rt = adf * sqrtf(1.f + t * t); }
  else if (adf < ab) { float t = adf / ab; rt = ab * sqrtf(1.f + t * t); }
  else { rt = ab * sqrtf(2.f); }
  int sgn1;
  if (sm < 0.f) {
    rt1 = 0.5f * (sm - rt); sgn1 = -1;
    rt2 = (acmx / rt1) * acmn - (b / rt1) * b;
  } else if (sm > 0.f) {
    rt1 = 0.5f * (sm + rt); sgn1 = 1;
    rt2 = (acmx / rt1) * acmn - (b / rt1) * b;
  } else {
    rt1 = 0.5f * rt; rt2 = -0.5f * rt; sgn1 = 1;
  }
  float cs; int sgn2;
  if (df >= 0.f) { cs = df + rt; sgn2 = 1; } else { cs = df - rt; sgn2 = -1; }
  float acs = fabsf(cs);
  if (acs > ab) {
    float ct = -tb / cs;
    sn1 = 1.f / sqrtf(1.f + ct * ct);
    cs1 = ct * sn1;
  } else {
    if (ab == 0.f) { cs1 = 1.f; sn1 = 0.f; }
    else {
      float tn = -cs / tb;
      cs1 = 1.f / sqrtf(1.f + tn * tn);
      sn1 = tn * cs1;
    }
  }
  if (sgn1 == sgn2) { float tn = cs1; cs1 = -sn1; sn1 = tn; }
}

// ssteqr for n=3, compz='I' (z must be identity on entry)
__device__ void ssteqr3_(float* d, float* e, float z[3][3]) {
#pragma clang fp contract(off)
  const float eps = 5.9604645e-08f;
  const float eps2 = 3.5527137e-15f;
  const float safmin = 1.17549435e-38f;
  const int n = 3;
  const int nmaxit = 90;
  int jtot = 0;
  int l1 = 1;

  while (1) {
    if (l1 > n) break;
    if (l1 > 1) e[l1 - 2] = 0.f;
    int m = n;
    if (l1 <= n - 1) {
      for (int mm = l1; mm <= n - 1; ++mm) {
        float tst = fabsf(e[mm - 1]);
        if (tst == 0.f) { m = mm; break; }
        if (tst <= (sqrtf(fabsf(d[mm - 1])) * sqrtf(fabsf(d[mm]))) * eps) {
          e[mm - 1] = 0.f; m = mm; break;
        }
      }
    }
    int l = l1, lsv = l, lend = m, lendsv = lend;
    (void)lsv; (void)lendsv;
    l1 = m + 1;
    if (lend == l) continue;

    float anorm = 0.f;
    for (int i = l; i <= lend; ++i) anorm = fmaxf(anorm, fabsf(d[i - 1]));
    for (int i = l; i <= lend - 1; ++i) anorm = fmaxf(anorm, fabsf(e[i - 1]));
    if (anorm == 0.f) continue;

    if (fabsf(d[lend - 1]) < fabsf(d[l - 1])) { lend = lsv; l = lendsv; }

    if (lend > l) {
      // --- QL iteration ---
      while (1) {
        int m2 = lend;
        if (l != lend) {
          for (int mm = l; mm <= lend - 1; ++mm) {
            float tst = fabsf(e[mm - 1]); tst = tst * tst;
            if (tst <= (eps2 * fabsf(d[mm - 1])) * fabsf(d[mm]) + safmin) { m2 = mm; break; }
          }
        }
        if (m2 < lend) e[m2 - 1] = 0.f;
        float p = d[l - 1];
        if (m2 == l) {
          d[l - 1] = p; l += 1;
          if (l <= lend) continue;
          break;
        }
        if (m2 == l + 1) {
          float rt1, rt2, cc, ss;
          slaev2_(d[l - 1], e[l - 1], d[l], rt1, rt2, cc, ss);
          for (int i = 0; i < 3; ++i) {
            float temp = z[i][l];
            z[i][l] = cc * temp - ss * z[i][l - 1];
            z[i][l - 1] = ss * temp + cc * z[i][l - 1];
          }
          d[l - 1] = rt1; d[l] = rt2; e[l - 1] = 0.f;
          l += 2;
          if (l <= lend) continue;
          break;
        }
        if (jtot == nmaxit) break;
        jtot++;
        float g = (d[l] - p) / (2.f * e[l - 1]);
        float r = slapy2_(g, 1.f);
        g = d[m2 - 1] - p + (e[l - 1] / (g + f_sign(r, g)));
        float s = 1.f, c = 1.f;
        p = 0.f;
        float csv[2], snv[2];
        for (int i = m2 - 1; i >= l; --i) {
          float f = s * e[i - 1];
          float b = c * e[i - 1];
          slartg_(g, f, c, s, r);
          if (i != m2 - 1) e[i] = r;
          g = d[i] - p;
          r = (d[i - 1] - g) * s + (2.f * c) * b;
          p = s * r;
          d[i] = g + p;
          g = c * r - b;
          csv[i - l] = c; snv[i - l] = -s;
        }
        int cnt = m2 - l;
        for (int j = cnt; j >= 1; --j) {       // slasr 'R','V','B'
          float cj = csv[j - 1], sj = snv[j - 1];
          int c0 = (l - 1) + (j - 1);
          for (int i = 0; i < 3; ++i) {
            float temp = z[i][c0 + 1];
            z[i][c0 + 1] = cj * temp - sj * z[i][c0];
            z[i][c0] = sj * temp + cj * z[i][c0];
          }
        }
        d[l - 1] = d[l - 1] - p;
        e[l - 1] = g;
      }
    } else {
      // --- QR iteration ---
      while (1) {
        int m2 = lend;
        if (l != lend) {
          for (int mm = l; mm >= lend + 1; --mm) {
            float tst = fabsf(e[mm - 2]); tst = tst * tst;
            if (tst <= (eps2 * fabsf(d[mm - 1])) * fabsf(d[mm - 2]) + safmin) { m2 = mm; break; }
          }
        }
        if (m2 > lend) e[m2 - 2] = 0.f;
        float p = d[l - 1];
        if (m2 == l) {
          d[l - 1] = p; l -= 1;
          if (l >= lend) continue;
          break;
        }
        if (m2 == l - 1) {
          float rt1, rt2, cc, ss;
          slaev2_(d[l - 2], e[l - 2], d[l - 1], rt1, rt2, cc, ss);
          for (int i = 0; i < 3; ++i) {
            float temp = z[i][l - 1];
            z[i][l - 1] = cc * temp - ss * z[i][l - 2];
            z[i][l - 2] = ss * temp + cc * z[i][l - 2];
          }
          d[l - 2] = rt1; d[l - 1] = rt2; e[l - 2] = 0.f;
          l -= 2;
          if (l >= lend) continue;
          break;
        }
        if (jtot == nmaxit) break;
        jtot++;
        float g = (d[l - 2] - p) / (2.f * e[l - 2]);
        float r = slapy2_(g, 1.f);
        g = d[m2 - 1] - p + (e[l - 2] / (g + f_sign(r, g)));
        float s = 1.f, c = 1.f;
        p = 0.f;
        float csv[2], snv[2];
        for (int i = m2; i <= l - 1; ++i) {
          float f = s * e[i - 1];
          float b = c * e[i - 1];
          slartg_(g, f, c, s, r);
          if (i != m2) e[i - 2] = r;
          g = d[i - 1] - p;
          r = (d[i] - g) * s + (2.f * c) * b;
          p = s * r;
          d[i - 1] = g + p;
          g = c * r - b;
          csv[i - m2] = c; snv[i - m2] = s;
        }
        int cnt = l - m2;
        for (int j = 1; j <= cnt; ++j) {       // slasr 'R','V','F'
          float cj = csv[j - 1], sj = snv[j - 1];
          int c0 = (m2 - 1) + (j - 1);
          for (int i = 0; i < 3; ++i) {
            float temp = z[i][c0 + 1];
            z[i][c0 + 1] = cj * temp - sj * z[i][c0];
            z[i][c0] = sj * temp + cj * z[i][c0];
          }
        }
        d[l - 1] = d[l - 1] - p;
        e[l - 2] = g;
      }
    }
  }

  // selection sort ascending, swap eigenvector columns (LAPACK exact)
  for (int ii = 2; ii <= n; ++ii) {
    int i = ii - 1, k = i;
    float p = d[i - 1];
    for (int j = ii; j <= n; ++j)
      if (d[j - 1] < p) { k = j; p = d[j - 1]; }
    if (k != i) {
      d[k - 1] = d[i - 1]; d[i - 1] = p;
      for (int r2 = 0; r2 < 3; ++r2) {
        float t = z[r2][i - 1]; z[r2][i - 1] = z[r2][k - 1]; z[r2][k - 1] = t;
      }
    }
  }
}

// full ssyevd replica for 3x3 symmetric (lower entries), eigenvectors only
__device__ void eigh3_(float a00, float a10, float a11, float a20, float a21,
                       float a22, float V[3][3]) {
#pragma clang fp contract(off)
  float d0, d1, d2, e0, e1, tau1 = 0.f, v2 = 0.f;
  {
    float alpha = a10;
    float xnorm = fabsf(a20);
    if (xnorm == 0.f) {
      tau1 = 0.f; v2 = 0.f;
      e0 = alpha; d0 = a00; d1 = a11; d2 = a22; e1 = a21;
    } else {
      float beta = -f_sign(slapy2_(alpha, xnorm), alpha);
      tau1 = (beta - alpha) / beta;
      float inv = 1.0f / (alpha - beta);
      v2 = a20 * inv;
      float y0 = tau1 * a11;
      float y1v = tau1 * a21;
      float temp2 = a21 * v2;
      y0 = y0 + tau1 * temp2;
      y1v = y1v + (tau1 * v2) * a22;
      float dotyv = y0 * 1.f + y1v * v2;
      float al = (-0.5f * tau1) * dotyv;
      float w0 = y0 + al * 1.f;
      float w1 = y1v + al * v2;
      a11 = (a11 + 1.f * (-w0)) + w0 * (-1.f);
      a21 = (a21 + v2 * (-w0)) + w1 * (-1.f);
      a22 = (a22 + v2 * (-w1)) + w1 * (-v2);
      e0 = beta; d0 = a00; d1 = a11; d2 = a22; e1 = a21;
    }
  }
  float dd[3] = { d0, d1, d2 };
  float ee[2] = { e0, e1 };
  float z[3][3] = { {1.f,0.f,0.f},{0.f,1.f,0.f},{0.f,0.f,1.f} };
  ssteqr3_(dd, ee, z);
  if (tau1 != 0.f) {
    for (int j = 0; j < 3; ++j) {
      float wj = z[1][j] * 1.f + z[2][j] * v2;
      float temp = -tau1 * wj;
      z[1][j] = z[1][j] + 1.f * temp;
      z[2][j] = z[2][j] + v2 * temp;
    }
  }
  for (int r = 0; r < 3; ++r)
    for (int cix = 0; cix < 3; ++cix)
      V[r][cix] = z[r][cix];
}

// ---------------- kernels ----------------

__global__ void zero_kernel(u32* p1, int n1, u32* p2, int n2) {
  int t = blockIdx.x * blockDim.x + threadIdx.x;
  if (t < n1) p1[t] = 0u;
  if (t < n2) p2[t] = 0u;
}

// one wave per query point; per-lane sorted top-20 + wave merge
__global__ __launch_bounds__(256) void knn_kernel(const float* __restrict__ pos,
                                                  int* __restrict__ idx) {
#pragma clang fp contract(off)
  int wid = blockIdx.x * 4 + (threadIdx.x >> 6);
  int lane = threadIdx.x & 63;
  int b = wid >> 11;
  int n = wid & 2047;
  const float* pc = pos + (size_t)b * NNp * 3;
  float qx = pc[n * 3 + 0], qy = pc[n * 3 + 1], qz = pc[n * 3 + 2];
  float d2n = (qx * qx + qy * qy) + qz * qz;
  float kd[20]; int ki[20];
#pragma unroll
  for (int j = 0; j < 20; ++j) { kd[j] = __builtin_inff(); ki[j] = 0x7fffffff; }
  for (int m = lane; m < NNp; m += 64) {
    if (m == n) continue;
    float x = pc[m * 3 + 0], y = pc[m * 3 + 1], zc = pc[m * 3 + 2];
    float d2m = (x * x + y * y) + zc * zc;
    float dot = (qx * x + qy * y) + qz * zc;
    float dist = (d2n + d2m) - 2.0f * dot;
    if (dist < kd[19]) {
      kd[19] = dist; ki[19] = m;
#pragma unroll
      for (int j = 19; j > 0; --j) {
        if (kd[j] < kd[j - 1]) {
          float td = kd[j]; kd[j] = kd[j - 1]; kd[j - 1] = td;
          int ti = ki[j]; ki[j] = ki[j - 1]; ki[j - 1] = ti;
        }
      }
    }
  }
  for (int t = 0; t < 20; ++t) {
    float hd = kd[0]; int hi = ki[0];
    float bd = hd; int bi = hi;
#pragma unroll
    for (int off = 32; off; off >>= 1) {
      float od = __shfl_xor(bd, off);
      int oi = __shfl_xor(bi, off);
      if (od < bd || (od == bd && oi < bi)) { bd = od; bi = oi; }
    }
    if (hd == bd && hi == bi) {
#pragma unroll
      for (int j = 0; j < 19; ++j) { kd[j] = kd[j + 1]; ki[j] = ki[j + 1]; }
      kd[19] = __builtin_inff(); ki[19] = 0x7fffffff;
    }
    if (lane == 0) idx[(size_t)wid * 20 + t] = bi;
  }
}

// per-point: covariance, LAPACK-replica eigh, loc = rel @ V
__global__ __launch_bounds__(64) void prep_kernel(const float* __restrict__ pos,
                                                  const int* __restrict__ idx,
                                                  float* __restrict__ loc,
                                                  float* __restrict__ Vout) {
#pragma clang fp contract(off)
  int p = blockIdx.x * 64 + threadIdx.x;
  int b = p >> 11, n = p & 2047;
  const float* pc = pos + (size_t)b * NNp * 3;
  float qx = pc[n * 3 + 0], qy = pc[n * 3 + 1], qz = pc[n * 3 + 2];
  const int* ip = idx + (size_t)p * 20;
  float c00 = 0, c01 = 0, c02 = 0, c11 = 0, c12 = 0, c22 = 0;
  for (int k = 0; k < 20; ++k) {
    int j = ip[k];
    float rx = pc[j * 3 + 0] - qx, ry = pc[j * 3 + 1] - qy, rz = pc[j * 3 + 2] - qz;
    c00 += rx * rx; c01 += rx * ry; c02 += rx * rz;
    c11 += ry * ry; c12 += ry * rz; c22 += rz * rz;
  }
  float Vm[3][3];
  eigh3_(c00, c01, c11, c02, c12, c22, Vm);
  float* vp = Vout + (size_t)p * 9;
  for (int d = 0; d < 3; ++d)
    for (int e = 0; e < 3; ++e) vp[d * 3 + e] = Vm[d][e];
  for (int k = 0; k < 20; ++k) {
    int j = ip[k];
    float rx = pc[j * 3 + 0] - qx, ry = pc[j * 3 + 1] - qy, rz = pc[j * 3 + 2] - qz;
    float l0 = rx * Vm[0][0] + ry * Vm[1][0] + rz * Vm[2][0];
    float l1 = rx * Vm[0][1] + ry * Vm[1][1] + rz * Vm[2][1];
    float l2 = rx * Vm[0][2] + ry * Vm[1][2] + rz * Vm[2][2];
    size_t e = ((size_t)p * 20 + k) * 3;
    loc[e + 0] = l0; loc[e + 1] = l1; loc[e + 2] = l2;
  }
}

// layer1: [E,3]@[3,64]+b, relu, store fp32
__global__ __launch_bounds__(256) void l1_kernel(const float* __restrict__ loc,
                                                 const float* __restrict__ W,
                                                 const float* __restrict__ bias,
                                                 float* __restrict__ h1) {
  __shared__ float sW[192];
  __shared__ float sB[64];
  int t = threadIdx.x;
  if (t < 192) sW[t] = W[t];
  if (t < 64) sB[t] = bias[t];
  __syncthreads();
  size_t e = (size_t)blockIdx.x * 256 + t;
  float x0 = loc[e * 3 + 0], x1 = loc[e * 3 + 1], x2 = loc[e * 3 + 2];
  for (int c0 = 0; c0 < 64; c0 += 4) {
    float4 st;
    st.x = fmaxf(sB[c0 + 0] + x0 * sW[c0 + 0] + x1 * sW[64 + c0 + 0] + x2 * sW[128 + c0 + 0], 0.f);
    st.y = fmaxf(sB[c0 + 1] + x0 * sW[c0 + 1] + x1 * sW[64 + c0 + 1] + x2 * sW[128 + c0 + 1], 0.f);
    st.z = fmaxf(sB[c0 + 2] + x0 * sW[c0 + 2] + x1 * sW[64 + c0 + 2] + x2 * sW[128 + c0 + 2], 0.f);
    st.w = fmaxf(sB[c0 + 3] + x0 * sW[c0 + 3] + x1 * sW[64 + c0 + 3] + x2 * sW[128 + c0 + 3], 0.f);
    *(float4*)&h1[e * 64 + c0] = st;
  }
}

// per-channel sum/sumsq of an fp32 [E,64] buffer -> double atomics
__global__ __launch_bounds__(256) void stats64_kernel(const float* __restrict__ h,
                                                      double* __restrict__ sums) {
  __shared__ float red[512];
  int t = threadIdx.x;
  int c = t & 63, w = t >> 6;
  size_t rbase = (size_t)blockIdx.x * 1280 + w;
  float s = 0.f, q = 0.f;
  for (int r = 0; r < 1280; r += 4) {
    float v = h[(rbase + r) * 64 + c];
    s += v; q += v * v;
  }
  red[t] = s; red[256 + t] = q;
  __syncthreads();
  if (t < 64) {
    float S = red[t] + red[64 + t] + red[128 + t] + red[192 + t];
    float Q = red[256 + t] + red[320 + t] + red[384 + t] + red[448 + t];
    atomicAdd(&sums[t], (double)S);
    atomicAdd(&sums[64 + t], (double)Q);
  }
}

// sums -> per-channel affine (scale, shift) implementing train-mode BN
__global__ void finalize_kernel(const double* __restrict__ sums, int nch,
                                double count, const float* __restrict__ g,
                                const float* __restrict__ be,
                                float* __restrict__ out) {
  int c = blockIdx.x * blockDim.x + threadIdx.x;
  if (c < nch) {
    double m = sums[c] / count;
    double var = sums[nch + c] / count - m * m;
    double inv = 1.0 / sqrt(var + 1e-5);
    double sc = (double)g[c] * inv;
    out[c] = (float)sc;
    out[nch + c] = (float)((double)be[c] - m * sc);
  }
}

// layers 2/3: fp32 [E,64] @ [64,64]+b, relu, IN-PLACE capable (hin==hout)
__global__ __launch_bounds__(256) void l23_kernel(const float* __restrict__ hin,
                                                  const float* __restrict__ ss,
                                                  const float* __restrict__ W,
                                                  const float* __restrict__ bias,
                                                  float* __restrict__ hout) {
  __shared__ float xT[64 * 84];
  int t = threadIdx.x;
  size_t e0 = (size_t)blockIdx.x * 80;
  for (int v = t; v < 80 * 64; v += 256) {
    int el = v >> 6, c = v & 63;
    float val = hin[(e0 + el) * 64 + c];
    val = val * ss[c] + ss[64 + c];
    xT[c * 84 + el] = val;
  }
  __syncthreads();
  int og = t & 15, eg = t >> 4;
  int o0 = og * 4, eb = eg * 5;
  float acc[5][4];
#pragma unroll
  for (int a = 0; a < 5; ++a)
#pragma unroll
    for (int o = 0; o < 4; ++o) acc[a][o] = 0.f;
  for (int i = 0; i < 64; ++i) {
    float4 w4 = *(const float4*)&W[i * 64 + o0];
    float xx[5];
#pragma unroll
    for (int a = 0; a < 5; ++a) xx[a] = xT[i * 84 + eb + a];
#pragma unroll
    for (int a = 0; a < 5; ++a) {
      acc[a][0] += xx[a] * w4.x;
      acc[a][1] += xx[a] * w4.y;
      acc[a][2] += xx[a] * w4.z;
      acc[a][3] += xx[a] * w4.w;
    }
  }
  float4 b4 = *(const float4*)&bias[o0];
#pragma unroll
  for (int a = 0; a < 5; ++a) {
    size_t e = e0 + eb + a;
    float4 st;
    st.x = fmaxf(acc[a][0] + b4.x, 0.f);
    st.y = fmaxf(acc[a][1] + b4.y, 0.f);
    st.z = fmaxf(acc[a][2] + b4.z, 0.f);
    st.w = fmaxf(acc[a][3] + b4.w, 0.f);
    *(float4*)&hout[e * 64 + o0] = st;
  }
}

// f3d[p][c][d] = max_k h3n[p,k,c] * loc[p,k,d]
__global__ __launch_bounds__(256) void f3d_kernel(const float* __restrict__ h3,
                                                  const float* __restrict__ ss3,
                                                  const float* __restrict__ loc,
                                                  float* __restrict__ f3d) {
  int t = threadIdx.x;
  int p = blockIdx.x * 4 + (t >> 6);
  int c = t & 63;
  float sc = ss3[c], sh = ss3[64 + c];
  float m0 = -__builtin_inff(), m1 = m0, m2 = m0;
  size_t eb = (size_t)p * 20;
  for (int k = 0; k < 20; ++k) {
    size_t e = eb + k;
    float h = h3[e * 64 + c] * sc + sh;
    float l0 = loc[e * 3 + 0], l1 = loc[e * 3 + 1], l2 = loc[e * 3 + 2];
    m0 = fmaxf(m0, h * l0);
    m1 = fmaxf(m1, h * l1);
    m2 = fmaxf(m2, h * l2);
  }
  size_t o = (size_t)p * 192 + c * 3;
  f3d[o + 0] = m0; f3d[o + 1] = m1; f3d[o + 2] = m2;
}

// DD2: gather f3d[idx], rotate by V, GEMM [80,192]@[192,128]+b, relu,
// per-point max over k, stats
__global__ __launch_bounds__(256) void dd2_kernel(const float* __restrict__ f3d,
                                                  const float* __restrict__ Vmat,
                                                  const int* __restrict__ idx,
                                                  const float* __restrict__ W,
                                                  const float* __restrict__ bias,
                                                  float* __restrict__ fdd2,
                                                  double* __restrict__ s4) {
  __shared__ float xT[192 * 84];     // staged X^T [i][edge], reused as zbuf
  __shared__ float sV[36];
  __shared__ float red[256];
  int t = threadIdx.x;
  int p0 = blockIdx.x * 4;
  if (t < 36) sV[t] = Vmat[(size_t)p0 * 9 + t];
  __syncthreads();
  // build X^T
  for (int v = t; v < 80 * 64; v += 256) {
    int el = v >> 6, c = v & 63;
    int pp = el / 20;
    int k = el - pp * 20;
    int pg = p0 + pp;
    int b = pg >> 11;
    int j = idx[(size_t)pg * 20 + k];
    size_t jg = ((size_t)(b << 11) + j) * 192;
    float f0 = f3d[jg + c * 3 + 0];
    float f1 = f3d[jg + c * 3 + 1];
    float f2 = f3d[jg + c * 3 + 2];
    const float* Vp = &sV[pp * 9];
    float x0 = f0 * Vp[0] + f1 * Vp[3] + f2 * Vp[6];
    float x1 = f0 * Vp[1] + f1 * Vp[4] + f2 * Vp[7];
    float x2 = f0 * Vp[2] + f1 * Vp[5] + f2 * Vp[8];
    xT[(c * 3 + 0) * 84 + el] = x0;
    xT[(c * 3 + 1) * 84 + el] = x1;
    xT[(c * 3 + 2) * 84 + el] = x2;
  }
  __syncthreads();
  int og = t & 15, eg = t >> 4;
  int o0 = og * 8, eb = eg * 5;
  float acc[5][8];
#pragma unroll
  for (int a = 0; a < 5; ++a)
#pragma unroll
    for (int o = 0; o < 8; ++o) acc[a][o] = 0.f;
  for (int i = 0; i < 192; ++i) {
    float4 w0 = *(const float4*)&W[i * 128 + o0];
    float4 w1 = *(const float4*)&W[i * 128 + o0 + 4];
    float xx[5];
#pragma unroll
    for (int a = 0; a < 5; ++a) xx[a] = xT[i * 84 + eb + a];
#pragma unroll
    for (int a = 0; a < 5; ++a) {
      acc[a][0] += xx[a] * w0.x;
      acc[a][1] += xx[a] * w0.y;
      acc[a][2] += xx[a] * w0.z;
      acc[a][3] += xx[a] * w0.w;
      acc[a][4] += xx[a] * w1.x;
      acc[a][5] += xx[a] * w1.y;
      acc[a][6] += xx[a] * w1.z;
      acc[a][7] += xx[a] * w1.w;
    }
  }
  __syncthreads();
  // z -> zbuf (reuse xT), relu(acc+bias)
  float* zbuf = xT;   // [80][132]
  float4 bb0 = *(const float4*)&bias[o0];
  float4 bb1 = *(const float4*)&bias[o0 + 4];
#pragma unroll
  for (int a = 0; a < 5; ++a) {
    int el = eb + a;
    float4 s0, s1;
    s0.x = fmaxf(acc[a][0] + bb0.x, 0.f);
    s0.y = fmaxf(acc[a][1] + bb0.y, 0.f);
    s0.z = fmaxf(acc[a][2] + bb0.z, 0.f);
    s0.w = fmaxf(acc[a][3] + bb0.w, 0.f);
    s1.x = fmaxf(acc[a][4] + bb1.x, 0.f);
    s1.y = fmaxf(acc[a][5] + bb1.y, 0.f);
    s1.z = fmaxf(acc[a][6] + bb1.z, 0.f);
    s1.w = fmaxf(acc[a][7] + bb1.w, 0.f);
    *(float4*)&zbuf[el * 132 + o0] = s0;
    *(float4*)&zbuf[el * 132 + o0 + 4] = s1;
  }
  __syncthreads();
  // per-point max over k
  {
    int pp = t >> 6, oc = t & 63;
#pragma unroll
    for (int oo = 0; oo < 2; ++oo) {
      int o = oc + oo * 64;
      float m = 0.f;
      for (int k = 0; k < 20; ++k)
        m = fmaxf(m, zbuf[(pp * 20 + k) * 132 + o]);
      fdd2[(size_t)(p0 + pp) * 128 + o] = m;
    }
  }
  // stats over all 80x128 z values
  {
    int o = t & 127, half = t >> 7;
    float s = 0.f, q = 0.f;
    for (int el = half * 40; el < half * 40 + 40; ++el) {
      float z = zbuf[el * 132 + o];
      s += z; q += z * z;
    }
    red[t] = s;
    __syncthreads();
    if (t < 128) atomicAdd(&s4[t], (double)(red[t] + red[t + 128]));
    __syncthreads();
    red[t] = q;
    __syncthreads();
    if (t < 128) atomicAdd(&s4[128 + t], (double)(red[t] + red[t + 128]));
  }
}

// y1: register-tiled fp32 GEMM [16384,128]@[128,1024] with fused max over n.
// Block: 256 threads, tile 64M x 64N, full K=128 in LDS (padded 68).
// Per thread 4x4 acc; k-order sequential 0..127 (bit-identical to R2).
// grid: bid = ntile*256 + mtile; mtile in [0,256), ntile in [0,16).
__global__ __launch_bounds__(256) void y1_kernel(const float* __restrict__ fdd2,
                                                 const float* __restrict__ ss4,
                                                 const float* __restrict__ wh1,
                                                 u32* __restrict__ y1key) {
  __shared__ float sX[128][68];   // [k][point]
  __shared__ float sW[128][68];   // [k][chan]
  int t = threadIdx.x;
  int bid = blockIdx.x;
  int mtile = bid & 255;
  int ntile = bid >> 8;
  int cl = mtile >> 5;                 // cloud
  size_t pbase = (size_t)mtile * 64;   // global point base
  int c0 = ntile * 64;

  // stage X (normalized): thread t -> point p0=t>>5 (+8 stride), k-quad kq=t&31
  {
    int kq = t & 31, pp = t >> 5;
    float4 sc4 = *(const float4*)&ss4[kq * 4];
    float4 sh4 = *(const float4*)&ss4[128 + kq * 4];
    for (int p = pp; p < 64; p += 8) {
      float4 x4 = *(const float4*)&fdd2[(pbase + p) * 128 + kq * 4];
      sX[kq * 4 + 0][p] = x4.x * sc4.x + sh4.x;
      sX[kq * 4 + 1][p] = x4.y * sc4.y + sh4.y;
      sX[kq * 4 + 2][p] = x4.z * sc4.z + sh4.z;
      sX[kq * 4 + 3][p] = x4.w * sc4.w + sh4.w;
    }
  }
  // stage W: thread t -> row r=t>>4 (+16 stride), col-quad cq=t&15
  {
    int cq = t & 15, rr = t >> 4;
    for (int r = rr; r < 128; r += 16) {
      float4 w4 = *(const float4*)&wh1[(size_t)r * 1024 + c0 + cq * 4];
      *(float4*)&sW[r][cq * 4] = w4;
    }
  }
  __syncthreads();

  int mg = t >> 4, ng = t & 15;
  int m0 = mg * 4, n0 = ng * 4;
  float acc[4][4];
#pragma unroll
  for (int i = 0; i < 4; ++i)
#pragma unroll
    for (int j = 0; j < 4; ++j) acc[i][j] = 0.f;
  for (int k = 0; k < 128; ++k) {
    float4 x4 = *(const float4*)&sX[k][m0];
    float4 w4 = *(const float4*)&sW[k][n0];
    acc[0][0] += x4.x * w4.x; acc[0][1] += x4.x * w4.y;
    acc[0][2] += x4.x * w4.z; acc[0][3] += x4.x * w4.w;
    acc[1][0] += x4.y * w4.x; acc[1][1] += x4.y * w4.y;
    acc[1][2] += x4.y * w4.z; acc[1][3] += x4.y * w4.w;
    acc[2][0] += x4.z * w4.x; acc[2][1] += x4.z * w4.y;
    acc[2][2] += x4.z * w4.z; acc[2][3] += x4.z * w4.w;
    acc[3][0] += x4.w * w4.x; acc[3][1] += x4.w * w4.y;
    acc[3][2] += x4.w * w4.z; acc[3][3] += x4.w * w4.w;
  }
  __syncthreads();
  // per-thread max over 4 points -> red[chan][mg]
  float* red = &sX[0][0];    // 64*16 floats
#pragma unroll
  for (int j = 0; j < 4; ++j) {
    float v = fmaxf(fmaxf(acc[0][j], acc[1][j]), fmaxf(acc[2][j], acc[3][j]));
    red[(n0 + j) * 16 + mg] = v;
  }
  __syncthreads();
  if (t < 64) {
    float m = red[t * 16];
#pragma unroll
    for (int i = 1; i < 16; ++i) m = fmaxf(m, red[t * 16 + i]);
    atomicMax(&y1key[(size_t)cl * 1024 + c0 + t], fkey(m));
  }
}

// y1 decode + bias + relu + BN over 8 clouds
__global__ void y1bn_kernel(const u32* __restrict__ y1key,
                            const float* __restrict__ bh1,
                            const float* __restrict__ g,
                            const float* __restrict__ be,
                            float* __restrict__ y1n) {
  int c = blockIdx.x * 256 + threadIdx.x;
  if (c >= 1024) return;
  float bs = bh1[c];
  float v[8]; double s = 0.0;
#pragma unroll
  for (int b = 0; b < 8; ++b) {
    v[b] = fmaxf(funkey(y1key[b * 1024 + c]) + bs, 0.f);
    s += (double)v[b];
  }
  double m = s / 8.0, q = 0.0;
#pragma unroll
  for (int b = 0; b < 8; ++b) { double d = (double)v[b] - m; q += d * d; }
  q /= 8.0;
  double inv = 1.0 / sqrt(q + 1e-5);
  double sg = (double)g[c] * inv;
#pragma unroll
  for (int b = 0; b < 8; ++b)
    y1n[b * 1024 + c] = (float)(((double)v[b] - m) * sg + (double)be[c]);
}

// small dense layer: [8,IN]@[IN,OUT]+b, relu, BN over 8 -> out
__global__ __launch_bounds__(64) void head_kernel(const float* __restrict__ yin,
                                                  const float* __restrict__ W,
                                                  const float* __restrict__ bias,
                                                  const float* __restrict__ g,
                                                  const float* __restrict__ be,
                                                  float* __restrict__ yout,
                                                  int INn, int OUTn) {
  __shared__ float sx[8192];
  int t = threadIdx.x;
  for (int v = t; v < 8 * INn; v += 64) sx[v] = yin[v];
  __syncthreads();
  int o = blockIdx.x * 64 + t;
  if (o >= OUTn) return;
  float acc[8];
#pragma unroll
  for (int b = 0; b < 8; ++b) acc[b] = 0.f;
  for (int i = 0; i < INn; ++i) {
    float w = W[(size_t)i * OUTn + o];
#pragma unroll
    for (int b = 0; b < 8; ++b) acc[b] += sx[b * INn + i] * w;
  }
  float bs = bias[o];
  float v[8]; double s = 0.0;
#pragma unroll
  for (int b = 0; b < 8; ++b) { v[b] = fmaxf(acc[b] + bs, 0.f); s += (double)v[b]; }
  double m = s / 8.0, q = 0.0;
#pragma unroll
  for (int b = 0; b < 8; ++b) { double d = (double)v[b] - m; q += d * d; }
  q /= 8.0;
  double inv = 1.0 / sqrt(q + 1e-5);
  double sg = (double)g[o] * inv;
#pragma unroll
  for (int b = 0; b < 8; ++b)
    yout[(size_t)b * OUTn + o] = (float)(((double)v[b] - m) * sg + (double)be[o]);
}

// final linear [8,265]@[265,40]+b then log_softmax per row
__global__ __launch_bounds__(384) void logits_kernel(const float* __restrict__ y3n,
                                                     const float* __restrict__ W,
                                                     const float* __restrict__ bias,
                                                     float* __restrict__ out) {
  __shared__ float sy[8 * 265];
  __shared__ float slog[320];
  __shared__ float sm[8], sl[8];
  int t = threadIdx.x;
  for (int v = t; v < 8 * 265; v += 384) sy[v] = y3n[v];
  __syncthreads();
  if (t < 320) {
    int b = t / 40, o = t % 40;
    float acc = 0.f;
    for (int i = 0; i < 265; ++i) acc += sy[b * 265 + i] * W[i * 40 + o];
    slog[t] = acc + bias[o];
  }
  __syncthreads();
  if (t < 8) {
    float m = slog[t * 40];
    for (int o = 1; o < 40; ++o) m = fmaxf(m, slog[t * 40 + o]);
    float s = 0.f;
    for (int o = 0; o < 40; ++o) s += expf(slog[t * 40 + o] - m);
    sm[t] = m; sl[t] = logf(s);
  }
  __syncthreads();
  if (t < 320) {
    int b = t / 40;
    out[t] = slog[t] - sm[b] - sl[b];
  }
}

// ---------------- launcher ----------------
extern "C" void kernel_launch(void* const* d_in, const int* in_sizes, int n_in,
                              void* d_out, int out_size, void* d_ws, size_t ws_size,
                              hipStream_t stream) {
  (void)in_sizes; (void)n_in; (void)out_size; (void)ws_size;
  const float* pos  = (const float*)d_in[0];
  const float* w11  = (const float*)d_in[1];
  const float* b11  = (const float*)d_in[2];
  const float* g11  = (const float*)d_in[3];
  const float* be11 = (const float*)d_in[4];
  const float* w12  = (const float*)d_in[5];
  const float* b12  = (const float*)d_in[6];
  const float* g12  = (const float*)d_in[7];
  const float* be12 = (const float*)d_in[8];
  const float* w13  = (const float*)d_in[9];
  const float* b13  = (const float*)d_in[10];
  const float* g13  = (const float*)d_in[11];
  const float* be13 = (const float*)d_in[12];
  const float* w21  = (const float*)d_in[13];
  const float* b21  = (const float*)d_in[14];
  const float* g21  = (const float*)d_in[15];
  const float* be21 = (const float*)d_in[16];
  const float* wh1  = (const float*)d_in[17];
  const float* bh1  = (const float*)d_in[18];
  const float* gh1  = (const float*)d_in[19];
  const float* beh1 = (const float*)d_in[20];
  const float* wh2  = (const float*)d_in[21];
  const float* bh2  = (const float*)d_in[22];
  const float* gh2  = (const float*)d_in[23];
  const float* beh2 = (const float*)d_in[24];
  const float* wh3  = (const float*)d_in[25];
  const float* bh3  = (const float*)d_in[26];
  const float* gh3  = (const float*)d_in[27];
  const float* beh3 = (const float*)d_in[28];
  const float* wh4  = (const float*)d_in[29];
  const float* bh4  = (const float*)d_in[30];

  char* ws = (char*)d_ws;
  int*    idx   = (int*)(ws + 0);                 // 1,310,720 B
  float*  loc   = (float*)(ws + 1310720);         // 3,932,160 B
  float*  V     = (float*)(ws + 5242880);         //   589,824 B
  float*  h     = (float*)(ws + 5832704);         // 83,886,080 B (fp32, in-place)
  float*  f3d   = (float*)(ws + 89718784);        // 12,582,912 B
  float*  fdd2  = (float*)(ws + 102301696);       //  8,388,608 B
  u32*    y1k   = (u32*)(ws + 110690304);         //     32,768 B
  float*  y1n   = (float*)(ws + 110723072);       //     32,768 B
  float*  y2n   = (float*)(ws + 110755840);       //     16,384 B
  float*  y3n   = (float*)(ws + 110772224);       //      8,512 B
  double* stats = (double*)(ws + 110780736);      // 640 doubles
  float*  param = (float*)(ws + 110785856);       // 640 floats
  float*  out   = (float*)d_out;

  zero_kernel<<<32, 256, 0, stream>>>((u32*)stats, 1280, y1k, 8192);
  knn_kernel<<<4096, 256, 0, stream>>>(pos, idx);
  prep_kernel<<<256, 64, 0, stream>>>(pos, idx, loc, V);

  l1_kernel<<<1280, 256, 0, stream>>>(loc, w11, b11, h);
  stats64_kernel<<<256, 256, 0, stream>>>(h, stats);
  finalize_kernel<<<1, 256, 0, stream>>>(stats, 64, (double)EE, g11, be11, param);

  l23_kernel<<<4096, 256, 0, stream>>>(h, param, w12, b12, h);          // in-place
  stats64_kernel<<<256, 256, 0, stream>>>(h, stats + 128);
  finalize_kernel<<<1, 256, 0, stream>>>(stats + 128, 64, (double)EE, g12, be12, param + 128);

  l23_kernel<<<4096, 256, 0, stream>>>(h, param + 128, w13, b13, h);    // in-place
  stats64_kernel<<<256, 256, 0, stream>>>(h, stats + 256);
  finalize_kernel<<<1, 256, 0, stream>>>(stats + 256, 64, (double)EE, g13, be13, param + 256);

  f3d_kernel<<<4096, 256, 0, stream>>>(h, param + 256, loc, f3d);
  dd2_kernel<<<4096, 256, 0, stream>>>(f3d, V, idx, w21, b21, fdd2, stats + 384);
  finalize_kernel<<<1, 256, 0, stream>>>(stats + 384, 128, (double)EE, g21, be21, param + 384);

  y1_kernel<<<4096, 256, 0, stream>>>(fdd2, param + 384, wh1, y1k);
  y1bn_kernel<<<4, 256, 0, stream>>>(y1k, bh1, gh1, beh1, y1n);

  head_kernel<<<8, 64, 0, stream>>>(y1n, wh2, bh2, gh2, beh2, y2n, 1024, 512);
  head_kernel<<<5, 64, 0, stream>>>(y2n, wh3, bh3, gh3, beh3, y3n, 512, 265);
  logits_kernel<<<1, 384, 0, stream>>>(y3n, wh4, bh4, out);
}

// Round 4
// 719.558 us; speedup vs baseline: 1.6366x; 1.2003x over previous
//
#include <hip/hip_runtime.h>

// ---------------------------------------------------------------------------
// Net_3152505995976: point-cloud classifier forward pass on MI355X.
// Round 4: dd2 -> bf16 MFMA (16x16x32), fp32 accumulate.
//   - W21 pre-transposed+bf16 once (wtcvt) into the dead h-region
//   - dd2: X gathered/rotated to LDS bf16 [80][200]; WT staged in two
//     K-halves [128][104]; 60 MFMA/wave; bias+relu+maxpool+stats fused
//     in-register from C fragments (no zbuf -> no bank conflicts)
//   - everything else identical to the passing R3 kernel.
// ---------------------------------------------------------------------------

#define NEW_SLARTG 1

typedef unsigned short u16;
typedef unsigned int u32;
typedef __attribute__((ext_vector_type(8))) short short8;
typedef __attribute__((ext_vector_type(4))) float f32x4;

#define BB 8
#define NNp 2048
#define KKn 20
#define NP 16384      // BB*NNp
#define EE 327680     // NP*KKn

// ---------------- small helpers ----------------
__device__ __forceinline__ u32 fkey(float f) {
  u32 u = __float_as_uint(f);
  return (u & 0x80000000u) ? ~u : (u | 0x80000000u);
}
__device__ __forceinline__ float funkey(u32 k) {
  u32 u = (k & 0x80000000u) ? (k ^ 0x80000000u) : ~k;
  return __uint_as_float(u);
}
__device__ __forceinline__ float f_sign(float a, float b) {
  return (b >= 0.f) ? fabsf(a) : -fabsf(a);
}
__device__ __forceinline__ u16 f2bf(float f) {
  u32 u = __float_as_uint(f);
  u32 r = (u + 0x7fffu + ((u >> 16) & 1u)) >> 16;
  return (u16)r;
}

// ---------------- LAPACK fp32 replicas ----------------
__device__ float slapy2_(float x, float y) {
#pragma clang fp contract(off)
  float xa = fabsf(x), ya = fabsf(y);
  float w = fmaxf(xa, ya), z = fminf(xa, ya);
  if (z == 0.f) return w;
  float t = z / w;
  return w * sqrtf(1.0f + t * t);
}

__device__ void slartg_(float f, float g, float& c, float& s, float& r) {
#pragma clang fp contract(off)
#if NEW_SLARTG
  const float safmin = 1.17549435e-38f;
  const float safmax = 8.50705917e+37f;
  const float rtmin = 1.08420217e-19f;   // sqrt(safmin)
  const float rtmax = 6.52221171e+18f;   // sqrt(safmax/2)
  float f1 = fabsf(f), g1 = fabsf(g);
  if (g == 0.f) { c = 1.f; s = 0.f; r = f; }
  else if (f == 0.f) { c = 0.f; s = (g >= 0.f) ? 1.f : -1.f; r = g1; }
  else {
    float d;
    if (f1 > rtmin && f1 < rtmax && g1 > rtmin && g1 < rtmax) {
      d = sqrtf(f * f + g * g);
      c = f1 / d;
      r = (f >= 0.f) ? d : -d;
    } else {
      float uu = fminf(safmax, fmaxf(safmin, fmaxf(f1, g1)));
      float fs = f / uu, gs = g / uu;
      d = sqrtf(fs * fs + gs * gs);
      c = fabsf(fs) / d;
      r = ((f >= 0.f) ? d : -d) * uu;
    }
    s = g / r;
  }
#else
  if (g == 0.f) { c = 1.f; s = 0.f; r = f; }
  else if (f == 0.f) { c = 0.f; s = 1.f; r = g; }
  else {
    float f1 = f, g1 = g;
    r = sqrtf(f1 * f1 + g1 * g1);
    c = f1 / r;
    s = g1 / r;
    if (fabsf(f) > fabsf(g) && c < 0.f) { c = -c; s = -s; r = -r; }
  }
#endif
}

__device__ void slaev2_(float a, float b, float c, float& rt1, float& rt2,
                        float& cs1, float& sn1) {
#pragma clang fp contract(off)
  float sm = a + c;
  float df = a - c;
  float adf = fabsf(df);
  float tb = b + b;
  float ab = fabsf(tb);
  float acmx, acmn;
  if (fabsf(a) > fabsf(c)) { acmx = a; acmn = c; } else { acmx = c; acmn = a; }
  float rt;
  if (adf > ab) { float t = ab / adf; rt = adf * sqrtf(1.f + t * t); }
  else if (adf < ab) { float t = adf / ab; rt = ab * sqrtf(1.f + t * t); }
  else { rt = ab * sqrtf(2.f); }
  int sgn1;
  if (sm < 0.f) {
    rt1 = 0.5f * (sm - rt); sgn1 = -1;
    rt2 = (acmx / rt1) * acmn - (b / rt1) * b;
  } else if (sm > 0.f) {
    rt1 = 0.5f * (sm + rt); sgn1 = 1;
    rt2 = (acmx / rt1) * acmn - (b / rt1) * b;
  } else {
    rt1 = 0.5f * rt; rt2 = -0.5f * rt; sgn1 = 1;
  }
  float cs; int sgn2;
  if (df >= 0.f) { cs = df + rt; sgn2 = 1; } else { cs = df - rt; sgn2 = -1; }
  float acs = fabsf(cs);
  if (acs > ab) {
    float ct = -tb / cs;
    sn1 = 1.f / sqrtf(1.f + ct * ct);
    cs1 = ct * sn1;
  } else {
    if (ab == 0.f) { cs1 = 1.f; sn1 = 0.f; }
    else {
      float tn = -cs / tb;
      cs1 = 1.f / sqrtf(1.f + tn * tn);
      sn1 = tn * cs1;
    }
  }
  if (sgn1 == sgn2) { float tn = cs1; cs1 = -sn1; sn1 = tn; }
}

// ssteqr for n=3, compz='I' (z must be identity on entry)
__device__ void ssteqr3_(float* d, float* e, float z[3][3]) {
#pragma clang fp contract(off)
  const float eps = 5.9604645e-08f;
  const float eps2 = 3.5527137e-15f;
  const float safmin = 1.17549435e-38f;
  const int n = 3;
  const int nmaxit = 90;
  int jtot = 0;
  int l1 = 1;

  while (1) {
    if (l1 > n) break;
    if (l1 > 1) e[l1 - 2] = 0.f;
    int m = n;
    if (l1 <= n - 1) {
      for (int mm = l1; mm <= n - 1; ++mm) {
        float tst = fabsf(e[mm - 1]);
        if (tst == 0.f) { m = mm; break; }
        if (tst <= (sqrtf(fabsf(d[mm - 1])) * sqrtf(fabsf(d[mm]))) * eps) {
          e[mm - 1] = 0.f; m = mm; break;
        }
      }
    }
    int l = l1, lsv = l, lend = m, lendsv = lend;
    (void)lsv; (void)lendsv;
    l1 = m + 1;
    if (lend == l) continue;

    float anorm = 0.f;
    for (int i = l; i <= lend; ++i) anorm = fmaxf(anorm, fabsf(d[i - 1]));
    for (int i = l; i <= lend - 1; ++i) anorm = fmaxf(anorm, fabsf(e[i - 1]));
    if (anorm == 0.f) continue;

    if (fabsf(d[lend - 1]) < fabsf(d[l - 1])) { lend = lsv; l = lendsv; }

    if (lend > l) {
      // --- QL iteration ---
      while (1) {
        int m2 = lend;
        if (l != lend) {
          for (int mm = l; mm <= lend - 1; ++mm) {
            float tst = fabsf(e[mm - 1]); tst = tst * tst;
            if (tst <= (eps2 * fabsf(d[mm - 1])) * fabsf(d[mm]) + safmin) { m2 = mm; break; }
          }
        }
        if (m2 < lend) e[m2 - 1] = 0.f;
        float p = d[l - 1];
        if (m2 == l) {
          d[l - 1] = p; l += 1;
          if (l <= lend) continue;
          break;
        }
        if (m2 == l + 1) {
          float rt1, rt2, cc, ss;
          slaev2_(d[l - 1], e[l - 1], d[l], rt1, rt2, cc, ss);
          for (int i = 0; i < 3; ++i) {
            float temp = z[i][l];
            z[i][l] = cc * temp - ss * z[i][l - 1];
            z[i][l - 1] = ss * temp + cc * z[i][l - 1];
          }
          d[l - 1] = rt1; d[l] = rt2; e[l - 1] = 0.f;
          l += 2;
          if (l <= lend) continue;
          break;
        }
        if (jtot == nmaxit) break;
        jtot++;
        float g = (d[l] - p) / (2.f * e[l - 1]);
        float r = slapy2_(g, 1.f);
        g = d[m2 - 1] - p + (e[l - 1] / (g + f_sign(r, g)));
        float s = 1.f, c = 1.f;
        p = 0.f;
        float csv[2], snv[2];
        for (int i = m2 - 1; i >= l; --i) {
          float f = s * e[i - 1];
          float b = c * e[i - 1];
          slartg_(g, f, c, s, r);
          if (i != m2 - 1) e[i] = r;
          g = d[i] - p;
          r = (d[i - 1] - g) * s + (2.f * c) * b;
          p = s * r;
          d[i] = g + p;
          g = c * r - b;
          csv[i - l] = c; snv[i - l] = -s;
        }
        int cnt = m2 - l;
        for (int j = cnt; j >= 1; --j) {       // slasr 'R','V','B'
          float cj = csv[j - 1], sj = snv[j - 1];
          int c0 = (l - 1) + (j - 1);
          for (int i = 0; i < 3; ++i) {
            float temp = z[i][c0 + 1];
            z[i][c0 + 1] = cj * temp - sj * z[i][c0];
            z[i][c0] = sj * temp + cj * z[i][c0];
          }
        }
        d[l - 1] = d[l - 1] - p;
        e[l - 1] = g;
      }
    } else {
      // --- QR iteration ---
      while (1) {
        int m2 = lend;
        if (l != lend) {
          for (int mm = l; mm >= lend + 1; --mm) {
            float tst = fabsf(e[mm - 2]); tst = tst * tst;
            if (tst <= (eps2 * fabsf(d[mm - 1])) * fabsf(d[mm - 2]) + safmin) { m2 = mm; break; }
          }
        }
        if (m2 > lend) e[m2 - 2] = 0.f;
        float p = d[l - 1];
        if (m2 == l) {
          d[l - 1] = p; l -= 1;
          if (l >= lend) continue;
          break;
        }
        if (m2 == l - 1) {
          float rt1, rt2, cc, ss;
          slaev2_(d[l - 2], e[l - 2], d[l - 1], rt1, rt2, cc, ss);
          for (int i = 0; i < 3; ++i) {
            float temp = z[i][l - 1];
            z[i][l - 1] = cc * temp - ss * z[i][l - 2];
            z[i][l - 2] = ss * temp + cc * z[i][l - 2];
          }
          d[l - 2] = rt1; d[l - 1] = rt2; e[l - 2] = 0.f;
          l -= 2;
          if (l >= lend) continue;
          break;
        }
        if (jtot == nmaxit) break;
        jtot++;
        float g = (d[l - 2] - p) / (2.f * e[l - 2]);
        float r = slapy2_(g, 1.f);
        g = d[m2 - 1] - p + (e[l - 2] / (g + f_sign(r, g)));
        float s = 1.f, c = 1.f;
        p = 0.f;
        float csv[2], snv[2];
        for (int i = m2; i <= l - 1; ++i) {
          float f = s * e[i - 1];
          float b = c * e[i - 1];
          slartg_(g, f, c, s, r);
          if (i != m2) e[i - 2] = r;
          g = d[i - 1] - p;
          r = (d[i] - g) * s + (2.f * c) * b;
          p = s * r;
          d[i - 1] = g + p;
          g = c * r - b;
          csv[i - m2] = c; snv[i - m2] = s;
        }
        int cnt = l - m2;
        for (int j = 1; j <= cnt; ++j) {       // slasr 'R','V','F'
          float cj = csv[j - 1], sj = snv[j - 1];
          int c0 = (m2 - 1) + (j - 1);
          for (int i = 0; i < 3; ++i) {
            float temp = z[i][c0 + 1];
            z[i][c0 + 1] = cj * temp - sj * z[i][c0];
            z[i][c0] = sj * temp + cj * z[i][c0];
          }
        }
        d[l - 1] = d[l - 1] - p;
        e[l - 2] = g;
      }
    }
  }

  // selection sort ascending, swap eigenvector columns (LAPACK exact)
  for (int ii = 2; ii <= n; ++ii) {
    int i = ii - 1, k = i;
    float p = d[i - 1];
    for (int j = ii; j <= n; ++j)
      if (d[j - 1] < p) { k = j; p = d[j - 1]; }
    if (k != i) {
      d[k - 1] = d[i - 1]; d[i - 1] = p;
      for (int r2 = 0; r2 < 3; ++r2) {
        float t = z[r2][i - 1]; z[r2][i - 1] = z[r2][k - 1]; z[r2][k - 1] = t;
      }
    }
  }
}

// full ssyevd replica for 3x3 symmetric (lower entries), eigenvectors only
__device__ void eigh3_(float a00, float a10, float a11, float a20, float a21,
                       float a22, float V[3][3]) {
#pragma clang fp contract(off)
  float d0, d1, d2, e0, e1, tau1 = 0.f, v2 = 0.f;
  {
    float alpha = a10;
    float xnorm = fabsf(a20);
    if (xnorm == 0.f) {
      tau1 = 0.f; v2 = 0.f;
      e0 = alpha; d0 = a00; d1 = a11; d2 = a22; e1 = a21;
    } else {
      float beta = -f_sign(slapy2_(alpha, xnorm), alpha);
      tau1 = (beta - alpha) / beta;
      float inv = 1.0f / (alpha - beta);
      v2 = a20 * inv;
      float y0 = tau1 * a11;
      float y1v = tau1 * a21;
      float temp2 = a21 * v2;
      y0 = y0 + tau1 * temp2;
      y1v = y1v + (tau1 * v2) * a22;
      float dotyv = y0 * 1.f + y1v * v2;
      float al = (-0.5f * tau1) * dotyv;
      float w0 = y0 + al * 1.f;
      float w1 = y1v + al * v2;
      a11 = (a11 + 1.f * (-w0)) + w0 * (-1.f);
      a21 = (a21 + v2 * (-w0)) + w1 * (-1.f);
      a22 = (a22 + v2 * (-w1)) + w1 * (-v2);
      e0 = beta; d0 = a00; d1 = a11; d2 = a22; e1 = a21;
    }
  }
  float dd[3] = { d0, d1, d2 };
  float ee[2] = { e0, e1 };
  float z[3][3] = { {1.f,0.f,0.f},{0.f,1.f,0.f},{0.f,0.f,1.f} };
  ssteqr3_(dd, ee, z);
  if (tau1 != 0.f) {
    for (int j = 0; j < 3; ++j) {
      float wj = z[1][j] * 1.f + z[2][j] * v2;
      float temp = -tau1 * wj;
      z[1][j] = z[1][j] + 1.f * temp;
      z[2][j] = z[2][j] + v2 * temp;
    }
  }
  for (int r = 0; r < 3; ++r)
    for (int cix = 0; cix < 3; ++cix)
      V[r][cix] = z[r][cix];
}

// ---------------- kernels ----------------

__global__ void zero_kernel(u32* p1, int n1, u32* p2, int n2) {
  int t = blockIdx.x * blockDim.x + threadIdx.x;
  if (t < n1) p1[t] = 0u;
  if (t < n2) p2[t] = 0u;
}

// one wave per query point; per-lane sorted top-20 + wave merge
__global__ __launch_bounds__(256) void knn_kernel(const float* __restrict__ pos,
                                                  int* __restrict__ idx) {
#pragma clang fp contract(off)
  int wid = blockIdx.x * 4 + (threadIdx.x >> 6);
  int lane = threadIdx.x & 63;
  int b = wid >> 11;
  int n = wid & 2047;
  const float* pc = pos + (size_t)b * NNp * 3;
  float qx = pc[n * 3 + 0], qy = pc[n * 3 + 1], qz = pc[n * 3 + 2];
  float d2n = (qx * qx + qy * qy) + qz * qz;
  float kd[20]; int ki[20];
#pragma unroll
  for (int j = 0; j < 20; ++j) { kd[j] = __builtin_inff(); ki[j] = 0x7fffffff; }
  for (int m = lane; m < NNp; m += 64) {
    if (m == n) continue;
    float x = pc[m * 3 + 0], y = pc[m * 3 + 1], zc = pc[m * 3 + 2];
    float d2m = (x * x + y * y) + zc * zc;
    float dot = (qx * x + qy * y) + qz * zc;
    float dist = (d2n + d2m) - 2.0f * dot;
    if (dist < kd[19]) {
      kd[19] = dist; ki[19] = m;
#pragma unroll
      for (int j = 19; j > 0; --j) {
        if (kd[j] < kd[j - 1]) {
          float td = kd[j]; kd[j] = kd[j - 1]; kd[j - 1] = td;
          int ti = ki[j]; ki[j] = ki[j - 1]; ki[j - 1] = ti;
        }
      }
    }
  }
  for (int t = 0; t < 20; ++t) {
    float hd = kd[0]; int hi = ki[0];
    float bd = hd; int bi = hi;
#pragma unroll
    for (int off = 32; off; off >>= 1) {
      float od = __shfl_xor(bd, off);
      int oi = __shfl_xor(bi, off);
      if (od < bd || (od == bd && oi < bi)) { bd = od; bi = oi; }
    }
    if (hd == bd && hi == bi) {
#pragma unroll
      for (int j = 0; j < 19; ++j) { kd[j] = kd[j + 1]; ki[j] = ki[j + 1]; }
      kd[19] = __builtin_inff(); ki[19] = 0x7fffffff;
    }
    if (lane == 0) idx[(size_t)wid * 20 + t] = bi;
  }
}

// per-point: covariance, LAPACK-replica eigh, loc = rel @ V
__global__ __launch_bounds__(64) void prep_kernel(const float* __restrict__ pos,
                                                  const int* __restrict__ idx,
                                                  float* __restrict__ loc,
                                                  float* __restrict__ Vout) {
#pragma clang fp contract(off)
  int p = blockIdx.x * 64 + threadIdx.x;
  int b = p >> 11, n = p & 2047;
  const float* pc = pos + (size_t)b * NNp * 3;
  float qx = pc[n * 3 + 0], qy = pc[n * 3 + 1], qz = pc[n * 3 + 2];
  const int* ip = idx + (size_t)p * 20;
  float c00 = 0, c01 = 0, c02 = 0, c11 = 0, c12 = 0, c22 = 0;
  for (int k = 0; k < 20; ++k) {
    int j = ip[k];
    float rx = pc[j * 3 + 0] - qx, ry = pc[j * 3 + 1] - qy, rz = pc[j * 3 + 2] - qz;
    c00 += rx * rx; c01 += rx * ry; c02 += rx * rz;
    c11 += ry * ry; c12 += ry * rz; c22 += rz * rz;
  }
  float Vm[3][3];
  eigh3_(c00, c01, c11, c02, c12, c22, Vm);
  float* vp = Vout + (size_t)p * 9;
  for (int d = 0; d < 3; ++d)
    for (int e = 0; e < 3; ++e) vp[d * 3 + e] = Vm[d][e];
  for (int k = 0; k < 20; ++k) {
    int j = ip[k];
    float rx = pc[j * 3 + 0] - qx, ry = pc[j * 3 + 1] - qy, rz = pc[j * 3 + 2] - qz;
    float l0 = rx * Vm[0][0] + ry * Vm[1][0] + rz * Vm[2][0];
    float l1 = rx * Vm[0][1] + ry * Vm[1][1] + rz * Vm[2][1];
    float l2 = rx * Vm[0][2] + ry * Vm[1][2] + rz * Vm[2][2];
    size_t e = ((size_t)p * 20 + k) * 3;
    loc[e + 0] = l0; loc[e + 1] = l1; loc[e + 2] = l2;
  }
}

// layer1: [E,3]@[3,64]+b, relu, store fp32
__global__ __launch_bounds__(256) void l1_kernel(const float* __restrict__ loc,
                                                 const float* __restrict__ W,
                                                 const float* __restrict__ bias,
                                                 float* __restrict__ h1) {
  __shared__ float sW[192];
  __shared__ float sB[64];
  int t = threadIdx.x;
  if (t < 192) sW[t] = W[t];
  if (t < 64) sB[t] = bias[t];
  __syncthreads();
  size_t e = (size_t)blockIdx.x * 256 + t;
  float x0 = loc[e * 3 + 0], x1 = loc[e * 3 + 1], x2 = loc[e * 3 + 2];
  for (int c0 = 0; c0 < 64; c0 += 4) {
    float4 st;
    st.x = fmaxf(sB[c0 + 0] + x0 * sW[c0 + 0] + x1 * sW[64 + c0 + 0] + x2 * sW[128 + c0 + 0], 0.f);
    st.y = fmaxf(sB[c0 + 1] + x0 * sW[c0 + 1] + x1 * sW[64 + c0 + 1] + x2 * sW[128 + c0 + 1], 0.f);
    st.z = fmaxf(sB[c0 + 2] + x0 * sW[c0 + 2] + x1 * sW[64 + c0 + 2] + x2 * sW[128 + c0 + 2], 0.f);
    st.w = fmaxf(sB[c0 + 3] + x0 * sW[c0 + 3] + x1 * sW[64 + c0 + 3] + x2 * sW[128 + c0 + 3], 0.f);
    *(float4*)&h1[e * 64 + c0] = st;
  }
}

// per-channel sum/sumsq of an fp32 [E,64] buffer -> double atomics
__global__ __launch_bounds__(256) void stats64_kernel(const float* __restrict__ h,
                                                      double* __restrict__ sums) {
  __shared__ float red[512];
  int t = threadIdx.x;
  int c = t & 63, w = t >> 6;
  size_t rbase = (size_t)blockIdx.x * 1280 + w;
  float s = 0.f, q = 0.f;
  for (int r = 0; r < 1280; r += 4) {
    float v = h[(rbase + r) * 64 + c];
    s += v; q += v * v;
  }
  red[t] = s; red[256 + t] = q;
  __syncthreads();
  if (t < 64) {
    float S = red[t] + red[64 + t] + red[128 + t] + red[192 + t];
    float Q = red[256 + t] + red[320 + t] + red[384 + t] + red[448 + t];
    atomicAdd(&sums[t], (double)S);
    atomicAdd(&sums[64 + t], (double)Q);
  }
}

// sums -> per-channel affine (scale, shift) implementing train-mode BN
__global__ void finalize_kernel(const double* __restrict__ sums, int nch,
                                double count, const float* __restrict__ g,
                                const float* __restrict__ be,
                                float* __restrict__ out) {
  int c = blockIdx.x * blockDim.x + threadIdx.x;
  if (c < nch) {
    double m = sums[c] / count;
    double var = sums[nch + c] / count - m * m;
    double inv = 1.0 / sqrt(var + 1e-5);
    double sc = (double)g[c] * inv;
    out[c] = (float)sc;
    out[nch + c] = (float)((double)be[c] - m * sc);
  }
}

// layers 2/3: fp32 [E,64] @ [64,64]+b, relu, IN-PLACE capable (hin==hout)
__global__ __launch_bounds__(256) void l23_kernel(const float* __restrict__ hin,
                                                  const float* __restrict__ ss,
                                                  const float* __restrict__ W,
                                                  const float* __restrict__ bias,
                                                  float* __restrict__ hout) {
  __shared__ float xT[64 * 84];
  int t = threadIdx.x;
  size_t e0 = (size_t)blockIdx.x * 80;
  for (int v = t; v < 80 * 64; v += 256) {
    int el = v >> 6, c = v & 63;
    float val = hin[(e0 + el) * 64 + c];
    val = val * ss[c] + ss[64 + c];
    xT[c * 84 + el] = val;
  }
  __syncthreads();
  int og = t & 15, eg = t >> 4;
  int o0 = og * 4, eb = eg * 5;
  float acc[5][4];
#pragma unroll
  for (int a = 0; a < 5; ++a)
#pragma unroll
    for (int o = 0; o < 4; ++o) acc[a][o] = 0.f;
  for (int i = 0; i < 64; ++i) {
    float4 w4 = *(const float4*)&W[i * 64 + o0];
    float xx[5];
#pragma unroll
    for (int a = 0; a < 5; ++a) xx[a] = xT[i * 84 + eb + a];
#pragma unroll
    for (int a = 0; a < 5; ++a) {
      acc[a][0] += xx[a] * w4.x;
      acc[a][1] += xx[a] * w4.y;
      acc[a][2] += xx[a] * w4.z;
      acc[a][3] += xx[a] * w4.w;
    }
  }
  float4 b4 = *(const float4*)&bias[o0];
#pragma unroll
  for (int a = 0; a < 5; ++a) {
    size_t e = e0 + eb + a;
    float4 st;
    st.x = fmaxf(acc[a][0] + b4.x, 0.f);
    st.y = fmaxf(acc[a][1] + b4.y, 0.f);
    st.z = fmaxf(acc[a][2] + b4.z, 0.f);
    st.w = fmaxf(acc[a][3] + b4.w, 0.f);
    *(float4*)&hout[e * 64 + o0] = st;
  }
}

// f3d[p][c][d] = max_k h3n[p,k,c] * loc[p,k,d]
__global__ __launch_bounds__(256) void f3d_kernel(const float* __restrict__ h3,
                                                  const float* __restrict__ ss3,
                                                  const float* __restrict__ loc,
                                                  float* __restrict__ f3d) {
  int t = threadIdx.x;
  int p = blockIdx.x * 4 + (t >> 6);
  int c = t & 63;
  float sc = ss3[c], sh = ss3[64 + c];
  float m0 = -__builtin_inff(), m1 = m0, m2 = m0;
  size_t eb = (size_t)p * 20;
  for (int k = 0; k < 20; ++k) {
    size_t e = eb + k;
    float h = h3[e * 64 + c] * sc + sh;
    float l0 = loc[e * 3 + 0], l1 = loc[e * 3 + 1], l2 = loc[e * 3 + 2];
    m0 = fmaxf(m0, h * l0);
    m1 = fmaxf(m1, h * l1);
    m2 = fmaxf(m2, h * l2);
  }
  size_t o = (size_t)p * 192 + c * 3;
  f3d[o + 0] = m0; f3d[o + 1] = m1; f3d[o + 2] = m2;
}

// W21 [192][128] fp32 -> WT bf16 [128][192] (n-major rows, k contiguous)
__global__ __launch_bounds__(256) void wtcvt_kernel(const float* __restrict__ W,
                                                    u16* __restrict__ wt) {
  int id = blockIdx.x * 256 + threadIdx.x;
  if (id < 192 * 128) {
    int n = id / 192, k = id - n * 192;
    wt[id] = f2bf(W[(size_t)k * 128 + n]);
  }
}

// DD2 via bf16 MFMA: gather f3d[idx], rotate by V -> X bf16 LDS [80][200];
// WT staged in two K-halves [128][104]; GEMM [80,192]@[192,128] with
// mfma_f32_16x16x32_bf16; bias+relu+maxpool(k)+per-channel stats in-register.
__global__ __launch_bounds__(256) void dd2_kernel(const float* __restrict__ f3d,
                                                  const float* __restrict__ Vmat,
                                                  const int* __restrict__ idx,
                                                  const u16* __restrict__ wt,
                                                  const float* __restrict__ bias,
                                                  float* __restrict__ fdd2,
                                                  double* __restrict__ s4) {
  __shared__ u16 sX[80 * 200];     // X bf16, row stride 200 (400B, 16B aligned)
  __shared__ u16 sWT[128 * 104];   // W^T bf16 half, row stride 104 (208B)
  __shared__ float sV[36];
  __shared__ int sJ[80];
  int t = threadIdx.x;
  int p0 = blockIdx.x * 4;
  int bcl = p0 >> 11;              // cloud (4 points never straddle clouds)

  if (t < 36) sV[t] = Vmat[(size_t)p0 * 9 + t];
  if (t < 80) sJ[t] = ((bcl << 11) + idx[(size_t)p0 * 20 + t]) * 192;
  __syncthreads();

  const u32* wt32 = (const u32*)wt;          // [128][96] u32 view
  u32* sWT32 = (u32*)sWT;                    // [128][52] u32 view
  // stage WT half 0 (k in [0,96))
  for (int v = t; v < 6144; v += 256) {
    int n = v / 48, kk = v - n * 48;
    sWT32[n * 52 + kk] = wt32[n * 96 + kk];
  }
  // build X: el = edge 0..79, c2 = channel-pair 0..31
  for (int v = t; v < 80 * 32; v += 256) {
    int el = v >> 5, c2 = v & 31;
    int pp = el / 20;
    const float* fp = f3d + (size_t)sJ[el] + 6 * c2;
    float f0 = fp[0], f1 = fp[1], f2 = fp[2];
    float f3 = fp[3], f4 = fp[4], f5 = fp[5];
    const float* Vp = &sV[pp * 9];
    float x0 = f0 * Vp[0] + f1 * Vp[3] + f2 * Vp[6];
    float x1 = f0 * Vp[1] + f1 * Vp[4] + f2 * Vp[7];
    float x2 = f0 * Vp[2] + f1 * Vp[5] + f2 * Vp[8];
    float y0 = f3 * Vp[0] + f4 * Vp[3] + f5 * Vp[6];
    float y1 = f3 * Vp[1] + f4 * Vp[4] + f5 * Vp[7];
    float y2 = f3 * Vp[2] + f4 * Vp[5] + f5 * Vp[8];
    u32* xp = (u32*)&sX[el * 200 + 6 * c2];
    xp[0] = (u32)f2bf(x0) | ((u32)f2bf(x1) << 16);
    xp[1] = (u32)f2bf(x2) | ((u32)f2bf(y0) << 16);
    xp[2] = (u32)f2bf(y1) | ((u32)f2bf(y2) << 16);
  }
  __syncthreads();

  int w = t >> 6, l = t & 63;
  int lr = l & 15, lg = l >> 4;
  f32x4 acc[5][2];
#pragma unroll
  for (int mt = 0; mt < 5; ++mt) {
    acc[mt][0] = (f32x4)(0.f);
    acc[mt][1] = (f32x4)(0.f);
  }

#define MFMA_STEP(H, KS)                                                       \
  {                                                                            \
    const int ko = (KS)*32 + lg * 8;                                           \
    short8 b0 = *(const short8*)&sWT[(w * 32 + lr) * 104 + ko];                \
    short8 b1 = *(const short8*)&sWT[(w * 32 + 16 + lr) * 104 + ko];           \
    _Pragma("unroll") for (int mt = 0; mt < 5; ++mt) {                         \
      short8 a = *(const short8*)&sX[(mt * 16 + lr) * 200 + (H)*96 + ko];      \
      acc[mt][0] = __builtin_amdgcn_mfma_f32_16x16x32_bf16(a, b0, acc[mt][0], 0, 0, 0); \
      acc[mt][1] = __builtin_amdgcn_mfma_f32_16x16x32_bf16(a, b1, acc[mt][1], 0, 0, 0); \
    }                                                                          \
  }

  MFMA_STEP(0, 0)
  MFMA_STEP(0, 1)
  MFMA_STEP(0, 2)
  __syncthreads();
  // stage WT half 1 (k in [96,192))
  for (int v = t; v < 6144; v += 256) {
    int n = v / 48, kk = v - n * 48;
    sWT32[n * 52 + kk] = wt32[n * 96 + 48 + kk];
  }
  __syncthreads();
  MFMA_STEP(1, 0)
  MFMA_STEP(1, 1)
  MFMA_STEP(1, 2)
#undef MFMA_STEP

  // epilogue: z = relu(acc+bias); maxpool over k per point; per-channel stats
#pragma unroll
  for (int nt = 0; nt < 2; ++nt) {
    int col = w * 32 + nt * 16 + lr;
    float bs = bias[col];
    float pm0 = 0.f, pm1 = 0.f, pm2 = 0.f, pm3 = 0.f;
    float s = 0.f, q = 0.f;
#pragma unroll
    for (int mt = 0; mt < 5; ++mt) {
#pragma unroll
      for (int r = 0; r < 4; ++r) {
        int edge = mt * 16 + lg * 4 + r;   // 0..79, exact (no padding)
        float z = fmaxf(acc[mt][nt][r] + bs, 0.f);
        pm0 = fmaxf(pm0, (edge < 20) ? z : 0.f);
        pm1 = fmaxf(pm1, (edge >= 20 && edge < 40) ? z : 0.f);
        pm2 = fmaxf(pm2, (edge >= 40 && edge < 60) ? z : 0.f);
        pm3 = fmaxf(pm3, (edge >= 60) ? z : 0.f);
        s += z; q += z * z;
      }
    }
    // reduce across the 4 row-lane-groups (lanes l, l^16, l^32, l^48)
#pragma unroll
    for (int off = 16; off < 64; off <<= 1) {
      pm0 = fmaxf(pm0, __shfl_xor(pm0, off));
      pm1 = fmaxf(pm1, __shfl_xor(pm1, off));
      pm2 = fmaxf(pm2, __shfl_xor(pm2, off));
      pm3 = fmaxf(pm3, __shfl_xor(pm3, off));
      s += __shfl_xor(s, off);
      q += __shfl_xor(q, off);
    }
    if (l < 16) {
      fdd2[(size_t)(p0 + 0) * 128 + col] = pm0;
      fdd2[(size_t)(p0 + 1) * 128 + col] = pm1;
      fdd2[(size_t)(p0 + 2) * 128 + col] = pm2;
      fdd2[(size_t)(p0 + 3) * 128 + col] = pm3;
      atomicAdd(&s4[col], (double)s);
      atomicAdd(&s4[128 + col], (double)q);
    }
  }
}

// y1: register-tiled fp32 GEMM [16384,128]@[128,1024] with fused max over n.
__global__ __launch_bounds__(256) void y1_kernel(const float* __restrict__ fdd2,
                                                 const float* __restrict__ ss4,
                                                 const float* __restrict__ wh1,
                                                 u32* __restrict__ y1key) {
  __shared__ float sX[128][68];   // [k][point]
  __shared__ float sW[128][68];   // [k][chan]
  int t = threadIdx.x;
  int bid = blockIdx.x;
  int mtile = bid & 255;
  int ntile = bid >> 8;
  int cl = mtile >> 5;                 // cloud
  size_t pbase = (size_t)mtile * 64;   // global point base
  int c0 = ntile * 64;

  {
    int kq = t & 31, pp = t >> 5;
    float4 sc4 = *(const float4*)&ss4[kq * 4];
    float4 sh4 = *(const float4*)&ss4[128 + kq * 4];
    for (int p = pp; p < 64; p += 8) {
      float4 x4 = *(const float4*)&fdd2[(pbase + p) * 128 + kq * 4];
      sX[kq * 4 + 0][p] = x4.x * sc4.x + sh4.x;
      sX[kq * 4 + 1][p] = x4.y * sc4.y + sh4.y;
      sX[kq * 4 + 2][p] = x4.z * sc4.z + sh4.z;
      sX[kq * 4 + 3][p] = x4.w * sc4.w + sh4.w;
    }
  }
  {
    int cq = t & 15, rr = t >> 4;
    for (int r = rr; r < 128; r += 16) {
      float4 w4 = *(const float4*)&wh1[(size_t)r * 1024 + c0 + cq * 4];
      *(float4*)&sW[r][cq * 4] = w4;
    }
  }
  __syncthreads();

  int mg = t >> 4, ng = t & 15;
  int m0 = mg * 4, n0 = ng * 4;
  float acc[4][4];
#pragma unroll
  for (int i = 0; i < 4; ++i)
#pragma unroll
    for (int j = 0; j < 4; ++j) acc[i][j] = 0.f;
  for (int k = 0; k < 128; ++k) {
    float4 x4 = *(const float4*)&sX[k][m0];
    float4 w4 = *(const float4*)&sW[k][n0];
    acc[0][0] += x4.x * w4.x; acc[0][1] += x4.x * w4.y;
    acc[0][2] += x4.x * w4.z; acc[0][3] += x4.x * w4.w;
    acc[1][0] += x4.y * w4.x; acc[1][1] += x4.y * w4.y;
    acc[1][2] += x4.y * w4.z; acc[1][3] += x4.y * w4.w;
    acc[2][0] += x4.z * w4.x; acc[2][1] += x4.z * w4.y;
    acc[2][2] += x4.z * w4.z; acc[2][3] += x4.z * w4.w;
    acc[3][0] += x4.w * w4.x; acc[3][1] += x4.w * w4.y;
    acc[3][2] += x4.w * w4.z; acc[3][3] += x4.w * w4.w;
  }
  __syncthreads();
  float* red = &sX[0][0];
#pragma unroll
  for (int j = 0; j < 4; ++j) {
    float v = fmaxf(fmaxf(acc[0][j], acc[1][j]), fmaxf(acc[2][j], acc[3][j]));
    red[(n0 + j) * 16 + mg] = v;
  }
  __syncthreads();
  if (t < 64) {
    float m = red[t * 16];
#pragma unroll
    for (int i = 1; i < 16; ++i) m = fmaxf(m, red[t * 16 + i]);
    atomicMax(&y1key[(size_t)cl * 1024 + c0 + t], fkey(m));
  }
}

// y1 decode + bias + relu + BN over 8 clouds
__global__ void y1bn_kernel(const u32* __restrict__ y1key,
                            const float* __restrict__ bh1,
                            const float* __restrict__ g,
                            const float* __restrict__ be,
                            float* __restrict__ y1n) {
  int c = blockIdx.x * 256 + threadIdx.x;
  if (c >= 1024) return;
  float bs = bh1[c];
  float v[8]; double s = 0.0;
#pragma unroll
  for (int b = 0; b < 8; ++b) {
    v[b] = fmaxf(funkey(y1key[b * 1024 + c]) + bs, 0.f);
    s += (double)v[b];
  }
  double m = s / 8.0, q = 0.0;
#pragma unroll
  for (int b = 0; b < 8; ++b) { double d = (double)v[b] - m; q += d * d; }
  q /= 8.0;
  double inv = 1.0 / sqrt(q + 1e-5);
  double sg = (double)g[c] * inv;
#pragma unroll
  for (int b = 0; b < 8; ++b)
    y1n[b * 1024 + c] = (float)(((double)v[b] - m) * sg + (double)be[c]);
}

// small dense layer: [8,IN]@[IN,OUT]+b, relu, BN over 8 -> out
__global__ __launch_bounds__(64) void head_kernel(const float* __restrict__ yin,
                                                  const float* __restrict__ W,
                                                  const float* __restrict__ bias,
                                                  const float* __restrict__ g,
                                                  const float* __restrict__ be,
                                                  float* __restrict__ yout,
                                                  int INn, int OUTn) {
  __shared__ float sx[8192];
  int t = threadIdx.x;
  for (int v = t; v < 8 * INn; v += 64) sx[v] = yin[v];
  __syncthreads();
  int o = blockIdx.x * 64 + t;
  if (o >= OUTn) return;
  float acc[8];
#pragma unroll
  for (int b = 0; b < 8; ++b) acc[b] = 0.f;
  for (int i = 0; i < INn; ++i) {
    float w = W[(size_t)i * OUTn + o];
#pragma unroll
    for (int b = 0; b < 8; ++b) acc[b] += sx[b * INn + i] * w;
  }
  float bs = bias[o];
  float v[8]; double s = 0.0;
#pragma unroll
  for (int b = 0; b < 8; ++b) { v[b] = fmaxf(acc[b] + bs, 0.f); s += (double)v[b]; }
  double m = s / 8.0, q = 0.0;
#pragma unroll
  for (int b = 0; b < 8; ++b) { double d = (double)v[b] - m; q += d * d; }
  q /= 8.0;
  double inv = 1.0 / sqrt(q + 1e-5);
  double sg = (double)g[o] * inv;
#pragma unroll
  for (int b = 0; b < 8; ++b)
    yout[(size_t)b * OUTn + o] = (float)(((double)v[b] - m) * sg + (double)be[o]);
}

// final linear [8,265]@[265,40]+b then log_softmax per row
__global__ __launch_bounds__(384) void logits_kernel(const float* __restrict__ y3n,
                                                     const float* __restrict__ W,
                                                     const float* __restrict__ bias,
                                                     float* __restrict__ out) {
  __shared__ float sy[8 * 265];
  __shared__ float slog[320];
  __shared__ float sm[8], sl[8];
  int t = threadIdx.x;
  for (int v = t; v < 8 * 265; v += 384) sy[v] = y3n[v];
  __syncthreads();
  if (t < 320) {
    int b = t / 40, o = t % 40;
    float acc = 0.f;
    for (int i = 0; i < 265; ++i) acc += sy[b * 265 + i] * W[i * 40 + o];
    slog[t] = acc + bias[o];
  }
  __syncthreads();
  if (t < 8) {
    float m = slog[t * 40];
    for (int o = 1; o < 40; ++o) m = fmaxf(m, slog[t * 40 + o]);
    float s = 0.f;
    for (int o = 0; o < 40; ++o) s += expf(slog[t * 40 + o] - m);
    sm[t] = m; sl[t] = logf(s);
  }
  __syncthreads();
  if (t < 320) {
    int b = t / 40;
    out[t] = slog[t] - sm[b] - sl[b];
  }
}

// ---------------- launcher ----------------
extern "C" void kernel_launch(void* const* d_in, const int* in_sizes, int n_in,
                              void* d_out, int out_size, void* d_ws, size_t ws_size,
                              hipStream_t stream) {
  (void)in_sizes; (void)n_in; (void)out_size; (void)ws_size;
  const float* pos  = (const float*)d_in[0];
  const float* w11  = (const float*)d_in[1];
  const float* b11  = (const float*)d_in[2];
  const float* g11  = (const float*)d_in[3];
  const float* be11 = (const float*)d_in[4];
  const float* w12  = (const float*)d_in[5];
  const float* b12  = (const float*)d_in[6];
  const float* g12  = (const float*)d_in[7];
  const float* be12 = (const float*)d_in[8];
  const float* w13  = (const float*)d_in[9];
  const float* b13  = (const float*)d_in[10];
  const float* g13  = (const float*)d_in[11];
  const float* be13 = (const float*)d_in[12];
  const float* w21  = (const float*)d_in[13];
  const float* b21  = (const float*)d_in[14];
  const float* g21  = (const float*)d_in[15];
  const float* be21 = (const float*)d_in[16];
  const float* wh1  = (const float*)d_in[17];
  const float* bh1  = (const float*)d_in[18];
  const float* gh1  = (const float*)d_in[19];
  const float* beh1 = (const float*)d_in[20];
  const float* wh2  = (const float*)d_in[21];
  const float* bh2  = (const float*)d_in[22];
  const float* gh2  = (const float*)d_in[23];
  const float* beh2 = (const float*)d_in[24];
  const float* wh3  = (const float*)d_in[25];
  const float* bh3  = (const float*)d_in[26];
  const float* gh3  = (const float*)d_in[27];
  const float* beh3 = (const float*)d_in[28];
  const float* wh4  = (const float*)d_in[29];
  const float* bh4  = (const float*)d_in[30];

  char* ws = (char*)d_ws;
  int*    idx   = (int*)(ws + 0);                 // 1,310,720 B
  float*  loc   = (float*)(ws + 1310720);         // 3,932,160 B
  float*  V     = (float*)(ws + 5242880);         //   589,824 B
  float*  h     = (float*)(ws + 5832704);         // 83,886,080 B (fp32, in-place)
  u16*    wt    = (u16*)(ws + 5832704);           // 49,152 B (overlays h AFTER f3d)
  float*  f3d   = (float*)(ws + 89718784);        // 12,582,912 B
  float*  fdd2  = (float*)(ws + 102301696);       //  8,388,608 B
  u32*    y1k   = (u32*)(ws + 110690304);         //     32,768 B
  float*  y1n   = (float*)(ws + 110723072);       //     32,768 B
  float*  y2n   = (float*)(ws + 110755840);       //     16,384 B
  float*  y3n   = (float*)(ws + 110772224);       //      8,512 B
  double* stats = (double*)(ws + 110780736);      // 640 doubles
  float*  param = (float*)(ws + 110785856);       // 640 floats
  float*  out   = (float*)d_out;

  zero_kernel<<<32, 256, 0, stream>>>((u32*)stats, 1280, y1k, 8192);
  knn_kernel<<<4096, 256, 0, stream>>>(pos, idx);
  prep_kernel<<<256, 64, 0, stream>>>(pos, idx, loc, V);

  l1_kernel<<<1280, 256, 0, stream>>>(loc, w11, b11, h);
  stats64_kernel<<<256, 256, 0, stream>>>(h, stats);
  finalize_kernel<<<1, 256, 0, stream>>>(stats, 64, (double)EE, g11, be11, param);

  l23_kernel<<<4096, 256, 0, stream>>>(h, param, w12, b12, h);          // in-place
  stats64_kernel<<<256, 256, 0, stream>>>(h, stats + 128);
  finalize_kernel<<<1, 256, 0, stream>>>(stats + 128, 64, (double)EE, g12, be12, param + 128);

  l23_kernel<<<4096, 256, 0, stream>>>(h, param + 128, w13, b13, h);    // in-place
  stats64_kernel<<<256, 256, 0, stream>>>(h, stats + 256);
  finalize_kernel<<<1, 256, 0, stream>>>(stats + 256, 64, (double)EE, g13, be13, param + 256);

  f3d_kernel<<<4096, 256, 0, stream>>>(h, param + 256, loc, f3d);
  // h is dead now; wt overlays it
  wtcvt_kernel<<<96, 256, 0, stream>>>(w21, wt);
  dd2_kernel<<<4096, 256, 0, stream>>>(f3d, V, idx, wt, b21, fdd2, stats + 384);
  finalize_kernel<<<1, 256, 0, stream>>>(stats + 384, 128, (double)EE, g21, be21, param + 384);

  y1_kernel<<<4096, 256, 0, stream>>>(fdd2, param + 384, wh1, y1k);
  y1bn_kernel<<<4, 256, 0, stream>>>(y1k, bh1, gh1, beh1, y1n);

  head_kernel<<<8, 64, 0, stream>>>(y1n, wh2, bh2, gh2, beh2, y2n, 1024, 512);
  head_kernel<<<5, 64, 0, stream>>>(y2n, wh3, bh3, gh3, beh3, y3n, 512, 265);
  logits_kernel<<<1, 384, 0, stream>>>(y3n, wh4, bh4, out);
}

// Round 5
// 631.429 us; speedup vs baseline: 1.8650x; 1.1396x over previous
//
#include <hip/hip_runtime.h>

// ---------------------------------------------------------------------------
// Net_3152505995976: point-cloud classifier forward pass on MI355X.
// Round 5: knn rewrite (147us -> target ~50us).
//   - exact threshold-select KNN: per-lane keys in VGPRs, count-guided
//     threshold search (secant + integer bisection, tie-exact fallback),
//     ballot compaction, wave bitonic sort of the <=128 survivors.
//   - dd2 bf16 MFMA, y1 reg-tiled GEMM, fp32 pipeline: unchanged from R4.
// ---------------------------------------------------------------------------

#define NEW_SLARTG 1

typedef unsigned short u16;
typedef unsigned int u32;
typedef unsigned long long u64;
typedef __attribute__((ext_vector_type(8))) short short8;
typedef __attribute__((ext_vector_type(4))) float f32x4;

#define BB 8
#define NNp 2048
#define KKn 20
#define NP 16384      // BB*NNp
#define EE 327680     // NP*KKn

// ---------------- small helpers ----------------
__device__ __forceinline__ u32 fkey(float f) {
  u32 u = __float_as_uint(f);
  return (u & 0x80000000u) ? ~u : (u | 0x80000000u);
}
__device__ __forceinline__ float funkey(u32 k) {
  u32 u = (k & 0x80000000u) ? (k ^ 0x80000000u) : ~k;
  return __uint_as_float(u);
}
__device__ __forceinline__ float f_sign(float a, float b) {
  return (b >= 0.f) ? fabsf(a) : -fabsf(a);
}
__device__ __forceinline__ u16 f2bf(float f) {
  u32 u = __float_as_uint(f);
  u32 r = (u + 0x7fffu + ((u >> 16) & 1u)) >> 16;
  return (u16)r;
}

__device__ __forceinline__ u64 sxor64(u64 v, int m) {
  union { u64 q; u32 d[2]; } a; a.q = v;
  a.d[0] = __shfl_xor(a.d[0], m);
  a.d[1] = __shfl_xor(a.d[1], m);
  return a.q;
}
__device__ __forceinline__ u64 sidx64(u64 v, int src) {
  union { u64 q; u32 d[2]; } a; a.q = v;
  a.d[0] = __shfl(a.d[0], src);
  a.d[1] = __shfl(a.d[1], src);
  return a.q;
}
// wave-wide bitonic sort, 64 u64 elements (1/lane), ascending
__device__ __forceinline__ void bsort64(u64& v, int lane) {
#pragma unroll
  for (int k = 2; k <= 64; k <<= 1) {
#pragma unroll
    for (int j = k >> 1; j > 0; j >>= 1) {
      u64 pv = sxor64(v, j);
      bool up = ((lane & k) == 0);
      bool lower = ((lane & j) == 0);
      bool keepmin = (lower == up);
      bool take = keepmin ? (pv < v) : (pv > v);
      v = take ? pv : v;
    }
  }
}

// ---------------- LAPACK fp32 replicas ----------------
__device__ float slapy2_(float x, float y) {
#pragma clang fp contract(off)
  float xa = fabsf(x), ya = fabsf(y);
  float w = fmaxf(xa, ya), z = fminf(xa, ya);
  if (z == 0.f) return w;
  float t = z / w;
  return w * sqrtf(1.0f + t * t);
}

__device__ void slartg_(float f, float g, float& c, float& s, float& r) {
#pragma clang fp contract(off)
#if NEW_SLARTG
  const float safmin = 1.17549435e-38f;
  const float safmax = 8.50705917e+37f;
  const float rtmin = 1.08420217e-19f;   // sqrt(safmin)
  const float rtmax = 6.52221171e+18f;   // sqrt(safmax/2)
  float f1 = fabsf(f), g1 = fabsf(g);
  if (g == 0.f) { c = 1.f; s = 0.f; r = f; }
  else if (f == 0.f) { c = 0.f; s = (g >= 0.f) ? 1.f : -1.f; r = g1; }
  else {
    float d;
    if (f1 > rtmin && f1 < rtmax && g1 > rtmin && g1 < rtmax) {
      d = sqrtf(f * f + g * g);
      c = f1 / d;
      r = (f >= 0.f) ? d : -d;
    } else {
      float uu = fminf(safmax, fmaxf(safmin, fmaxf(f1, g1)));
      float fs = f / uu, gs = g / uu;
      d = sqrtf(fs * fs + gs * gs);
      c = fabsf(fs) / d;
      r = ((f >= 0.f) ? d : -d) * uu;
    }
    s = g / r;
  }
#else
  if (g == 0.f) { c = 1.f; s = 0.f; r = f; }
  else if (f == 0.f) { c = 0.f; s = 1.f; r = g; }
  else {
    float f1 = f, g1 = g;
    r = sqrtf(f1 * f1 + g1 * g1);
    c = f1 / r;
    s = g1 / r;
    if (fabsf(f) > fabsf(g) && c < 0.f) { c = -c; s = -s; r = -r; }
  }
#endif
}

__device__ void slaev2_(float a, float b, float c, float& rt1, float& rt2,
                        float& cs1, float& sn1) {
#pragma clang fp contract(off)
  float sm = a + c;
  float df = a - c;
  float adf = fabsf(df);
  float tb = b + b;
  float ab = fabsf(tb);
  float acmx, acmn;
  if (fabsf(a) > fabsf(c)) { acmx = a; acmn = c; } else { acmx = c; acmn = a; }
  float rt;
  if (adf > ab) { float t = ab / adf; rt = adf * sqrtf(1.f + t * t); }
  else if (adf < ab) { float t = adf / ab; rt = ab * sqrtf(1.f + t * t); }
  else { rt = ab * sqrtf(2.f); }
  int sgn1;
  if (sm < 0.f) {
    rt1 = 0.5f * (sm - rt); sgn1 = -1;
    rt2 = (acmx / rt1) * acmn - (b / rt1) * b;
  } else if (sm > 0.f) {
    rt1 = 0.5f * (sm + rt); sgn1 = 1;
    rt2 = (acmx / rt1) * acmn - (b / rt1) * b;
  } else {
    rt1 = 0.5f * rt; rt2 = -0.5f * rt; sgn1 = 1;
  }
  float cs; int sgn2;
  if (df >= 0.f) { cs = df + rt; sgn2 = 1; } else { cs = df - rt; sgn2 = -1; }
  float acs = fabsf(cs);
  if (acs > ab) {
    float ct = -tb / cs;
    sn1 = 1.f / sqrtf(1.f + ct * ct);
    cs1 = ct * sn1;
  } else {
    if (ab == 0.f) { cs1 = 1.f; sn1 = 0.f; }
    else {
      float tn = -cs / tb;
      cs1 = 1.f / sqrtf(1.f + tn * tn);
      sn1 = tn * cs1;
    }
  }
  if (sgn1 == sgn2) { float tn = cs1; cs1 = -sn1; sn1 = tn; }
}

// ssteqr for n=3, compz='I' (z must be identity on entry)
__device__ void ssteqr3_(float* d, float* e, float z[3][3]) {
#pragma clang fp contract(off)
  const float eps = 5.9604645e-08f;
  const float eps2 = 3.5527137e-15f;
  const float safmin = 1.17549435e-38f;
  const int n = 3;
  const int nmaxit = 90;
  int jtot = 0;
  int l1 = 1;

  while (1) {
    if (l1 > n) break;
    if (l1 > 1) e[l1 - 2] = 0.f;
    int m = n;
    if (l1 <= n - 1) {
      for (int mm = l1; mm <= n - 1; ++mm) {
        float tst = fabsf(e[mm - 1]);
        if (tst == 0.f) { m = mm; break; }
        if (tst <= (sqrtf(fabsf(d[mm - 1])) * sqrtf(fabsf(d[mm]))) * eps) {
          e[mm - 1] = 0.f; m = mm; break;
        }
      }
    }
    int l = l1, lsv = l, lend = m, lendsv = lend;
    (void)lsv; (void)lendsv;
    l1 = m + 1;
    if (lend == l) continue;

    float anorm = 0.f;
    for (int i = l; i <= lend; ++i) anorm = fmaxf(anorm, fabsf(d[i - 1]));
    for (int i = l; i <= lend - 1; ++i) anorm = fmaxf(anorm, fabsf(e[i - 1]));
    if (anorm == 0.f) continue;

    if (fabsf(d[lend - 1]) < fabsf(d[l - 1])) { lend = lsv; l = lendsv; }

    if (lend > l) {
      // --- QL iteration ---
      while (1) {
        int m2 = lend;
        if (l != lend) {
          for (int mm = l; mm <= lend - 1; ++mm) {
            float tst = fabsf(e[mm - 1]); tst = tst * tst;
            if (tst <= (eps2 * fabsf(d[mm - 1])) * fabsf(d[mm]) + safmin) { m2 = mm; break; }
          }
        }
        if (m2 < lend) e[m2 - 1] = 0.f;
        float p = d[l - 1];
        if (m2 == l) {
          d[l - 1] = p; l += 1;
          if (l <= lend) continue;
          break;
        }
        if (m2 == l + 1) {
          float rt1, rt2, cc, ss;
          slaev2_(d[l - 1], e[l - 1], d[l], rt1, rt2, cc, ss);
          for (int i = 0; i < 3; ++i) {
            float temp = z[i][l];
            z[i][l] = cc * temp - ss * z[i][l - 1];
            z[i][l - 1] = ss * temp + cc * z[i][l - 1];
          }
          d[l - 1] = rt1; d[l] = rt2; e[l - 1] = 0.f;
          l += 2;
          if (l <= lend) continue;
          break;
        }
        if (jtot == nmaxit) break;
        jtot++;
        float g = (d[l] - p) / (2.f * e[l - 1]);
        float r = slapy2_(g, 1.f);
        g = d[m2 - 1] - p + (e[l - 1] / (g + f_sign(r, g)));
        float s = 1.f, c = 1.f;
        p = 0.f;
        float csv[2], snv[2];
        for (int i = m2 - 1; i >= l; --i) {
          float f = s * e[i - 1];
          float b = c * e[i - 1];
          slartg_(g, f, c, s, r);
          if (i != m2 - 1) e[i] = r;
          g = d[i] - p;
          r = (d[i - 1] - g) * s + (2.f * c) * b;
          p = s * r;
          d[i] = g + p;
          g = c * r - b;
          csv[i - l] = c; snv[i - l] = -s;
        }
        int cnt = m2 - l;
        for (int j = cnt; j >= 1; --j) {       // slasr 'R','V','B'
          float cj = csv[j - 1], sj = snv[j - 1];
          int c0 = (l - 1) + (j - 1);
          for (int i = 0; i < 3; ++i) {
            float temp = z[i][c0 + 1];
            z[i][c0 + 1] = cj * temp - sj * z[i][c0];
            z[i][c0] = sj * temp + cj * z[i][c0];
          }
        }
        d[l - 1] = d[l - 1] - p;
        e[l - 1] = g;
      }
    } else {
      // --- QR iteration ---
      while (1) {
        int m2 = lend;
        if (l != lend) {
          for (int mm = l; mm >= lend + 1; --mm) {
            float tst = fabsf(e[mm - 2]); tst = tst * tst;
            if (tst <= (eps2 * fabsf(d[mm - 1])) * fabsf(d[mm - 2]) + safmin) { m2 = mm; break; }
          }
        }
        if (m2 > lend) e[m2 - 2] = 0.f;
        float p = d[l - 1];
        if (m2 == l) {
          d[l - 1] = p; l -= 1;
          if (l >= lend) continue;
          break;
        }
        if (m2 == l - 1) {
          float rt1, rt2, cc, ss;
          slaev2_(d[l - 2], e[l - 2], d[l - 1], rt1, rt2, cc, ss);
          for (int i = 0; i < 3; ++i) {
            float temp = z[i][l - 1];
            z[i][l - 1] = cc * temp - ss * z[i][l - 2];
            z[i][l - 2] = ss * temp + cc * z[i][l - 2];
          }
          d[l - 2] = rt1; d[l - 1] = rt2; e[l - 2] = 0.f;
          l -= 2;
          if (l >= lend) continue;
          break;
        }
        if (jtot == nmaxit) break;
        jtot++;
        float g = (d[l - 2] - p) / (2.f * e[l - 2]);
        float r = slapy2_(g, 1.f);
        g = d[m2 - 1] - p + (e[l - 2] / (g + f_sign(r, g)));
        float s = 1.f, c = 1.f;
        p = 0.f;
        float csv[2], snv[2];
        for (int i = m2; i <= l - 1; ++i) {
          float f = s * e[i - 1];
          float b = c * e[i - 1];
          slartg_(g, f, c, s, r);
          if (i != m2) e[i - 2] = r;
          g = d[i - 1] - p;
          r = (d[i] - g) * s + (2.f * c) * b;
          p = s * r;
          d[i - 1] = g + p;
          g = c * r - b;
          csv[i - m2] = c; snv[i - m2] = s;
        }
        int cnt = l - m2;
        for (int j = 1; j <= cnt; ++j) {       // slasr 'R','V','F'
          float cj = csv[j - 1], sj = snv[j - 1];
          int c0 = (m2 - 1) + (j - 1);
          for (int i = 0; i < 3; ++i) {
            float temp = z[i][c0 + 1];
            z[i][c0 + 1] = cj * temp - sj * z[i][c0];
            z[i][c0] = sj * temp + cj * z[i][c0];
          }
        }
        d[l - 1] = d[l - 1] - p;
        e[l - 2] = g;
      }
    }
  }

  // selection sort ascending, swap eigenvector columns (LAPACK exact)
  for (int ii = 2; ii <= n; ++ii) {
    int i = ii - 1, k = i;
    float p = d[i - 1];
    for (int j = ii; j <= n; ++j)
      if (d[j - 1] < p) { k = j; p = d[j - 1]; }
    if (k != i) {
      d[k - 1] = d[i - 1]; d[i - 1] = p;
      for (int r2 = 0; r2 < 3; ++r2) {
        float t = z[r2][i - 1]; z[r2][i - 1] = z[r2][k - 1]; z[r2][k - 1] = t;
      }
    }
  }
}

// full ssyevd replica for 3x3 symmetric (lower entries), eigenvectors only
__device__ void eigh3_(float a00, float a10, float a11, float a20, float a21,
                       float a22, float V[3][3]) {
#pragma clang fp contract(off)
  float d0, d1, d2, e0, e1, tau1 = 0.f, v2 = 0.f;
  {
    float alpha = a10;
    float xnorm = fabsf(a20);
    if (xnorm == 0.f) {
      tau1 = 0.f; v2 = 0.f;
      e0 = alpha; d0 = a00; d1 = a11; d2 = a22; e1 = a21;
    } else {
      float beta = -f_sign(slapy2_(alpha, xnorm), alpha);
      tau1 = (beta - alpha) / beta;
      float inv = 1.0f / (alpha - beta);
      v2 = a20 * inv;
      float y0 = tau1 * a11;
      float y1v = tau1 * a21;
      float temp2 = a21 * v2;
      y0 = y0 + tau1 * temp2;
      y1v = y1v + (tau1 * v2) * a22;
      float dotyv = y0 * 1.f + y1v * v2;
      float al = (-0.5f * tau1) * dotyv;
      float w0 = y0 + al * 1.f;
      float w1 = y1v + al * v2;
      a11 = (a11 + 1.f * (-w0)) + w0 * (-1.f);
      a21 = (a21 + v2 * (-w0)) + w1 * (-1.f);
      a22 = (a22 + v2 * (-w1)) + w1 * (-v2);
      e0 = beta; d0 = a00; d1 = a11; d2 = a22; e1 = a21;
    }
  }
  float dd[3] = { d0, d1, d2 };
  float ee[2] = { e0, e1 };
  float z[3][3] = { {1.f,0.f,0.f},{0.f,1.f,0.f},{0.f,0.f,1.f} };
  ssteqr3_(dd, ee, z);
  if (tau1 != 0.f) {
    for (int j = 0; j < 3; ++j) {
      float wj = z[1][j] * 1.f + z[2][j] * v2;
      float temp = -tau1 * wj;
      z[1][j] = z[1][j] + 1.f * temp;
      z[2][j] = z[2][j] + v2 * temp;
    }
  }
  for (int r = 0; r < 3; ++r)
    for (int cix = 0; cix < 3; ++cix)
      V[r][cix] = z[r][cix];
}

// ---------------- kernels ----------------

__global__ void zero_kernel(u32* p1, int n1, u32* p2, int n2) {
  int t = blockIdx.x * blockDim.x + threadIdx.x;
  if (t < n1) p1[t] = 0u;
  if (t < n2) p2[t] = 0u;
}

// exact KNN top-20 per point: threshold-select + wave bitonic sort.
// one wave per query; keys in VGPRs; no __syncthreads (waves independent).
__global__ __launch_bounds__(256) void knn_kernel(const float* __restrict__ pos,
                                                  int* __restrict__ idx) {
#pragma clang fp contract(off)
  __shared__ u64 cke[4][128];
  int w = threadIdx.x >> 6;
  int lane = threadIdx.x & 63;
  int wid = blockIdx.x * 4 + w;
  int b = wid >> 11;
  int n = wid & 2047;
  const float* pc = pos + (size_t)b * NNp * 3;
  float qx = pc[n * 3 + 0], qy = pc[n * 3 + 1], qz = pc[n * 3 + 2];
  float d2n = (qx * qx + qy * qy) + qz * qz;

  // pass A: 32 keys per lane, in registers; track wave-min
  u32 kreg[32];
  u32 mk = 0xFFFFFFFFu;
#pragma unroll
  for (int t = 0; t < 32; ++t) {
    int m = lane + 64 * t;
    float x = pc[m * 3 + 0], y = pc[m * 3 + 1], zc = pc[m * 3 + 2];
    float d2m = (x * x + y * y) + zc * zc;
    float dot = (qx * x + qy * y) + qz * zc;
    float dist = (d2n + d2m) - 2.0f * dot;
    u32 key = fkey(dist);
    if (m == n) key = 0xFFFFFFFFu;   // self-exclusion (== +1e10 diag in ref)
    kreg[t] = key;
    mk = key < mk ? key : mk;
  }
#pragma unroll
  for (int off = 32; off; off >>= 1) {
    u32 o = __shfl_xor(mk, off);
    mk = o < mk ? o : mk;
  }

  // threshold search: find hi with 20 <= count(key<=hi) <= 128 (exact,
  // tie-robust: bracket [lo,hi] with count(lo)<20, integer bisection floor)
  u32 lo_b = mk - 1u, hi_b = 0xFFFFFFFEu;
  int c_hi = 2047;
  float tf = funkey(mk) * 7.368f;     // count ~ T^1.5 => rank-20 guess
  u32 T = fkey(tf);
  if (T < mk) T = mk;
  if (T > 0xFFFFFFFEu) T = 0xFFFFFFFEu;
  for (int it = 0; it < 48; ++it) {
    int cnt = 0;
#pragma unroll
    for (int t = 0; t < 32; ++t) cnt += (kreg[t] <= T) ? 1 : 0;
#pragma unroll
    for (int off = 32; off; off >>= 1) cnt += __shfl_xor(cnt, off);
    if (cnt >= 20) {
      hi_b = T; c_hi = cnt;
      if (cnt <= 128) break;
    } else {
      lo_b = T;
    }
    if (hi_b <= lo_b + 1u) break;
    u32 Tn;
    if (it < 12) {
      float tfc = funkey(T);
      int cc = cnt < 1 ? 1 : cnt;
      float guess = tfc * __builtin_exp2f(0.66667f * __builtin_log2f(45.0f / (float)cc));
      Tn = fkey(guess);
      if (!(Tn > lo_b && Tn < hi_b)) Tn = lo_b + ((hi_b - lo_b) >> 1);
    } else {
      Tn = lo_b + ((hi_b - lo_b) >> 1);   // pure bisection: guaranteed done <=44
    }
    T = Tn;
  }

  // collect survivors (key <= hi_b) in m-ascending order via ballot prefix
  u64* ck = cke[w];
  u32 base = 0;
#pragma unroll
  for (int t = 0; t < 32; ++t) {
    bool pass = kreg[t] <= hi_b;
    u64 ball = __ballot(pass);
    if (pass) {
      u32 posn = base + (u32)__popcll(ball & ((1ull << lane) - 1ull));
      if (posn < 128u)
        ck[posn] = ((u64)kreg[t] << 32) | (u32)(lane + 64 * t);
    }
    base += (u32)__popcll(ball);
  }
  if (base > 128u) {
    // pathological (massive key ties at boundary; hi_b == lo_b+1 here):
    // class A: key <= lo_b (count < 20, all kept); class B: boundary keys
    // in m order, truncated at 128 -> exact under (key, m) tie rule.
    base = 0;
#pragma unroll
    for (int t = 0; t < 32; ++t) {
      bool pass = kreg[t] <= lo_b;
      u64 ball = __ballot(pass);
      if (pass) {
        u32 posn = base + (u32)__popcll(ball & ((1ull << lane) - 1ull));
        ck[posn] = ((u64)kreg[t] << 32) | (u32)(lane + 64 * t);
      }
      base += (u32)__popcll(ball);
    }
#pragma unroll
    for (int t = 0; t < 32; ++t) {
      bool pass = (kreg[t] > lo_b) && (kreg[t] <= hi_b);
      u64 ball = __ballot(pass);
      if (pass) {
        u32 posn = base + (u32)__popcll(ball & ((1ull << lane) - 1ull));
        if (posn < 128u)
          ck[posn] = ((u64)kreg[t] << 32) | (u32)(lane + 64 * t);
      }
      base += (u32)__popcll(ball);
    }
  }
  u32 ctot = base < 128u ? base : 128u;

  // sort survivors ascending by (key, m); take first 20
  u64 e0 = (lane < (int)ctot) ? ck[lane] : ~0ull;
  bsort64(e0, lane);
  if (ctot > 64u) {
    u64 e1 = (lane + 64 < (int)ctot) ? ck[lane + 64] : ~0ull;
    bsort64(e1, lane);
    u64 r = sidx64(e1, 63 - lane);          // reverse second run
    u64 mn = r < e0 ? r : e0;               // bitonic
#pragma unroll
    for (int j = 32; j > 0; j >>= 1) {      // clean
      u64 pv = sxor64(mn, j);
      bool lower2 = ((lane & j) == 0);
      bool take = lower2 ? (pv < mn) : (pv > mn);
      mn = take ? pv : mn;
    }
    e0 = mn;
  }
  if (lane < 20)
    idx[(size_t)wid * 20 + lane] = (int)(u32)(e0 & 0xFFFFFFFFull);
}

// per-point: covariance, LAPACK-replica eigh, loc = rel @ V
__global__ __launch_bounds__(64) void prep_kernel(const float* __restrict__ pos,
                                                  const int* __restrict__ idx,
                                                  float* __restrict__ loc,
                                                  float* __restrict__ Vout) {
#pragma clang fp contract(off)
  int p = blockIdx.x * 64 + threadIdx.x;
  int b = p >> 11, n = p & 2047;
  const float* pc = pos + (size_t)b * NNp * 3;
  float qx = pc[n * 3 + 0], qy = pc[n * 3 + 1], qz = pc[n * 3 + 2];
  const int* ip = idx + (size_t)p * 20;
  float c00 = 0, c01 = 0, c02 = 0, c11 = 0, c12 = 0, c22 = 0;
  for (int k = 0; k < 20; ++k) {
    int j = ip[k];
    float rx = pc[j * 3 + 0] - qx, ry = pc[j * 3 + 1] - qy, rz = pc[j * 3 + 2] - qz;
    c00 += rx * rx; c01 += rx * ry; c02 += rx * rz;
    c11 += ry * ry; c12 += ry * rz; c22 += rz * rz;
  }
  float Vm[3][3];
  eigh3_(c00, c01, c11, c02, c12, c22, Vm);
  float* vp = Vout + (size_t)p * 9;
  for (int d = 0; d < 3; ++d)
    for (int e = 0; e < 3; ++e) vp[d * 3 + e] = Vm[d][e];
  for (int k = 0; k < 20; ++k) {
    int j = ip[k];
    float rx = pc[j * 3 + 0] - qx, ry = pc[j * 3 + 1] - qy, rz = pc[j * 3 + 2] - qz;
    float l0 = rx * Vm[0][0] + ry * Vm[1][0] + rz * Vm[2][0];
    float l1 = rx * Vm[0][1] + ry * Vm[1][1] + rz * Vm[2][1];
    float l2 = rx * Vm[0][2] + ry * Vm[1][2] + rz * Vm[2][2];
    size_t e = ((size_t)p * 20 + k) * 3;
    loc[e + 0] = l0; loc[e + 1] = l1; loc[e + 2] = l2;
  }
}

// layer1: [E,3]@[3,64]+b, relu, store fp32
__global__ __launch_bounds__(256) void l1_kernel(const float* __restrict__ loc,
                                                 const float* __restrict__ W,
                                                 const float* __restrict__ bias,
                                                 float* __restrict__ h1) {
  __shared__ float sW[192];
  __shared__ float sB[64];
  int t = threadIdx.x;
  if (t < 192) sW[t] = W[t];
  if (t < 64) sB[t] = bias[t];
  __syncthreads();
  size_t e = (size_t)blockIdx.x * 256 + t;
  float x0 = loc[e * 3 + 0], x1 = loc[e * 3 + 1], x2 = loc[e * 3 + 2];
  for (int c0 = 0; c0 < 64; c0 += 4) {
    float4 st;
    st.x = fmaxf(sB[c0 + 0] + x0 * sW[c0 + 0] + x1 * sW[64 + c0 + 0] + x2 * sW[128 + c0 + 0], 0.f);
    st.y = fmaxf(sB[c0 + 1] + x0 * sW[c0 + 1] + x1 * sW[64 + c0 + 1] + x2 * sW[128 + c0 + 1], 0.f);
    st.z = fmaxf(sB[c0 + 2] + x0 * sW[c0 + 2] + x1 * sW[64 + c0 + 2] + x2 * sW[128 + c0 + 2], 0.f);
    st.w = fmaxf(sB[c0 + 3] + x0 * sW[c0 + 3] + x1 * sW[64 + c0 + 3] + x2 * sW[128 + c0 + 3], 0.f);
    *(float4*)&h1[e * 64 + c0] = st;
  }
}

// per-channel sum/sumsq of an fp32 [E,64] buffer -> double atomics
__global__ __launch_bounds__(256) void stats64_kernel(const float* __restrict__ h,
                                                      double* __restrict__ sums) {
  __shared__ float red[512];
  int t = threadIdx.x;
  int c = t & 63, w = t >> 6;
  size_t rbase = (size_t)blockIdx.x * 1280 + w;
  float s = 0.f, q = 0.f;
  for (int r = 0; r < 1280; r += 4) {
    float v = h[(rbase + r) * 64 + c];
    s += v; q += v * v;
  }
  red[t] = s; red[256 + t] = q;
  __syncthreads();
  if (t < 64) {
    float S = red[t] + red[64 + t] + red[128 + t] + red[192 + t];
    float Q = red[256 + t] + red[320 + t] + red[384 + t] + red[448 + t];
    atomicAdd(&sums[t], (double)S);
    atomicAdd(&sums[64 + t], (double)Q);
  }
}

// sums -> per-channel affine (scale, shift) implementing train-mode BN
__global__ void finalize_kernel(const double* __restrict__ sums, int nch,
                                double count, const float* __restrict__ g,
                                const float* __restrict__ be,
                                float* __restrict__ out) {
  int c = blockIdx.x * blockDim.x + threadIdx.x;
  if (c < nch) {
    double m = sums[c] / count;
    double var = sums[nch + c] / count - m * m;
    double inv = 1.0 / sqrt(var + 1e-5);
    double sc = (double)g[c] * inv;
    out[c] = (float)sc;
    out[nch + c] = (float)((double)be[c] - m * sc);
  }
}

// layers 2/3: fp32 [E,64] @ [64,64]+b, relu, IN-PLACE capable (hin==hout)
__global__ __launch_bounds__(256) void l23_kernel(const float* __restrict__ hin,
                                                  const float* __restrict__ ss,
                                                  const float* __restrict__ W,
                                                  const float* __restrict__ bias,
                                                  float* __restrict__ hout) {
  __shared__ float xT[64 * 84];
  int t = threadIdx.x;
  size_t e0 = (size_t)blockIdx.x * 80;
  for (int v = t; v < 80 * 64; v += 256) {
    int el = v >> 6, c = v & 63;
    float val = hin[(e0 + el) * 64 + c];
    val = val * ss[c] + ss[64 + c];
    xT[c * 84 + el] = val;
  }
  __syncthreads();
  int og = t & 15, eg = t >> 4;
  int o0 = og * 4, eb = eg * 5;
  float acc[5][4];
#pragma unroll
  for (int a = 0; a < 5; ++a)
#pragma unroll
    for (int o = 0; o < 4; ++o) acc[a][o] = 0.f;
  for (int i = 0; i < 64; ++i) {
    float4 w4 = *(const float4*)&W[i * 64 + o0];
    float xx[5];
#pragma unroll
    for (int a = 0; a < 5; ++a) xx[a] = xT[i * 84 + eb + a];
#pragma unroll
    for (int a = 0; a < 5; ++a) {
      acc[a][0] += xx[a] * w4.x;
      acc[a][1] += xx[a] * w4.y;
      acc[a][2] += xx[a] * w4.z;
      acc[a][3] += xx[a] * w4.w;
    }
  }
  float4 b4 = *(const float4*)&bias[o0];
#pragma unroll
  for (int a = 0; a < 5; ++a) {
    size_t e = e0 + eb + a;
    float4 st;
    st.x = fmaxf(acc[a][0] + b4.x, 0.f);
    st.y = fmaxf(acc[a][1] + b4.y, 0.f);
    st.z = fmaxf(acc[a][2] + b4.z, 0.f);
    st.w = fmaxf(acc[a][3] + b4.w, 0.f);
    *(float4*)&hout[e * 64 + o0] = st;
  }
}

// f3d[p][c][d] = max_k h3n[p,k,c] * loc[p,k,d]
__global__ __launch_bounds__(256) void f3d_kernel(const float* __restrict__ h3,
                                                  const float* __restrict__ ss3,
                                                  const float* __restrict__ loc,
                                                  float* __restrict__ f3d) {
  int t = threadIdx.x;
  int p = blockIdx.x * 4 + (t >> 6);
  int c = t & 63;
  float sc = ss3[c], sh = ss3[64 + c];
  float m0 = -__builtin_inff(), m1 = m0, m2 = m0;
  size_t eb = (size_t)p * 20;
  for (int k = 0; k < 20; ++k) {
    size_t e = eb + k;
    float h = h3[e * 64 + c] * sc + sh;
    float l0 = loc[e * 3 + 0], l1 = loc[e * 3 + 1], l2 = loc[e * 3 + 2];
    m0 = fmaxf(m0, h * l0);
    m1 = fmaxf(m1, h * l1);
    m2 = fmaxf(m2, h * l2);
  }
  size_t o = (size_t)p * 192 + c * 3;
  f3d[o + 0] = m0; f3d[o + 1] = m1; f3d[o + 2] = m2;
}

// W21 [192][128] fp32 -> WT bf16 [128][192] (n-major rows, k contiguous)
__global__ __launch_bounds__(256) void wtcvt_kernel(const float* __restrict__ W,
                                                    u16* __restrict__ wt) {
  int id = blockIdx.x * 256 + threadIdx.x;
  if (id < 192 * 128) {
    int n = id / 192, k = id - n * 192;
    wt[id] = f2bf(W[(size_t)k * 128 + n]);
  }
}

// DD2 via bf16 MFMA: gather f3d[idx], rotate by V -> X bf16 LDS [80][200];
// WT staged in two K-halves [128][104]; GEMM [80,192]@[192,128] with
// mfma_f32_16x16x32_bf16; bias+relu+maxpool(k)+per-channel stats in-register.
__global__ __launch_bounds__(256) void dd2_kernel(const float* __restrict__ f3d,
                                                  const float* __restrict__ Vmat,
                                                  const int* __restrict__ idx,
                                                  const u16* __restrict__ wt,
                                                  const float* __restrict__ bias,
                                                  float* __restrict__ fdd2,
                                                  double* __restrict__ s4) {
  __shared__ u16 sX[80 * 200];     // X bf16, row stride 200 (400B, 16B aligned)
  __shared__ u16 sWT[128 * 104];   // W^T bf16 half, row stride 104 (208B)
  __shared__ float sV[36];
  __shared__ int sJ[80];
  int t = threadIdx.x;
  int p0 = blockIdx.x * 4;
  int bcl = p0 >> 11;              // cloud (4 points never straddle clouds)

  if (t < 36) sV[t] = Vmat[(size_t)p0 * 9 + t];
  if (t < 80) sJ[t] = ((bcl << 11) + idx[(size_t)p0 * 20 + t]) * 192;
  __syncthreads();

  const u32* wt32 = (const u32*)wt;          // [128][96] u32 view
  u32* sWT32 = (u32*)sWT;                    // [128][52] u32 view
  // stage WT half 0 (k in [0,96))
  for (int v = t; v < 6144; v += 256) {
    int n = v / 48, kk = v - n * 48;
    sWT32[n * 52 + kk] = wt32[n * 96 + kk];
  }
  // build X: el = edge 0..79, c2 = channel-pair 0..31
  for (int v = t; v < 80 * 32; v += 256) {
    int el = v >> 5, c2 = v & 31;
    int pp = el / 20;
    const float* fp = f3d + (size_t)sJ[el] + 6 * c2;
    float f0 = fp[0], f1 = fp[1], f2 = fp[2];
    float f3 = fp[3], f4 = fp[4], f5 = fp[5];
    const float* Vp = &sV[pp * 9];
    float x0 = f0 * Vp[0] + f1 * Vp[3] + f2 * Vp[6];
    float x1 = f0 * Vp[1] + f1 * Vp[4] + f2 * Vp[7];
    float x2 = f0 * Vp[2] + f1 * Vp[5] + f2 * Vp[8];
    float y0 = f3 * Vp[0] + f4 * Vp[3] + f5 * Vp[6];
    float y1 = f3 * Vp[1] + f4 * Vp[4] + f5 * Vp[7];
    float y2 = f3 * Vp[2] + f4 * Vp[5] + f5 * Vp[8];
    u32* xp = (u32*)&sX[el * 200 + 6 * c2];
    xp[0] = (u32)f2bf(x0) | ((u32)f2bf(x1) << 16);
    xp[1] = (u32)f2bf(x2) | ((u32)f2bf(y0) << 16);
    xp[2] = (u32)f2bf(y1) | ((u32)f2bf(y2) << 16);
  }
  __syncthreads();

  int w = t >> 6, l = t & 63;
  int lr = l & 15, lg = l >> 4;
  f32x4 acc[5][2];
#pragma unroll
  for (int mt = 0; mt < 5; ++mt) {
    acc[mt][0] = (f32x4)(0.f);
    acc[mt][1] = (f32x4)(0.f);
  }

#define MFMA_STEP(H, KS)                                                       \
  {                                                                            \
    const int ko = (KS)*32 + lg * 8;                                           \
    short8 b0 = *(const short8*)&sWT[(w * 32 + lr) * 104 + ko];                \
    short8 b1 = *(const short8*)&sWT[(w * 32 + 16 + lr) * 104 + ko];           \
    _Pragma("unroll") for (int mt = 0; mt < 5; ++mt) {                         \
      short8 a = *(const short8*)&sX[(mt * 16 + lr) * 200 + (H)*96 + ko];      \
      acc[mt][0] = __builtin_amdgcn_mfma_f32_16x16x32_bf16(a, b0, acc[mt][0], 0, 0, 0); \
      acc[mt][1] = __builtin_amdgcn_mfma_f32_16x16x32_bf16(a, b1, acc[mt][1], 0, 0, 0); \
    }                                                                          \
  }

  MFMA_STEP(0, 0)
  MFMA_STEP(0, 1)
  MFMA_STEP(0, 2)
  __syncthreads();
  // stage WT half 1 (k in [96,192))
  for (int v = t; v < 6144; v += 256) {
    int n = v / 48, kk = v - n * 48;
    sWT32[n * 52 + kk] = wt32[n * 96 + 48 + kk];
  }
  __syncthreads();
  MFMA_STEP(1, 0)
  MFMA_STEP(1, 1)
  MFMA_STEP(1, 2)
#undef MFMA_STEP

  // epilogue: z = relu(acc+bias); maxpool over k per point; per-channel stats
#pragma unroll
  for (int nt = 0; nt < 2; ++nt) {
    int col = w * 32 + nt * 16 + lr;
    float bs = bias[col];
    float pm0 = 0.f, pm1 = 0.f, pm2 = 0.f, pm3 = 0.f;
    float s = 0.f, q = 0.f;
#pragma unroll
    for (int mt = 0; mt < 5; ++mt) {
#pragma unroll
      for (int r = 0; r < 4; ++r) {
        int edge = mt * 16 + lg * 4 + r;   // 0..79, exact (no padding)
        float z = fmaxf(acc[mt][nt][r] + bs, 0.f);
        pm0 = fmaxf(pm0, (edge < 20) ? z : 0.f);
        pm1 = fmaxf(pm1, (edge >= 20 && edge < 40) ? z : 0.f);
        pm2 = fmaxf(pm2, (edge >= 40 && edge < 60) ? z : 0.f);
        pm3 = fmaxf(pm3, (edge >= 60) ? z : 0.f);
        s += z; q += z * z;
      }
    }
    // reduce across the 4 row-lane-groups (lanes l, l^16, l^32, l^48)
#pragma unroll
    for (int off = 16; off < 64; off <<= 1) {
      pm0 = fmaxf(pm0, __shfl_xor(pm0, off));
      pm1 = fmaxf(pm1, __shfl_xor(pm1, off));
      pm2 = fmaxf(pm2, __shfl_xor(pm2, off));
      pm3 = fmaxf(pm3, __shfl_xor(pm3, off));
      s += __shfl_xor(s, off);
      q += __shfl_xor(q, off);
    }
    if (l < 16) {
      fdd2[(size_t)(p0 + 0) * 128 + col] = pm0;
      fdd2[(size_t)(p0 + 1) * 128 + col] = pm1;
      fdd2[(size_t)(p0 + 2) * 128 + col] = pm2;
      fdd2[(size_t)(p0 + 3) * 128 + col] = pm3;
      atomicAdd(&s4[col], (double)s);
      atomicAdd(&s4[128 + col], (double)q);
    }
  }
}

// y1: register-tiled fp32 GEMM [16384,128]@[128,1024] with fused max over n.
__global__ __launch_bounds__(256) void y1_kernel(const float* __restrict__ fdd2,
                                                 const float* __restrict__ ss4,
                                                 const float* __restrict__ wh1,
                                                 u32* __restrict__ y1key) {
  __shared__ float sX[128][68];   // [k][point]
  __shared__ float sW[128][68];   // [k][chan]
  int t = threadIdx.x;
  int bid = blockIdx.x;
  int mtile = bid & 255;
  int ntile = bid >> 8;
  int cl = mtile >> 5;                 // cloud
  size_t pbase = (size_t)mtile * 64;   // global point base
  int c0 = ntile * 64;

  {
    int kq = t & 31, pp = t >> 5;
    float4 sc4 = *(const float4*)&ss4[kq * 4];
    float4 sh4 = *(const float4*)&ss4[128 + kq * 4];
    for (int p = pp; p < 64; p += 8) {
      float4 x4 = *(const float4*)&fdd2[(pbase + p) * 128 + kq * 4];
      sX[kq * 4 + 0][p] = x4.x * sc4.x + sh4.x;
      sX[kq * 4 + 1][p] = x4.y * sc4.y + sh4.y;
      sX[kq * 4 + 2][p] = x4.z * sc4.z + sh4.z;
      sX[kq * 4 + 3][p] = x4.w * sc4.w + sh4.w;
    }
  }
  {
    int cq = t & 15, rr = t >> 4;
    for (int r = rr; r < 128; r += 16) {
      float4 w4 = *(const float4*)&wh1[(size_t)r * 1024 + c0 + cq * 4];
      *(float4*)&sW[r][cq * 4] = w4;
    }
  }
  __syncthreads();

  int mg = t >> 4, ng = t & 15;
  int m0 = mg * 4, n0 = ng * 4;
  float acc[4][4];
#pragma unroll
  for (int i = 0; i < 4; ++i)
#pragma unroll
    for (int j = 0; j < 4; ++j) acc[i][j] = 0.f;
  for (int k = 0; k < 128; ++k) {
    float4 x4 = *(const float4*)&sX[k][m0];
    float4 w4 = *(const float4*)&sW[k][n0];
    acc[0][0] += x4.x * w4.x; acc[0][1] += x4.x * w4.y;
    acc[0][2] += x4.x * w4.z; acc[0][3] += x4.x * w4.w;
    acc[1][0] += x4.y * w4.x; acc[1][1] += x4.y * w4.y;
    acc[1][2] += x4.y * w4.z; acc[1][3] += x4.y * w4.w;
    acc[2][0] += x4.z * w4.x; acc[2][1] += x4.z * w4.y;
    acc[2][2] += x4.z * w4.z; acc[2][3] += x4.z * w4.w;
    acc[3][0] += x4.w * w4.x; acc[3][1] += x4.w * w4.y;
    acc[3][2] += x4.w * w4.z; acc[3][3] += x4.w * w4.w;
  }
  __syncthreads();
  float* red = &sX[0][0];
#pragma unroll
  for (int j = 0; j < 4; ++j) {
    float v = fmaxf(fmaxf(acc[0][j], acc[1][j]), fmaxf(acc[2][j], acc[3][j]));
    red[(n0 + j) * 16 + mg] = v;
  }
  __syncthreads();
  if (t < 64) {
    float m = red[t * 16];
#pragma unroll
    for (int i = 1; i < 16; ++i) m = fmaxf(m, red[t * 16 + i]);
    atomicMax(&y1key[(size_t)cl * 1024 + c0 + t], fkey(m));
  }
}

// y1 decode + bias + relu + BN over 8 clouds
__global__ void y1bn_kernel(const u32* __restrict__ y1key,
                            const float* __restrict__ bh1,
                            const float* __restrict__ g,
                            const float* __restrict__ be,
                            float* __restrict__ y1n) {
  int c = blockIdx.x * 256 + threadIdx.x;
  if (c >= 1024) return;
  float bs = bh1[c];
  float v[8]; double s = 0.0;
#pragma unroll
  for (int b = 0; b < 8; ++b) {
    v[b] = fmaxf(funkey(y1key[b * 1024 + c]) + bs, 0.f);
    s += (double)v[b];
  }
  double m = s / 8.0, q = 0.0;
#pragma unroll
  for (int b = 0; b < 8; ++b) { double d = (double)v[b] - m; q += d * d; }
  q /= 8.0;
  double inv = 1.0 / sqrt(q + 1e-5);
  double sg = (double)g[c] * inv;
#pragma unroll
  for (int b = 0; b < 8; ++b)
    y1n[b * 1024 + c] = (float)(((double)v[b] - m) * sg + (double)be[c]);
}

// small dense layer: [8,IN]@[IN,OUT]+b, relu, BN over 8 -> out
__global__ __launch_bounds__(64) void head_kernel(const float* __restrict__ yin,
                                                  const float* __restrict__ W,
                                                  const float* __restrict__ bias,
                                                  const float* __restrict__ g,
                                                  const float* __restrict__ be,
                                                  float* __restrict__ yout,
                                                  int INn, int OUTn) {
  __shared__ float sx[8192];
  int t = threadIdx.x;
  for (int v = t; v < 8 * INn; v += 64) sx[v] = yin[v];
  __syncthreads();
  int o = blockIdx.x * 64 + t;
  if (o >= OUTn) return;
  float acc[8];
#pragma unroll
  for (int b = 0; b < 8; ++b) acc[b] = 0.f;
  for (int i = 0; i < INn; ++i) {
    float w = W[(size_t)i * OUTn + o];
#pragma unroll
    for (int b = 0; b < 8; ++b) acc[b] += sx[b * INn + i] * w;
  }
  float bs = bias[o];
  float v[8]; double s = 0.0;
#pragma unroll
  for (int b = 0; b < 8; ++b) { v[b] = fmaxf(acc[b] + bs, 0.f); s += (double)v[b]; }
  double m = s / 8.0, q = 0.0;
#pragma unroll
  for (int b = 0; b < 8; ++b) { double d = (double)v[b] - m; q += d * d; }
  q /= 8.0;
  double inv = 1.0 / sqrt(q + 1e-5);
  double sg = (double)g[o] * inv;
#pragma unroll
  for (int b = 0; b < 8; ++b)
    yout[(size_t)b * OUTn + o] = (float)(((double)v[b] - m) * sg + (double)be[o]);
}

// final linear [8,265]@[265,40]+b then log_softmax per row
__global__ __launch_bounds__(384) void logits_kernel(const float* __restrict__ y3n,
                                                     const float* __restrict__ W,
                                                     const float* __restrict__ bias,
                                                     float* __restrict__ out) {
  __shared__ float sy[8 * 265];
  __shared__ float slog[320];
  __shared__ float sm[8], sl[8];
  int t = threadIdx.x;
  for (int v = t; v < 8 * 265; v += 384) sy[v] = y3n[v];
  __syncthreads();
  if (t < 320) {
    int b = t / 40, o = t % 40;
    float acc = 0.f;
    for (int i = 0; i < 265; ++i) acc += sy[b * 265 + i] * W[i * 40 + o];
    slog[t] = acc + bias[o];
  }
  __syncthreads();
  if (t < 8) {
    float m = slog[t * 40];
    for (int o = 1; o < 40; ++o) m = fmaxf(m, slog[t * 40 + o]);
    float s = 0.f;
    for (int o = 0; o < 40; ++o) s += expf(slog[t * 40 + o] - m);
    sm[t] = m; sl[t] = logf(s);
  }
  __syncthreads();
  if (t < 320) {
    int b = t / 40;
    out[t] = slog[t] - sm[b] - sl[b];
  }
}

// ---------------- launcher ----------------
extern "C" void kernel_launch(void* const* d_in, const int* in_sizes, int n_in,
                              void* d_out, int out_size, void* d_ws, size_t ws_size,
                              hipStream_t stream) {
  (void)in_sizes; (void)n_in; (void)out_size; (void)ws_size;
  const float* pos  = (const float*)d_in[0];
  const float* w11  = (const float*)d_in[1];
  const float* b11  = (const float*)d_in[2];
  const float* g11  = (const float*)d_in[3];
  const float* be11 = (const float*)d_in[4];
  const float* w12  = (const float*)d_in[5];
  const float* b12  = (const float*)d_in[6];
  const float* g12  = (const float*)d_in[7];
  const float* be12 = (const float*)d_in[8];
  const float* w13  = (const float*)d_in[9];
  const float* b13  = (const float*)d_in[10];
  const float* g13  = (const float*)d_in[11];
  const float* be13 = (const float*)d_in[12];
  const float* w21  = (const float*)d_in[13];
  const float* b21  = (const float*)d_in[14];
  const float* g21  = (const float*)d_in[15];
  const float* be21 = (const float*)d_in[16];
  const float* wh1  = (const float*)d_in[17];
  const float* bh1  = (const float*)d_in[18];
  const float* gh1  = (const float*)d_in[19];
  const float* beh1 = (const float*)d_in[20];
  const float* wh2  = (const float*)d_in[21];
  const float* bh2  = (const float*)d_in[22];
  const float* gh2  = (const float*)d_in[23];
  const float* beh2 = (const float*)d_in[24];
  const float* wh3  = (const float*)d_in[25];
  const float* bh3  = (const float*)d_in[26];
  const float* gh3  = (const float*)d_in[27];
  const float* beh3 = (const float*)d_in[28];
  const float* wh4  = (const float*)d_in[29];
  const float* bh4  = (const float*)d_in[30];

  char* ws = (char*)d_ws;
  int*    idx   = (int*)(ws + 0);                 // 1,310,720 B
  float*  loc   = (float*)(ws + 1310720);         // 3,932,160 B
  float*  V     = (float*)(ws + 5242880);         //   589,824 B
  float*  h     = (float*)(ws + 5832704);         // 83,886,080 B (fp32, in-place)
  u16*    wt    = (u16*)(ws + 5832704);           // 49,152 B (overlays h AFTER f3d)
  float*  f3d   = (float*)(ws + 89718784);        // 12,582,912 B
  float*  fdd2  = (float*)(ws + 102301696);       //  8,388,608 B
  u32*    y1k   = (u32*)(ws + 110690304);         //     32,768 B
  float*  y1n   = (float*)(ws + 110723072);       //     32,768 B
  float*  y2n   = (float*)(ws + 110755840);       //     16,384 B
  float*  y3n   = (float*)(ws + 110772224);       //      8,512 B
  double* stats = (double*)(ws + 110780736);      // 640 doubles
  float*  param = (float*)(ws + 110785856);       // 640 floats
  float*  out   = (float*)d_out;

  zero_kernel<<<32, 256, 0, stream>>>((u32*)stats, 1280, y1k, 8192);
  knn_kernel<<<4096, 256, 0, stream>>>(pos, idx);
  prep_kernel<<<256, 64, 0, stream>>>(pos, idx, loc, V);

  l1_kernel<<<1280, 256, 0, stream>>>(loc, w11, b11, h);
  stats64_kernel<<<256, 256, 0, stream>>>(h, stats);
  finalize_kernel<<<1, 256, 0, stream>>>(stats, 64, (double)EE, g11, be11, param);

  l23_kernel<<<4096, 256, 0, stream>>>(h, param, w12, b12, h);          // in-place
  stats64_kernel<<<256, 256, 0, stream>>>(h, stats + 128);
  finalize_kernel<<<1, 256, 0, stream>>>(stats + 128, 64, (double)EE, g12, be12, param + 128);

  l23_kernel<<<4096, 256, 0, stream>>>(h, param + 128, w13, b13, h);    // in-place
  stats64_kernel<<<256, 256, 0, stream>>>(h, stats + 256);
  finalize_kernel<<<1, 256, 0, stream>>>(stats + 256, 64, (double)EE, g13, be13, param + 256);

  f3d_kernel<<<4096, 256, 0, stream>>>(h, param + 256, loc, f3d);
  // h is dead now; wt overlays it
  wtcvt_kernel<<<96, 256, 0, stream>>>(w21, wt);
  dd2_kernel<<<4096, 256, 0, stream>>>(f3d, V, idx, wt, b21, fdd2, stats + 384);
  finalize_kernel<<<1, 256, 0, stream>>>(stats + 384, 128, (double)EE, g21, be21, param + 384);

  y1_kernel<<<4096, 256, 0, stream>>>(fdd2, param + 384, wh1, y1k);
  y1bn_kernel<<<4, 256, 0, stream>>>(y1k, bh1, gh1, beh1, y1n);

  head_kernel<<<8, 64, 0, stream>>>(y1n, wh2, bh2, gh2, beh2, y2n, 1024, 512);
  head_kernel<<<5, 64, 0, stream>>>(y2n, wh3, bh3, gh3, beh3, y3n, 512, 265);
  logits_kernel<<<1, 384, 0, stream>>>(y3n, wh4, bh4, out);
}

// Round 6
// 627.316 us; speedup vs baseline: 1.8772x; 1.0066x over previous
//
#include <hip/hip_runtime.h>

// ---------------------------------------------------------------------------
// Net_3152505995976: point-cloud classifier forward pass on MI355X.
// Round 6: dd2 memory-locality fix (119us -> target ~45us).
//   - cloud->XCD affinity swizzle: wk=(bid&7)*512+(bid>>3); XCD k owns
//     cloud k -> its 1.5MB f3d slice stays L2-resident (FETCH 46MB->14MB)
//   - W-fragments preloaded to registers (breg[2][6], static unroll);
//     sWT LDS + 2 barriers removed; LDS 58KB->33KB -> ~3 blk/CU
//   - MFMA step order unchanged -> bit-identical dd2 output
//   - everything else identical to the passing R5 kernel.
// ---------------------------------------------------------------------------

#define NEW_SLARTG 1

typedef unsigned short u16;
typedef unsigned int u32;
typedef unsigned long long u64;
typedef __attribute__((ext_vector_type(8))) short short8;
typedef __attribute__((ext_vector_type(4))) float f32x4;

#define BB 8
#define NNp 2048
#define KKn 20
#define NP 16384      // BB*NNp
#define EE 327680     // NP*KKn

// ---------------- small helpers ----------------
__device__ __forceinline__ u32 fkey(float f) {
  u32 u = __float_as_uint(f);
  return (u & 0x80000000u) ? ~u : (u | 0x80000000u);
}
__device__ __forceinline__ float funkey(u32 k) {
  u32 u = (k & 0x80000000u) ? (k ^ 0x80000000u) : ~k;
  return __uint_as_float(u);
}
__device__ __forceinline__ float f_sign(float a, float b) {
  return (b >= 0.f) ? fabsf(a) : -fabsf(a);
}
__device__ __forceinline__ u16 f2bf(float f) {
  u32 u = __float_as_uint(f);
  u32 r = (u + 0x7fffu + ((u >> 16) & 1u)) >> 16;
  return (u16)r;
}

__device__ __forceinline__ u64 sxor64(u64 v, int m) {
  union { u64 q; u32 d[2]; } a; a.q = v;
  a.d[0] = __shfl_xor(a.d[0], m);
  a.d[1] = __shfl_xor(a.d[1], m);
  return a.q;
}
__device__ __forceinline__ u64 sidx64(u64 v, int src) {
  union { u64 q; u32 d[2]; } a; a.q = v;
  a.d[0] = __shfl(a.d[0], src);
  a.d[1] = __shfl(a.d[1], src);
  return a.q;
}
// wave-wide bitonic sort, 64 u64 elements (1/lane), ascending
__device__ __forceinline__ void bsort64(u64& v, int lane) {
#pragma unroll
  for (int k = 2; k <= 64; k <<= 1) {
#pragma unroll
    for (int j = k >> 1; j > 0; j >>= 1) {
      u64 pv = sxor64(v, j);
      bool up = ((lane & k) == 0);
      bool lower = ((lane & j) == 0);
      bool keepmin = (lower == up);
      bool take = keepmin ? (pv < v) : (pv > v);
      v = take ? pv : v;
    }
  }
}

// ---------------- LAPACK fp32 replicas ----------------
__device__ float slapy2_(float x, float y) {
#pragma clang fp contract(off)
  float xa = fabsf(x), ya = fabsf(y);
  float w = fmaxf(xa, ya), z = fminf(xa, ya);
  if (z == 0.f) return w;
  float t = z / w;
  return w * sqrtf(1.0f + t * t);
}

__device__ void slartg_(float f, float g, float& c, float& s, float& r) {
#pragma clang fp contract(off)
#if NEW_SLARTG
  const float safmin = 1.17549435e-38f;
  const float safmax = 8.50705917e+37f;
  const float rtmin = 1.08420217e-19f;   // sqrt(safmin)
  const float rtmax = 6.52221171e+18f;   // sqrt(safmax/2)
  float f1 = fabsf(f), g1 = fabsf(g);
  if (g == 0.f) { c = 1.f; s = 0.f; r = f; }
  else if (f == 0.f) { c = 0.f; s = (g >= 0.f) ? 1.f : -1.f; r = g1; }
  else {
    float d;
    if (f1 > rtmin && f1 < rtmax && g1 > rtmin && g1 < rtmax) {
      d = sqrtf(f * f + g * g);
      c = f1 / d;
      r = (f >= 0.f) ? d : -d;
    } else {
      float uu = fminf(safmax, fmaxf(safmin, fmaxf(f1, g1)));
      float fs = f / uu, gs = g / uu;
      d = sqrtf(fs * fs + gs * gs);
      c = fabsf(fs) / d;
      r = ((f >= 0.f) ? d : -d) * uu;
    }
    s = g / r;
  }
#else
  if (g == 0.f) { c = 1.f; s = 0.f; r = f; }
  else if (f == 0.f) { c = 0.f; s = 1.f; r = g; }
  else {
    float f1 = f, g1 = g;
    r = sqrtf(f1 * f1 + g1 * g1);
    c = f1 / r;
    s = g1 / r;
    if (fabsf(f) > fabsf(g) && c < 0.f) { c = -c; s = -s; r = -r; }
  }
#endif
}

__device__ void slaev2_(float a, float b, float c, float& rt1, float& rt2,
                        float& cs1, float& sn1) {
#pragma clang fp contract(off)
  float sm = a + c;
  float df = a - c;
  float adf = fabsf(df);
  float tb = b + b;
  float ab = fabsf(tb);
  float acmx, acmn;
  if (fabsf(a) > fabsf(c)) { acmx = a; acmn = c; } else { acmx = c; acmn = a; }
  float rt;
  if (adf > ab) { float t = ab / adf; rt = adf * sqrtf(1.f + t * t); }
  else if (adf < ab) { float t = adf / ab; rt = ab * sqrtf(1.f + t * t); }
  else { rt = ab * sqrtf(2.f); }
  int sgn1;
  if (sm < 0.f) {
    rt1 = 0.5f * (sm - rt); sgn1 = -1;
    rt2 = (acmx / rt1) * acmn - (b / rt1) * b;
  } else if (sm > 0.f) {
    rt1 = 0.5f * (sm + rt); sgn1 = 1;
    rt2 = (acmx / rt1) * acmn - (b / rt1) * b;
  } else {
    rt1 = 0.5f * rt; rt2 = -0.5f * rt; sgn1 = 1;
  }
  float cs; int sgn2;
  if (df >= 0.f) { cs = df + rt; sgn2 = 1; } else { cs = df - rt; sgn2 = -1; }
  float acs = fabsf(cs);
  if (acs > ab) {
    float ct = -tb / cs;
    sn1 = 1.f / sqrtf(1.f + ct * ct);
    cs1 = ct * sn1;
  } else {
    if (ab == 0.f) { cs1 = 1.f; sn1 = 0.f; }
    else {
      float tn = -cs / tb;
      cs1 = 1.f / sqrtf(1.f + tn * tn);
      sn1 = tn * cs1;
    }
  }
  if (sgn1 == sgn2) { float tn = cs1; cs1 = -sn1; sn1 = tn; }
}

// ssteqr for n=3, compz='I' (z must be identity on entry)
__device__ void ssteqr3_(float* d, float* e, float z[3][3]) {
#pragma clang fp contract(off)
  const float eps = 5.9604645e-08f;
  const float eps2 = 3.5527137e-15f;
  const float safmin = 1.17549435e-38f;
  const int n = 3;
  const int nmaxit = 90;
  int jtot = 0;
  int l1 = 1;

  while (1) {
    if (l1 > n) break;
    if (l1 > 1) e[l1 - 2] = 0.f;
    int m = n;
    if (l1 <= n - 1) {
      for (int mm = l1; mm <= n - 1; ++mm) {
        float tst = fabsf(e[mm - 1]);
        if (tst == 0.f) { m = mm; break; }
        if (tst <= (sqrtf(fabsf(d[mm - 1])) * sqrtf(fabsf(d[mm]))) * eps) {
          e[mm - 1] = 0.f; m = mm; break;
        }
      }
    }
    int l = l1, lsv = l, lend = m, lendsv = lend;
    (void)lsv; (void)lendsv;
    l1 = m + 1;
    if (lend == l) continue;

    float anorm = 0.f;
    for (int i = l; i <= lend; ++i) anorm = fmaxf(anorm, fabsf(d[i - 1]));
    for (int i = l; i <= lend - 1; ++i) anorm = fmaxf(anorm, fabsf(e[i - 1]));
    if (anorm == 0.f) continue;

    if (fabsf(d[lend - 1]) < fabsf(d[l - 1])) { lend = lsv; l = lendsv; }

    if (lend > l) {
      // --- QL iteration ---
      while (1) {
        int m2 = lend;
        if (l != lend) {
          for (int mm = l; mm <= lend - 1; ++mm) {
            float tst = fabsf(e[mm - 1]); tst = tst * tst;
            if (tst <= (eps2 * fabsf(d[mm - 1])) * fabsf(d[mm]) + safmin) { m2 = mm; break; }
          }
        }
        if (m2 < lend) e[m2 - 1] = 0.f;
        float p = d[l - 1];
        if (m2 == l) {
          d[l - 1] = p; l += 1;
          if (l <= lend) continue;
          break;
        }
        if (m2 == l + 1) {
          float rt1, rt2, cc, ss;
          slaev2_(d[l - 1], e[l - 1], d[l], rt1, rt2, cc, ss);
          for (int i = 0; i < 3; ++i) {
            float temp = z[i][l];
            z[i][l] = cc * temp - ss * z[i][l - 1];
            z[i][l - 1] = ss * temp + cc * z[i][l - 1];
          }
          d[l - 1] = rt1; d[l] = rt2; e[l - 1] = 0.f;
          l += 2;
          if (l <= lend) continue;
          break;
        }
        if (jtot == nmaxit) break;
        jtot++;
        float g = (d[l] - p) / (2.f * e[l - 1]);
        float r = slapy2_(g, 1.f);
        g = d[m2 - 1] - p + (e[l - 1] / (g + f_sign(r, g)));
        float s = 1.f, c = 1.f;
        p = 0.f;
        float csv[2], snv[2];
        for (int i = m2 - 1; i >= l; --i) {
          float f = s * e[i - 1];
          float b = c * e[i - 1];
          slartg_(g, f, c, s, r);
          if (i != m2 - 1) e[i] = r;
          g = d[i] - p;
          r = (d[i - 1] - g) * s + (2.f * c) * b;
          p = s * r;
          d[i] = g + p;
          g = c * r - b;
          csv[i - l] = c; snv[i - l] = -s;
        }
        int cnt = m2 - l;
        for (int j = cnt; j >= 1; --j) {       // slasr 'R','V','B'
          float cj = csv[j - 1], sj = snv[j - 1];
          int c0 = (l - 1) + (j - 1);
          for (int i = 0; i < 3; ++i) {
            float temp = z[i][c0 + 1];
            z[i][c0 + 1] = cj * temp - sj * z[i][c0];
            z[i][c0] = sj * temp + cj * z[i][c0];
          }
        }
        d[l - 1] = d[l - 1] - p;
        e[l - 1] = g;
      }
    } else {
      // --- QR iteration ---
      while (1) {
        int m2 = lend;
        if (l != lend) {
          for (int mm = l; mm >= lend + 1; --mm) {
            float tst = fabsf(e[mm - 2]); tst = tst * tst;
            if (tst <= (eps2 * fabsf(d[mm - 1])) * fabsf(d[mm - 2]) + safmin) { m2 = mm; break; }
          }
        }
        if (m2 > lend) e[m2 - 2] = 0.f;
        float p = d[l - 1];
        if (m2 == l) {
          d[l - 1] = p; l -= 1;
          if (l >= lend) continue;
          break;
        }
        if (m2 == l - 1) {
          float rt1, rt2, cc, ss;
          slaev2_(d[l - 2], e[l - 2], d[l - 1], rt1, rt2, cc, ss);
          for (int i = 0; i < 3; ++i) {
            float temp = z[i][l - 1];
            z[i][l - 1] = cc * temp - ss * z[i][l - 2];
            z[i][l - 2] = ss * temp + cc * z[i][l - 2];
          }
          d[l - 2] = rt1; d[l - 1] = rt2; e[l - 2] = 0.f;
          l -= 2;
          if (l >= lend) continue;
          break;
        }
        if (jtot == nmaxit) break;
        jtot++;
        float g = (d[l - 2] - p) / (2.f * e[l - 2]);
        float r = slapy2_(g, 1.f);
        g = d[m2 - 1] - p + (e[l - 2] / (g + f_sign(r, g)));
        float s = 1.f, c = 1.f;
        p = 0.f;
        float csv[2], snv[2];
        for (int i = m2; i <= l - 1; ++i) {
          float f = s * e[i - 1];
          float b = c * e[i - 1];
          slartg_(g, f, c, s, r);
          if (i != m2) e[i - 2] = r;
          g = d[i - 1] - p;
          r = (d[i] - g) * s + (2.f * c) * b;
          p = s * r;
          d[i - 1] = g + p;
          g = c * r - b;
          csv[i - m2] = c; snv[i - m2] = s;
        }
        int cnt = l - m2;
        for (int j = 1; j <= cnt; ++j) {       // slasr 'R','V','F'
          float cj = csv[j - 1], sj = snv[j - 1];
          int c0 = (m2 - 1) + (j - 1);
          for (int i = 0; i < 3; ++i) {
            float temp = z[i][c0 + 1];
            z[i][c0 + 1] = cj * temp - sj * z[i][c0];
            z[i][c0] = sj * temp + cj * z[i][c0];
          }
        }
        d[l - 1] = d[l - 1] - p;
        e[l - 2] = g;
      }
    }
  }

  // selection sort ascending, swap eigenvector columns (LAPACK exact)
  for (int ii = 2; ii <= n; ++ii) {
    int i = ii - 1, k = i;
    float p = d[i - 1];
    for (int j = ii; j <= n; ++j)
      if (d[j - 1] < p) { k = j; p = d[j - 1]; }
    if (k != i) {
      d[k - 1] = d[i - 1]; d[i - 1] = p;
      for (int r2 = 0; r2 < 3; ++r2) {
        float t = z[r2][i - 1]; z[r2][i - 1] = z[r2][k - 1]; z[r2][k - 1] = t;
      }
    }
  }
}

// full ssyevd replica for 3x3 symmetric (lower entries), eigenvectors only
__device__ void eigh3_(float a00, float a10, float a11, float a20, float a21,
                       float a22, float V[3][3]) {
#pragma clang fp contract(off)
  float d0, d1, d2, e0, e1, tau1 = 0.f, v2 = 0.f;
  {
    float alpha = a10;
    float xnorm = fabsf(a20);
    if (xnorm == 0.f) {
      tau1 = 0.f; v2 = 0.f;
      e0 = alpha; d0 = a00; d1 = a11; d2 = a22; e1 = a21;
    } else {
      float beta = -f_sign(slapy2_(alpha, xnorm), alpha);
      tau1 = (beta - alpha) / beta;
      float inv = 1.0f / (alpha - beta);
      v2 = a20 * inv;
      float y0 = tau1 * a11;
      float y1v = tau1 * a21;
      float temp2 = a21 * v2;
      y0 = y0 + tau1 * temp2;
      y1v = y1v + (tau1 * v2) * a22;
      float dotyv = y0 * 1.f + y1v * v2;
      float al = (-0.5f * tau1) * dotyv;
      float w0 = y0 + al * 1.f;
      float w1 = y1v + al * v2;
      a11 = (a11 + 1.f * (-w0)) + w0 * (-1.f);
      a21 = (a21 + v2 * (-w0)) + w1 * (-1.f);
      a22 = (a22 + v2 * (-w1)) + w1 * (-v2);
      e0 = beta; d0 = a00; d1 = a11; d2 = a22; e1 = a21;
    }
  }
  float dd[3] = { d0, d1, d2 };
  float ee[2] = { e0, e1 };
  float z[3][3] = { {1.f,0.f,0.f},{0.f,1.f,0.f},{0.f,0.f,1.f} };
  ssteqr3_(dd, ee, z);
  if (tau1 != 0.f) {
    for (int j = 0; j < 3; ++j) {
      float wj = z[1][j] * 1.f + z[2][j] * v2;
      float temp = -tau1 * wj;
      z[1][j] = z[1][j] + 1.f * temp;
      z[2][j] = z[2][j] + v2 * temp;
    }
  }
  for (int r = 0; r < 3; ++r)
    for (int cix = 0; cix < 3; ++cix)
      V[r][cix] = z[r][cix];
}

// ---------------- kernels ----------------

__global__ void zero_kernel(u32* p1, int n1, u32* p2, int n2) {
  int t = blockIdx.x * blockDim.x + threadIdx.x;
  if (t < n1) p1[t] = 0u;
  if (t < n2) p2[t] = 0u;
}

// exact KNN top-20 per point: threshold-select + wave bitonic sort.
__global__ __launch_bounds__(256) void knn_kernel(const float* __restrict__ pos,
                                                  int* __restrict__ idx) {
#pragma clang fp contract(off)
  __shared__ u64 cke[4][128];
  int w = threadIdx.x >> 6;
  int lane = threadIdx.x & 63;
  int wid = blockIdx.x * 4 + w;
  int b = wid >> 11;
  int n = wid & 2047;
  const float* pc = pos + (size_t)b * NNp * 3;
  float qx = pc[n * 3 + 0], qy = pc[n * 3 + 1], qz = pc[n * 3 + 2];
  float d2n = (qx * qx + qy * qy) + qz * qz;

  // pass A: 32 keys per lane, in registers; track wave-min
  u32 kreg[32];
  u32 mk = 0xFFFFFFFFu;
#pragma unroll
  for (int t = 0; t < 32; ++t) {
    int m = lane + 64 * t;
    float x = pc[m * 3 + 0], y = pc[m * 3 + 1], zc = pc[m * 3 + 2];
    float d2m = (x * x + y * y) + zc * zc;
    float dot = (qx * x + qy * y) + qz * zc;
    float dist = (d2n + d2m) - 2.0f * dot;
    u32 key = fkey(dist);
    if (m == n) key = 0xFFFFFFFFu;   // self-exclusion (== +1e10 diag in ref)
    kreg[t] = key;
    mk = key < mk ? key : mk;
  }
#pragma unroll
  for (int off = 32; off; off >>= 1) {
    u32 o = __shfl_xor(mk, off);
    mk = o < mk ? o : mk;
  }

  // threshold search: find hi with 20 <= count(key<=hi) <= 128
  u32 lo_b = mk - 1u, hi_b = 0xFFFFFFFEu;
  int c_hi = 2047;
  float tf = funkey(mk) * 7.368f;     // count ~ T^1.5 => rank-20 guess
  u32 T = fkey(tf);
  if (T < mk) T = mk;
  if (T > 0xFFFFFFFEu) T = 0xFFFFFFFEu;
  for (int it = 0; it < 48; ++it) {
    int cnt = 0;
#pragma unroll
    for (int t = 0; t < 32; ++t) cnt += (kreg[t] <= T) ? 1 : 0;
#pragma unroll
    for (int off = 32; off; off >>= 1) cnt += __shfl_xor(cnt, off);
    if (cnt >= 20) {
      hi_b = T; c_hi = cnt;
      if (cnt <= 128) break;
    } else {
      lo_b = T;
    }
    if (hi_b <= lo_b + 1u) break;
    u32 Tn;
    if (it < 12) {
      float tfc = funkey(T);
      int cc = cnt < 1 ? 1 : cnt;
      float guess = tfc * __builtin_exp2f(0.66667f * __builtin_log2f(45.0f / (float)cc));
      Tn = fkey(guess);
      if (!(Tn > lo_b && Tn < hi_b)) Tn = lo_b + ((hi_b - lo_b) >> 1);
    } else {
      Tn = lo_b + ((hi_b - lo_b) >> 1);   // pure bisection
    }
    T = Tn;
  }

  // collect survivors (key <= hi_b) in m-ascending order via ballot prefix
  u64* ck = cke[w];
  u32 base = 0;
#pragma unroll
  for (int t = 0; t < 32; ++t) {
    bool pass = kreg[t] <= hi_b;
    u64 ball = __ballot(pass);
    if (pass) {
      u32 posn = base + (u32)__popcll(ball & ((1ull << lane) - 1ull));
      if (posn < 128u)
        ck[posn] = ((u64)kreg[t] << 32) | (u32)(lane + 64 * t);
    }
    base += (u32)__popcll(ball);
  }
  if (base > 128u) {
    base = 0;
#pragma unroll
    for (int t = 0; t < 32; ++t) {
      bool pass = kreg[t] <= lo_b;
      u64 ball = __ballot(pass);
      if (pass) {
        u32 posn = base + (u32)__popcll(ball & ((1ull << lane) - 1ull));
        ck[posn] = ((u64)kreg[t] << 32) | (u32)(lane + 64 * t);
      }
      base += (u32)__popcll(ball);
    }
#pragma unroll
    for (int t = 0; t < 32; ++t) {
      bool pass = (kreg[t] > lo_b) && (kreg[t] <= hi_b);
      u64 ball = __ballot(pass);
      if (pass) {
        u32 posn = base + (u32)__popcll(ball & ((1ull << lane) - 1ull));
        if (posn < 128u)
          ck[posn] = ((u64)kreg[t] << 32) | (u32)(lane + 64 * t);
      }
      base += (u32)__popcll(ball);
    }
  }
  u32 ctot = base < 128u ? base : 128u;

  // sort survivors ascending by (key, m); take first 20
  u64 e0 = (lane < (int)ctot) ? ck[lane] : ~0ull;
  bsort64(e0, lane);
  if (ctot > 64u) {
    u64 e1 = (lane + 64 < (int)ctot) ? ck[lane + 64] : ~0ull;
    bsort64(e1, lane);
    u64 r = sidx64(e1, 63 - lane);          // reverse second run
    u64 mn = r < e0 ? r : e0;               // bitonic
#pragma unroll
    for (int j = 32; j > 0; j >>= 1) {      // clean
      u64 pv = sxor64(mn, j);
      bool lower2 = ((lane & j) == 0);
      bool take = lower2 ? (pv < mn) : (pv > mn);
      mn = take ? pv : mn;
    }
    e0 = mn;
  }
  if (lane < 20)
    idx[(size_t)wid * 20 + lane] = (int)(u32)(e0 & 0xFFFFFFFFull);
}

// per-point: covariance, LAPACK-replica eigh, loc = rel @ V
__global__ __launch_bounds__(64) void prep_kernel(const float* __restrict__ pos,
                                                  const int* __restrict__ idx,
                                                  float* __restrict__ loc,
                                                  float* __restrict__ Vout) {
#pragma clang fp contract(off)
  int p = blockIdx.x * 64 + threadIdx.x;
  int b = p >> 11, n = p & 2047;
  const float* pc = pos + (size_t)b * NNp * 3;
  float qx = pc[n * 3 + 0], qy = pc[n * 3 + 1], qz = pc[n * 3 + 2];
  const int* ip = idx + (size_t)p * 20;
  float c00 = 0, c01 = 0, c02 = 0, c11 = 0, c12 = 0, c22 = 0;
  for (int k = 0; k < 20; ++k) {
    int j = ip[k];
    float rx = pc[j * 3 + 0] - qx, ry = pc[j * 3 + 1] - qy, rz = pc[j * 3 + 2] - qz;
    c00 += rx * rx; c01 += rx * ry; c02 += rx * rz;
    c11 += ry * ry; c12 += ry * rz; c22 += rz * rz;
  }
  float Vm[3][3];
  eigh3_(c00, c01, c11, c02, c12, c22, Vm);
  float* vp = Vout + (size_t)p * 9;
  for (int d = 0; d < 3; ++d)
    for (int e = 0; e < 3; ++e) vp[d * 3 + e] = Vm[d][e];
  for (int k = 0; k < 20; ++k) {
    int j = ip[k];
    float rx = pc[j * 3 + 0] - qx, ry = pc[j * 3 + 1] - qy, rz = pc[j * 3 + 2] - qz;
    float l0 = rx * Vm[0][0] + ry * Vm[1][0] + rz * Vm[2][0];
    float l1 = rx * Vm[0][1] + ry * Vm[1][1] + rz * Vm[2][1];
    float l2 = rx * Vm[0][2] + ry * Vm[1][2] + rz * Vm[2][2];
    size_t e = ((size_t)p * 20 + k) * 3;
    loc[e + 0] = l0; loc[e + 1] = l1; loc[e + 2] = l2;
  }
}

// layer1: [E,3]@[3,64]+b, relu, store fp32
__global__ __launch_bounds__(256) void l1_kernel(const float* __restrict__ loc,
                                                 const float* __restrict__ W,
                                                 const float* __restrict__ bias,
                                                 float* __restrict__ h1) {
  __shared__ float sW[192];
  __shared__ float sB[64];
  int t = threadIdx.x;
  if (t < 192) sW[t] = W[t];
  if (t < 64) sB[t] = bias[t];
  __syncthreads();
  size_t e = (size_t)blockIdx.x * 256 + t;
  float x0 = loc[e * 3 + 0], x1 = loc[e * 3 + 1], x2 = loc[e * 3 + 2];
  for (int c0 = 0; c0 < 64; c0 += 4) {
    float4 st;
    st.x = fmaxf(sB[c0 + 0] + x0 * sW[c0 + 0] + x1 * sW[64 + c0 + 0] + x2 * sW[128 + c0 + 0], 0.f);
    st.y = fmaxf(sB[c0 + 1] + x0 * sW[c0 + 1] + x1 * sW[64 + c0 + 1] + x2 * sW[128 + c0 + 1], 0.f);
    st.z = fmaxf(sB[c0 + 2] + x0 * sW[c0 + 2] + x1 * sW[64 + c0 + 2] + x2 * sW[128 + c0 + 2], 0.f);
    st.w = fmaxf(sB[c0 + 3] + x0 * sW[c0 + 3] + x1 * sW[64 + c0 + 3] + x2 * sW[128 + c0 + 3], 0.f);
    *(float4*)&h1[e * 64 + c0] = st;
  }
}

// per-channel sum/sumsq of an fp32 [E,64] buffer -> double atomics
__global__ __launch_bounds__(256) void stats64_kernel(const float* __restrict__ h,
                                                      double* __restrict__ sums) {
  __shared__ float red[512];
  int t = threadIdx.x;
  int c = t & 63, w = t >> 6;
  size_t rbase = (size_t)blockIdx.x * 1280 + w;
  float s = 0.f, q = 0.f;
  for (int r = 0; r < 1280; r += 4) {
    float v = h[(rbase + r) * 64 + c];
    s += v; q += v * v;
  }
  red[t] = s; red[256 + t] = q;
  __syncthreads();
  if (t < 64) {
    float S = red[t] + red[64 + t] + red[128 + t] + red[192 + t];
    float Q = red[256 + t] + red[320 + t] + red[384 + t] + red[448 + t];
    atomicAdd(&sums[t], (double)S);
    atomicAdd(&sums[64 + t], (double)Q);
  }
}

// sums -> per-channel affine (scale, shift) implementing train-mode BN
__global__ void finalize_kernel(const double* __restrict__ sums, int nch,
                                double count, const float* __restrict__ g,
                                const float* __restrict__ be,
                                float* __restrict__ out) {
  int c = blockIdx.x * blockDim.x + threadIdx.x;
  if (c < nch) {
    double m = sums[c] / count;
    double var = sums[nch + c] / count - m * m;
    double inv = 1.0 / sqrt(var + 1e-5);
    double sc = (double)g[c] * inv;
    out[c] = (float)sc;
    out[nch + c] = (float)((double)be[c] - m * sc);
  }
}

// layers 2/3: fp32 [E,64] @ [64,64]+b, relu, IN-PLACE capable (hin==hout)
__global__ __launch_bounds__(256) void l23_kernel(const float* __restrict__ hin,
                                                  const float* __restrict__ ss,
                                                  const float* __restrict__ W,
                                                  const float* __restrict__ bias,
                                                  float* __restrict__ hout) {
  __shared__ float xT[64 * 84];
  int t = threadIdx.x;
  size_t e0 = (size_t)blockIdx.x * 80;
  for (int v = t; v < 80 * 64; v += 256) {
    int el = v >> 6, c = v & 63;
    float val = hin[(e0 + el) * 64 + c];
    val = val * ss[c] + ss[64 + c];
    xT[c * 84 + el] = val;
  }
  __syncthreads();
  int og = t & 15, eg = t >> 4;
  int o0 = og * 4, eb = eg * 5;
  float acc[5][4];
#pragma unroll
  for (int a = 0; a < 5; ++a)
#pragma unroll
    for (int o = 0; o < 4; ++o) acc[a][o] = 0.f;
  for (int i = 0; i < 64; ++i) {
    float4 w4 = *(const float4*)&W[i * 64 + o0];
    float xx[5];
#pragma unroll
    for (int a = 0; a < 5; ++a) xx[a] = xT[i * 84 + eb + a];
#pragma unroll
    for (int a = 0; a < 5; ++a) {
      acc[a][0] += xx[a] * w4.x;
      acc[a][1] += xx[a] * w4.y;
      acc[a][2] += xx[a] * w4.z;
      acc[a][3] += xx[a] * w4.w;
    }
  }
  float4 b4 = *(const float4*)&bias[o0];
#pragma unroll
  for (int a = 0; a < 5; ++a) {
    size_t e = e0 + eb + a;
    float4 st;
    st.x = fmaxf(acc[a][0] + b4.x, 0.f);
    st.y = fmaxf(acc[a][1] + b4.y, 0.f);
    st.z = fmaxf(acc[a][2] + b4.z, 0.f);
    st.w = fmaxf(acc[a][3] + b4.w, 0.f);
    *(float4*)&hout[e * 64 + o0] = st;
  }
}

// f3d[p][c][d] = max_k h3n[p,k,c] * loc[p,k,d]
__global__ __launch_bounds__(256) void f3d_kernel(const float* __restrict__ h3,
                                                  const float* __restrict__ ss3,
                                                  const float* __restrict__ loc,
                                                  float* __restrict__ f3d) {
  int t = threadIdx.x;
  int p = blockIdx.x * 4 + (t >> 6);
  int c = t & 63;
  float sc = ss3[c], sh = ss3[64 + c];
  float m0 = -__builtin_inff(), m1 = m0, m2 = m0;
  size_t eb = (size_t)p * 20;
  for (int k = 0; k < 20; ++k) {
    size_t e = eb + k;
    float h = h3[e * 64 + c] * sc + sh;
    float l0 = loc[e * 3 + 0], l1 = loc[e * 3 + 1], l2 = loc[e * 3 + 2];
    m0 = fmaxf(m0, h * l0);
    m1 = fmaxf(m1, h * l1);
    m2 = fmaxf(m2, h * l2);
  }
  size_t o = (size_t)p * 192 + c * 3;
  f3d[o + 0] = m0; f3d[o + 1] = m1; f3d[o + 2] = m2;
}

// W21 [192][128] fp32 -> WT bf16 [128][192] (n-major rows, k contiguous)
__global__ __launch_bounds__(256) void wtcvt_kernel(const float* __restrict__ W,
                                                    u16* __restrict__ wt) {
  int id = blockIdx.x * 256 + threadIdx.x;
  if (id < 192 * 128) {
    int n = id / 192, k = id - n * 192;
    wt[id] = f2bf(W[(size_t)k * 128 + n]);
  }
}

// DD2 via bf16 MFMA: cloud->XCD swizzle; gather f3d[idx], rotate by V ->
// X bf16 LDS [80][200]; W-fragments preloaded to registers from global
// (L2-resident 49KB); GEMM [80,192]@[192,128]; bias+relu+maxpool+stats
// fused in-register. MFMA step order identical to R5 (bit-identical out).
__global__ __launch_bounds__(256) void dd2_kernel(const float* __restrict__ f3d,
                                                  const float* __restrict__ Vmat,
                                                  const int* __restrict__ idx,
                                                  const u16* __restrict__ wt,
                                                  const float* __restrict__ bias,
                                                  float* __restrict__ fdd2,
                                                  double* __restrict__ s4) {
  __shared__ u16 sX[80 * 200];     // X bf16, row stride 200 (400B, 16B aligned)
  __shared__ float sV[36];
  __shared__ int sJ[80];
  int t = threadIdx.x;
  // cloud->XCD affinity: XCD k (= bid%8 under round-robin dispatch) gets
  // the contiguous block range of cloud k -> per-XCD L2 holds one cloud.
  int wk = (blockIdx.x & 7) * 512 + (blockIdx.x >> 3);
  int p0 = wk * 4;
  int bcl = p0 >> 11;              // cloud (4 points never straddle clouds)

  int w = t >> 6, l = t & 63;
  int lr = l & 15, lg = l >> 4;

  // preload B fragments: lane holds cols (w*32+nt*16+lr), k-slices lg*8+...
  short8 breg[2][6];
#pragma unroll
  for (int nt = 0; nt < 2; ++nt)
#pragma unroll
    for (int s = 0; s < 6; ++s) {
      const int kk = (s / 3) * 96 + (s % 3) * 32 + lg * 8;
      breg[nt][s] = *(const short8*)&wt[(w * 32 + nt * 16 + lr) * 192 + kk];
    }

  if (t < 36) sV[t] = Vmat[(size_t)p0 * 9 + t];
  if (t < 80) sJ[t] = ((bcl << 11) + idx[(size_t)p0 * 20 + t]) * 192;
  __syncthreads();

  // build X: el = edge 0..79, c2 = channel-pair 0..31
  for (int v = t; v < 80 * 32; v += 256) {
    int el = v >> 5, c2 = v & 31;
    int pp = el / 20;
    const float* fp = f3d + (size_t)sJ[el] + 6 * c2;
    float f0 = fp[0], f1 = fp[1], f2 = fp[2];
    float f3 = fp[3], f4 = fp[4], f5 = fp[5];
    const float* Vp = &sV[pp * 9];
    float x0 = f0 * Vp[0] + f1 * Vp[3] + f2 * Vp[6];
    float x1 = f0 * Vp[1] + f1 * Vp[4] + f2 * Vp[7];
    float x2 = f0 * Vp[2] + f1 * Vp[5] + f2 * Vp[8];
    float y0 = f3 * Vp[0] + f4 * Vp[3] + f5 * Vp[6];
    float y1 = f3 * Vp[1] + f4 * Vp[4] + f5 * Vp[7];
    float y2 = f3 * Vp[2] + f4 * Vp[5] + f5 * Vp[8];
    u32* xp = (u32*)&sX[el * 200 + 6 * c2];
    xp[0] = (u32)f2bf(x0) | ((u32)f2bf(x1) << 16);
    xp[1] = (u32)f2bf(x2) | ((u32)f2bf(y0) << 16);
    xp[2] = (u32)f2bf(y1) | ((u32)f2bf(y2) << 16);
  }
  __syncthreads();

  f32x4 acc[5][2];
#pragma unroll
  for (int mt = 0; mt < 5; ++mt) {
    acc[mt][0] = (f32x4)(0.f);
    acc[mt][1] = (f32x4)(0.f);
  }

  // K-steps in the same order as R5 (H0:KS0,1,2 then H1:KS0,1,2)
#pragma unroll
  for (int s = 0; s < 6; ++s) {
    const int kbase = (s / 3) * 96 + (s % 3) * 32 + lg * 8;
#pragma unroll
    for (int mt = 0; mt < 5; ++mt) {
      short8 a = *(const short8*)&sX[(mt * 16 + lr) * 200 + kbase];
      acc[mt][0] = __builtin_amdgcn_mfma_f32_16x16x32_bf16(a, breg[0][s], acc[mt][0], 0, 0, 0);
      acc[mt][1] = __builtin_amdgcn_mfma_f32_16x16x32_bf16(a, breg[1][s], acc[mt][1], 0, 0, 0);
    }
  }

  // epilogue: z = relu(acc+bias); maxpool over k per point; per-channel stats
#pragma unroll
  for (int nt = 0; nt < 2; ++nt) {
    int col = w * 32 + nt * 16 + lr;
    float bs = bias[col];
    float pm0 = 0.f, pm1 = 0.f, pm2 = 0.f, pm3 = 0.f;
    float s = 0.f, q = 0.f;
#pragma unroll
    for (int mt = 0; mt < 5; ++mt) {
#pragma unroll
      for (int r = 0; r < 4; ++r) {
        int edge = mt * 16 + lg * 4 + r;   // 0..79, exact (no padding)
        float z = fmaxf(acc[mt][nt][r] + bs, 0.f);
        pm0 = fmaxf(pm0, (edge < 20) ? z : 0.f);
        pm1 = fmaxf(pm1, (edge >= 20 && edge < 40) ? z : 0.f);
        pm2 = fmaxf(pm2, (edge >= 40 && edge < 60) ? z : 0.f);
        pm3 = fmaxf(pm3, (edge >= 60) ? z : 0.f);
        s += z; q += z * z;
      }
    }
#pragma unroll
    for (int off = 16; off < 64; off <<= 1) {
      pm0 = fmaxf(pm0, __shfl_xor(pm0, off));
      pm1 = fmaxf(pm1, __shfl_xor(pm1, off));
      pm2 = fmaxf(pm2, __shfl_xor(pm2, off));
      pm3 = fmaxf(pm3, __shfl_xor(pm3, off));
      s += __shfl_xor(s, off);
      q += __shfl_xor(q, off);
    }
    if (l < 16) {
      fdd2[(size_t)(p0 + 0) * 128 + col] = pm0;
      fdd2[(size_t)(p0 + 1) * 128 + col] = pm1;
      fdd2[(size_t)(p0 + 2) * 128 + col] = pm2;
      fdd2[(size_t)(p0 + 3) * 128 + col] = pm3;
      atomicAdd(&s4[col], (double)s);
      atomicAdd(&s4[128 + col], (double)q);
    }
  }
}

// y1: register-tiled fp32 GEMM [16384,128]@[128,1024] with fused max over n.
__global__ __launch_bounds__(256) void y1_kernel(const float* __restrict__ fdd2,
                                                 const float* __restrict__ ss4,
                                                 const float* __restrict__ wh1,
                                                 u32* __restrict__ y1key) {
  __shared__ float sX[128][68];   // [k][point]
  __shared__ float sW[128][68];   // [k][chan]
  int t = threadIdx.x;
  int bid = blockIdx.x;
  int mtile = bid & 255;
  int ntile = bid >> 8;
  int cl = mtile >> 5;                 // cloud
  size_t pbase = (size_t)mtile * 64;   // global point base
  int c0 = ntile * 64;

  {
    int kq = t & 31, pp = t >> 5;
    float4 sc4 = *(const float4*)&ss4[kq * 4];
    float4 sh4 = *(const float4*)&ss4[128 + kq * 4];
    for (int p = pp; p < 64; p += 8) {
      float4 x4 = *(const float4*)&fdd2[(pbase + p) * 128 + kq * 4];
      sX[kq * 4 + 0][p] = x4.x * sc4.x + sh4.x;
      sX[kq * 4 + 1][p] = x4.y * sc4.y + sh4.y;
      sX[kq * 4 + 2][p] = x4.z * sc4.z + sh4.z;
      sX[kq * 4 + 3][p] = x4.w * sc4.w + sh4.w;
    }
  }
  {
    int cq = t & 15, rr = t >> 4;
    for (int r = rr; r < 128; r += 16) {
      float4 w4 = *(const float4*)&wh1[(size_t)r * 1024 + c0 + cq * 4];
      *(float4*)&sW[r][cq * 4] = w4;
    }
  }
  __syncthreads();

  int mg = t >> 4, ng = t & 15;
  int m0 = mg * 4, n0 = ng * 4;
  float acc[4][4];
#pragma unroll
  for (int i = 0; i < 4; ++i)
#pragma unroll
    for (int j = 0; j < 4; ++j) acc[i][j] = 0.f;
  for (int k = 0; k < 128; ++k) {
    float4 x4 = *(const float4*)&sX[k][m0];
    float4 w4 = *(const float4*)&sW[k][n0];
    acc[0][0] += x4.x * w4.x; acc[0][1] += x4.x * w4.y;
    acc[0][2] += x4.x * w4.z; acc[0][3] += x4.x * w4.w;
    acc[1][0] += x4.y * w4.x; acc[1][1] += x4.y * w4.y;
    acc[1][2] += x4.y * w4.z; acc[1][3] += x4.y * w4.w;
    acc[2][0] += x4.z * w4.x; acc[2][1] += x4.z * w4.y;
    acc[2][2] += x4.z * w4.z; acc[2][3] += x4.z * w4.w;
    acc[3][0] += x4.w * w4.x; acc[3][1] += x4.w * w4.y;
    acc[3][2] += x4.w * w4.z; acc[3][3] += x4.w * w4.w;
  }
  __syncthreads();
  float* red = &sX[0][0];
#pragma unroll
  for (int j = 0; j < 4; ++j) {
    float v = fmaxf(fmaxf(acc[0][j], acc[1][j]), fmaxf(acc[2][j], acc[3][j]));
    red[(n0 + j) * 16 + mg] = v;
  }
  __syncthreads();
  if (t < 64) {
    float m = red[t * 16];
#pragma unroll
    for (int i = 1; i < 16; ++i) m = fmaxf(m, red[t * 16 + i]);
    atomicMax(&y1key[(size_t)cl * 1024 + c0 + t], fkey(m));
  }
}

// y1 decode + bias + relu + BN over 8 clouds
__global__ void y1bn_kernel(const u32* __restrict__ y1key,
                            const float* __restrict__ bh1,
                            const float* __restrict__ g,
                            const float* __restrict__ be,
                            float* __restrict__ y1n) {
  int c = blockIdx.x * 256 + threadIdx.x;
  if (c >= 1024) return;
  float bs = bh1[c];
  float v[8]; double s = 0.0;
#pragma unroll
  for (int b = 0; b < 8; ++b) {
    v[b] = fmaxf(funkey(y1key[b * 1024 + c]) + bs, 0.f);
    s += (double)v[b];
  }
  double m = s / 8.0, q = 0.0;
#pragma unroll
  for (int b = 0; b < 8; ++b) { double d = (double)v[b] - m; q += d * d; }
  q /= 8.0;
  double inv = 1.0 / sqrt(q + 1e-5);
  double sg = (double)g[c] * inv;
#pragma unroll
  for (int b = 0; b < 8; ++b)
    y1n[b * 1024 + c] = (float)(((double)v[b] - m) * sg + (double)be[c]);
}

// small dense layer: [8,IN]@[IN,OUT]+b, relu, BN over 8 -> out
__global__ __launch_bounds__(64) void head_kernel(const float* __restrict__ yin,
                                                  const float* __restrict__ W,
                                                  const float* __restrict__ bias,
                                                  const float* __restrict__ g,
                                                  const float* __restrict__ be,
                                                  float* __restrict__ yout,
                                                  int INn, int OUTn) {
  __shared__ float sx[8192];
  int t = threadIdx.x;
  for (int v = t; v < 8 * INn; v += 64) sx[v] = yin[v];
  __syncthreads();
  int o = blockIdx.x * 64 + t;
  if (o >= OUTn) return;
  float acc[8];
#pragma unroll
  for (int b = 0; b < 8; ++b) acc[b] = 0.f;
  for (int i = 0; i < INn; ++i) {
    float w = W[(size_t)i * OUTn + o];
#pragma unroll
    for (int b = 0; b < 8; ++b) acc[b] += sx[b * INn + i] * w;
  }
  float bs = bias[o];
  float v[8]; double s = 0.0;
#pragma unroll
  for (int b = 0; b < 8; ++b) { v[b] = fmaxf(acc[b] + bs, 0.f); s += (double)v[b]; }
  double m = s / 8.0, q = 0.0;
#pragma unroll
  for (int b = 0; b < 8; ++b) { double d = (double)v[b] - m; q += d * d; }
  q /= 8.0;
  double inv = 1.0 / sqrt(q + 1e-5);
  double sg = (double)g[o] * inv;
#pragma unroll
  for (int b = 0; b < 8; ++b)
    yout[(size_t)b * OUTn + o] = (float)(((double)v[b] - m) * sg + (double)be[o]);
}

// final linear [8,265]@[265,40]+b then log_softmax per row
__global__ __launch_bounds__(384) void logits_kernel(const float* __restrict__ y3n,
                                                     const float* __restrict__ W,
                                                     const float* __restrict__ bias,
                                                     float* __restrict__ out) {
  __shared__ float sy[8 * 265];
  __shared__ float slog[320];
  __shared__ float sm[8], sl[8];
  int t = threadIdx.x;
  for (int v = t; v < 8 * 265; v += 384) sy[v] = y3n[v];
  __syncthreads();
  if (t < 320) {
    int b = t / 40, o = t % 40;
    float acc = 0.f;
    for (int i = 0; i < 265; ++i) acc += sy[b * 265 + i] * W[i * 40 + o];
    slog[t] = acc + bias[o];
  }
  __syncthreads();
  if (t < 8) {
    float m = slog[t * 40];
    for (int o = 1; o < 40; ++o) m = fmaxf(m, slog[t * 40 + o]);
    float s = 0.f;
    for (int o = 0; o < 40; ++o) s += expf(slog[t * 40 + o] - m);
    sm[t] = m; sl[t] = logf(s);
  }
  __syncthreads();
  if (t < 320) {
    int b = t / 40;
    out[t] = slog[t] - sm[b] - sl[b];
  }
}

// ---------------- launcher ----------------
extern "C" void kernel_launch(void* const* d_in, const int* in_sizes, int n_in,
                              void* d_out, int out_size, void* d_ws, size_t ws_size,
                              hipStream_t stream) {
  (void)in_sizes; (void)n_in; (void)out_size; (void)ws_size;
  const float* pos  = (const float*)d_in[0];
  const float* w11  = (const float*)d_in[1];
  const float* b11  = (const float*)d_in[2];
  const float* g11  = (const float*)d_in[3];
  const float* be11 = (const float*)d_in[4];
  const float* w12  = (const float*)d_in[5];
  const float* b12  = (const float*)d_in[6];
  const float* g12  = (const float*)d_in[7];
  const float* be12 = (const float*)d_in[8];
  const float* w13  = (const float*)d_in[9];
  const float* b13  = (const float*)d_in[10];
  const float* g13  = (const float*)d_in[11];
  const float* be13 = (const float*)d_in[12];
  const float* w21  = (const float*)d_in[13];
  const float* b21  = (const float*)d_in[14];
  const float* g21  = (const float*)d_in[15];
  const float* be21 = (const float*)d_in[16];
  const float* wh1  = (const float*)d_in[17];
  const float* bh1  = (const float*)d_in[18];
  const float* gh1  = (const float*)d_in[19];
  const float* beh1 = (const float*)d_in[20];
  const float* wh2  = (const float*)d_in[21];
  const float* bh2  = (const float*)d_in[22];
  const float* gh2  = (const float*)d_in[23];
  const float* beh2 = (const float*)d_in[24];
  const float* wh3  = (const float*)d_in[25];
  const float* bh3  = (const float*)d_in[26];
  const float* gh3  = (const float*)d_in[27];
  const float* beh3 = (const float*)d_in[28];
  const float* wh4  = (const float*)d_in[29];
  const float* bh4  = (const float*)d_in[30];

  char* ws = (char*)d_ws;
  int*    idx   = (int*)(ws + 0);                 // 1,310,720 B
  float*  loc   = (float*)(ws + 1310720);         // 3,932,160 B
  float*  V     = (float*)(ws + 5242880);         //   589,824 B
  float*  h     = (float*)(ws + 5832704);         // 83,886,080 B (fp32, in-place)
  u16*    wt    = (u16*)(ws + 5832704);           // 49,152 B (overlays h AFTER f3d)
  float*  f3d   = (float*)(ws + 89718784);        // 12,582,912 B
  float*  fdd2  = (float*)(ws + 102301696);       //  8,388,608 B
  u32*    y1k   = (u32*)(ws + 110690304);         //     32,768 B
  float*  y1n   = (float*)(ws + 110723072);       //     32,768 B
  float*  y2n   = (float*)(ws + 110755840);       //     16,384 B
  float*  y3n   = (float*)(ws + 110772224);       //      8,512 B
  double* stats = (double*)(ws + 110780736);      // 640 doubles
  float*  param = (float*)(ws + 110785856);       // 640 floats
  float*  out   = (float*)d_out;

  zero_kernel<<<32, 256, 0, stream>>>((u32*)stats, 1280, y1k, 8192);
  knn_kernel<<<4096, 256, 0, stream>>>(pos, idx);
  prep_kernel<<<256, 64, 0, stream>>>(pos, idx, loc, V);

  l1_kernel<<<1280, 256, 0, stream>>>(loc, w11, b11, h);
  stats64_kernel<<<256, 256, 0, stream>>>(h, stats);
  finalize_kernel<<<1, 256, 0, stream>>>(stats, 64, (double)EE, g11, be11, param);

  l23_kernel<<<4096, 256, 0, stream>>>(h, param, w12, b12, h);          // in-place
  stats64_kernel<<<256, 256, 0, stream>>>(h, stats + 128);
  finalize_kernel<<<1, 256, 0, stream>>>(stats + 128, 64, (double)EE, g12, be12, param + 128);

  l23_kernel<<<4096, 256, 0, stream>>>(h, param + 128, w13, b13, h);    // in-place
  stats64_kernel<<<256, 256, 0, stream>>>(h, stats + 256);
  finalize_kernel<<<1, 256, 0, stream>>>(stats + 256, 64, (double)EE, g13, be13, param + 256);

  f3d_kernel<<<4096, 256, 0, stream>>>(h, param + 256, loc, f3d);
  // h is dead now; wt overlays it
  wtcvt_kernel<<<96, 256, 0, stream>>>(w21, wt);
  dd2_kernel<<<4096, 256, 0, stream>>>(f3d, V, idx, wt, b21, fdd2, stats + 384);
  finalize_kernel<<<1, 256, 0, stream>>>(stats + 384, 128, (double)EE, g21, be21, param + 384);

  y1_kernel<<<4096, 256, 0, stream>>>(fdd2, param + 384, wh1, y1k);
  y1bn_kernel<<<4, 256, 0, stream>>>(y1k, bh1, gh1, beh1, y1n);

  head_kernel<<<8, 64, 0, stream>>>(y1n, wh2, bh2, gh2, beh2, y2n, 1024, 512);
  head_kernel<<<5, 64, 0, stream>>>(y2n, wh3, bh3, gh3, beh3, y3n, 512, 265);
  logits_kernel<<<1, 384, 0, stream>>>(y3n, wh4, bh4, out);
}

// Round 7
// 489.086 us; speedup vs baseline: 2.4078x; 1.2826x over previous
//
#include <hip/hip_runtime.h>

// ---------------------------------------------------------------------------
// Net_3152505995976: point-cloud classifier forward pass on MI355X.
// Round 7: kill the two ~112us latency floors.
//   - dd2 stats: 64-way bucketed fp64 atomics (chain 4096 -> 64/address);
//     finalize64 reduces buckets in fixed order (deterministic)
//   - head layers: K-split GEMM (grid (OUT/64)x8, 256 thr, LDS-staged x,
//     coalesced W, fixed-order reductions) + tiny reduce+BN kernel
//   - everything else identical to the passing R6 kernel.
// ---------------------------------------------------------------------------

#define NEW_SLARTG 1

typedef unsigned short u16;
typedef unsigned int u32;
typedef unsigned long long u64;
typedef __attribute__((ext_vector_type(8))) short short8;
typedef __attribute__((ext_vector_type(4))) float f32x4;

#define BB 8
#define NNp 2048
#define KKn 20
#define NP 16384      // BB*NNp
#define EE 327680     // NP*KKn

// ---------------- small helpers ----------------
__device__ __forceinline__ u32 fkey(float f) {
  u32 u = __float_as_uint(f);
  return (u & 0x80000000u) ? ~u : (u | 0x80000000u);
}
__device__ __forceinline__ float funkey(u32 k) {
  u32 u = (k & 0x80000000u) ? (k ^ 0x80000000u) : ~k;
  return __uint_as_float(u);
}
__device__ __forceinline__ float f_sign(float a, float b) {
  return (b >= 0.f) ? fabsf(a) : -fabsf(a);
}
__device__ __forceinline__ u16 f2bf(float f) {
  u32 u = __float_as_uint(f);
  u32 r = (u + 0x7fffu + ((u >> 16) & 1u)) >> 16;
  return (u16)r;
}

__device__ __forceinline__ u64 sxor64(u64 v, int m) {
  union { u64 q; u32 d[2]; } a; a.q = v;
  a.d[0] = __shfl_xor(a.d[0], m);
  a.d[1] = __shfl_xor(a.d[1], m);
  return a.q;
}
__device__ __forceinline__ u64 sidx64(u64 v, int src) {
  union { u64 q; u32 d[2]; } a; a.q = v;
  a.d[0] = __shfl(a.d[0], src);
  a.d[1] = __shfl(a.d[1], src);
  return a.q;
}
// wave-wide bitonic sort, 64 u64 elements (1/lane), ascending
__device__ __forceinline__ void bsort64(u64& v, int lane) {
#pragma unroll
  for (int k = 2; k <= 64; k <<= 1) {
#pragma unroll
    for (int j = k >> 1; j > 0; j >>= 1) {
      u64 pv = sxor64(v, j);
      bool up = ((lane & k) == 0);
      bool lower = ((lane & j) == 0);
      bool keepmin = (lower == up);
      bool take = keepmin ? (pv < v) : (pv > v);
      v = take ? pv : v;
    }
  }
}

// ---------------- LAPACK fp32 replicas ----------------
__device__ float slapy2_(float x, float y) {
#pragma clang fp contract(off)
  float xa = fabsf(x), ya = fabsf(y);
  float w = fmaxf(xa, ya), z = fminf(xa, ya);
  if (z == 0.f) return w;
  float t = z / w;
  return w * sqrtf(1.0f + t * t);
}

__device__ void slartg_(float f, float g, float& c, float& s, float& r) {
#pragma clang fp contract(off)
#if NEW_SLARTG
  const float safmin = 1.17549435e-38f;
  const float safmax = 8.50705917e+37f;
  const float rtmin = 1.08420217e-19f;   // sqrt(safmin)
  const float rtmax = 6.52221171e+18f;   // sqrt(safmax/2)
  float f1 = fabsf(f), g1 = fabsf(g);
  if (g == 0.f) { c = 1.f; s = 0.f; r = f; }
  else if (f == 0.f) { c = 0.f; s = (g >= 0.f) ? 1.f : -1.f; r = g1; }
  else {
    float d;
    if (f1 > rtmin && f1 < rtmax && g1 > rtmin && g1 < rtmax) {
      d = sqrtf(f * f + g * g);
      c = f1 / d;
      r = (f >= 0.f) ? d : -d;
    } else {
      float uu = fminf(safmax, fmaxf(safmin, fmaxf(f1, g1)));
      float fs = f / uu, gs = g / uu;
      d = sqrtf(fs * fs + gs * gs);
      c = fabsf(fs) / d;
      r = ((f >= 0.f) ? d : -d) * uu;
    }
    s = g / r;
  }
#else
  if (g == 0.f) { c = 1.f; s = 0.f; r = f; }
  else if (f == 0.f) { c = 0.f; s = 1.f; r = g; }
  else {
    float f1 = f, g1 = g;
    r = sqrtf(f1 * f1 + g1 * g1);
    c = f1 / r;
    s = g1 / r;
    if (fabsf(f) > fabsf(g) && c < 0.f) { c = -c; s = -s; r = -r; }
  }
#endif
}

__device__ void slaev2_(float a, float b, float c, float& rt1, float& rt2,
                        float& cs1, float& sn1) {
#pragma clang fp contract(off)
  float sm = a + c;
  float df = a - c;
  float adf = fabsf(df);
  float tb = b + b;
  float ab = fabsf(tb);
  float acmx, acmn;
  if (fabsf(a) > fabsf(c)) { acmx = a; acmn = c; } else { acmx = c; acmn = a; }
  float rt;
  if (adf > ab) { float t = ab / adf; rt = adf * sqrtf(1.f + t * t); }
  else if (adf < ab) { float t = adf / ab; rt = ab * sqrtf(1.f + t * t); }
  else { rt = ab * sqrtf(2.f); }
  int sgn1;
  if (sm < 0.f) {
    rt1 = 0.5f * (sm - rt); sgn1 = -1;
    rt2 = (acmx / rt1) * acmn - (b / rt1) * b;
  } else if (sm > 0.f) {
    rt1 = 0.5f * (sm + rt); sgn1 = 1;
    rt2 = (acmx / rt1) * acmn - (b / rt1) * b;
  } else {
    rt1 = 0.5f * rt; rt2 = -0.5f * rt; sgn1 = 1;
  }
  float cs; int sgn2;
  if (df >= 0.f) { cs = df + rt; sgn2 = 1; } else { cs = df - rt; sgn2 = -1; }
  float acs = fabsf(cs);
  if (acs > ab) {
    float ct = -tb / cs;
    sn1 = 1.f / sqrtf(1.f + ct * ct);
    cs1 = ct * sn1;
  } else {
    if (ab == 0.f) { cs1 = 1.f; sn1 = 0.f; }
    else {
      float tn = -cs / tb;
      cs1 = 1.f / sqrtf(1.f + tn * tn);
      sn1 = tn * cs1;
    }
  }
  if (sgn1 == sgn2) { float tn = cs1; cs1 = -sn1; sn1 = tn; }
}

// ssteqr for n=3, compz='I' (z must be identity on entry)
__device__ void ssteqr3_(float* d, float* e, float z[3][3]) {
#pragma clang fp contract(off)
  const float eps = 5.9604645e-08f;
  const float eps2 = 3.5527137e-15f;
  const float safmin = 1.17549435e-38f;
  const int n = 3;
  const int nmaxit = 90;
  int jtot = 0;
  int l1 = 1;

  while (1) {
    if (l1 > n) break;
    if (l1 > 1) e[l1 - 2] = 0.f;
    int m = n;
    if (l1 <= n - 1) {
      for (int mm = l1; mm <= n - 1; ++mm) {
        float tst = fabsf(e[mm - 1]);
        if (tst == 0.f) { m = mm; break; }
        if (tst <= (sqrtf(fabsf(d[mm - 1])) * sqrtf(fabsf(d[mm]))) * eps) {
          e[mm - 1] = 0.f; m = mm; break;
        }
      }
    }
    int l = l1, lsv = l, lend = m, lendsv = lend;
    (void)lsv; (void)lendsv;
    l1 = m + 1;
    if (lend == l) continue;

    float anorm = 0.f;
    for (int i = l; i <= lend; ++i) anorm = fmaxf(anorm, fabsf(d[i - 1]));
    for (int i = l; i <= lend - 1; ++i) anorm = fmaxf(anorm, fabsf(e[i - 1]));
    if (anorm == 0.f) continue;

    if (fabsf(d[lend - 1]) < fabsf(d[l - 1])) { lend = lsv; l = lendsv; }

    if (lend > l) {
      // --- QL iteration ---
      while (1) {
        int m2 = lend;
        if (l != lend) {
          for (int mm = l; mm <= lend - 1; ++mm) {
            float tst = fabsf(e[mm - 1]); tst = tst * tst;
            if (tst <= (eps2 * fabsf(d[mm - 1])) * fabsf(d[mm]) + safmin) { m2 = mm; break; }
          }
        }
        if (m2 < lend) e[m2 - 1] = 0.f;
        float p = d[l - 1];
        if (m2 == l) {
          d[l - 1] = p; l += 1;
          if (l <= lend) continue;
          break;
        }
        if (m2 == l + 1) {
          float rt1, rt2, cc, ss;
          slaev2_(d[l - 1], e[l - 1], d[l], rt1, rt2, cc, ss);
          for (int i = 0; i < 3; ++i) {
            float temp = z[i][l];
            z[i][l] = cc * temp - ss * z[i][l - 1];
            z[i][l - 1] = ss * temp + cc * z[i][l - 1];
          }
          d[l - 1] = rt1; d[l] = rt2; e[l - 1] = 0.f;
          l += 2;
          if (l <= lend) continue;
          break;
        }
        if (jtot == nmaxit) break;
        jtot++;
        float g = (d[l] - p) / (2.f * e[l - 1]);
        float r = slapy2_(g, 1.f);
        g = d[m2 - 1] - p + (e[l - 1] / (g + f_sign(r, g)));
        float s = 1.f, c = 1.f;
        p = 0.f;
        float csv[2], snv[2];
        for (int i = m2 - 1; i >= l; --i) {
          float f = s * e[i - 1];
          float b = c * e[i - 1];
          slartg_(g, f, c, s, r);
          if (i != m2 - 1) e[i] = r;
          g = d[i] - p;
          r = (d[i - 1] - g) * s + (2.f * c) * b;
          p = s * r;
          d[i] = g + p;
          g = c * r - b;
          csv[i - l] = c; snv[i - l] = -s;
        }
        int cnt = m2 - l;
        for (int j = cnt; j >= 1; --j) {       // slasr 'R','V','B'
          float cj = csv[j - 1], sj = snv[j - 1];
          int c0 = (l - 1) + (j - 1);
          for (int i = 0; i < 3; ++i) {
            float temp = z[i][c0 + 1];
            z[i][c0 + 1] = cj * temp - sj * z[i][c0];
            z[i][c0] = sj * temp + cj * z[i][c0];
          }
        }
        d[l - 1] = d[l - 1] - p;
        e[l - 1] = g;
      }
    } else {
      // --- QR iteration ---
      while (1) {
        int m2 = lend;
        if (l != lend) {
          for (int mm = l; mm >= lend + 1; --mm) {
            float tst = fabsf(e[mm - 2]); tst = tst * tst;
            if (tst <= (eps2 * fabsf(d[mm - 1])) * fabsf(d[mm - 2]) + safmin) { m2 = mm; break; }
          }
        }
        if (m2 > lend) e[m2 - 2] = 0.f;
        float p = d[l - 1];
        if (m2 == l) {
          d[l - 1] = p; l -= 1;
          if (l >= lend) continue;
          break;
        }
        if (m2 == l - 1) {
          float rt1, rt2, cc, ss;
          slaev2_(d[l - 2], e[l - 2], d[l - 1], rt1, rt2, cc, ss);
          for (int i = 0; i < 3; ++i) {
            float temp = z[i][l - 1];
            z[i][l - 1] = cc * temp - ss * z[i][l - 2];
            z[i][l - 2] = ss * temp + cc * z[i][l - 2];
          }
          d[l - 2] = rt1; d[l - 1] = rt2; e[l - 2] = 0.f;
          l -= 2;
          if (l >= lend) continue;
          break;
        }
        if (jtot == nmaxit) break;
        jtot++;
        float g = (d[l - 2] - p) / (2.f * e[l - 2]);
        float r = slapy2_(g, 1.f);
        g = d[m2 - 1] - p + (e[l - 2] / (g + f_sign(r, g)));
        float s = 1.f, c = 1.f;
        p = 0.f;
        float csv[2], snv[2];
        for (int i = m2; i <= l - 1; ++i) {
          float f = s * e[i - 1];
          float b = c * e[i - 1];
          slartg_(g, f, c, s, r);
          if (i != m2) e[i - 2] = r;
          g = d[i - 1] - p;
          r = (d[i] - g) * s + (2.f * c) * b;
          p = s * r;
          d[i - 1] = g + p;
          g = c * r - b;
          csv[i - m2] = c; snv[i - m2] = s;
        }
        int cnt = l - m2;
        for (int j = 1; j <= cnt; ++j) {       // slasr 'R','V','F'
          float cj = csv[j - 1], sj = snv[j - 1];
          int c0 = (m2 - 1) + (j - 1);
          for (int i = 0; i < 3; ++i) {
            float temp = z[i][c0 + 1];
            z[i][c0 + 1] = cj * temp - sj * z[i][c0];
            z[i][c0] = sj * temp + cj * z[i][c0];
          }
        }
        d[l - 1] = d[l - 1] - p;
        e[l - 2] = g;
      }
    }
  }

  // selection sort ascending, swap eigenvector columns (LAPACK exact)
  for (int ii = 2; ii <= n; ++ii) {
    int i = ii - 1, k = i;
    float p = d[i - 1];
    for (int j = ii; j <= n; ++j)
      if (d[j - 1] < p) { k = j; p = d[j - 1]; }
    if (k != i) {
      d[k - 1] = d[i - 1]; d[i - 1] = p;
      for (int r2 = 0; r2 < 3; ++r2) {
        float t = z[r2][i - 1]; z[r2][i - 1] = z[r2][k - 1]; z[r2][k - 1] = t;
      }
    }
  }
}

// full ssyevd replica for 3x3 symmetric (lower entries), eigenvectors only
__device__ void eigh3_(float a00, float a10, float a11, float a20, float a21,
                       float a22, float V[3][3]) {
#pragma clang fp contract(off)
  float d0, d1, d2, e0, e1, tau1 = 0.f, v2 = 0.f;
  {
    float alpha = a10;
    float xnorm = fabsf(a20);
    if (xnorm == 0.f) {
      tau1 = 0.f; v2 = 0.f;
      e0 = alpha; d0 = a00; d1 = a11; d2 = a22; e1 = a21;
    } else {
      float beta = -f_sign(slapy2_(alpha, xnorm), alpha);
      tau1 = (beta - alpha) / beta;
      float inv = 1.0f / (alpha - beta);
      v2 = a20 * inv;
      float y0 = tau1 * a11;
      float y1v = tau1 * a21;
      float temp2 = a21 * v2;
      y0 = y0 + tau1 * temp2;
      y1v = y1v + (tau1 * v2) * a22;
      float dotyv = y0 * 1.f + y1v * v2;
      float al = (-0.5f * tau1) * dotyv;
      float w0 = y0 + al * 1.f;
      float w1 = y1v + al * v2;
      a11 = (a11 + 1.f * (-w0)) + w0 * (-1.f);
      a21 = (a21 + v2 * (-w0)) + w1 * (-1.f);
      a22 = (a22 + v2 * (-w1)) + w1 * (-v2);
      e0 = beta; d0 = a00; d1 = a11; d2 = a22; e1 = a21;
    }
  }
  float dd[3] = { d0, d1, d2 };
  float ee[2] = { e0, e1 };
  float z[3][3] = { {1.f,0.f,0.f},{0.f,1.f,0.f},{0.f,0.f,1.f} };
  ssteqr3_(dd, ee, z);
  if (tau1 != 0.f) {
    for (int j = 0; j < 3; ++j) {
      float wj = z[1][j] * 1.f + z[2][j] * v2;
      float temp = -tau1 * wj;
      z[1][j] = z[1][j] + 1.f * temp;
      z[2][j] = z[2][j] + v2 * temp;
    }
  }
  for (int r = 0; r < 3; ++r)
    for (int cix = 0; cix < 3; ++cix)
      V[r][cix] = z[r][cix];
}

// ---------------- kernels ----------------

__global__ void zero_kernel(u32* p1, int n1, u32* p2, int n2) {
  int t = blockIdx.x * blockDim.x + threadIdx.x;
  if (t < n1) p1[t] = 0u;
  if (t < n2) p2[t] = 0u;
}

// exact KNN top-20 per point: threshold-select + wave bitonic sort.
__global__ __launch_bounds__(256) void knn_kernel(const float* __restrict__ pos,
                                                  int* __restrict__ idx) {
#pragma clang fp contract(off)
  __shared__ u64 cke[4][128];
  int w = threadIdx.x >> 6;
  int lane = threadIdx.x & 63;
  int wid = blockIdx.x * 4 + w;
  int b = wid >> 11;
  int n = wid & 2047;
  const float* pc = pos + (size_t)b * NNp * 3;
  float qx = pc[n * 3 + 0], qy = pc[n * 3 + 1], qz = pc[n * 3 + 2];
  float d2n = (qx * qx + qy * qy) + qz * qz;

  // pass A: 32 keys per lane, in registers; track wave-min
  u32 kreg[32];
  u32 mk = 0xFFFFFFFFu;
#pragma unroll
  for (int t = 0; t < 32; ++t) {
    int m = lane + 64 * t;
    float x = pc[m * 3 + 0], y = pc[m * 3 + 1], zc = pc[m * 3 + 2];
    float d2m = (x * x + y * y) + zc * zc;
    float dot = (qx * x + qy * y) + qz * zc;
    float dist = (d2n + d2m) - 2.0f * dot;
    u32 key = fkey(dist);
    if (m == n) key = 0xFFFFFFFFu;   // self-exclusion (== +1e10 diag in ref)
    kreg[t] = key;
    mk = key < mk ? key : mk;
  }
#pragma unroll
  for (int off = 32; off; off >>= 1) {
    u32 o = __shfl_xor(mk, off);
    mk = o < mk ? o : mk;
  }

  // threshold search: find hi with 20 <= count(key<=hi) <= 128
  u32 lo_b = mk - 1u, hi_b = 0xFFFFFFFEu;
  int c_hi = 2047;
  float tf = funkey(mk) * 7.368f;     // count ~ T^1.5 => rank-20 guess
  u32 T = fkey(tf);
  if (T < mk) T = mk;
  if (T > 0xFFFFFFFEu) T = 0xFFFFFFFEu;
  for (int it = 0; it < 48; ++it) {
    int cnt = 0;
#pragma unroll
    for (int t = 0; t < 32; ++t) cnt += (kreg[t] <= T) ? 1 : 0;
#pragma unroll
    for (int off = 32; off; off >>= 1) cnt += __shfl_xor(cnt, off);
    if (cnt >= 20) {
      hi_b = T; c_hi = cnt;
      if (cnt <= 128) break;
    } else {
      lo_b = T;
    }
    if (hi_b <= lo_b + 1u) break;
    u32 Tn;
    if (it < 12) {
      float tfc = funkey(T);
      int cc = cnt < 1 ? 1 : cnt;
      float guess = tfc * __builtin_exp2f(0.66667f * __builtin_log2f(45.0f / (float)cc));
      Tn = fkey(guess);
      if (!(Tn > lo_b && Tn < hi_b)) Tn = lo_b + ((hi_b - lo_b) >> 1);
    } else {
      Tn = lo_b + ((hi_b - lo_b) >> 1);   // pure bisection
    }
    T = Tn;
  }

  // collect survivors (key <= hi_b) in m-ascending order via ballot prefix
  u64* ck = cke[w];
  u32 base = 0;
#pragma unroll
  for (int t = 0; t < 32; ++t) {
    bool pass = kreg[t] <= hi_b;
    u64 ball = __ballot(pass);
    if (pass) {
      u32 posn = base + (u32)__popcll(ball & ((1ull << lane) - 1ull));
      if (posn < 128u)
        ck[posn] = ((u64)kreg[t] << 32) | (u32)(lane + 64 * t);
    }
    base += (u32)__popcll(ball);
  }
  if (base > 128u) {
    base = 0;
#pragma unroll
    for (int t = 0; t < 32; ++t) {
      bool pass = kreg[t] <= lo_b;
      u64 ball = __ballot(pass);
      if (pass) {
        u32 posn = base + (u32)__popcll(ball & ((1ull << lane) - 1ull));
        ck[posn] = ((u64)kreg[t] << 32) | (u32)(lane + 64 * t);
      }
      base += (u32)__popcll(ball);
    }
#pragma unroll
    for (int t = 0; t < 32; ++t) {
      bool pass = (kreg[t] > lo_b) && (kreg[t] <= hi_b);
      u64 ball = __ballot(pass);
      if (pass) {
        u32 posn = base + (u32)__popcll(ball & ((1ull << lane) - 1ull));
        if (posn < 128u)
          ck[posn] = ((u64)kreg[t] << 32) | (u32)(lane + 64 * t);
      }
      base += (u32)__popcll(ball);
    }
  }
  u32 ctot = base < 128u ? base : 128u;

  // sort survivors ascending by (key, m); take first 20
  u64 e0 = (lane < (int)ctot) ? ck[lane] : ~0ull;
  bsort64(e0, lane);
  if (ctot > 64u) {
    u64 e1 = (lane + 64 < (int)ctot) ? ck[lane + 64] : ~0ull;
    bsort64(e1, lane);
    u64 r = sidx64(e1, 63 - lane);          // reverse second run
    u64 mn = r < e0 ? r : e0;               // bitonic
#pragma unroll
    for (int j = 32; j > 0; j >>= 1) {      // clean
      u64 pv = sxor64(mn, j);
      bool lower2 = ((lane & j) == 0);
      bool take = lower2 ? (pv < mn) : (pv > mn);
      mn = take ? pv : mn;
    }
    e0 = mn;
  }
  if (lane < 20)
    idx[(size_t)wid * 20 + lane] = (int)(u32)(e0 & 0xFFFFFFFFull);
}

// per-point: covariance, LAPACK-replica eigh, loc = rel @ V
__global__ __launch_bounds__(64) void prep_kernel(const float* __restrict__ pos,
                                                  const int* __restrict__ idx,
                                                  float* __restrict__ loc,
                                                  float* __restrict__ Vout) {
#pragma clang fp contract(off)
  int p = blockIdx.x * 64 + threadIdx.x;
  int b = p >> 11, n = p & 2047;
  const float* pc = pos + (size_t)b * NNp * 3;
  float qx = pc[n * 3 + 0], qy = pc[n * 3 + 1], qz = pc[n * 3 + 2];
  const int* ip = idx + (size_t)p * 20;
  float c00 = 0, c01 = 0, c02 = 0, c11 = 0, c12 = 0, c22 = 0;
  for (int k = 0; k < 20; ++k) {
    int j = ip[k];
    float rx = pc[j * 3 + 0] - qx, ry = pc[j * 3 + 1] - qy, rz = pc[j * 3 + 2] - qz;
    c00 += rx * rx; c01 += rx * ry; c02 += rx * rz;
    c11 += ry * ry; c12 += ry * rz; c22 += rz * rz;
  }
  float Vm[3][3];
  eigh3_(c00, c01, c11, c02, c12, c22, Vm);
  float* vp = Vout + (size_t)p * 9;
  for (int d = 0; d < 3; ++d)
    for (int e = 0; e < 3; ++e) vp[d * 3 + e] = Vm[d][e];
  for (int k = 0; k < 20; ++k) {
    int j = ip[k];
    float rx = pc[j * 3 + 0] - qx, ry = pc[j * 3 + 1] - qy, rz = pc[j * 3 + 2] - qz;
    float l0 = rx * Vm[0][0] + ry * Vm[1][0] + rz * Vm[2][0];
    float l1 = rx * Vm[0][1] + ry * Vm[1][1] + rz * Vm[2][1];
    float l2 = rx * Vm[0][2] + ry * Vm[1][2] + rz * Vm[2][2];
    size_t e = ((size_t)p * 20 + k) * 3;
    loc[e + 0] = l0; loc[e + 1] = l1; loc[e + 2] = l2;
  }
}

// layer1: [E,3]@[3,64]+b, relu, store fp32
__global__ __launch_bounds__(256) void l1_kernel(const float* __restrict__ loc,
                                                 const float* __restrict__ W,
                                                 const float* __restrict__ bias,
                                                 float* __restrict__ h1) {
  __shared__ float sW[192];
  __shared__ float sB[64];
  int t = threadIdx.x;
  if (t < 192) sW[t] = W[t];
  if (t < 64) sB[t] = bias[t];
  __syncthreads();
  size_t e = (size_t)blockIdx.x * 256 + t;
  float x0 = loc[e * 3 + 0], x1 = loc[e * 3 + 1], x2 = loc[e * 3 + 2];
  for (int c0 = 0; c0 < 64; c0 += 4) {
    float4 st;
    st.x = fmaxf(sB[c0 + 0] + x0 * sW[c0 + 0] + x1 * sW[64 + c0 + 0] + x2 * sW[128 + c0 + 0], 0.f);
    st.y = fmaxf(sB[c0 + 1] + x0 * sW[c0 + 1] + x1 * sW[64 + c0 + 1] + x2 * sW[128 + c0 + 1], 0.f);
    st.z = fmaxf(sB[c0 + 2] + x0 * sW[c0 + 2] + x1 * sW[64 + c0 + 2] + x2 * sW[128 + c0 + 2], 0.f);
    st.w = fmaxf(sB[c0 + 3] + x0 * sW[c0 + 3] + x1 * sW[64 + c0 + 3] + x2 * sW[128 + c0 + 3], 0.f);
    *(float4*)&h1[e * 64 + c0] = st;
  }
}

// per-channel sum/sumsq of an fp32 [E,64] buffer -> double atomics
__global__ __launch_bounds__(256) void stats64_kernel(const float* __restrict__ h,
                                                      double* __restrict__ sums) {
  __shared__ float red[512];
  int t = threadIdx.x;
  int c = t & 63, w = t >> 6;
  size_t rbase = (size_t)blockIdx.x * 1280 + w;
  float s = 0.f, q = 0.f;
  for (int r = 0; r < 1280; r += 4) {
    float v = h[(rbase + r) * 64 + c];
    s += v; q += v * v;
  }
  red[t] = s; red[256 + t] = q;
  __syncthreads();
  if (t < 64) {
    float S = red[t] + red[64 + t] + red[128 + t] + red[192 + t];
    float Q = red[256 + t] + red[320 + t] + red[384 + t] + red[448 + t];
    atomicAdd(&sums[t], (double)S);
    atomicAdd(&sums[64 + t], (double)Q);
  }
}

// sums -> per-channel affine (scale, shift) implementing train-mode BN
__global__ void finalize_kernel(const double* __restrict__ sums, int nch,
                                double count, const float* __restrict__ g,
                                const float* __restrict__ be,
                                float* __restrict__ out) {
  int c = blockIdx.x * blockDim.x + threadIdx.x;
  if (c < nch) {
    double m = sums[c] / count;
    double var = sums[nch + c] / count - m * m;
    double inv = 1.0 / sqrt(var + 1e-5);
    double sc = (double)g[c] * inv;
    out[c] = (float)sc;
    out[nch + c] = (float)((double)be[c] - m * sc);
  }
}

// 64-bucket stats -> per-channel affine for BN4 (fixed-order bucket reduce)
__global__ void finalize64_kernel(const double* __restrict__ s4b,
                                  const float* __restrict__ g,
                                  const float* __restrict__ be,
                                  float* __restrict__ outp) {
  int c = threadIdx.x;   // 128 threads
  double s = 0.0, q = 0.0;
  for (int buk = 0; buk < 64; ++buk) {
    s += s4b[buk * 256 + c];
    q += s4b[buk * 256 + 128 + c];
  }
  double m = s / (double)EE;
  double var = q / (double)EE - m * m;
  double inv = 1.0 / sqrt(var + 1e-5);
  double sc = (double)g[c] * inv;
  outp[c] = (float)sc;
  outp[128 + c] = (float)((double)be[c] - m * sc);
}

// layers 2/3: fp32 [E,64] @ [64,64]+b, relu, IN-PLACE capable (hin==hout)
__global__ __launch_bounds__(256) void l23_kernel(const float* __restrict__ hin,
                                                  const float* __restrict__ ss,
                                                  const float* __restrict__ W,
                                                  const float* __restrict__ bias,
                                                  float* __restrict__ hout) {
  __shared__ float xT[64 * 84];
  int t = threadIdx.x;
  size_t e0 = (size_t)blockIdx.x * 80;
  for (int v = t; v < 80 * 64; v += 256) {
    int el = v >> 6, c = v & 63;
    float val = hin[(e0 + el) * 64 + c];
    val = val * ss[c] + ss[64 + c];
    xT[c * 84 + el] = val;
  }
  __syncthreads();
  int og = t & 15, eg = t >> 4;
  int o0 = og * 4, eb = eg * 5;
  float acc[5][4];
#pragma unroll
  for (int a = 0; a < 5; ++a)
#pragma unroll
    for (int o = 0; o < 4; ++o) acc[a][o] = 0.f;
  for (int i = 0; i < 64; ++i) {
    float4 w4 = *(const float4*)&W[i * 64 + o0];
    float xx[5];
#pragma unroll
    for (int a = 0; a < 5; ++a) xx[a] = xT[i * 84 + eb + a];
#pragma unroll
    for (int a = 0; a < 5; ++a) {
      acc[a][0] += xx[a] * w4.x;
      acc[a][1] += xx[a] * w4.y;
      acc[a][2] += xx[a] * w4.z;
      acc[a][3] += xx[a] * w4.w;
    }
  }
  float4 b4 = *(const float4*)&bias[o0];
#pragma unroll
  for (int a = 0; a < 5; ++a) {
    size_t e = e0 + eb + a;
    float4 st;
    st.x = fmaxf(acc[a][0] + b4.x, 0.f);
    st.y = fmaxf(acc[a][1] + b4.y, 0.f);
    st.z = fmaxf(acc[a][2] + b4.z, 0.f);
    st.w = fmaxf(acc[a][3] + b4.w, 0.f);
    *(float4*)&hout[e * 64 + o0] = st;
  }
}

// f3d[p][c][d] = max_k h3n[p,k,c] * loc[p,k,d]
__global__ __launch_bounds__(256) void f3d_kernel(const float* __restrict__ h3,
                                                  const float* __restrict__ ss3,
                                                  const float* __restrict__ loc,
                                                  float* __restrict__ f3d) {
  int t = threadIdx.x;
  int p = blockIdx.x * 4 + (t >> 6);
  int c = t & 63;
  float sc = ss3[c], sh = ss3[64 + c];
  float m0 = -__builtin_inff(), m1 = m0, m2 = m0;
  size_t eb = (size_t)p * 20;
  for (int k = 0; k < 20; ++k) {
    size_t e = eb + k;
    float h = h3[e * 64 + c] * sc + sh;
    float l0 = loc[e * 3 + 0], l1 = loc[e * 3 + 1], l2 = loc[e * 3 + 2];
    m0 = fmaxf(m0, h * l0);
    m1 = fmaxf(m1, h * l1);
    m2 = fmaxf(m2, h * l2);
  }
  size_t o = (size_t)p * 192 + c * 3;
  f3d[o + 0] = m0; f3d[o + 1] = m1; f3d[o + 2] = m2;
}

// W21 [192][128] fp32 -> WT bf16 [128][192]; also zeroes the s4b buckets
__global__ __launch_bounds__(256) void wtcvt_kernel(const float* __restrict__ W,
                                                    u16* __restrict__ wt,
                                                    double* __restrict__ s4b) {
  int id = blockIdx.x * 256 + threadIdx.x;
  if (id < 192 * 128) {
    int n = id / 192, k = id - n * 192;
    wt[id] = f2bf(W[(size_t)k * 128 + n]);
  }
  if (id < 64 * 256) s4b[id] = 0.0;
}

// DD2 via bf16 MFMA: cloud->XCD swizzle; gather f3d[idx], rotate by V ->
// X bf16 LDS [80][200]; W-fragments in registers; GEMM [80,192]@[192,128];
// bias+relu+maxpool+stats fused; stats -> 64-way bucketed fp64 atomics.
__global__ __launch_bounds__(256) void dd2_kernel(const float* __restrict__ f3d,
                                                  const float* __restrict__ Vmat,
                                                  const int* __restrict__ idx,
                                                  const u16* __restrict__ wt,
                                                  const float* __restrict__ bias,
                                                  float* __restrict__ fdd2,
                                                  double* __restrict__ s4b) {
  __shared__ u16 sX[80 * 200];     // X bf16, row stride 200 (400B, 16B aligned)
  __shared__ float sV[36];
  __shared__ int sJ[80];
  int t = threadIdx.x;
  // cloud->XCD affinity: XCD k (= bid%8 under round-robin dispatch) gets
  // the contiguous block range of cloud k -> per-XCD L2 holds one cloud.
  int wk = (blockIdx.x & 7) * 512 + (blockIdx.x >> 3);
  int p0 = wk * 4;
  int bcl = p0 >> 11;              // cloud (4 points never straddle clouds)
  int buk = ((int)blockIdx.x & 63) << 8;   // stats bucket base

  int w = t >> 6, l = t & 63;
  int lr = l & 15, lg = l >> 4;

  // preload B fragments: lane holds cols (w*32+nt*16+lr), k-slices lg*8+...
  short8 breg[2][6];
#pragma unroll
  for (int nt = 0; nt < 2; ++nt)
#pragma unroll
    for (int s = 0; s < 6; ++s) {
      const int kk = (s / 3) * 96 + (s % 3) * 32 + lg * 8;
      breg[nt][s] = *(const short8*)&wt[(w * 32 + nt * 16 + lr) * 192 + kk];
    }

  if (t < 36) sV[t] = Vmat[(size_t)p0 * 9 + t];
  if (t < 80) sJ[t] = ((bcl << 11) + idx[(size_t)p0 * 20 + t]) * 192;
  __syncthreads();

  // build X: el = edge 0..79, c2 = channel-pair 0..31
  for (int v = t; v < 80 * 32; v += 256) {
    int el = v >> 5, c2 = v & 31;
    int pp = el / 20;
    const float* fp = f3d + (size_t)sJ[el] + 6 * c2;
    float f0 = fp[0], f1 = fp[1], f2 = fp[2];
    float f3 = fp[3], f4 = fp[4], f5 = fp[5];
    const float* Vp = &sV[pp * 9];
    float x0 = f0 * Vp[0] + f1 * Vp[3] + f2 * Vp[6];
    float x1 = f0 * Vp[1] + f1 * Vp[4] + f2 * Vp[7];
    float x2 = f0 * Vp[2] + f1 * Vp[5] + f2 * Vp[8];
    float y0 = f3 * Vp[0] + f4 * Vp[3] + f5 * Vp[6];
    float y1 = f3 * Vp[1] + f4 * Vp[4] + f5 * Vp[7];
    float y2 = f3 * Vp[2] + f4 * Vp[5] + f5 * Vp[8];
    u32* xp = (u32*)&sX[el * 200 + 6 * c2];
    xp[0] = (u32)f2bf(x0) | ((u32)f2bf(x1) << 16);
    xp[1] = (u32)f2bf(x2) | ((u32)f2bf(y0) << 16);
    xp[2] = (u32)f2bf(y1) | ((u32)f2bf(y2) << 16);
  }
  __syncthreads();

  f32x4 acc[5][2];
#pragma unroll
  for (int mt = 0; mt < 5; ++mt) {
    acc[mt][0] = (f32x4)(0.f);
    acc[mt][1] = (f32x4)(0.f);
  }

  // K-steps in the same order as R5 (H0:KS0,1,2 then H1:KS0,1,2)
#pragma unroll
  for (int s = 0; s < 6; ++s) {
    const int kbase = (s / 3) * 96 + (s % 3) * 32 + lg * 8;
#pragma unroll
    for (int mt = 0; mt < 5; ++mt) {
      short8 a = *(const short8*)&sX[(mt * 16 + lr) * 200 + kbase];
      acc[mt][0] = __builtin_amdgcn_mfma_f32_16x16x32_bf16(a, breg[0][s], acc[mt][0], 0, 0, 0);
      acc[mt][1] = __builtin_amdgcn_mfma_f32_16x16x32_bf16(a, breg[1][s], acc[mt][1], 0, 0, 0);
    }
  }

  // epilogue: z = relu(acc+bias); maxpool over k per point; per-channel stats
#pragma unroll
  for (int nt = 0; nt < 2; ++nt) {
    int col = w * 32 + nt * 16 + lr;
    float bs = bias[col];
    float pm0 = 0.f, pm1 = 0.f, pm2 = 0.f, pm3 = 0.f;
    float s = 0.f, q = 0.f;
#pragma unroll
    for (int mt = 0; mt < 5; ++mt) {
#pragma unroll
      for (int r = 0; r < 4; ++r) {
        int edge = mt * 16 + lg * 4 + r;   // 0..79, exact (no padding)
        float z = fmaxf(acc[mt][nt][r] + bs, 0.f);
        pm0 = fmaxf(pm0, (edge < 20) ? z : 0.f);
        pm1 = fmaxf(pm1, (edge >= 20 && edge < 40) ? z : 0.f);
        pm2 = fmaxf(pm2, (edge >= 40 && edge < 60) ? z : 0.f);
        pm3 = fmaxf(pm3, (edge >= 60) ? z : 0.f);
        s += z; q += z * z;
      }
    }
#pragma unroll
    for (int off = 16; off < 64; off <<= 1) {
      pm0 = fmaxf(pm0, __shfl_xor(pm0, off));
      pm1 = fmaxf(pm1, __shfl_xor(pm1, off));
      pm2 = fmaxf(pm2, __shfl_xor(pm2, off));
      pm3 = fmaxf(pm3, __shfl_xor(pm3, off));
      s += __shfl_xor(s, off);
      q += __shfl_xor(q, off);
    }
    if (l < 16) {
      fdd2[(size_t)(p0 + 0) * 128 + col] = pm0;
      fdd2[(size_t)(p0 + 1) * 128 + col] = pm1;
      fdd2[(size_t)(p0 + 2) * 128 + col] = pm2;
      fdd2[(size_t)(p0 + 3) * 128 + col] = pm3;
      atomicAdd(&s4b[buk + col], (double)s);
      atomicAdd(&s4b[buk + 128 + col], (double)q);
    }
  }
}

// y1: register-tiled fp32 GEMM [16384,128]@[128,1024] with fused max over n.
__global__ __launch_bounds__(256) void y1_kernel(const float* __restrict__ fdd2,
                                                 const float* __restrict__ ss4,
                                                 const float* __restrict__ wh1,
                                                 u32* __restrict__ y1key) {
  __shared__ float sX[128][68];   // [k][point]
  __shared__ float sW[128][68];   // [k][chan]
  int t = threadIdx.x;
  int bid = blockIdx.x;
  int mtile = bid & 255;
  int ntile = bid >> 8;
  int cl = mtile >> 5;                 // cloud
  size_t pbase = (size_t)mtile * 64;   // global point base
  int c0 = ntile * 64;

  {
    int kq = t & 31, pp = t >> 5;
    float4 sc4 = *(const float4*)&ss4[kq * 4];
    float4 sh4 = *(const float4*)&ss4[128 + kq * 4];
    for (int p = pp; p < 64; p += 8) {
      float4 x4 = *(const float4*)&fdd2[(pbase + p) * 128 + kq * 4];
      sX[kq * 4 + 0][p] = x4.x * sc4.x + sh4.x;
      sX[kq * 4 + 1][p] = x4.y * sc4.y + sh4.y;
      sX[kq * 4 + 2][p] = x4.z * sc4.z + sh4.z;
      sX[kq * 4 + 3][p] = x4.w * sc4.w + sh4.w;
    }
  }
  {
    int cq = t & 15, rr = t >> 4;
    for (int r = rr; r < 128; r += 16) {
      float4 w4 = *(const float4*)&wh1[(size_t)r * 1024 + c0 + cq * 4];
      *(float4*)&sW[r][cq * 4] = w4;
    }
  }
  __syncthreads();

  int mg = t >> 4, ng = t & 15;
  int m0 = mg * 4, n0 = ng * 4;
  float acc[4][4];
#pragma unroll
  for (int i = 0; i < 4; ++i)
#pragma unroll
    for (int j = 0; j < 4; ++j) acc[i][j] = 0.f;
  for (int k = 0; k < 128; ++k) {
    float4 x4 = *(const float4*)&sX[k][m0];
    float4 w4 = *(const float4*)&sW[k][n0];
    acc[0][0] += x4.x * w4.x; acc[0][1] += x4.x * w4.y;
    acc[0][2] += x4.x * w4.z; acc[0][3] += x4.x * w4.w;
    acc[1][0] += x4.y * w4.x; acc[1][1] += x4.y * w4.y;
    acc[1][2] += x4.y * w4.z; acc[1][3] += x4.y * w4.w;
    acc[2][0] += x4.z * w4.x; acc[2][1] += x4.z * w4.y;
    acc[2][2] += x4.z * w4.z; acc[2][3] += x4.z * w4.w;
    acc[3][0] += x4.w * w4.x; acc[3][1] += x4.w * w4.y;
    acc[3][2] += x4.w * w4.z; acc[3][3] += x4.w * w4.w;
  }
  __syncthreads();
  float* red = &sX[0][0];
#pragma unroll
  for (int j = 0; j < 4; ++j) {
    float v = fmaxf(fmaxf(acc[0][j], acc[1][j]), fmaxf(acc[2][j], acc[3][j]));
    red[(n0 + j) * 16 + mg] = v;
  }
  __syncthreads();
  if (t < 64) {
    float m = red[t * 16];
#pragma unroll
    for (int i = 1; i < 16; ++i) m = fmaxf(m, red[t * 16 + i]);
    atomicMax(&y1key[(size_t)cl * 1024 + c0 + t], fkey(m));
  }
}

// y1 decode + bias + relu + BN over 8 clouds
__global__ void y1bn_kernel(const u32* __restrict__ y1key,
                            const float* __restrict__ bh1,
                            const float* __restrict__ g,
                            const float* __restrict__ be,
                            float* __restrict__ y1n) {
  int c = blockIdx.x * 256 + threadIdx.x;
  if (c >= 1024) return;
  float bs = bh1[c];
  float v[8]; double s = 0.0;
#pragma unroll
  for (int b = 0; b < 8; ++b) {
    v[b] = fmaxf(funkey(y1key[b * 1024 + c]) + bs, 0.f);
    s += (double)v[b];
  }
  double m = s / 8.0, q = 0.0;
#pragma unroll
  for (int b = 0; b < 8; ++b) { double d = (double)v[b] - m; q += d * d; }
  q /= 8.0;
  double inv = 1.0 / sqrt(q + 1e-5);
  double sg = (double)g[c] * inv;
#pragma unroll
  for (int b = 0; b < 8; ++b)
    y1n[b * 1024 + c] = (float)(((double)v[b] - m) * sg + (double)be[c]);
}

// head GEMM, K-split: grid = notile*8; block 256 = 64 outs x 4 k-subs.
// partials -> part[(ks*8+b)*512 + o], summed later in fixed order.
__global__ __launch_bounds__(256) void hgemm_kernel(const float* __restrict__ yin,
                                                    const float* __restrict__ W,
                                                    float* __restrict__ part,
                                                    int INn, int OUTn, int notile) {
  __shared__ float sx[8 * 128];
  __shared__ float red[4][8][64];
  int t = threadIdx.x;
  int og = blockIdx.x % notile;
  int ks = blockIdx.x / notile;
  int KC = INn >> 3;                 // IN/8
  int k0 = ks * KC;
  for (int v = t; v < 8 * KC; v += 256) {
    int b = v / KC, i = v - b * KC;
    sx[b * KC + i] = yin[(size_t)b * INn + k0 + i];
  }
  __syncthreads();
  int o = og * 64 + (t & 63);
  int kq = t >> 6;
  int sub = KC >> 2;
  float acc[8];
#pragma unroll
  for (int b = 0; b < 8; ++b) acc[b] = 0.f;
  if (o < OUTn) {
    for (int i = kq * sub; i < kq * sub + sub; ++i) {
      float w = W[(size_t)(k0 + i) * OUTn + o];
#pragma unroll
      for (int b = 0; b < 8; ++b) acc[b] += sx[b * KC + i] * w;
    }
  }
#pragma unroll
  for (int b = 0; b < 8; ++b) red[kq][b][t & 63] = acc[b];
  __syncthreads();
  if (kq == 0 && o < OUTn) {
#pragma unroll
    for (int b = 0; b < 8; ++b) {
      float s = ((red[0][b][t] + red[1][b][t]) + red[2][b][t]) + red[3][b][t];
      part[(size_t)(ks * 8 + b) * 512 + o] = s;
    }
  }
}

// head reduce: sum 8 K-chunks in fixed order + bias + relu + BN over 8
__global__ void hreduce_kernel(const float* __restrict__ part,
                               const float* __restrict__ bias,
                               const float* __restrict__ g,
                               const float* __restrict__ be,
                               float* __restrict__ yout, int OUTn) {
  int o = blockIdx.x * 256 + threadIdx.x;
  if (o >= OUTn) return;
  float bs = bias[o];
  float v[8]; double s = 0.0;
#pragma unroll
  for (int b = 0; b < 8; ++b) {
    float p = 0.f;
#pragma unroll
    for (int ks = 0; ks < 8; ++ks) p += part[(size_t)(ks * 8 + b) * 512 + o];
    v[b] = fmaxf(p + bs, 0.f);
    s += (double)v[b];
  }
  double m = s / 8.0, q = 0.0;
#pragma unroll
  for (int b = 0; b < 8; ++b) { double d = (double)v[b] - m; q += d * d; }
  q /= 8.0;
  double inv = 1.0 / sqrt(q + 1e-5);
  double sg = (double)g[o] * inv;
#pragma unroll
  for (int b = 0; b < 8; ++b)
    yout[(size_t)b * OUTn + o] = (float)(((double)v[b] - m) * sg + (double)be[o]);
}

// final linear [8,265]@[265,40]+b then log_softmax per row
__global__ __launch_bounds__(384) void logits_kernel(const float* __restrict__ y3n,
                                                     const float* __restrict__ W,
                                                     const float* __restrict__ bias,
                                                     float* __restrict__ out) {
  __shared__ float sy[8 * 265];
  __shared__ float slog[320];
  __shared__ float sm[8], sl[8];
  int t = threadIdx.x;
  for (int v = t; v < 8 * 265; v += 384) sy[v] = y3n[v];
  __syncthreads();
  if (t < 320) {
    int b = t / 40, o = t % 40;
    float acc = 0.f;
    for (int i = 0; i < 265; ++i) acc += sy[b * 265 + i] * W[i * 40 + o];
    slog[t] = acc + bias[o];
  }
  __syncthreads();
  if (t < 8) {
    float m = slog[t * 40];
    for (int o = 1; o < 40; ++o) m = fmaxf(m, slog[t * 40 + o]);
    float s = 0.f;
    for (int o = 0; o < 40; ++o) s += expf(slog[t * 40 + o] - m);
    sm[t] = m; sl[t] = logf(s);
  }
  __syncthreads();
  if (t < 320) {
    int b = t / 40;
    out[t] = slog[t] - sm[b] - sl[b];
  }
}

// ---------------- launcher ----------------
extern "C" void kernel_launch(void* const* d_in, const int* in_sizes, int n_in,
                              void* d_out, int out_size, void* d_ws, size_t ws_size,
                              hipStream_t stream) {
  (void)in_sizes; (void)n_in; (void)out_size; (void)ws_size;
  const float* pos  = (const float*)d_in[0];
  const float* w11  = (const float*)d_in[1];
  const float* b11  = (const float*)d_in[2];
  const float* g11  = (const float*)d_in[3];
  const float* be11 = (const float*)d_in[4];
  const float* w12  = (const float*)d_in[5];
  const float* b12  = (const float*)d_in[6];
  const float* g12  = (const float*)d_in[7];
  const float* be12 = (const float*)d_in[8];
  const float* w13  = (const float*)d_in[9];
  const float* b13  = (const float*)d_in[10];
  const float* g13  = (const float*)d_in[11];
  const float* be13 = (const float*)d_in[12];
  const float* w21  = (const float*)d_in[13];
  const float* b21  = (const float*)d_in[14];
  const float* g21  = (const float*)d_in[15];
  const float* be21 = (const float*)d_in[16];
  const float* wh1  = (const float*)d_in[17];
  const float* bh1  = (const float*)d_in[18];
  const float* gh1  = (const float*)d_in[19];
  const float* beh1 = (const float*)d_in[20];
  const float* wh2  = (const float*)d_in[21];
  const float* bh2  = (const float*)d_in[22];
  const float* gh2  = (const float*)d_in[23];
  const float* beh2 = (const float*)d_in[24];
  const float* wh3  = (const float*)d_in[25];
  const float* bh3  = (const float*)d_in[26];
  const float* gh3  = (const float*)d_in[27];
  const float* beh3 = (const float*)d_in[28];
  const float* wh4  = (const float*)d_in[29];
  const float* bh4  = (const float*)d_in[30];

  char* ws = (char*)d_ws;
  int*    idx   = (int*)(ws + 0);                 // 1,310,720 B
  float*  loc   = (float*)(ws + 1310720);         // 3,932,160 B
  float*  V     = (float*)(ws + 5242880);         //   589,824 B
  float*  h     = (float*)(ws + 5832704);         // 83,886,080 B (fp32, in-place)
  u16*    wt    = (u16*)(ws + 5832704);           // 49,152 B (overlays h AFTER f3d)
  double* s4b   = (double*)(ws + 5898240);        // 131,072 B (h + 64KB)
  float*  hpart = (float*)(ws + 6881280);         // 131,072 B (h + 1MB)
  float*  f3d   = (float*)(ws + 89718784);        // 12,582,912 B
  float*  fdd2  = (float*)(ws + 102301696);       //  8,388,608 B
  u32*    y1k   = (u32*)(ws + 110690304);         //     32,768 B
  float*  y1n   = (float*)(ws + 110723072);       //     32,768 B
  float*  y2n   = (float*)(ws + 110755840);       //     16,384 B
  float*  y3n   = (float*)(ws + 110772224);       //      8,512 B
  double* stats = (double*)(ws + 110780736);      // 640 doubles
  float*  param = (float*)(ws + 110785856);       // 640 floats
  float*  out   = (float*)d_out;

  zero_kernel<<<32, 256, 0, stream>>>((u32*)stats, 1280, y1k, 8192);
  knn_kernel<<<4096, 256, 0, stream>>>(pos, idx);
  prep_kernel<<<256, 64, 0, stream>>>(pos, idx, loc, V);

  l1_kernel<<<1280, 256, 0, stream>>>(loc, w11, b11, h);
  stats64_kernel<<<256, 256, 0, stream>>>(h, stats);
  finalize_kernel<<<1, 256, 0, stream>>>(stats, 64, (double)EE, g11, be11, param);

  l23_kernel<<<4096, 256, 0, stream>>>(h, param, w12, b12, h);          // in-place
  stats64_kernel<<<256, 256, 0, stream>>>(h, stats + 128);
  finalize_kernel<<<1, 256, 0, stream>>>(stats + 128, 64, (double)EE, g12, be12, param + 128);

  l23_kernel<<<4096, 256, 0, stream>>>(h, param + 128, w13, b13, h);    // in-place
  stats64_kernel<<<256, 256, 0, stream>>>(h, stats + 256);
  finalize_kernel<<<1, 256, 0, stream>>>(stats + 256, 64, (double)EE, g13, be13, param + 256);

  f3d_kernel<<<4096, 256, 0, stream>>>(h, param + 256, loc, f3d);
  // h is dead now; wt + s4b + hpart overlay it
  wtcvt_kernel<<<96, 256, 0, stream>>>(w21, wt, s4b);
  dd2_kernel<<<4096, 256, 0, stream>>>(f3d, V, idx, wt, b21, fdd2, s4b);
  finalize64_kernel<<<1, 128, 0, stream>>>(s4b, g21, be21, param + 384);

  y1_kernel<<<4096, 256, 0, stream>>>(fdd2, param + 384, wh1, y1k);
  y1bn_kernel<<<4, 256, 0, stream>>>(y1k, bh1, gh1, beh1, y1n);

  hgemm_kernel<<<64, 256, 0, stream>>>(y1n, wh2, hpart, 1024, 512, 8);
  hreduce_kernel<<<2, 256, 0, stream>>>(hpart, bh2, gh2, beh2, y2n, 512);
  hgemm_kernel<<<40, 256, 0, stream>>>(y2n, wh3, hpart, 512, 265, 5);
  hreduce_kernel<<<2, 256, 0, stream>>>(hpart, bh3, gh3, beh3, y3n, 265);
  logits_kernel<<<1, 384, 0, stream>>>(y3n, wh4, bh4, out);
}

// Round 8
// 464.410 us; speedup vs baseline: 2.5357x; 1.0531x over previous
//
#include <hip/hip_runtime.h>

// ---------------------------------------------------------------------------
// Net_3152505995976: point-cloud classifier forward pass on MI355X.
// Round 8: y1 bank-conflict fix (94us -> target ~32us).
//   - dd2 now writes fdd2T[128][16384] (channel-major): each lane's
//     pm0..pm3 is one float4 row segment -> no LDS transpose anywhere
//   - y1 stages sX[k][p] straight from fdd2T rows (coalesced read,
//     uniform 8-lanes/16B-slot writes = conflict-free); k-loop unchanged
//   - values bit-identical to R7 (layout-only change)
//   - everything else identical to the passing R7 kernel.
// ---------------------------------------------------------------------------

#define NEW_SLARTG 1

typedef unsigned short u16;
typedef unsigned int u32;
typedef unsigned long long u64;
typedef __attribute__((ext_vector_type(8))) short short8;
typedef __attribute__((ext_vector_type(4))) float f32x4;

#define BB 8
#define NNp 2048
#define KKn 20
#define NP 16384      // BB*NNp
#define EE 327680     // NP*KKn

// ---------------- small helpers ----------------
__device__ __forceinline__ u32 fkey(float f) {
  u32 u = __float_as_uint(f);
  return (u & 0x80000000u) ? ~u : (u | 0x80000000u);
}
__device__ __forceinline__ float funkey(u32 k) {
  u32 u = (k & 0x80000000u) ? (k ^ 0x80000000u) : ~k;
  return __uint_as_float(u);
}
__device__ __forceinline__ float f_sign(float a, float b) {
  return (b >= 0.f) ? fabsf(a) : -fabsf(a);
}
__device__ __forceinline__ u16 f2bf(float f) {
  u32 u = __float_as_uint(f);
  u32 r = (u + 0x7fffu + ((u >> 16) & 1u)) >> 16;
  return (u16)r;
}

__device__ __forceinline__ u64 sxor64(u64 v, int m) {
  union { u64 q; u32 d[2]; } a; a.q = v;
  a.d[0] = __shfl_xor(a.d[0], m);
  a.d[1] = __shfl_xor(a.d[1], m);
  return a.q;
}
__device__ __forceinline__ u64 sidx64(u64 v, int src) {
  union { u64 q; u32 d[2]; } a; a.q = v;
  a.d[0] = __shfl(a.d[0], src);
  a.d[1] = __shfl(a.d[1], src);
  return a.q;
}
// wave-wide bitonic sort, 64 u64 elements (1/lane), ascending
__device__ __forceinline__ void bsort64(u64& v, int lane) {
#pragma unroll
  for (int k = 2; k <= 64; k <<= 1) {
#pragma unroll
    for (int j = k >> 1; j > 0; j >>= 1) {
      u64 pv = sxor64(v, j);
      bool up = ((lane & k) == 0);
      bool lower = ((lane & j) == 0);
      bool keepmin = (lower == up);
      bool take = keepmin ? (pv < v) : (pv > v);
      v = take ? pv : v;
    }
  }
}

// ---------------- LAPACK fp32 replicas ----------------
__device__ float slapy2_(float x, float y) {
#pragma clang fp contract(off)
  float xa = fabsf(x), ya = fabsf(y);
  float w = fmaxf(xa, ya), z = fminf(xa, ya);
  if (z == 0.f) return w;
  float t = z / w;
  return w * sqrtf(1.0f + t * t);
}

__device__ void slartg_(float f, float g, float& c, float& s, float& r) {
#pragma clang fp contract(off)
#if NEW_SLARTG
  const float safmin = 1.17549435e-38f;
  const float safmax = 8.50705917e+37f;
  const float rtmin = 1.08420217e-19f;   // sqrt(safmin)
  const float rtmax = 6.52221171e+18f;   // sqrt(safmax/2)
  float f1 = fabsf(f), g1 = fabsf(g);
  if (g == 0.f) { c = 1.f; s = 0.f; r = f; }
  else if (f == 0.f) { c = 0.f; s = (g >= 0.f) ? 1.f : -1.f; r = g1; }
  else {
    float d;
    if (f1 > rtmin && f1 < rtmax && g1 > rtmin && g1 < rtmax) {
      d = sqrtf(f * f + g * g);
      c = f1 / d;
      r = (f >= 0.f) ? d : -d;
    } else {
      float uu = fminf(safmax, fmaxf(safmin, fmaxf(f1, g1)));
      float fs = f / uu, gs = g / uu;
      d = sqrtf(fs * fs + gs * gs);
      c = fabsf(fs) / d;
      r = ((f >= 0.f) ? d : -d) * uu;
    }
    s = g / r;
  }
#else
  if (g == 0.f) { c = 1.f; s = 0.f; r = f; }
  else if (f == 0.f) { c = 0.f; s = 1.f; r = g; }
  else {
    float f1 = f, g1 = g;
    r = sqrtf(f1 * f1 + g1 * g1);
    c = f1 / r;
    s = g1 / r;
    if (fabsf(f) > fabsf(g) && c < 0.f) { c = -c; s = -s; r = -r; }
  }
#endif
}

__device__ void slaev2_(float a, float b, float c, float& rt1, float& rt2,
                        float& cs1, float& sn1) {
#pragma clang fp contract(off)
  float sm = a + c;
  float df = a - c;
  float adf = fabsf(df);
  float tb = b + b;
  float ab = fabsf(tb);
  float acmx, acmn;
  if (fabsf(a) > fabsf(c)) { acmx = a; acmn = c; } else { acmx = c; acmn = a; }
  float rt;
  if (adf > ab) { float t = ab / adf; rt = adf * sqrtf(1.f + t * t); }
  else if (adf < ab) { float t = adf / ab; rt = ab * sqrtf(1.f + t * t); }
  else { rt = ab * sqrtf(2.f); }
  int sgn1;
  if (sm < 0.f) {
    rt1 = 0.5f * (sm - rt); sgn1 = -1;
    rt2 = (acmx / rt1) * acmn - (b / rt1) * b;
  } else if (sm > 0.f) {
    rt1 = 0.5f * (sm + rt); sgn1 = 1;
    rt2 = (acmx / rt1) * acmn - (b / rt1) * b;
  } else {
    rt1 = 0.5f * rt; rt2 = -0.5f * rt; sgn1 = 1;
  }
  float cs; int sgn2;
  if (df >= 0.f) { cs = df + rt; sgn2 = 1; } else { cs = df - rt; sgn2 = -1; }
  float acs = fabsf(cs);
  if (acs > ab) {
    float ct = -tb / cs;
    sn1 = 1.f / sqrtf(1.f + ct * ct);
    cs1 = ct * sn1;
  } else {
    if (ab == 0.f) { cs1 = 1.f; sn1 = 0.f; }
    else {
      float tn = -cs / tb;
      cs1 = 1.f / sqrtf(1.f + tn * tn);
      sn1 = tn * cs1;
    }
  }
  if (sgn1 == sgn2) { float tn = cs1; cs1 = -sn1; sn1 = tn; }
}

// ssteqr for n=3, compz='I' (z must be identity on entry)
__device__ void ssteqr3_(float* d, float* e, float z[3][3]) {
#pragma clang fp contract(off)
  const float eps = 5.9604645e-08f;
  const float eps2 = 3.5527137e-15f;
  const float safmin = 1.17549435e-38f;
  const int n = 3;
  const int nmaxit = 90;
  int jtot = 0;
  int l1 = 1;

  while (1) {
    if (l1 > n) break;
    if (l1 > 1) e[l1 - 2] = 0.f;
    int m = n;
    if (l1 <= n - 1) {
      for (int mm = l1; mm <= n - 1; ++mm) {
        float tst = fabsf(e[mm - 1]);
        if (tst == 0.f) { m = mm; break; }
        if (tst <= (sqrtf(fabsf(d[mm - 1])) * sqrtf(fabsf(d[mm]))) * eps) {
          e[mm - 1] = 0.f; m = mm; break;
        }
      }
    }
    int l = l1, lsv = l, lend = m, lendsv = lend;
    (void)lsv; (void)lendsv;
    l1 = m + 1;
    if (lend == l) continue;

    float anorm = 0.f;
    for (int i = l; i <= lend; ++i) anorm = fmaxf(anorm, fabsf(d[i - 1]));
    for (int i = l; i <= lend - 1; ++i) anorm = fmaxf(anorm, fabsf(e[i - 1]));
    if (anorm == 0.f) continue;

    if (fabsf(d[lend - 1]) < fabsf(d[l - 1])) { lend = lsv; l = lendsv; }

    if (lend > l) {
      // --- QL iteration ---
      while (1) {
        int m2 = lend;
        if (l != lend) {
          for (int mm = l; mm <= lend - 1; ++mm) {
            float tst = fabsf(e[mm - 1]); tst = tst * tst;
            if (tst <= (eps2 * fabsf(d[mm - 1])) * fabsf(d[mm]) + safmin) { m2 = mm; break; }
          }
        }
        if (m2 < lend) e[m2 - 1] = 0.f;
        float p = d[l - 1];
        if (m2 == l) {
          d[l - 1] = p; l += 1;
          if (l <= lend) continue;
          break;
        }
        if (m2 == l + 1) {
          float rt1, rt2, cc, ss;
          slaev2_(d[l - 1], e[l - 1], d[l], rt1, rt2, cc, ss);
          for (int i = 0; i < 3; ++i) {
            float temp = z[i][l];
            z[i][l] = cc * temp - ss * z[i][l - 1];
            z[i][l - 1] = ss * temp + cc * z[i][l - 1];
          }
          d[l - 1] = rt1; d[l] = rt2; e[l - 1] = 0.f;
          l += 2;
          if (l <= lend) continue;
          break;
        }
        if (jtot == nmaxit) break;
        jtot++;
        float g = (d[l] - p) / (2.f * e[l - 1]);
        float r = slapy2_(g, 1.f);
        g = d[m2 - 1] - p + (e[l - 1] / (g + f_sign(r, g)));
        float s = 1.f, c = 1.f;
        p = 0.f;
        float csv[2], snv[2];
        for (int i = m2 - 1; i >= l; --i) {
          float f = s * e[i - 1];
          float b = c * e[i - 1];
          slartg_(g, f, c, s, r);
          if (i != m2 - 1) e[i] = r;
          g = d[i] - p;
          r = (d[i - 1] - g) * s + (2.f * c) * b;
          p = s * r;
          d[i] = g + p;
          g = c * r - b;
          csv[i - l] = c; snv[i - l] = -s;
        }
        int cnt = m2 - l;
        for (int j = cnt; j >= 1; --j) {       // slasr 'R','V','B'
          float cj = csv[j - 1], sj = snv[j - 1];
          int c0 = (l - 1) + (j - 1);
          for (int i = 0; i < 3; ++i) {
            float temp = z[i][c0 + 1];
            z[i][c0 + 1] = cj * temp - sj * z[i][c0];
            z[i][c0] = sj * temp + cj * z[i][c0];
          }
        }
        d[l - 1] = d[l - 1] - p;
        e[l - 1] = g;
      }
    } else {
      // --- QR iteration ---
      while (1) {
        int m2 = lend;
        if (l != lend) {
          for (int mm = l; mm >= lend + 1; --mm) {
            float tst = fabsf(e[mm - 2]); tst = tst * tst;
            if (tst <= (eps2 * fabsf(d[mm - 1])) * fabsf(d[mm - 2]) + safmin) { m2 = mm; break; }
          }
        }
        if (m2 > lend) e[m2 - 2] = 0.f;
        float p = d[l - 1];
        if (m2 == l) {
          d[l - 1] = p; l -= 1;
          if (l >= lend) continue;
          break;
        }
        if (m2 == l - 1) {
          float rt1, rt2, cc, ss;
          slaev2_(d[l - 2], e[l - 2], d[l - 1], rt1, rt2, cc, ss);
          for (int i = 0; i < 3; ++i) {
            float temp = z[i][l - 1];
            z[i][l - 1] = cc * temp - ss * z[i][l - 2];
            z[i][l - 2] = ss * temp + cc * z[i][l - 2];
          }
          d[l - 2] = rt1; d[l - 1] = rt2; e[l - 2] = 0.f;
          l -= 2;
          if (l >= lend) continue;
          break;
        }
        if (jtot == nmaxit) break;
        jtot++;
        float g = (d[l - 2] - p) / (2.f * e[l - 2]);
        float r = slapy2_(g, 1.f);
        g = d[m2 - 1] - p + (e[l - 2] / (g + f_sign(r, g)));
        float s = 1.f, c = 1.f;
        p = 0.f;
        float csv[2], snv[2];
        for (int i = m2; i <= l - 1; ++i) {
          float f = s * e[i - 1];
          float b = c * e[i - 1];
          slartg_(g, f, c, s, r);
          if (i != m2) e[i - 2] = r;
          g = d[i - 1] - p;
          r = (d[i] - g) * s + (2.f * c) * b;
          p = s * r;
          d[i - 1] = g + p;
          g = c * r - b;
          csv[i - m2] = c; snv[i - m2] = s;
        }
        int cnt = l - m2;
        for (int j = 1; j <= cnt; ++j) {       // slasr 'R','V','F'
          float cj = csv[j - 1], sj = snv[j - 1];
          int c0 = (m2 - 1) + (j - 1);
          for (int i = 0; i < 3; ++i) {
            float temp = z[i][c0 + 1];
            z[i][c0 + 1] = cj * temp - sj * z[i][c0];
            z[i][c0] = sj * temp + cj * z[i][c0];
          }
        }
        d[l - 1] = d[l - 1] - p;
        e[l - 2] = g;
      }
    }
  }

  // selection sort ascending, swap eigenvector columns (LAPACK exact)
  for (int ii = 2; ii <= n; ++ii) {
    int i = ii - 1, k = i;
    float p = d[i - 1];
    for (int j = ii; j <= n; ++j)
      if (d[j - 1] < p) { k = j; p = d[j - 1]; }
    if (k != i) {
      d[k - 1] = d[i - 1]; d[i - 1] = p;
      for (int r2 = 0; r2 < 3; ++r2) {
        float t = z[r2][i - 1]; z[r2][i - 1] = z[r2][k - 1]; z[r2][k - 1] = t;
      }
    }
  }
}

// full ssyevd replica for 3x3 symmetric (lower entries), eigenvectors only
__device__ void eigh3_(float a00, float a10, float a11, float a20, float a21,
                       float a22, float V[3][3]) {
#pragma clang fp contract(off)
  float d0, d1, d2, e0, e1, tau1 = 0.f, v2 = 0.f;
  {
    float alpha = a10;
    float xnorm = fabsf(a20);
    if (xnorm == 0.f) {
      tau1 = 0.f; v2 = 0.f;
      e0 = alpha; d0 = a00; d1 = a11; d2 = a22; e1 = a21;
    } else {
      float beta = -f_sign(slapy2_(alpha, xnorm), alpha);
      tau1 = (beta - alpha) / beta;
      float inv = 1.0f / (alpha - beta);
      v2 = a20 * inv;
      float y0 = tau1 * a11;
      float y1v = tau1 * a21;
      float temp2 = a21 * v2;
      y0 = y0 + tau1 * temp2;
      y1v = y1v + (tau1 * v2) * a22;
      float dotyv = y0 * 1.f + y1v * v2;
      float al = (-0.5f * tau1) * dotyv;
      float w0 = y0 + al * 1.f;
      float w1 = y1v + al * v2;
      a11 = (a11 + 1.f * (-w0)) + w0 * (-1.f);
      a21 = (a21 + v2 * (-w0)) + w1 * (-1.f);
      a22 = (a22 + v2 * (-w1)) + w1 * (-v2);
      e0 = beta; d0 = a00; d1 = a11; d2 = a22; e1 = a21;
    }
  }
  float dd[3] = { d0, d1, d2 };
  float ee[2] = { e0, e1 };
  float z[3][3] = { {1.f,0.f,0.f},{0.f,1.f,0.f},{0.f,0.f,1.f} };
  ssteqr3_(dd, ee, z);
  if (tau1 != 0.f) {
    for (int j = 0; j < 3; ++j) {
      float wj = z[1][j] * 1.f + z[2][j] * v2;
      float temp = -tau1 * wj;
      z[1][j] = z[1][j] + 1.f * temp;
      z[2][j] = z[2][j] + v2 * temp;
    }
  }
  for (int r = 0; r < 3; ++r)
    for (int cix = 0; cix < 3; ++cix)
      V[r][cix] = z[r][cix];
}

// ---------------- kernels ----------------

__global__ void zero_kernel(u32* p1, int n1, u32* p2, int n2) {
  int t = blockIdx.x * blockDim.x + threadIdx.x;
  if (t < n1) p1[t] = 0u;
  if (t < n2) p2[t] = 0u;
}

// exact KNN top-20 per point: threshold-select + wave bitonic sort.
__global__ __launch_bounds__(256) void knn_kernel(const float* __restrict__ pos,
                                                  int* __restrict__ idx) {
#pragma clang fp contract(off)
  __shared__ u64 cke[4][128];
  int w = threadIdx.x >> 6;
  int lane = threadIdx.x & 63;
  int wid = blockIdx.x * 4 + w;
  int b = wid >> 11;
  int n = wid & 2047;
  const float* pc = pos + (size_t)b * NNp * 3;
  float qx = pc[n * 3 + 0], qy = pc[n * 3 + 1], qz = pc[n * 3 + 2];
  float d2n = (qx * qx + qy * qy) + qz * qz;

  // pass A: 32 keys per lane, in registers; track wave-min
  u32 kreg[32];
  u32 mk = 0xFFFFFFFFu;
#pragma unroll
  for (int t = 0; t < 32; ++t) {
    int m = lane + 64 * t;
    float x = pc[m * 3 + 0], y = pc[m * 3 + 1], zc = pc[m * 3 + 2];
    float d2m = (x * x + y * y) + zc * zc;
    float dot = (qx * x + qy * y) + qz * zc;
    float dist = (d2n + d2m) - 2.0f * dot;
    u32 key = fkey(dist);
    if (m == n) key = 0xFFFFFFFFu;   // self-exclusion (== +1e10 diag in ref)
    kreg[t] = key;
    mk = key < mk ? key : mk;
  }
#pragma unroll
  for (int off = 32; off; off >>= 1) {
    u32 o = __shfl_xor(mk, off);
    mk = o < mk ? o : mk;
  }

  // threshold search: find hi with 20 <= count(key<=hi) <= 128
  u32 lo_b = mk - 1u, hi_b = 0xFFFFFFFEu;
  int c_hi = 2047;
  float tf = funkey(mk) * 7.368f;     // count ~ T^1.5 => rank-20 guess
  u32 T = fkey(tf);
  if (T < mk) T = mk;
  if (T > 0xFFFFFFFEu) T = 0xFFFFFFFEu;
  for (int it = 0; it < 48; ++it) {
    int cnt = 0;
#pragma unroll
    for (int t = 0; t < 32; ++t) cnt += (kreg[t] <= T) ? 1 : 0;
#pragma unroll
    for (int off = 32; off; off >>= 1) cnt += __shfl_xor(cnt, off);
    if (cnt >= 20) {
      hi_b = T; c_hi = cnt;
      if (cnt <= 128) break;
    } else {
      lo_b = T;
    }
    if (hi_b <= lo_b + 1u) break;
    u32 Tn;
    if (it < 12) {
      float tfc = funkey(T);
      int cc = cnt < 1 ? 1 : cnt;
      float guess = tfc * __builtin_exp2f(0.66667f * __builtin_log2f(45.0f / (float)cc));
      Tn = fkey(guess);
      if (!(Tn > lo_b && Tn < hi_b)) Tn = lo_b + ((hi_b - lo_b) >> 1);
    } else {
      Tn = lo_b + ((hi_b - lo_b) >> 1);   // pure bisection
    }
    T = Tn;
  }

  // collect survivors (key <= hi_b) in m-ascending order via ballot prefix
  u64* ck = cke[w];
  u32 base = 0;
#pragma unroll
  for (int t = 0; t < 32; ++t) {
    bool pass = kreg[t] <= hi_b;
    u64 ball = __ballot(pass);
    if (pass) {
      u32 posn = base + (u32)__popcll(ball & ((1ull << lane) - 1ull));
      if (posn < 128u)
        ck[posn] = ((u64)kreg[t] << 32) | (u32)(lane + 64 * t);
    }
    base += (u32)__popcll(ball);
  }
  if (base > 128u) {
    base = 0;
#pragma unroll
    for (int t = 0; t < 32; ++t) {
      bool pass = kreg[t] <= lo_b;
      u64 ball = __ballot(pass);
      if (pass) {
        u32 posn = base + (u32)__popcll(ball & ((1ull << lane) - 1ull));
        ck[posn] = ((u64)kreg[t] << 32) | (u32)(lane + 64 * t);
      }
      base += (u32)__popcll(ball);
    }
#pragma unroll
    for (int t = 0; t < 32; ++t) {
      bool pass = (kreg[t] > lo_b) && (kreg[t] <= hi_b);
      u64 ball = __ballot(pass);
      if (pass) {
        u32 posn = base + (u32)__popcll(ball & ((1ull << lane) - 1ull));
        if (posn < 128u)
          ck[posn] = ((u64)kreg[t] << 32) | (u32)(lane + 64 * t);
      }
      base += (u32)__popcll(ball);
    }
  }
  u32 ctot = base < 128u ? base : 128u;

  // sort survivors ascending by (key, m); take first 20
  u64 e0 = (lane < (int)ctot) ? ck[lane] : ~0ull;
  bsort64(e0, lane);
  if (ctot > 64u) {
    u64 e1 = (lane + 64 < (int)ctot) ? ck[lane + 64] : ~0ull;
    bsort64(e1, lane);
    u64 r = sidx64(e1, 63 - lane);          // reverse second run
    u64 mn = r < e0 ? r : e0;               // bitonic
#pragma unroll
    for (int j = 32; j > 0; j >>= 1) {      // clean
      u64 pv = sxor64(mn, j);
      bool lower2 = ((lane & j) == 0);
      bool take = lower2 ? (pv < mn) : (pv > mn);
      mn = take ? pv : mn;
    }
    e0 = mn;
  }
  if (lane < 20)
    idx[(size_t)wid * 20 + lane] = (int)(u32)(e0 & 0xFFFFFFFFull);
}

// per-point: covariance, LAPACK-replica eigh, loc = rel @ V
__global__ __launch_bounds__(64) void prep_kernel(const float* __restrict__ pos,
                                                  const int* __restrict__ idx,
                                                  float* __restrict__ loc,
                                                  float* __restrict__ Vout) {
#pragma clang fp contract(off)
  int p = blockIdx.x * 64 + threadIdx.x;
  int b = p >> 11, n = p & 2047;
  const float* pc = pos + (size_t)b * NNp * 3;
  float qx = pc[n * 3 + 0], qy = pc[n * 3 + 1], qz = pc[n * 3 + 2];
  const int* ip = idx + (size_t)p * 20;
  float c00 = 0, c01 = 0, c02 = 0, c11 = 0, c12 = 0, c22 = 0;
  for (int k = 0; k < 20; ++k) {
    int j = ip[k];
    float rx = pc[j * 3 + 0] - qx, ry = pc[j * 3 + 1] - qy, rz = pc[j * 3 + 2] - qz;
    c00 += rx * rx; c01 += rx * ry; c02 += rx * rz;
    c11 += ry * ry; c12 += ry * rz; c22 += rz * rz;
  }
  float Vm[3][3];
  eigh3_(c00, c01, c11, c02, c12, c22, Vm);
  float* vp = Vout + (size_t)p * 9;
  for (int d = 0; d < 3; ++d)
    for (int e = 0; e < 3; ++e) vp[d * 3 + e] = Vm[d][e];
  for (int k = 0; k < 20; ++k) {
    int j = ip[k];
    float rx = pc[j * 3 + 0] - qx, ry = pc[j * 3 + 1] - qy, rz = pc[j * 3 + 2] - qz;
    float l0 = rx * Vm[0][0] + ry * Vm[1][0] + rz * Vm[2][0];
    float l1 = rx * Vm[0][1] + ry * Vm[1][1] + rz * Vm[2][1];
    float l2 = rx * Vm[0][2] + ry * Vm[1][2] + rz * Vm[2][2];
    size_t e = ((size_t)p * 20 + k) * 3;
    loc[e + 0] = l0; loc[e + 1] = l1; loc[e + 2] = l2;
  }
}

// layer1: [E,3]@[3,64]+b, relu, store fp32
__global__ __launch_bounds__(256) void l1_kernel(const float* __restrict__ loc,
                                                 const float* __restrict__ W,
                                                 const float* __restrict__ bias,
                                                 float* __restrict__ h1) {
  __shared__ float sW[192];
  __shared__ float sB[64];
  int t = threadIdx.x;
  if (t < 192) sW[t] = W[t];
  if (t < 64) sB[t] = bias[t];
  __syncthreads();
  size_t e = (size_t)blockIdx.x * 256 + t;
  float x0 = loc[e * 3 + 0], x1 = loc[e * 3 + 1], x2 = loc[e * 3 + 2];
  for (int c0 = 0; c0 < 64; c0 += 4) {
    float4 st;
    st.x = fmaxf(sB[c0 + 0] + x0 * sW[c0 + 0] + x1 * sW[64 + c0 + 0] + x2 * sW[128 + c0 + 0], 0.f);
    st.y = fmaxf(sB[c0 + 1] + x0 * sW[c0 + 1] + x1 * sW[64 + c0 + 1] + x2 * sW[128 + c0 + 1], 0.f);
    st.z = fmaxf(sB[c0 + 2] + x0 * sW[c0 + 2] + x1 * sW[64 + c0 + 2] + x2 * sW[128 + c0 + 2], 0.f);
    st.w = fmaxf(sB[c0 + 3] + x0 * sW[c0 + 3] + x1 * sW[64 + c0 + 3] + x2 * sW[128 + c0 + 3], 0.f);
    *(float4*)&h1[e * 64 + c0] = st;
  }
}

// per-channel sum/sumsq of an fp32 [E,64] buffer -> double atomics
__global__ __launch_bounds__(256) void stats64_kernel(const float* __restrict__ h,
                                                      double* __restrict__ sums) {
  __shared__ float red[512];
  int t = threadIdx.x;
  int c = t & 63, w = t >> 6;
  size_t rbase = (size_t)blockIdx.x * 1280 + w;
  float s = 0.f, q = 0.f;
  for (int r = 0; r < 1280; r += 4) {
    float v = h[(rbase + r) * 64 + c];
    s += v; q += v * v;
  }
  red[t] = s; red[256 + t] = q;
  __syncthreads();
  if (t < 64) {
    float S = red[t] + red[64 + t] + red[128 + t] + red[192 + t];
    float Q = red[256 + t] + red[320 + t] + red[384 + t] + red[448 + t];
    atomicAdd(&sums[t], (double)S);
    atomicAdd(&sums[64 + t], (double)Q);
  }
}

// sums -> per-channel affine (scale, shift) implementing train-mode BN
__global__ void finalize_kernel(const double* __restrict__ sums, int nch,
                                double count, const float* __restrict__ g,
                                const float* __restrict__ be,
                                float* __restrict__ out) {
  int c = blockIdx.x * blockDim.x + threadIdx.x;
  if (c < nch) {
    double m = sums[c] / count;
    double var = sums[nch + c] / count - m * m;
    double inv = 1.0 / sqrt(var + 1e-5);
    double sc = (double)g[c] * inv;
    out[c] = (float)sc;
    out[nch + c] = (float)((double)be[c] - m * sc);
  }
}

// 64-bucket stats -> per-channel affine for BN4 (fixed-order bucket reduce)
__global__ void finalize64_kernel(const double* __restrict__ s4b,
                                  const float* __restrict__ g,
                                  const float* __restrict__ be,
                                  float* __restrict__ outp) {
  int c = threadIdx.x;   // 128 threads
  double s = 0.0, q = 0.0;
  for (int buk = 0; buk < 64; ++buk) {
    s += s4b[buk * 256 + c];
    q += s4b[buk * 256 + 128 + c];
  }
  double m = s / (double)EE;
  double var = q / (double)EE - m * m;
  double inv = 1.0 / sqrt(var + 1e-5);
  double sc = (double)g[c] * inv;
  outp[c] = (float)sc;
  outp[128 + c] = (float)((double)be[c] - m * sc);
}

// layers 2/3: fp32 [E,64] @ [64,64]+b, relu, IN-PLACE capable (hin==hout)
__global__ __launch_bounds__(256) void l23_kernel(const float* __restrict__ hin,
                                                  const float* __restrict__ ss,
                                                  const float* __restrict__ W,
                                                  const float* __restrict__ bias,
                                                  float* __restrict__ hout) {
  __shared__ float xT[64 * 84];
  int t = threadIdx.x;
  size_t e0 = (size_t)blockIdx.x * 80;
  for (int v = t; v < 80 * 64; v += 256) {
    int el = v >> 6, c = v & 63;
    float val = hin[(e0 + el) * 64 + c];
    val = val * ss[c] + ss[64 + c];
    xT[c * 84 + el] = val;
  }
  __syncthreads();
  int og = t & 15, eg = t >> 4;
  int o0 = og * 4, eb = eg * 5;
  float acc[5][4];
#pragma unroll
  for (int a = 0; a < 5; ++a)
#pragma unroll
    for (int o = 0; o < 4; ++o) acc[a][o] = 0.f;
  for (int i = 0; i < 64; ++i) {
    float4 w4 = *(const float4*)&W[i * 64 + o0];
    float xx[5];
#pragma unroll
    for (int a = 0; a < 5; ++a) xx[a] = xT[i * 84 + eb + a];
#pragma unroll
    for (int a = 0; a < 5; ++a) {
      acc[a][0] += xx[a] * w4.x;
      acc[a][1] += xx[a] * w4.y;
      acc[a][2] += xx[a] * w4.z;
      acc[a][3] += xx[a] * w4.w;
    }
  }
  float4 b4 = *(const float4*)&bias[o0];
#pragma unroll
  for (int a = 0; a < 5; ++a) {
    size_t e = e0 + eb + a;
    float4 st;
    st.x = fmaxf(acc[a][0] + b4.x, 0.f);
    st.y = fmaxf(acc[a][1] + b4.y, 0.f);
    st.z = fmaxf(acc[a][2] + b4.z, 0.f);
    st.w = fmaxf(acc[a][3] + b4.w, 0.f);
    *(float4*)&hout[e * 64 + o0] = st;
  }
}

// f3d[p][c][d] = max_k h3n[p,k,c] * loc[p,k,d]
__global__ __launch_bounds__(256) void f3d_kernel(const float* __restrict__ h3,
                                                  const float* __restrict__ ss3,
                                                  const float* __restrict__ loc,
                                                  float* __restrict__ f3d) {
  int t = threadIdx.x;
  int p = blockIdx.x * 4 + (t >> 6);
  int c = t & 63;
  float sc = ss3[c], sh = ss3[64 + c];
  float m0 = -__builtin_inff(), m1 = m0, m2 = m0;
  size_t eb = (size_t)p * 20;
  for (int k = 0; k < 20; ++k) {
    size_t e = eb + k;
    float h = h3[e * 64 + c] * sc + sh;
    float l0 = loc[e * 3 + 0], l1 = loc[e * 3 + 1], l2 = loc[e * 3 + 2];
    m0 = fmaxf(m0, h * l0);
    m1 = fmaxf(m1, h * l1);
    m2 = fmaxf(m2, h * l2);
  }
  size_t o = (size_t)p * 192 + c * 3;
  f3d[o + 0] = m0; f3d[o + 1] = m1; f3d[o + 2] = m2;
}

// W21 [192][128] fp32 -> WT bf16 [128][192]; also zeroes the s4b buckets
__global__ __launch_bounds__(256) void wtcvt_kernel(const float* __restrict__ W,
                                                    u16* __restrict__ wt,
                                                    double* __restrict__ s4b) {
  int id = blockIdx.x * 256 + threadIdx.x;
  if (id < 192 * 128) {
    int n = id / 192, k = id - n * 192;
    wt[id] = f2bf(W[(size_t)k * 128 + n]);
  }
  if (id < 64 * 256) s4b[id] = 0.0;
}

// DD2 via bf16 MFMA: cloud->XCD swizzle; gather f3d[idx], rotate by V ->
// X bf16 LDS [80][200]; W-fragments in registers; GEMM [80,192]@[192,128];
// bias+relu+maxpool+stats fused; stats -> 64-way bucketed fp64 atomics.
// OUTPUT IS TRANSPOSED: fdd2T[128][16384] (each lane stores one float4 row
// segment pm0..pm3 = points p0..p0+3 of its channel) -> y1 needs no LDS
// transpose. Values bit-identical to the fdd2 layout.
__global__ __launch_bounds__(256) void dd2_kernel(const float* __restrict__ f3d,
                                                  const float* __restrict__ Vmat,
                                                  const int* __restrict__ idx,
                                                  const u16* __restrict__ wt,
                                                  const float* __restrict__ bias,
                                                  float* __restrict__ fdd2T,
                                                  double* __restrict__ s4b) {
  __shared__ u16 sX[80 * 200];     // X bf16, row stride 200 (400B, 16B aligned)
  __shared__ float sV[36];
  __shared__ int sJ[80];
  int t = threadIdx.x;
  // cloud->XCD affinity: XCD k (= bid%8 under round-robin dispatch) gets
  // the contiguous block range of cloud k -> per-XCD L2 holds one cloud.
  int wk = (blockIdx.x & 7) * 512 + (blockIdx.x >> 3);
  int p0 = wk * 4;
  int bcl = p0 >> 11;              // cloud (4 points never straddle clouds)
  int buk = ((int)blockIdx.x & 63) << 8;   // stats bucket base

  int w = t >> 6, l = t & 63;
  int lr = l & 15, lg = l >> 4;

  // preload B fragments: lane holds cols (w*32+nt*16+lr), k-slices lg*8+...
  short8 breg[2][6];
#pragma unroll
  for (int nt = 0; nt < 2; ++nt)
#pragma unroll
    for (int s = 0; s < 6; ++s) {
      const int kk = (s / 3) * 96 + (s % 3) * 32 + lg * 8;
      breg[nt][s] = *(const short8*)&wt[(w * 32 + nt * 16 + lr) * 192 + kk];
    }

  if (t < 36) sV[t] = Vmat[(size_t)p0 * 9 + t];
  if (t < 80) sJ[t] = ((bcl << 11) + idx[(size_t)p0 * 20 + t]) * 192;
  __syncthreads();

  // build X: el = edge 0..79, c2 = channel-pair 0..31
  for (int v = t; v < 80 * 32; v += 256) {
    int el = v >> 5, c2 = v & 31;
    int pp = el / 20;
    const float* fp = f3d + (size_t)sJ[el] + 6 * c2;
    float f0 = fp[0], f1 = fp[1], f2 = fp[2];
    float f3 = fp[3], f4 = fp[4], f5 = fp[5];
    const float* Vp = &sV[pp * 9];
    float x0 = f0 * Vp[0] + f1 * Vp[3] + f2 * Vp[6];
    float x1 = f0 * Vp[1] + f1 * Vp[4] + f2 * Vp[7];
    float x2 = f0 * Vp[2] + f1 * Vp[5] + f2 * Vp[8];
    float y0 = f3 * Vp[0] + f4 * Vp[3] + f5 * Vp[6];
    float y1 = f3 * Vp[1] + f4 * Vp[4] + f5 * Vp[7];
    float y2 = f3 * Vp[2] + f4 * Vp[5] + f5 * Vp[8];
    u32* xp = (u32*)&sX[el * 200 + 6 * c2];
    xp[0] = (u32)f2bf(x0) | ((u32)f2bf(x1) << 16);
    xp[1] = (u32)f2bf(x2) | ((u32)f2bf(y0) << 16);
    xp[2] = (u32)f2bf(y1) | ((u32)f2bf(y2) << 16);
  }
  __syncthreads();

  f32x4 acc[5][2];
#pragma unroll
  for (int mt = 0; mt < 5; ++mt) {
    acc[mt][0] = (f32x4)(0.f);
    acc[mt][1] = (f32x4)(0.f);
  }

  // K-steps in the same order as R5 (H0:KS0,1,2 then H1:KS0,1,2)
#pragma unroll
  for (int s = 0; s < 6; ++s) {
    const int kbase = (s / 3) * 96 + (s % 3) * 32 + lg * 8;
#pragma unroll
    for (int mt = 0; mt < 5; ++mt) {
      short8 a = *(const short8*)&sX[(mt * 16 + lr) * 200 + kbase];
      acc[mt][0] = __builtin_amdgcn_mfma_f32_16x16x32_bf16(a, breg[0][s], acc[mt][0], 0, 0, 0);
      acc[mt][1] = __builtin_amdgcn_mfma_f32_16x16x32_bf16(a, breg[1][s], acc[mt][1], 0, 0, 0);
    }
  }

  // epilogue: z = relu(acc+bias); maxpool over k per point; per-channel stats
#pragma unroll
  for (int nt = 0; nt < 2; ++nt) {
    int col = w * 32 + nt * 16 + lr;
    float bs = bias[col];
    float pm0 = 0.f, pm1 = 0.f, pm2 = 0.f, pm3 = 0.f;
    float s = 0.f, q = 0.f;
#pragma unroll
    for (int mt = 0; mt < 5; ++mt) {
#pragma unroll
      for (int r = 0; r < 4; ++r) {
        int edge = mt * 16 + lg * 4 + r;   // 0..79, exact (no padding)
        float z = fmaxf(acc[mt][nt][r] + bs, 0.f);
        pm0 = fmaxf(pm0, (edge < 20) ? z : 0.f);
        pm1 = fmaxf(pm1, (edge >= 20 && edge < 40) ? z : 0.f);
        pm2 = fmaxf(pm2, (edge >= 40 && edge < 60) ? z : 0.f);
        pm3 = fmaxf(pm3, (edge >= 60) ? z : 0.f);
        s += z; q += z * z;
      }
    }
#pragma unroll
    for (int off = 16; off < 64; off <<= 1) {
      pm0 = fmaxf(pm0, __shfl_xor(pm0, off));
      pm1 = fmaxf(pm1, __shfl_xor(pm1, off));
      pm2 = fmaxf(pm2, __shfl_xor(pm2, off));
      pm3 = fmaxf(pm3, __shfl_xor(pm3, off));
      s += __shfl_xor(s, off);
      q += __shfl_xor(q, off);
    }
    if (l < 16) {
      float4 pv;
      pv.x = pm0; pv.y = pm1; pv.z = pm2; pv.w = pm3;
      *(float4*)&fdd2T[(size_t)col * NP + p0] = pv;
      atomicAdd(&s4b[buk + col], (double)s);
      atomicAdd(&s4b[buk + 128 + col], (double)q);
    }
  }
}

// y1: register-tiled fp32 GEMM [16384,128]@[128,1024] with fused max over n.
// X staged from fdd2T rows (no transpose; conflict-free); k-order unchanged.
__global__ __launch_bounds__(256) void y1_kernel(const float* __restrict__ fdd2T,
                                                 const float* __restrict__ ss4,
                                                 const float* __restrict__ wh1,
                                                 u32* __restrict__ y1key) {
  __shared__ float sX[128][68];   // [k][point]
  __shared__ float sW[128][68];   // [k][chan]
  int t = threadIdx.x;
  int bid = blockIdx.x;
  int mtile = bid & 255;
  int ntile = bid >> 8;
  int cl = mtile >> 5;                 // cloud
  size_t pbase = (size_t)mtile * 64;   // global point base
  int c0 = ntile * 64;

  // stage X (normalized) from fdd2T: row r = k, 16 float4 cols per row
  {
    int rr = t >> 4, cq = t & 15;
    for (int r = rr; r < 128; r += 16) {
      float4 x4 = *(const float4*)&fdd2T[(size_t)r * NP + pbase + cq * 4];
      float sc = ss4[r], sh = ss4[128 + r];
      float4 st;
      st.x = x4.x * sc + sh;
      st.y = x4.y * sc + sh;
      st.z = x4.z * sc + sh;
      st.w = x4.w * sc + sh;
      *(float4*)&sX[r][cq * 4] = st;
    }
  }
  // stage W: thread t -> row r=t>>4 (+16 stride), col-quad cq=t&15
  {
    int cq = t & 15, rr = t >> 4;
    for (int r = rr; r < 128; r += 16) {
      float4 w4 = *(const float4*)&wh1[(size_t)r * 1024 + c0 + cq * 4];
      *(float4*)&sW[r][cq * 4] = w4;
    }
  }
  __syncthreads();

  int mg = t >> 4, ng = t & 15;
  int m0 = mg * 4, n0 = ng * 4;
  float acc[4][4];
#pragma unroll
  for (int i = 0; i < 4; ++i)
#pragma unroll
    for (int j = 0; j < 4; ++j) acc[i][j] = 0.f;
  for (int k = 0; k < 128; ++k) {
    float4 x4 = *(const float4*)&sX[k][m0];
    float4 w4 = *(const float4*)&sW[k][n0];
    acc[0][0] += x4.x * w4.x; acc[0][1] += x4.x * w4.y;
    acc[0][2] += x4.x * w4.z; acc[0][3] += x4.x * w4.w;
    acc[1][0] += x4.y * w4.x; acc[1][1] += x4.y * w4.y;
    acc[1][2] += x4.y * w4.z; acc[1][3] += x4.y * w4.w;
    acc[2][0] += x4.z * w4.x; acc[2][1] += x4.z * w4.y;
    acc[2][2] += x4.z * w4.z; acc[2][3] += x4.z * w4.w;
    acc[3][0] += x4.w * w4.x; acc[3][1] += x4.w * w4.y;
    acc[3][2] += x4.w * w4.z; acc[3][3] += x4.w * w4.w;
  }
  __syncthreads();
  float* red = &sX[0][0];
#pragma unroll
  for (int j = 0; j < 4; ++j) {
    float v = fmaxf(fmaxf(acc[0][j], acc[1][j]), fmaxf(acc[2][j], acc[3][j]));
    red[(n0 + j) * 16 + mg] = v;
  }
  __syncthreads();
  if (t < 64) {
    float m = red[t * 16];
#pragma unroll
    for (int i = 1; i < 16; ++i) m = fmaxf(m, red[t * 16 + i]);
    atomicMax(&y1key[(size_t)cl * 1024 + c0 + t], fkey(m));
  }
}

// y1 decode + bias + relu + BN over 8 clouds
__global__ void y1bn_kernel(const u32* __restrict__ y1key,
                            const float* __restrict__ bh1,
                            const float* __restrict__ g,
                            const float* __restrict__ be,
                            float* __restrict__ y1n) {
  int c = blockIdx.x * 256 + threadIdx.x;
  if (c >= 1024) return;
  float bs = bh1[c];
  float v[8]; double s = 0.0;
#pragma unroll
  for (int b = 0; b < 8; ++b) {
    v[b] = fmaxf(funkey(y1key[b * 1024 + c]) + bs, 0.f);
    s += (double)v[b];
  }
  double m = s / 8.0, q = 0.0;
#pragma unroll
  for (int b = 0; b < 8; ++b) { double d = (double)v[b] - m; q += d * d; }
  q /= 8.0;
  double inv = 1.0 / sqrt(q + 1e-5);
  double sg = (double)g[c] * inv;
#pragma unroll
  for (int b = 0; b < 8; ++b)
    y1n[b * 1024 + c] = (float)(((double)v[b] - m) * sg + (double)be[c]);
}

// head GEMM, K-split: grid = notile*8; block 256 = 64 outs x 4 k-subs.
__global__ __launch_bounds__(256) void hgemm_kernel(const float* __restrict__ yin,
                                                    const float* __restrict__ W,
                                                    float* __restrict__ part,
                                                    int INn, int OUTn, int notile) {
  __shared__ float sx[8 * 128];
  __shared__ float red[4][8][64];
  int t = threadIdx.x;
  int og = blockIdx.x % notile;
  int ks = blockIdx.x / notile;
  int KC = INn >> 3;                 // IN/8
  int k0 = ks * KC;
  for (int v = t; v < 8 * KC; v += 256) {
    int b = v / KC, i = v - b * KC;
    sx[b * KC + i] = yin[(size_t)b * INn + k0 + i];
  }
  __syncthreads();
  int o = og * 64 + (t & 63);
  int kq = t >> 6;
  int sub = KC >> 2;
  float acc[8];
#pragma unroll
  for (int b = 0; b < 8; ++b) acc[b] = 0.f;
  if (o < OUTn) {
    for (int i = kq * sub; i < kq * sub + sub; ++i) {
      float w = W[(size_t)(k0 + i) * OUTn + o];
#pragma unroll
      for (int b = 0; b < 8; ++b) acc[b] += sx[b * KC + i] * w;
    }
  }
#pragma unroll
  for (int b = 0; b < 8; ++b) red[kq][b][t & 63] = acc[b];
  __syncthreads();
  if (kq == 0 && o < OUTn) {
#pragma unroll
    for (int b = 0; b < 8; ++b) {
      float s = ((red[0][b][t] + red[1][b][t]) + red[2][b][t]) + red[3][b][t];
      part[(size_t)(ks * 8 + b) * 512 + o] = s;
    }
  }
}

// head reduce: sum 8 K-chunks in fixed order + bias + relu + BN over 8
__global__ void hreduce_kernel(const float* __restrict__ part,
                               const float* __restrict__ bias,
                               const float* __restrict__ g,
                               const float* __restrict__ be,
                               float* __restrict__ yout, int OUTn) {
  int o = blockIdx.x * 256 + threadIdx.x;
  if (o >= OUTn) return;
  float bs = bias[o];
  float v[8]; double s = 0.0;
#pragma unroll
  for (int b = 0; b < 8; ++b) {
    float p = 0.f;
#pragma unroll
    for (int ks = 0; ks < 8; ++ks) p += part[(size_t)(ks * 8 + b) * 512 + o];
    v[b] = fmaxf(p + bs, 0.f);
    s += (double)v[b];
  }
  double m = s / 8.0, q = 0.0;
#pragma unroll
  for (int b = 0; b < 8; ++b) { double d = (double)v[b] - m; q += d * d; }
  q /= 8.0;
  double inv = 1.0 / sqrt(q + 1e-5);
  double sg = (double)g[o] * inv;
#pragma unroll
  for (int b = 0; b < 8; ++b)
    yout[(size_t)b * OUTn + o] = (float)(((double)v[b] - m) * sg + (double)be[o]);
}

// final linear [8,265]@[265,40]+b then log_softmax per row
__global__ __launch_bounds__(384) void logits_kernel(const float* __restrict__ y3n,
                                                     const float* __restrict__ W,
                                                     const float* __restrict__ bias,
                                                     float* __restrict__ out) {
  __shared__ float sy[8 * 265];
  __shared__ float slog[320];
  __shared__ float sm[8], sl[8];
  int t = threadIdx.x;
  for (int v = t; v < 8 * 265; v += 384) sy[v] = y3n[v];
  __syncthreads();
  if (t < 320) {
    int b = t / 40, o = t % 40;
    float acc = 0.f;
    for (int i = 0; i < 265; ++i) acc += sy[b * 265 + i] * W[i * 40 + o];
    slog[t] = acc + bias[o];
  }
  __syncthreads();
  if (t < 8) {
    float m = slog[t * 40];
    for (int o = 1; o < 40; ++o) m = fmaxf(m, slog[t * 40 + o]);
    float s = 0.f;
    for (int o = 0; o < 40; ++o) s += expf(slog[t * 40 + o] - m);
    sm[t] = m; sl[t] = logf(s);
  }
  __syncthreads();
  if (t < 320) {
    int b = t / 40;
    out[t] = slog[t] - sm[b] - sl[b];
  }
}

// ---------------- launcher ----------------
extern "C" void kernel_launch(void* const* d_in, const int* in_sizes, int n_in,
                              void* d_out, int out_size, void* d_ws, size_t ws_size,
                              hipStream_t stream) {
  (void)in_sizes; (void)n_in; (void)out_size; (void)ws_size;
  const float* pos  = (const float*)d_in[0];
  const float* w11  = (const float*)d_in[1];
  const float* b11  = (const float*)d_in[2];
  const float* g11  = (const float*)d_in[3];
  const float* be11 = (const float*)d_in[4];
  const float* w12  = (const float*)d_in[5];
  const float* b12  = (const float*)d_in[6];
  const float* g12  = (const float*)d_in[7];
  const float* be12 = (const float*)d_in[8];
  const float* w13  = (const float*)d_in[9];
  const float* b13  = (const float*)d_in[10];
  const float* g13  = (const float*)d_in[11];
  const float* be13 = (const float*)d_in[12];
  const float* w21  = (const float*)d_in[13];
  const float* b21  = (const float*)d_in[14];
  const float* g21  = (const float*)d_in[15];
  const float* be21 = (const float*)d_in[16];
  const float* wh1  = (const float*)d_in[17];
  const float* bh1  = (const float*)d_in[18];
  const float* gh1  = (const float*)d_in[19];
  const float* beh1 = (const float*)d_in[20];
  const float* wh2  = (const float*)d_in[21];
  const float* bh2  = (const float*)d_in[22];
  const float* gh2  = (const float*)d_in[23];
  const float* beh2 = (const float*)d_in[24];
  const float* wh3  = (const float*)d_in[25];
  const float* bh3  = (const float*)d_in[26];
  const float* gh3  = (const float*)d_in[27];
  const float* beh3 = (const float*)d_in[28];
  const float* wh4  = (const float*)d_in[29];
  const float* bh4  = (const float*)d_in[30];

  char* ws = (char*)d_ws;
  int*    idx   = (int*)(ws + 0);                 // 1,310,720 B
  float*  loc   = (float*)(ws + 1310720);         // 3,932,160 B
  float*  V     = (float*)(ws + 5242880);         //   589,824 B
  float*  h     = (float*)(ws + 5832704);         // 83,886,080 B (fp32, in-place)
  u16*    wt    = (u16*)(ws + 5832704);           // 49,152 B (overlays h AFTER f3d)
  double* s4b   = (double*)(ws + 5898240);        // 131,072 B (h + 64KB)
  float*  hpart = (float*)(ws + 6881280);         // 131,072 B (h + 1MB)
  float*  f3d   = (float*)(ws + 89718784);        // 12,582,912 B
  float*  fdd2T = (float*)(ws + 102301696);       //  8,388,608 B ([128][16384])
  u32*    y1k   = (u32*)(ws + 110690304);         //     32,768 B
  float*  y1n   = (float*)(ws + 110723072);       //     32,768 B
  float*  y2n   = (float*)(ws + 110755840);       //     16,384 B
  float*  y3n   = (float*)(ws + 110772224);       //      8,512 B
  double* stats = (double*)(ws + 110780736);      // 640 doubles
  float*  param = (float*)(ws + 110785856);       // 640 floats
  float*  out   = (float*)d_out;

  zero_kernel<<<32, 256, 0, stream>>>((u32*)stats, 1280, y1k, 8192);
  knn_kernel<<<4096, 256, 0, stream>>>(pos, idx);
  prep_kernel<<<256, 64, 0, stream>>>(pos, idx, loc, V);

  l1_kernel<<<1280, 256, 0, stream>>>(loc, w11, b11, h);
  stats64_kernel<<<256, 256, 0, stream>>>(h, stats);
  finalize_kernel<<<1, 256, 0, stream>>>(stats, 64, (double)EE, g11, be11, param);

  l23_kernel<<<4096, 256, 0, stream>>>(h, param, w12, b12, h);          // in-place
  stats64_kernel<<<256, 256, 0, stream>>>(h, stats + 128);
  finalize_kernel<<<1, 256, 0, stream>>>(stats + 128, 64, (double)EE, g12, be12, param + 128);

  l23_kernel<<<4096, 256, 0, stream>>>(h, param + 128, w13, b13, h);    // in-place
  stats64_kernel<<<256, 256, 0, stream>>>(h, stats + 256);
  finalize_kernel<<<1, 256, 0, stream>>>(stats + 256, 64, (double)EE, g13, be13, param + 256);

  f3d_kernel<<<4096, 256, 0, stream>>>(h, param + 256, loc, f3d);
  // h is dead now; wt + s4b + hpart overlay it
  wtcvt_kernel<<<96, 256, 0, stream>>>(w21, wt, s4b);
  dd2_kernel<<<4096, 256, 0, stream>>>(f3d, V, idx, wt, b21, fdd2T, s4b);
  finalize64_kernel<<<1, 128, 0, stream>>>(s4b, g21, be21, param + 384);

  y1_kernel<<<4096, 256, 0, stream>>>(fdd2T, param + 384, wh1, y1k);
  y1bn_kernel<<<4, 256, 0, stream>>>(y1k, bh1, gh1, beh1, y1n);

  hgemm_kernel<<<64, 256, 0, stream>>>(y1n, wh2, hpart, 1024, 512, 8);
  hreduce_kernel<<<2, 256, 0, stream>>>(hpart, bh2, gh2, beh2, y2n, 512);
  hgemm_kernel<<<40, 256, 0, stream>>>(y2n, wh3, hpart, 512, 265, 5);
  hreduce_kernel<<<2, 256, 0, stream>>>(hpart, bh3, gh3, beh3, y3n, 265);
  logits_kernel<<<1, 384, 0, stream>>>(y3n, wh4, bh4, out);
}

// Round 9
// 386.778 us; speedup vs baseline: 3.0447x; 1.2007x over previous
//
#include <hip/hip_runtime.h>

// ---------------------------------------------------------------------------
// Net_3152505995976: point-cloud classifier forward pass on MI355X.
// Round 9: y1 arithmetic-intensity fix + fused BN stats.
//   - y1: 128x128 tile, 8x8 acc/thread (2x fewer LDS reads per FMA),
//     K split in two 64-deep LDS stages (64KB -> 2 blk/CU); column pairs
//     at 16B stride (2-way = free). k-order sequential -> bit-identical.
//   - BN1-3 stats fused into l1/l23 epilogues (64-way bucketed fp64
//     atomics in the dead f3d region) -> three 84MB stats passes removed.
//   - everything else identical to the passing R8 kernel.
// ---------------------------------------------------------------------------

#define NEW_SLARTG 1

typedef unsigned short u16;
typedef unsigned int u32;
typedef unsigned long long u64;
typedef __attribute__((ext_vector_type(8))) short short8;
typedef __attribute__((ext_vector_type(4))) float f32x4;

#define BB 8
#define NNp 2048
#define KKn 20
#define NP 16384      // BB*NNp
#define EE 327680     // NP*KKn

// ---------------- small helpers ----------------
__device__ __forceinline__ u32 fkey(float f) {
  u32 u = __float_as_uint(f);
  return (u & 0x80000000u) ? ~u : (u | 0x80000000u);
}
__device__ __forceinline__ float funkey(u32 k) {
  u32 u = (k & 0x80000000u) ? (k ^ 0x80000000u) : ~k;
  return __uint_as_float(u);
}
__device__ __forceinline__ float f_sign(float a, float b) {
  return (b >= 0.f) ? fabsf(a) : -fabsf(a);
}
__device__ __forceinline__ u16 f2bf(float f) {
  u32 u = __float_as_uint(f);
  u32 r = (u + 0x7fffu + ((u >> 16) & 1u)) >> 16;
  return (u16)r;
}

__device__ __forceinline__ u64 sxor64(u64 v, int m) {
  union { u64 q; u32 d[2]; } a; a.q = v;
  a.d[0] = __shfl_xor(a.d[0], m);
  a.d[1] = __shfl_xor(a.d[1], m);
  return a.q;
}
__device__ __forceinline__ u64 sidx64(u64 v, int src) {
  union { u64 q; u32 d[2]; } a; a.q = v;
  a.d[0] = __shfl(a.d[0], src);
  a.d[1] = __shfl(a.d[1], src);
  return a.q;
}
// wave-wide bitonic sort, 64 u64 elements (1/lane), ascending
__device__ __forceinline__ void bsort64(u64& v, int lane) {
#pragma unroll
  for (int k = 2; k <= 64; k <<= 1) {
#pragma unroll
    for (int j = k >> 1; j > 0; j >>= 1) {
      u64 pv = sxor64(v, j);
      bool up = ((lane & k) == 0);
      bool lower = ((lane & j) == 0);
      bool keepmin = (lower == up);
      bool take = keepmin ? (pv < v) : (pv > v);
      v = take ? pv : v;
    }
  }
}

// ---------------- LAPACK fp32 replicas ----------------
__device__ float slapy2_(float x, float y) {
#pragma clang fp contract(off)
  float xa = fabsf(x), ya = fabsf(y);
  float w = fmaxf(xa, ya), z = fminf(xa, ya);
  if (z == 0.f) return w;
  float t = z / w;
  return w * sqrtf(1.0f + t * t);
}

__device__ void slartg_(float f, float g, float& c, float& s, float& r) {
#pragma clang fp contract(off)
#if NEW_SLARTG
  const float safmin = 1.17549435e-38f;
  const float safmax = 8.50705917e+37f;
  const float rtmin = 1.08420217e-19f;   // sqrt(safmin)
  const float rtmax = 6.52221171e+18f;   // sqrt(safmax/2)
  float f1 = fabsf(f), g1 = fabsf(g);
  if (g == 0.f) { c = 1.f; s = 0.f; r = f; }
  else if (f == 0.f) { c = 0.f; s = (g >= 0.f) ? 1.f : -1.f; r = g1; }
  else {
    float d;
    if (f1 > rtmin && f1 < rtmax && g1 > rtmin && g1 < rtmax) {
      d = sqrtf(f * f + g * g);
      c = f1 / d;
      r = (f >= 0.f) ? d : -d;
    } else {
      float uu = fminf(safmax, fmaxf(safmin, fmaxf(f1, g1)));
      float fs = f / uu, gs = g / uu;
      d = sqrtf(fs * fs + gs * gs);
      c = fabsf(fs) / d;
      r = ((f >= 0.f) ? d : -d) * uu;
    }
    s = g / r;
  }
#else
  if (g == 0.f) { c = 1.f; s = 0.f; r = f; }
  else if (f == 0.f) { c = 0.f; s = 1.f; r = g; }
  else {
    float f1 = f, g1 = g;
    r = sqrtf(f1 * f1 + g1 * g1);
    c = f1 / r;
    s = g1 / r;
    if (fabsf(f) > fabsf(g) && c < 0.f) { c = -c; s = -s; r = -r; }
  }
#endif
}

__device__ void slaev2_(float a, float b, float c, float& rt1, float& rt2,
                        float& cs1, float& sn1) {
#pragma clang fp contract(off)
  float sm = a + c;
  float df = a - c;
  float adf = fabsf(df);
  float tb = b + b;
  float ab = fabsf(tb);
  float acmx, acmn;
  if (fabsf(a) > fabsf(c)) { acmx = a; acmn = c; } else { acmx = c; acmn = a; }
  float rt;
  if (adf > ab) { float t = ab / adf; rt = adf * sqrtf(1.f + t * t); }
  else if (adf < ab) { float t = adf / ab; rt = ab * sqrtf(1.f + t * t); }
  else { rt = ab * sqrtf(2.f); }
  int sgn1;
  if (sm < 0.f) {
    rt1 = 0.5f * (sm - rt); sgn1 = -1;
    rt2 = (acmx / rt1) * acmn - (b / rt1) * b;
  } else if (sm > 0.f) {
    rt1 = 0.5f * (sm + rt); sgn1 = 1;
    rt2 = (acmx / rt1) * acmn - (b / rt1) * b;
  } else {
    rt1 = 0.5f * rt; rt2 = -0.5f * rt; sgn1 = 1;
  }
  float cs; int sgn2;
  if (df >= 0.f) { cs = df + rt; sgn2 = 1; } else { cs = df - rt; sgn2 = -1; }
  float acs = fabsf(cs);
  if (acs > ab) {
    float ct = -tb / cs;
    sn1 = 1.f / sqrtf(1.f + ct * ct);
    cs1 = ct * sn1;
  } else {
    if (ab == 0.f) { cs1 = 1.f; sn1 = 0.f; }
    else {
      float tn = -cs / tb;
      cs1 = 1.f / sqrtf(1.f + tn * tn);
      sn1 = tn * cs1;
    }
  }
  if (sgn1 == sgn2) { float tn = cs1; cs1 = -sn1; sn1 = tn; }
}

// ssteqr for n=3, compz='I' (z must be identity on entry)
__device__ void ssteqr3_(float* d, float* e, float z[3][3]) {
#pragma clang fp contract(off)
  const float eps = 5.9604645e-08f;
  const float eps2 = 3.5527137e-15f;
  const float safmin = 1.17549435e-38f;
  const int n = 3;
  const int nmaxit = 90;
  int jtot = 0;
  int l1 = 1;

  while (1) {
    if (l1 > n) break;
    if (l1 > 1) e[l1 - 2] = 0.f;
    int m = n;
    if (l1 <= n - 1) {
      for (int mm = l1; mm <= n - 1; ++mm) {
        float tst = fabsf(e[mm - 1]);
        if (tst == 0.f) { m = mm; break; }
        if (tst <= (sqrtf(fabsf(d[mm - 1])) * sqrtf(fabsf(d[mm]))) * eps) {
          e[mm - 1] = 0.f; m = mm; break;
        }
      }
    }
    int l = l1, lsv = l, lend = m, lendsv = lend;
    (void)lsv; (void)lendsv;
    l1 = m + 1;
    if (lend == l) continue;

    float anorm = 0.f;
    for (int i = l; i <= lend; ++i) anorm = fmaxf(anorm, fabsf(d[i - 1]));
    for (int i = l; i <= lend - 1; ++i) anorm = fmaxf(anorm, fabsf(e[i - 1]));
    if (anorm == 0.f) continue;

    if (fabsf(d[lend - 1]) < fabsf(d[l - 1])) { lend = lsv; l = lendsv; }

    if (lend > l) {
      // --- QL iteration ---
      while (1) {
        int m2 = lend;
        if (l != lend) {
          for (int mm = l; mm <= lend - 1; ++mm) {
            float tst = fabsf(e[mm - 1]); tst = tst * tst;
            if (tst <= (eps2 * fabsf(d[mm - 1])) * fabsf(d[mm]) + safmin) { m2 = mm; break; }
          }
        }
        if (m2 < lend) e[m2 - 1] = 0.f;
        float p = d[l - 1];
        if (m2 == l) {
          d[l - 1] = p; l += 1;
          if (l <= lend) continue;
          break;
        }
        if (m2 == l + 1) {
          float rt1, rt2, cc, ss;
          slaev2_(d[l - 1], e[l - 1], d[l], rt1, rt2, cc, ss);
          for (int i = 0; i < 3; ++i) {
            float temp = z[i][l];
            z[i][l] = cc * temp - ss * z[i][l - 1];
            z[i][l - 1] = ss * temp + cc * z[i][l - 1];
          }
          d[l - 1] = rt1; d[l] = rt2; e[l - 1] = 0.f;
          l += 2;
          if (l <= lend) continue;
          break;
        }
        if (jtot == nmaxit) break;
        jtot++;
        float g = (d[l] - p) / (2.f * e[l - 1]);
        float r = slapy2_(g, 1.f);
        g = d[m2 - 1] - p + (e[l - 1] / (g + f_sign(r, g)));
        float s = 1.f, c = 1.f;
        p = 0.f;
        float csv[2], snv[2];
        for (int i = m2 - 1; i >= l; --i) {
          float f = s * e[i - 1];
          float b = c * e[i - 1];
          slartg_(g, f, c, s, r);
          if (i != m2 - 1) e[i] = r;
          g = d[i] - p;
          r = (d[i - 1] - g) * s + (2.f * c) * b;
          p = s * r;
          d[i] = g + p;
          g = c * r - b;
          csv[i - l] = c; snv[i - l] = -s;
        }
        int cnt = m2 - l;
        for (int j = cnt; j >= 1; --j) {       // slasr 'R','V','B'
          float cj = csv[j - 1], sj = snv[j - 1];
          int c0 = (l - 1) + (j - 1);
          for (int i = 0; i < 3; ++i) {
            float temp = z[i][c0 + 1];
            z[i][c0 + 1] = cj * temp - sj * z[i][c0];
            z[i][c0] = sj * temp + cj * z[i][c0];
          }
        }
        d[l - 1] = d[l - 1] - p;
        e[l - 1] = g;
      }
    } else {
      // --- QR iteration ---
      while (1) {
        int m2 = lend;
        if (l != lend) {
          for (int mm = l; mm >= lend + 1; --mm) {
            float tst = fabsf(e[mm - 2]); tst = tst * tst;
            if (tst <= (eps2 * fabsf(d[mm - 1])) * fabsf(d[mm - 2]) + safmin) { m2 = mm; break; }
          }
        }
        if (m2 > lend) e[m2 - 2] = 0.f;
        float p = d[l - 1];
        if (m2 == l) {
          d[l - 1] = p; l -= 1;
          if (l >= lend) continue;
          break;
        }
        if (m2 == l - 1) {
          float rt1, rt2, cc, ss;
          slaev2_(d[l - 2], e[l - 2], d[l - 1], rt1, rt2, cc, ss);
          for (int i = 0; i < 3; ++i) {
            float temp = z[i][l - 1];
            z[i][l - 1] = cc * temp - ss * z[i][l - 2];
            z[i][l - 2] = ss * temp + cc * z[i][l - 2];
          }
          d[l - 2] = rt1; d[l - 1] = rt2; e[l - 2] = 0.f;
          l -= 2;
          if (l >= lend) continue;
          break;
        }
        if (jtot == nmaxit) break;
        jtot++;
        float g = (d[l - 2] - p) / (2.f * e[l - 2]);
        float r = slapy2_(g, 1.f);
        g = d[m2 - 1] - p + (e[l - 2] / (g + f_sign(r, g)));
        float s = 1.f, c = 1.f;
        p = 0.f;
        float csv[2], snv[2];
        for (int i = m2; i <= l - 1; ++i) {
          float f = s * e[i - 1];
          float b = c * e[i - 1];
          slartg_(g, f, c, s, r);
          if (i != m2) e[i - 2] = r;
          g = d[i - 1] - p;
          r = (d[i] - g) * s + (2.f * c) * b;
          p = s * r;
          d[i - 1] = g + p;
          g = c * r - b;
          csv[i - m2] = c; snv[i - m2] = s;
        }
        int cnt = l - m2;
        for (int j = 1; j <= cnt; ++j) {       // slasr 'R','V','F'
          float cj = csv[j - 1], sj = snv[j - 1];
          int c0 = (m2 - 1) + (j - 1);
          for (int i = 0; i < 3; ++i) {
            float temp = z[i][c0 + 1];
            z[i][c0 + 1] = cj * temp - sj * z[i][c0];
            z[i][c0] = sj * temp + cj * z[i][c0];
          }
        }
        d[l - 1] = d[l - 1] - p;
        e[l - 2] = g;
      }
    }
  }

  // selection sort ascending, swap eigenvector columns (LAPACK exact)
  for (int ii = 2; ii <= n; ++ii) {
    int i = ii - 1, k = i;
    float p = d[i - 1];
    for (int j = ii; j <= n; ++j)
      if (d[j - 1] < p) { k = j; p = d[j - 1]; }
    if (k != i) {
      d[k - 1] = d[i - 1]; d[i - 1] = p;
      for (int r2 = 0; r2 < 3; ++r2) {
        float t = z[r2][i - 1]; z[r2][i - 1] = z[r2][k - 1]; z[r2][k - 1] = t;
      }
    }
  }
}

// full ssyevd replica for 3x3 symmetric (lower entries), eigenvectors only
__device__ void eigh3_(float a00, float a10, float a11, float a20, float a21,
                       float a22, float V[3][3]) {
#pragma clang fp contract(off)
  float d0, d1, d2, e0, e1, tau1 = 0.f, v2 = 0.f;
  {
    float alpha = a10;
    float xnorm = fabsf(a20);
    if (xnorm == 0.f) {
      tau1 = 0.f; v2 = 0.f;
      e0 = alpha; d0 = a00; d1 = a11; d2 = a22; e1 = a21;
    } else {
      float beta = -f_sign(slapy2_(alpha, xnorm), alpha);
      tau1 = (beta - alpha) / beta;
      float inv = 1.0f / (alpha - beta);
      v2 = a20 * inv;
      float y0 = tau1 * a11;
      float y1v = tau1 * a21;
      float temp2 = a21 * v2;
      y0 = y0 + tau1 * temp2;
      y1v = y1v + (tau1 * v2) * a22;
      float dotyv = y0 * 1.f + y1v * v2;
      float al = (-0.5f * tau1) * dotyv;
      float w0 = y0 + al * 1.f;
      float w1 = y1v + al * v2;
      a11 = (a11 + 1.f * (-w0)) + w0 * (-1.f);
      a21 = (a21 + v2 * (-w0)) + w1 * (-1.f);
      a22 = (a22 + v2 * (-w1)) + w1 * (-v2);
      e0 = beta; d0 = a00; d1 = a11; d2 = a22; e1 = a21;
    }
  }
  float dd[3] = { d0, d1, d2 };
  float ee[2] = { e0, e1 };
  float z[3][3] = { {1.f,0.f,0.f},{0.f,1.f,0.f},{0.f,0.f,1.f} };
  ssteqr3_(dd, ee, z);
  if (tau1 != 0.f) {
    for (int j = 0; j < 3; ++j) {
      float wj = z[1][j] * 1.f + z[2][j] * v2;
      float temp = -tau1 * wj;
      z[1][j] = z[1][j] + 1.f * temp;
      z[2][j] = z[2][j] + v2 * temp;
    }
  }
  for (int r = 0; r < 3; ++r)
    for (int cix = 0; cix < 3; ++cix)
      V[r][cix] = z[r][cix];
}

// ---------------- kernels ----------------

// zero the BN1-3 stat buckets (doubles) and y1key
__global__ void zero_kernel(double* sb, int nd, u32* p2, int n2) {
  int t = blockIdx.x * blockDim.x + threadIdx.x;
  if (t < nd) sb[t] = 0.0;
  if (t < n2) p2[t] = 0u;
}

// exact KNN top-20 per point: threshold-select + wave bitonic sort.
__global__ __launch_bounds__(256) void knn_kernel(const float* __restrict__ pos,
                                                  int* __restrict__ idx) {
#pragma clang fp contract(off)
  __shared__ u64 cke[4][128];
  int w = threadIdx.x >> 6;
  int lane = threadIdx.x & 63;
  int wid = blockIdx.x * 4 + w;
  int b = wid >> 11;
  int n = wid & 2047;
  const float* pc = pos + (size_t)b * NNp * 3;
  float qx = pc[n * 3 + 0], qy = pc[n * 3 + 1], qz = pc[n * 3 + 2];
  float d2n = (qx * qx + qy * qy) + qz * qz;

  // pass A: 32 keys per lane, in registers; track wave-min
  u32 kreg[32];
  u32 mk = 0xFFFFFFFFu;
#pragma unroll
  for (int t = 0; t < 32; ++t) {
    int m = lane + 64 * t;
    float x = pc[m * 3 + 0], y = pc[m * 3 + 1], zc = pc[m * 3 + 2];
    float d2m = (x * x + y * y) + zc * zc;
    float dot = (qx * x + qy * y) + qz * zc;
    float dist = (d2n + d2m) - 2.0f * dot;
    u32 key = fkey(dist);
    if (m == n) key = 0xFFFFFFFFu;   // self-exclusion (== +1e10 diag in ref)
    kreg[t] = key;
    mk = key < mk ? key : mk;
  }
#pragma unroll
  for (int off = 32; off; off >>= 1) {
    u32 o = __shfl_xor(mk, off);
    mk = o < mk ? o : mk;
  }

  // threshold search: find hi with 20 <= count(key<=hi) <= 128
  u32 lo_b = mk - 1u, hi_b = 0xFFFFFFFEu;
  int c_hi = 2047;
  float tf = funkey(mk) * 7.368f;     // count ~ T^1.5 => rank-20 guess
  u32 T = fkey(tf);
  if (T < mk) T = mk;
  if (T > 0xFFFFFFFEu) T = 0xFFFFFFFEu;
  for (int it = 0; it < 48; ++it) {
    int cnt = 0;
#pragma unroll
    for (int t = 0; t < 32; ++t) cnt += (kreg[t] <= T) ? 1 : 0;
#pragma unroll
    for (int off = 32; off; off >>= 1) cnt += __shfl_xor(cnt, off);
    if (cnt >= 20) {
      hi_b = T; c_hi = cnt;
      if (cnt <= 128) break;
    } else {
      lo_b = T;
    }
    if (hi_b <= lo_b + 1u) break;
    u32 Tn;
    if (it < 12) {
      float tfc = funkey(T);
      int cc = cnt < 1 ? 1 : cnt;
      float guess = tfc * __builtin_exp2f(0.66667f * __builtin_log2f(45.0f / (float)cc));
      Tn = fkey(guess);
      if (!(Tn > lo_b && Tn < hi_b)) Tn = lo_b + ((hi_b - lo_b) >> 1);
    } else {
      Tn = lo_b + ((hi_b - lo_b) >> 1);   // pure bisection
    }
    T = Tn;
  }

  // collect survivors (key <= hi_b) in m-ascending order via ballot prefix
  u64* ck = cke[w];
  u32 base = 0;
#pragma unroll
  for (int t = 0; t < 32; ++t) {
    bool pass = kreg[t] <= hi_b;
    u64 ball = __ballot(pass);
    if (pass) {
      u32 posn = base + (u32)__popcll(ball & ((1ull << lane) - 1ull));
      if (posn < 128u)
        ck[posn] = ((u64)kreg[t] << 32) | (u32)(lane + 64 * t);
    }
    base += (u32)__popcll(ball);
  }
  if (base > 128u) {
    base = 0;
#pragma unroll
    for (int t = 0; t < 32; ++t) {
      bool pass = kreg[t] <= lo_b;
      u64 ball = __ballot(pass);
      if (pass) {
        u32 posn = base + (u32)__popcll(ball & ((1ull << lane) - 1ull));
        ck[posn] = ((u64)kreg[t] << 32) | (u32)(lane + 64 * t);
      }
      base += (u32)__popcll(ball);
    }
#pragma unroll
    for (int t = 0; t < 32; ++t) {
      bool pass = (kreg[t] > lo_b) && (kreg[t] <= hi_b);
      u64 ball = __ballot(pass);
      if (pass) {
        u32 posn = base + (u32)__popcll(ball & ((1ull << lane) - 1ull));
        if (posn < 128u)
          ck[posn] = ((u64)kreg[t] << 32) | (u32)(lane + 64 * t);
      }
      base += (u32)__popcll(ball);
    }
  }
  u32 ctot = base < 128u ? base : 128u;

  // sort survivors ascending by (key, m); take first 20
  u64 e0 = (lane < (int)ctot) ? ck[lane] : ~0ull;
  bsort64(e0, lane);
  if (ctot > 64u) {
    u64 e1 = (lane + 64 < (int)ctot) ? ck[lane + 64] : ~0ull;
    bsort64(e1, lane);
    u64 r = sidx64(e1, 63 - lane);          // reverse second run
    u64 mn = r < e0 ? r : e0;               // bitonic
#pragma unroll
    for (int j = 32; j > 0; j >>= 1) {      // clean
      u64 pv = sxor64(mn, j);
      bool lower2 = ((lane & j) == 0);
      bool take = lower2 ? (pv < mn) : (pv > mn);
      mn = take ? pv : mn;
    }
    e0 = mn;
  }
  if (lane < 20)
    idx[(size_t)wid * 20 + lane] = (int)(u32)(e0 & 0xFFFFFFFFull);
}

// per-point: covariance, LAPACK-replica eigh, loc = rel @ V
__global__ __launch_bounds__(64) void prep_kernel(const float* __restrict__ pos,
                                                  const int* __restrict__ idx,
                                                  float* __restrict__ loc,
                                                  float* __restrict__ Vout) {
#pragma clang fp contract(off)
  int p = blockIdx.x * 64 + threadIdx.x;
  int b = p >> 11, n = p & 2047;
  const float* pc = pos + (size_t)b * NNp * 3;
  float qx = pc[n * 3 + 0], qy = pc[n * 3 + 1], qz = pc[n * 3 + 2];
  const int* ip = idx + (size_t)p * 20;
  float c00 = 0, c01 = 0, c02 = 0, c11 = 0, c12 = 0, c22 = 0;
  for (int k = 0; k < 20; ++k) {
    int j = ip[k];
    float rx = pc[j * 3 + 0] - qx, ry = pc[j * 3 + 1] - qy, rz = pc[j * 3 + 2] - qz;
    c00 += rx * rx; c01 += rx * ry; c02 += rx * rz;
    c11 += ry * ry; c12 += ry * rz; c22 += rz * rz;
  }
  float Vm[3][3];
  eigh3_(c00, c01, c11, c02, c12, c22, Vm);
  float* vp = Vout + (size_t)p * 9;
  for (int d = 0; d < 3; ++d)
    for (int e = 0; e < 3; ++e) vp[d * 3 + e] = Vm[d][e];
  for (int k = 0; k < 20; ++k) {
    int j = ip[k];
    float rx = pc[j * 3 + 0] - qx, ry = pc[j * 3 + 1] - qy, rz = pc[j * 3 + 2] - qz;
    float l0 = rx * Vm[0][0] + ry * Vm[1][0] + rz * Vm[2][0];
    float l1 = rx * Vm[0][1] + ry * Vm[1][1] + rz * Vm[2][1];
    float l2 = rx * Vm[0][2] + ry * Vm[1][2] + rz * Vm[2][2];
    size_t e = ((size_t)p * 20 + k) * 3;
    loc[e + 0] = l0; loc[e + 1] = l1; loc[e + 2] = l2;
  }
}

// layer1: [E,3]@[3,64]+b, relu, store fp32; fused per-channel stats
// (wave = 64 edges, lane = channel; s/q accumulate in-register).
__global__ __launch_bounds__(256) void l1_kernel(const float* __restrict__ loc,
                                                 const float* __restrict__ W,
                                                 const float* __restrict__ bias,
                                                 float* __restrict__ h1,
                                                 double* __restrict__ sb) {
  __shared__ float sW[192];
  __shared__ float sB[64];
  __shared__ float red[512];
  int t = threadIdx.x;
  if (t < 192) sW[t] = W[t];
  if (t < 64) sB[t] = bias[t];
  __syncthreads();
  int w = t >> 6, c = t & 63;
  size_t e0 = (size_t)blockIdx.x * 256 + w * 64;
  float wc0 = sW[c], wc1 = sW[64 + c], wc2 = sW[128 + c], bc = sB[c];
  float s = 0.f, q = 0.f;
  for (int e = 0; e < 64; ++e) {
    float x0 = loc[(e0 + e) * 3 + 0];
    float x1 = loc[(e0 + e) * 3 + 1];
    float x2 = loc[(e0 + e) * 3 + 2];
    float z = fmaxf(bc + x0 * wc0 + x1 * wc1 + x2 * wc2, 0.f);
    h1[(e0 + e) * 64 + c] = z;
    s += z; q += z * z;
  }
  red[w * 64 + c] = s;
  red[256 + w * 64 + c] = q;
  __syncthreads();
  if (t < 64) {
    float S = red[t] + red[64 + t] + red[128 + t] + red[192 + t];
    float Q = red[256 + t] + red[320 + t] + red[384 + t] + red[448 + t];
    atomicAdd(&sb[((int)blockIdx.x & 63) * 128 + t], (double)S);
    atomicAdd(&sb[((int)blockIdx.x & 63) * 128 + 64 + t], (double)Q);
  }
}

// 64-bucket stats (64 ch) -> per-channel BN affine (fixed-order reduce)
__global__ void finalizeB_kernel(const double* __restrict__ sb,
                                 const float* __restrict__ g,
                                 const float* __restrict__ be,
                                 float* __restrict__ outp) {
  int c = threadIdx.x;   // 64 threads
  if (c >= 64) return;
  double s = 0.0, q = 0.0;
  for (int buk = 0; buk < 64; ++buk) {
    s += sb[buk * 128 + c];
    q += sb[buk * 128 + 64 + c];
  }
  double m = s / (double)EE;
  double var = q / (double)EE - m * m;
  double inv = 1.0 / sqrt(var + 1e-5);
  double sc = (double)g[c] * inv;
  outp[c] = (float)sc;
  outp[64 + c] = (float)((double)be[c] - m * sc);
}

// 64-bucket stats (128 ch) -> BN4 affine (fixed-order bucket reduce)
__global__ void finalize64_kernel(const double* __restrict__ s4b,
                                  const float* __restrict__ g,
                                  const float* __restrict__ be,
                                  float* __restrict__ outp) {
  int c = threadIdx.x;   // 128 threads
  double s = 0.0, q = 0.0;
  for (int buk = 0; buk < 64; ++buk) {
    s += s4b[buk * 256 + c];
    q += s4b[buk * 256 + 128 + c];
  }
  double m = s / (double)EE;
  double var = q / (double)EE - m * m;
  double inv = 1.0 / sqrt(var + 1e-5);
  double sc = (double)g[c] * inv;
  outp[c] = (float)sc;
  outp[128 + c] = (float)((double)be[c] - m * sc);
}

// layers 2/3: fp32 [E,64] @ [64,64]+b, relu, IN-PLACE capable (hin==hout);
// fused per-channel stats -> 64-way bucketed fp64 atomics.
__global__ __launch_bounds__(256) void l23_kernel(const float* __restrict__ hin,
                                                  const float* __restrict__ ss,
                                                  const float* __restrict__ W,
                                                  const float* __restrict__ bias,
                                                  float* __restrict__ hout,
                                                  double* __restrict__ sb) {
  __shared__ float xT[64 * 84];
  int t = threadIdx.x;
  size_t e0 = (size_t)blockIdx.x * 80;
  for (int v = t; v < 80 * 64; v += 256) {
    int el = v >> 6, c = v & 63;
    float val = hin[(e0 + el) * 64 + c];
    val = val * ss[c] + ss[64 + c];
    xT[c * 84 + el] = val;
  }
  __syncthreads();
  int og = t & 15, eg = t >> 4;
  int o0 = og * 4, eb = eg * 5;
  float acc[5][4];
#pragma unroll
  for (int a = 0; a < 5; ++a)
#pragma unroll
    for (int o = 0; o < 4; ++o) acc[a][o] = 0.f;
  for (int i = 0; i < 64; ++i) {
    float4 w4 = *(const float4*)&W[i * 64 + o0];
    float xx[5];
#pragma unroll
    for (int a = 0; a < 5; ++a) xx[a] = xT[i * 84 + eb + a];
#pragma unroll
    for (int a = 0; a < 5; ++a) {
      acc[a][0] += xx[a] * w4.x;
      acc[a][1] += xx[a] * w4.y;
      acc[a][2] += xx[a] * w4.z;
      acc[a][3] += xx[a] * w4.w;
    }
  }
  float4 b4 = *(const float4*)&bias[o0];
  float so0 = 0.f, so1 = 0.f, so2 = 0.f, so3 = 0.f;
  float qo0 = 0.f, qo1 = 0.f, qo2 = 0.f, qo3 = 0.f;
#pragma unroll
  for (int a = 0; a < 5; ++a) {
    size_t e = e0 + eb + a;
    float4 st;
    st.x = fmaxf(acc[a][0] + b4.x, 0.f);
    st.y = fmaxf(acc[a][1] + b4.y, 0.f);
    st.z = fmaxf(acc[a][2] + b4.z, 0.f);
    st.w = fmaxf(acc[a][3] + b4.w, 0.f);
    *(float4*)&hout[e * 64 + o0] = st;
    so0 += st.x; qo0 += st.x * st.x;
    so1 += st.y; qo1 += st.y * st.y;
    so2 += st.z; qo2 += st.z * st.z;
    so3 += st.w; qo3 += st.w * st.w;
  }
  __syncthreads();     // done with xT as input tile
  float* sred = xT;          // 1024 floats
  float* qred = xT + 1024;   // 1024 floats
  sred[(o0 + 0) * 16 + eg] = so0;
  sred[(o0 + 1) * 16 + eg] = so1;
  sred[(o0 + 2) * 16 + eg] = so2;
  sred[(o0 + 3) * 16 + eg] = so3;
  qred[(o0 + 0) * 16 + eg] = qo0;
  qred[(o0 + 1) * 16 + eg] = qo1;
  qred[(o0 + 2) * 16 + eg] = qo2;
  qred[(o0 + 3) * 16 + eg] = qo3;
  __syncthreads();
  if (t < 64) {
    float S = 0.f, Q = 0.f;
#pragma unroll
    for (int i = 0; i < 16; ++i) {
      S += sred[t * 16 + i];
      Q += qred[t * 16 + i];
    }
    atomicAdd(&sb[((int)blockIdx.x & 63) * 128 + t], (double)S);
    atomicAdd(&sb[((int)blockIdx.x & 63) * 128 + 64 + t], (double)Q);
  }
}

// f3d[p][c][d] = max_k h3n[p,k,c] * loc[p,k,d]
__global__ __launch_bounds__(256) void f3d_kernel(const float* __restrict__ h3,
                                                  const float* __restrict__ ss3,
                                                  const float* __restrict__ loc,
                                                  float* __restrict__ f3d) {
  int t = threadIdx.x;
  int p = blockIdx.x * 4 + (t >> 6);
  int c = t & 63;
  float sc = ss3[c], sh = ss3[64 + c];
  float m0 = -__builtin_inff(), m1 = m0, m2 = m0;
  size_t eb = (size_t)p * 20;
  for (int k = 0; k < 20; ++k) {
    size_t e = eb + k;
    float h = h3[e * 64 + c] * sc + sh;
    float l0 = loc[e * 3 + 0], l1 = loc[e * 3 + 1], l2 = loc[e * 3 + 2];
    m0 = fmaxf(m0, h * l0);
    m1 = fmaxf(m1, h * l1);
    m2 = fmaxf(m2, h * l2);
  }
  size_t o = (size_t)p * 192 + c * 3;
  f3d[o + 0] = m0; f3d[o + 1] = m1; f3d[o + 2] = m2;
}

// W21 [192][128] fp32 -> WT bf16 [128][192]; also zeroes the s4b buckets
__global__ __launch_bounds__(256) void wtcvt_kernel(const float* __restrict__ W,
                                                    u16* __restrict__ wt,
                                                    double* __restrict__ s4b) {
  int id = blockIdx.x * 256 + threadIdx.x;
  if (id < 192 * 128) {
    int n = id / 192, k = id - n * 192;
    wt[id] = f2bf(W[(size_t)k * 128 + n]);
  }
  if (id < 64 * 256) s4b[id] = 0.0;
}

// DD2 via bf16 MFMA: cloud->XCD swizzle; gather f3d[idx], rotate by V ->
// X bf16 LDS [80][200]; W-fragments in registers; GEMM [80,192]@[192,128];
// bias+relu+maxpool+stats fused; stats -> 64-way bucketed fp64 atomics.
// OUTPUT TRANSPOSED: fdd2T[128][16384].
__global__ __launch_bounds__(256) void dd2_kernel(const float* __restrict__ f3d,
                                                  const float* __restrict__ Vmat,
                                                  const int* __restrict__ idx,
                                                  const u16* __restrict__ wt,
                                                  const float* __restrict__ bias,
                                                  float* __restrict__ fdd2T,
                                                  double* __restrict__ s4b) {
  __shared__ u16 sX[80 * 200];     // X bf16, row stride 200 (400B, 16B aligned)
  __shared__ float sV[36];
  __shared__ int sJ[80];
  int t = threadIdx.x;
  int wk = (blockIdx.x & 7) * 512 + (blockIdx.x >> 3);
  int p0 = wk * 4;
  int bcl = p0 >> 11;              // cloud (4 points never straddle clouds)
  int buk = ((int)blockIdx.x & 63) << 8;   // stats bucket base

  int w = t >> 6, l = t & 63;
  int lr = l & 15, lg = l >> 4;

  // preload B fragments: lane holds cols (w*32+nt*16+lr), k-slices lg*8+...
  short8 breg[2][6];
#pragma unroll
  for (int nt = 0; nt < 2; ++nt)
#pragma unroll
    for (int s = 0; s < 6; ++s) {
      const int kk = (s / 3) * 96 + (s % 3) * 32 + lg * 8;
      breg[nt][s] = *(const short8*)&wt[(w * 32 + nt * 16 + lr) * 192 + kk];
    }

  if (t < 36) sV[t] = Vmat[(size_t)p0 * 9 + t];
  if (t < 80) sJ[t] = ((bcl << 11) + idx[(size_t)p0 * 20 + t]) * 192;
  __syncthreads();

  // build X: el = edge 0..79, c2 = channel-pair 0..31
  for (int v = t; v < 80 * 32; v += 256) {
    int el = v >> 5, c2 = v & 31;
    int pp = el / 20;
    const float* fp = f3d + (size_t)sJ[el] + 6 * c2;
    float f0 = fp[0], f1 = fp[1], f2 = fp[2];
    float f3 = fp[3], f4 = fp[4], f5 = fp[5];
    const float* Vp = &sV[pp * 9];
    float x0 = f0 * Vp[0] + f1 * Vp[3] + f2 * Vp[6];
    float x1 = f0 * Vp[1] + f1 * Vp[4] + f2 * Vp[7];
    float x2 = f0 * Vp[2] + f1 * Vp[5] + f2 * Vp[8];
    float y0 = f3 * Vp[0] + f4 * Vp[3] + f5 * Vp[6];
    float y1 = f3 * Vp[1] + f4 * Vp[4] + f5 * Vp[7];
    float y2 = f3 * Vp[2] + f4 * Vp[5] + f5 * Vp[8];
    u32* xp = (u32*)&sX[el * 200 + 6 * c2];
    xp[0] = (u32)f2bf(x0) | ((u32)f2bf(x1) << 16);
    xp[1] = (u32)f2bf(x2) | ((u32)f2bf(y0) << 16);
    xp[2] = (u32)f2bf(y1) | ((u32)f2bf(y2) << 16);
  }
  __syncthreads();

  f32x4 acc[5][2];
#pragma unroll
  for (int mt = 0; mt < 5; ++mt) {
    acc[mt][0] = (f32x4)(0.f);
    acc[mt][1] = (f32x4)(0.f);
  }

  // K-steps in the same order as R5 (H0:KS0,1,2 then H1:KS0,1,2)
#pragma unroll
  for (int s = 0; s < 6; ++s) {
    const int kbase = (s / 3) * 96 + (s % 3) * 32 + lg * 8;
#pragma unroll
    for (int mt = 0; mt < 5; ++mt) {
      short8 a = *(const short8*)&sX[(mt * 16 + lr) * 200 + kbase];
      acc[mt][0] = __builtin_amdgcn_mfma_f32_16x16x32_bf16(a, breg[0][s], acc[mt][0], 0, 0, 0);
      acc[mt][1] = __builtin_amdgcn_mfma_f32_16x16x32_bf16(a, breg[1][s], acc[mt][1], 0, 0, 0);
    }
  }

  // epilogue: z = relu(acc+bias); maxpool over k per point; per-channel stats
#pragma unroll
  for (int nt = 0; nt < 2; ++nt) {
    int col = w * 32 + nt * 16 + lr;
    float bs = bias[col];
    float pm0 = 0.f, pm1 = 0.f, pm2 = 0.f, pm3 = 0.f;
    float s = 0.f, q = 0.f;
#pragma unroll
    for (int mt = 0; mt < 5; ++mt) {
#pragma unroll
      for (int r = 0; r < 4; ++r) {
        int edge = mt * 16 + lg * 4 + r;   // 0..79, exact (no padding)
        float z = fmaxf(acc[mt][nt][r] + bs, 0.f);
        pm0 = fmaxf(pm0, (edge < 20) ? z : 0.f);
        pm1 = fmaxf(pm1, (edge >= 20 && edge < 40) ? z : 0.f);
        pm2 = fmaxf(pm2, (edge >= 40 && edge < 60) ? z : 0.f);
        pm3 = fmaxf(pm3, (edge >= 60) ? z : 0.f);
        s += z; q += z * z;
      }
    }
#pragma unroll
    for (int off = 16; off < 64; off <<= 1) {
      pm0 = fmaxf(pm0, __shfl_xor(pm0, off));
      pm1 = fmaxf(pm1, __shfl_xor(pm1, off));
      pm2 = fmaxf(pm2, __shfl_xor(pm2, off));
      pm3 = fmaxf(pm3, __shfl_xor(pm3, off));
      s += __shfl_xor(s, off);
      q += __shfl_xor(q, off);
    }
    if (l < 16) {
      float4 pv;
      pv.x = pm0; pv.y = pm1; pv.z = pm2; pv.w = pm3;
      *(float4*)&fdd2T[(size_t)col * NP + p0] = pv;
      atomicAdd(&s4b[buk + col], (double)s);
      atomicAdd(&s4b[buk + 128 + col], (double)q);
    }
  }
}

// y1: fp32 GEMM [16384,128]@[128,1024] with fused max over n.
// 128Mx128N tile, 8x8 acc/thread (two 4-col groups at 16B stride = no
// conflicts), K in two 64-deep LDS stages (64KB -> 2 blk/CU).
// k-order sequential 0..127 -> outputs bit-identical to R8.
__global__ __launch_bounds__(256) void y1_kernel(const float* __restrict__ fdd2T,
                                                 const float* __restrict__ ss4,
                                                 const float* __restrict__ wh1,
                                                 u32* __restrict__ y1key) {
  __shared__ float sX[64][128];   // [k][point]
  __shared__ float sW[64][128];   // [k][chan]
  int t = threadIdx.x;
  int mtile = blockIdx.x & 127;
  int ntile = blockIdx.x >> 7;
  int cl = mtile >> 4;                  // 16 mtiles per cloud
  size_t pbase = (size_t)mtile * 128;
  int c0 = ntile * 128;
  int mg = t >> 4, ng = t & 15;

  float acc[8][8];
#pragma unroll
  for (int i = 0; i < 8; ++i)
#pragma unroll
    for (int j = 0; j < 8; ++j) acc[i][j] = 0.f;

  for (int ks = 0; ks < 2; ++ks) {
    // stage 64 k-rows of X (normalized) and W
    int rr = t >> 5, mq = t & 31;
#pragma unroll
    for (int i = 0; i < 8; ++i) {
      int r = rr + i * 8;
      int k = ks * 64 + r;
      float4 x4 = *(const float4*)&fdd2T[(size_t)k * NP + pbase + mq * 4];
      float sc = ss4[k], sh = ss4[128 + k];
      float4 st;
      st.x = x4.x * sc + sh;
      st.y = x4.y * sc + sh;
      st.z = x4.z * sc + sh;
      st.w = x4.w * sc + sh;
      *(float4*)&sX[r][mq * 4] = st;
      float4 w4 = *(const float4*)&wh1[(size_t)k * 1024 + c0 + mq * 4];
      *(float4*)&sW[r][mq * 4] = w4;
    }
    __syncthreads();
#pragma unroll 8
    for (int kk = 0; kk < 64; ++kk) {
      float4 xa = *(const float4*)&sX[kk][mg * 4];
      float4 xb = *(const float4*)&sX[kk][64 + mg * 4];
      float4 wa = *(const float4*)&sW[kk][ng * 4];
      float4 wb = *(const float4*)&sW[kk][64 + ng * 4];
      float xr[8] = { xa.x, xa.y, xa.z, xa.w, xb.x, xb.y, xb.z, xb.w };
      float wc[8] = { wa.x, wa.y, wa.z, wa.w, wb.x, wb.y, wb.z, wb.w };
#pragma unroll
      for (int i = 0; i < 8; ++i)
#pragma unroll
        for (int j = 0; j < 8; ++j) acc[i][j] += xr[i] * wc[j];
    }
    __syncthreads();
  }

  // per-thread max over its 8 rows (all same cloud) per column
  float colmax[8];
#pragma unroll
  for (int j = 0; j < 8; ++j) {
    float v = acc[0][j];
#pragma unroll
    for (int i = 1; i < 8; ++i) v = fmaxf(v, acc[i][j]);
    colmax[j] = v;
  }
  float* red = &sX[0][0];   // 2048 floats needed
#pragma unroll
  for (int j = 0; j < 8; ++j) {
    int col = (j < 4) ? (ng * 4 + j) : (64 + ng * 4 + (j - 4));
    red[col * 16 + mg] = colmax[j];
  }
  __syncthreads();
  if (t < 128) {
    float m = red[t * 16];
#pragma unroll
    for (int i = 1; i < 16; ++i) m = fmaxf(m, red[t * 16 + i]);
    atomicMax(&y1key[(size_t)cl * 1024 + c0 + t], fkey(m));
  }
}

// y1 decode + bias + relu + BN over 8 clouds
__global__ void y1bn_kernel(const u32* __restrict__ y1key,
                            const float* __restrict__ bh1,
                            const float* __restrict__ g,
                            const float* __restrict__ be,
                            float* __restrict__ y1n) {
  int c = blockIdx.x * 256 + threadIdx.x;
  if (c >= 1024) return;
  float bs = bh1[c];
  float v[8]; double s = 0.0;
#pragma unroll
  for (int b = 0; b < 8; ++b) {
    v[b] = fmaxf(funkey(y1key[b * 1024 + c]) + bs, 0.f);
    s += (double)v[b];
  }
  double m = s / 8.0, q = 0.0;
#pragma unroll
  for (int b = 0; b < 8; ++b) { double d = (double)v[b] - m; q += d * d; }
  q /= 8.0;
  double inv = 1.0 / sqrt(q + 1e-5);
  double sg = (double)g[c] * inv;
#pragma unroll
  for (int b = 0; b < 8; ++b)
    y1n[b * 1024 + c] = (float)(((double)v[b] - m) * sg + (double)be[c]);
}

// head GEMM, K-split: grid = notile*8; block 256 = 64 outs x 4 k-subs.
__global__ __launch_bounds__(256) void hgemm_kernel(const float* __restrict__ yin,
                                                    const float* __restrict__ W,
                                                    float* __restrict__ part,
                                                    int INn, int OUTn, int notile) {
  __shared__ float sx[8 * 128];
  __shared__ float red[4][8][64];
  int t = threadIdx.x;
  int og = blockIdx.x % notile;
  int ks = blockIdx.x / notile;
  int KC = INn >> 3;                 // IN/8
  int k0 = ks * KC;
  for (int v = t; v < 8 * KC; v += 256) {
    int b = v / KC, i = v - b * KC;
    sx[b * KC + i] = yin[(size_t)b * INn + k0 + i];
  }
  __syncthreads();
  int o = og * 64 + (t & 63);
  int kq = t >> 6;
  int sub = KC >> 2;
  float acc[8];
#pragma unroll
  for (int b = 0; b < 8; ++b) acc[b] = 0.f;
  if (o < OUTn) {
    for (int i = kq * sub; i < kq * sub + sub; ++i) {
      float w = W[(size_t)(k0 + i) * OUTn + o];
#pragma unroll
      for (int b = 0; b < 8; ++b) acc[b] += sx[b * KC + i] * w;
    }
  }
#pragma unroll
  for (int b = 0; b < 8; ++b) red[kq][b][t & 63] = acc[b];
  __syncthreads();
  if (kq == 0 && o < OUTn) {
#pragma unroll
    for (int b = 0; b < 8; ++b) {
      float s = ((red[0][b][t] + red[1][b][t]) + red[2][b][t]) + red[3][b][t];
      part[(size_t)(ks * 8 + b) * 512 + o] = s;
    }
  }
}

// head reduce: sum 8 K-chunks in fixed order + bias + relu + BN over 8
__global__ void hreduce_kernel(const float* __restrict__ part,
                               const float* __restrict__ bias,
                               const float* __restrict__ g,
                               const float* __restrict__ be,
                               float* __restrict__ yout, int OUTn) {
  int o = blockIdx.x * 256 + threadIdx.x;
  if (o >= OUTn) return;
  float bs = bias[o];
  float v[8]; double s = 0.0;
#pragma unroll
  for (int b = 0; b < 8; ++b) {
    float p = 0.f;
#pragma unroll
    for (int ks = 0; ks < 8; ++ks) p += part[(size_t)(ks * 8 + b) * 512 + o];
    v[b] = fmaxf(p + bs, 0.f);
    s += (double)v[b];
  }
  double m = s / 8.0, q = 0.0;
#pragma unroll
  for (int b = 0; b < 8; ++b) { double d = (double)v[b] - m; q += d * d; }
  q /= 8.0;
  double inv = 1.0 / sqrt(q + 1e-5);
  double sg = (double)g[o] * inv;
#pragma unroll
  for (int b = 0; b < 8; ++b)
    yout[(size_t)b * OUTn + o] = (float)(((double)v[b] - m) * sg + (double)be[o]);
}

// final linear [8,265]@[265,40]+b then log_softmax per row
__global__ __launch_bounds__(384) void logits_kernel(const float* __restrict__ y3n,
                                                     const float* __restrict__ W,
                                                     const float* __restrict__ bias,
                                                     float* __restrict__ out) {
  __shared__ float sy[8 * 265];
  __shared__ float slog[320];
  __shared__ float sm[8], sl[8];
  int t = threadIdx.x;
  for (int v = t; v < 8 * 265; v += 384) sy[v] = y3n[v];
  __syncthreads();
  if (t < 320) {
    int b = t / 40, o = t % 40;
    float acc = 0.f;
    for (int i = 0; i < 265; ++i) acc += sy[b * 265 + i] * W[i * 40 + o];
    slog[t] = acc + bias[o];
  }
  __syncthreads();
  if (t < 8) {
    float m = slog[t * 40];
    for (int o = 1; o < 40; ++o) m = fmaxf(m, slog[t * 40 + o]);
    float s = 0.f;
    for (int o = 0; o < 40; ++o) s += expf(slog[t * 40 + o] - m);
    sm[t] = m; sl[t] = logf(s);
  }
  __syncthreads();
  if (t < 320) {
    int b = t / 40;
    out[t] = slog[t] - sm[b] - sl[b];
  }
}

// ---------------- launcher ----------------
extern "C" void kernel_launch(void* const* d_in, const int* in_sizes, int n_in,
                              void* d_out, int out_size, void* d_ws, size_t ws_size,
                              hipStream_t stream) {
  (void)in_sizes; (void)n_in; (void)out_size; (void)ws_size;
  const float* pos  = (const float*)d_in[0];
  const float* w11  = (const float*)d_in[1];
  const float* b11  = (const float*)d_in[2];
  const float* g11  = (const float*)d_in[3];
  const float* be11 = (const float*)d_in[4];
  const float* w12  = (const float*)d_in[5];
  const float* b12  = (const float*)d_in[6];
  const float* g12  = (const float*)d_in[7];
  const float* be12 = (const float*)d_in[8];
  const float* w13  = (const float*)d_in[9];
  const float* b13  = (const float*)d_in[10];
  const float* g13  = (const float*)d_in[11];
  const float* be13 = (const float*)d_in[12];
  const float* w21  = (const float*)d_in[13];
  const float* b21  = (const float*)d_in[14];
  const float* g21  = (const float*)d_in[15];
  const float* be21 = (const float*)d_in[16];
  const float* wh1  = (const float*)d_in[17];
  const float* bh1  = (const float*)d_in[18];
  const float* gh1  = (const float*)d_in[19];
  const float* beh1 = (const float*)d_in[20];
  const float* wh2  = (const float*)d_in[21];
  const float* bh2  = (const float*)d_in[22];
  const float* gh2  = (const float*)d_in[23];
  const float* beh2 = (const float*)d_in[24];
  const float* wh3  = (const float*)d_in[25];
  const float* bh3  = (const float*)d_in[26];
  const float* gh3  = (const float*)d_in[27];
  const float* beh3 = (const float*)d_in[28];
  const float* wh4  = (const float*)d_in[29];
  const float* bh4  = (const float*)d_in[30];

  char* ws = (char*)d_ws;
  int*    idx   = (int*)(ws + 0);                 // 1,310,720 B
  float*  loc   = (float*)(ws + 1310720);         // 3,932,160 B
  float*  V     = (float*)(ws + 5242880);         //   589,824 B
  float*  h     = (float*)(ws + 5832704);         // 83,886,080 B (fp32, in-place)
  u16*    wt    = (u16*)(ws + 5832704);           // 49,152 B (overlays h AFTER f3d)
  double* s4b   = (double*)(ws + 5898240);        // 131,072 B (h + 64KB)
  float*  hpart = (float*)(ws + 6881280);         // 131,072 B (h + 1MB)
  float*  f3d   = (float*)(ws + 89718784);        // 12,582,912 B
  double* sbkt  = (double*)(ws + 89718784);       // 196,608 B (3x64-bucket BN1-3,
                                                  //   consumed before f3d writes)
  float*  fdd2T = (float*)(ws + 102301696);       //  8,388,608 B ([128][16384])
  u32*    y1k   = (u32*)(ws + 110690304);         //     32,768 B
  float*  y1n   = (float*)(ws + 110723072);       //     32,768 B
  float*  y2n   = (float*)(ws + 110755840);       //     16,384 B
  float*  y3n   = (float*)(ws + 110772224);       //      8,512 B
  float*  param = (float*)(ws + 110785856);       // 640 floats
  float*  out   = (float*)d_out;

  double* sbL1 = sbkt;
  double* sbL2 = sbkt + 8192;
  double* sbL3 = sbkt + 16384;

  zero_kernel<<<96, 256, 0, stream>>>(sbkt, 24576, y1k, 8192);
  knn_kernel<<<4096, 256, 0, stream>>>(pos, idx);
  prep_kernel<<<256, 64, 0, stream>>>(pos, idx, loc, V);

  l1_kernel<<<1280, 256, 0, stream>>>(loc, w11, b11, h, sbL1);
  finalizeB_kernel<<<1, 64, 0, stream>>>(sbL1, g11, be11, param);

  l23_kernel<<<4096, 256, 0, stream>>>(h, param, w12, b12, h, sbL2);       // in-place
  finalizeB_kernel<<<1, 64, 0, stream>>>(sbL2, g12, be12, param + 128);

  l23_kernel<<<4096, 256, 0, stream>>>(h, param + 128, w13, b13, h, sbL3); // in-place
  finalizeB_kernel<<<1, 64, 0, stream>>>(sbL3, g13, be13, param + 256);

  f3d_kernel<<<4096, 256, 0, stream>>>(h, param + 256, loc, f3d);
  // h is dead now; wt + s4b + hpart overlay it
  wtcvt_kernel<<<96, 256, 0, stream>>>(w21, wt, s4b);
  dd2_kernel<<<4096, 256, 0, stream>>>(f3d, V, idx, wt, b21, fdd2T, s4b);
  finalize64_kernel<<<1, 128, 0, stream>>>(s4b, g21, be21, param + 384);

  y1_kernel<<<1024, 256, 0, stream>>>(fdd2T, param + 384, wh1, y1k);
  y1bn_kernel<<<4, 256, 0, stream>>>(y1k, bh1, gh1, beh1, y1n);

  hgemm_kernel<<<64, 256, 0, stream>>>(y1n, wh2, hpart, 1024, 512, 8);
  hreduce_kernel<<<2, 256, 0, stream>>>(hpart, bh2, gh2, beh2, y2n, 512);
  hgemm_kernel<<<40, 256, 0, stream>>>(y2n, wh3, hpart, 512, 265, 5);
  hreduce_kernel<<<2, 256, 0, stream>>>(hpart, bh3, gh3, beh3, y3n, 265);
  logits_kernel<<<1, 384, 0, stream>>>(y3n, wh4, bh4, out);
}

// Round 10
// 370.018 us; speedup vs baseline: 3.1826x; 1.0453x over previous
//
#include <hip/hip_runtime.h>

// ---------------------------------------------------------------------------
// Net_3152505995976: point-cloud classifier forward pass on MI355X.
// Round 10: l23 -> split-bf16 MFMA (fp32-grade accuracy, 3 MFMAs/tile).
//   - x and W split as hi+lo bf16 (Markidis): acc += Ahi*Bhi + Alo*Bhi +
//     Ahi*Blo; dropped lo*lo term ~2^-18 rel -> accuracy ~= fp32
//   - W pre-split once (wsplit_kernel) into the dead f3d region
//   - block = 128 edges x 64 outs, B-frags in registers, LDS 36.9 KB,
//     fused bias+relu+store+bucketed stats epilogue; in-place safe
//   - everything else identical to the passing R9 kernel.
// ---------------------------------------------------------------------------

#define NEW_SLARTG 1

typedef unsigned short u16;
typedef unsigned int u32;
typedef unsigned long long u64;
typedef __attribute__((ext_vector_type(8))) short short8;
typedef __attribute__((ext_vector_type(4))) float f32x4;

#define BB 8
#define NNp 2048
#define KKn 20
#define NP 16384      // BB*NNp
#define EE 327680     // NP*KKn

// ---------------- small helpers ----------------
__device__ __forceinline__ u32 fkey(float f) {
  u32 u = __float_as_uint(f);
  return (u & 0x80000000u) ? ~u : (u | 0x80000000u);
}
__device__ __forceinline__ float funkey(u32 k) {
  u32 u = (k & 0x80000000u) ? (k ^ 0x80000000u) : ~k;
  return __uint_as_float(u);
}
__device__ __forceinline__ float f_sign(float a, float b) {
  return (b >= 0.f) ? fabsf(a) : -fabsf(a);
}
__device__ __forceinline__ u16 f2bf(float f) {
  u32 u = __float_as_uint(f);
  u32 r = (u + 0x7fffu + ((u >> 16) & 1u)) >> 16;
  return (u16)r;
}

__device__ __forceinline__ u64 sxor64(u64 v, int m) {
  union { u64 q; u32 d[2]; } a; a.q = v;
  a.d[0] = __shfl_xor(a.d[0], m);
  a.d[1] = __shfl_xor(a.d[1], m);
  return a.q;
}
__device__ __forceinline__ u64 sidx64(u64 v, int src) {
  union { u64 q; u32 d[2]; } a; a.q = v;
  a.d[0] = __shfl(a.d[0], src);
  a.d[1] = __shfl(a.d[1], src);
  return a.q;
}
// wave-wide bitonic sort, 64 u64 elements (1/lane), ascending
__device__ __forceinline__ void bsort64(u64& v, int lane) {
#pragma unroll
  for (int k = 2; k <= 64; k <<= 1) {
#pragma unroll
    for (int j = k >> 1; j > 0; j >>= 1) {
      u64 pv = sxor64(v, j);
      bool up = ((lane & k) == 0);
      bool lower = ((lane & j) == 0);
      bool keepmin = (lower == up);
      bool take = keepmin ? (pv < v) : (pv > v);
      v = take ? pv : v;
    }
  }
}

// ---------------- LAPACK fp32 replicas ----------------
__device__ float slapy2_(float x, float y) {
#pragma clang fp contract(off)
  float xa = fabsf(x), ya = fabsf(y);
  float w = fmaxf(xa, ya), z = fminf(xa, ya);
  if (z == 0.f) return w;
  float t = z / w;
  return w * sqrtf(1.0f + t * t);
}

__device__ void slartg_(float f, float g, float& c, float& s, float& r) {
#pragma clang fp contract(off)
#if NEW_SLARTG
  const float safmin = 1.17549435e-38f;
  const float safmax = 8.50705917e+37f;
  const float rtmin = 1.08420217e-19f;   // sqrt(safmin)
  const float rtmax = 6.52221171e+18f;   // sqrt(safmax/2)
  float f1 = fabsf(f), g1 = fabsf(g);
  if (g == 0.f) { c = 1.f; s = 0.f; r = f; }
  else if (f == 0.f) { c = 0.f; s = (g >= 0.f) ? 1.f : -1.f; r = g1; }
  else {
    float d;
    if (f1 > rtmin && f1 < rtmax && g1 > rtmin && g1 < rtmax) {
      d = sqrtf(f * f + g * g);
      c = f1 / d;
      r = (f >= 0.f) ? d : -d;
    } else {
      float uu = fminf(safmax, fmaxf(safmin, fmaxf(f1, g1)));
      float fs = f / uu, gs = g / uu;
      d = sqrtf(fs * fs + gs * gs);
      c = fabsf(fs) / d;
      r = ((f >= 0.f) ? d : -d) * uu;
    }
    s = g / r;
  }
#else
  if (g == 0.f) { c = 1.f; s = 0.f; r = f; }
  else if (f == 0.f) { c = 0.f; s = 1.f; r = g; }
  else {
    float f1 = f, g1 = g;
    r = sqrtf(f1 * f1 + g1 * g1);
    c = f1 / r;
    s = g1 / r;
    if (fabsf(f) > fabsf(g) && c < 0.f) { c = -c; s = -s; r = -r; }
  }
#endif
}

__device__ void slaev2_(float a, float b, float c, float& rt1, float& rt2,
                        float& cs1, float& sn1) {
#pragma clang fp contract(off)
  float sm = a + c;
  float df = a - c;
  float adf = fabsf(df);
  float tb = b + b;
  float ab = fabsf(tb);
  float acmx, acmn;
  if (fabsf(a) > fabsf(c)) { acmx = a; acmn = c; } else { acmx = c; acmn = a; }
  float rt;
  if (adf > ab) { float t = ab / adf; rt = adf * sqrtf(1.f + t * t); }
  else if (adf < ab) { float t = adf / ab; rt = ab * sqrtf(1.f + t * t); }
  else { rt = ab * sqrtf(2.f); }
  int sgn1;
  if (sm < 0.f) {
    rt1 = 0.5f * (sm - rt); sgn1 = -1;
    rt2 = (acmx / rt1) * acmn - (b / rt1) * b;
  } else if (sm > 0.f) {
    rt1 = 0.5f * (sm + rt); sgn1 = 1;
    rt2 = (acmx / rt1) * acmn - (b / rt1) * b;
  } else {
    rt1 = 0.5f * rt; rt2 = -0.5f * rt; sgn1 = 1;
  }
  float cs; int sgn2;
  if (df >= 0.f) { cs = df + rt; sgn2 = 1; } else { cs = df - rt; sgn2 = -1; }
  float acs = fabsf(cs);
  if (acs > ab) {
    float ct = -tb / cs;
    sn1 = 1.f / sqrtf(1.f + ct * ct);
    cs1 = ct * sn1;
  } else {
    if (ab == 0.f) { cs1 = 1.f; sn1 = 0.f; }
    else {
      float tn = -cs / tb;
      cs1 = 1.f / sqrtf(1.f + tn * tn);
      sn1 = tn * cs1;
    }
  }
  if (sgn1 == sgn2) { float tn = cs1; cs1 = -sn1; sn1 = tn; }
}

// ssteqr for n=3, compz='I' (z must be identity on entry)
__device__ void ssteqr3_(float* d, float* e, float z[3][3]) {
#pragma clang fp contract(off)
  const float eps = 5.9604645e-08f;
  const float eps2 = 3.5527137e-15f;
  const float safmin = 1.17549435e-38f;
  const int n = 3;
  const int nmaxit = 90;
  int jtot = 0;
  int l1 = 1;

  while (1) {
    if (l1 > n) break;
    if (l1 > 1) e[l1 - 2] = 0.f;
    int m = n;
    if (l1 <= n - 1) {
      for (int mm = l1; mm <= n - 1; ++mm) {
        float tst = fabsf(e[mm - 1]);
        if (tst == 0.f) { m = mm; break; }
        if (tst <= (sqrtf(fabsf(d[mm - 1])) * sqrtf(fabsf(d[mm]))) * eps) {
          e[mm - 1] = 0.f; m = mm; break;
        }
      }
    }
    int l = l1, lsv = l, lend = m, lendsv = lend;
    (void)lsv; (void)lendsv;
    l1 = m + 1;
    if (lend == l) continue;

    float anorm = 0.f;
    for (int i = l; i <= lend; ++i) anorm = fmaxf(anorm, fabsf(d[i - 1]));
    for (int i = l; i <= lend - 1; ++i) anorm = fmaxf(anorm, fabsf(e[i - 1]));
    if (anorm == 0.f) continue;

    if (fabsf(d[lend - 1]) < fabsf(d[l - 1])) { lend = lsv; l = lendsv; }

    if (lend > l) {
      // --- QL iteration ---
      while (1) {
        int m2 = lend;
        if (l != lend) {
          for (int mm = l; mm <= lend - 1; ++mm) {
            float tst = fabsf(e[mm - 1]); tst = tst * tst;
            if (tst <= (eps2 * fabsf(d[mm - 1])) * fabsf(d[mm]) + safmin) { m2 = mm; break; }
          }
        }
        if (m2 < lend) e[m2 - 1] = 0.f;
        float p = d[l - 1];
        if (m2 == l) {
          d[l - 1] = p; l += 1;
          if (l <= lend) continue;
          break;
        }
        if (m2 == l + 1) {
          float rt1, rt2, cc, ss;
          slaev2_(d[l - 1], e[l - 1], d[l], rt1, rt2, cc, ss);
          for (int i = 0; i < 3; ++i) {
            float temp = z[i][l];
            z[i][l] = cc * temp - ss * z[i][l - 1];
            z[i][l - 1] = ss * temp + cc * z[i][l - 1];
          }
          d[l - 1] = rt1; d[l] = rt2; e[l - 1] = 0.f;
          l += 2;
          if (l <= lend) continue;
          break;
        }
        if (jtot == nmaxit) break;
        jtot++;
        float g = (d[l] - p) / (2.f * e[l - 1]);
        float r = slapy2_(g, 1.f);
        g = d[m2 - 1] - p + (e[l - 1] / (g + f_sign(r, g)));
        float s = 1.f, c = 1.f;
        p = 0.f;
        float csv[2], snv[2];
        for (int i = m2 - 1; i >= l; --i) {
          float f = s * e[i - 1];
          float b = c * e[i - 1];
          slartg_(g, f, c, s, r);
          if (i != m2 - 1) e[i] = r;
          g = d[i] - p;
          r = (d[i - 1] - g) * s + (2.f * c) * b;
          p = s * r;
          d[i] = g + p;
          g = c * r - b;
          csv[i - l] = c; snv[i - l] = -s;
        }
        int cnt = m2 - l;
        for (int j = cnt; j >= 1; --j) {       // slasr 'R','V','B'
          float cj = csv[j - 1], sj = snv[j - 1];
          int c0 = (l - 1) + (j - 1);
          for (int i = 0; i < 3; ++i) {
            float temp = z[i][c0 + 1];
            z[i][c0 + 1] = cj * temp - sj * z[i][c0];
            z[i][c0] = sj * temp + cj * z[i][c0];
          }
        }
        d[l - 1] = d[l - 1] - p;
        e[l - 1] = g;
      }
    } else {
      // --- QR iteration ---
      while (1) {
        int m2 = lend;
        if (l != lend) {
          for (int mm = l; mm >= lend + 1; --mm) {
            float tst = fabsf(e[mm - 2]); tst = tst * tst;
            if (tst <= (eps2 * fabsf(d[mm - 1])) * fabsf(d[mm - 2]) + safmin) { m2 = mm; break; }
          }
        }
        if (m2 > lend) e[m2 - 2] = 0.f;
        float p = d[l - 1];
        if (m2 == l) {
          d[l - 1] = p; l -= 1;
          if (l >= lend) continue;
          break;
        }
        if (m2 == l - 1) {
          float rt1, rt2, cc, ss;
          slaev2_(d[l - 2], e[l - 2], d[l - 1], rt1, rt2, cc, ss);
          for (int i = 0; i < 3; ++i) {
            float temp = z[i][l - 1];
            z[i][l - 1] = cc * temp - ss * z[i][l - 2];
            z[i][l - 2] = ss * temp + cc * z[i][l - 2];
          }
          d[l - 2] = rt1; d[l - 1] = rt2; e[l - 2] = 0.f;
          l -= 2;
          if (l >= lend) continue;
          break;
        }
        if (jtot == nmaxit) break;
        jtot++;
        float g = (d[l - 2] - p) / (2.f * e[l - 2]);
        float r = slapy2_(g, 1.f);
        g = d[m2 - 1] - p + (e[l - 2] / (g + f_sign(r, g)));
        float s = 1.f, c = 1.f;
        p = 0.f;
        float csv[2], snv[2];
        for (int i = m2; i <= l - 1; ++i) {
          float f = s * e[i - 1];
          float b = c * e[i - 1];
          slartg_(g, f, c, s, r);
          if (i != m2) e[i - 2] = r;
          g = d[i - 1] - p;
          r = (d[i] - g) * s + (2.f * c) * b;
          p = s * r;
          d[i - 1] = g + p;
          g = c * r - b;
          csv[i - m2] = c; snv[i - m2] = s;
        }
        int cnt = l - m2;
        for (int j = 1; j <= cnt; ++j) {       // slasr 'R','V','F'
          float cj = csv[j - 1], sj = snv[j - 1];
          int c0 = (m2 - 1) + (j - 1);
          for (int i = 0; i < 3; ++i) {
            float temp = z[i][c0 + 1];
            z[i][c0 + 1] = cj * temp - sj * z[i][c0];
            z[i][c0] = sj * temp + cj * z[i][c0];
          }
        }
        d[l - 1] = d[l - 1] - p;
        e[l - 2] = g;
      }
    }
  }

  // selection sort ascending, swap eigenvector columns (LAPACK exact)
  for (int ii = 2; ii <= n; ++ii) {
    int i = ii - 1, k = i;
    float p = d[i - 1];
    for (int j = ii; j <= n; ++j)
      if (d[j - 1] < p) { k = j; p = d[j - 1]; }
    if (k != i) {
      d[k - 1] = d[i - 1]; d[i - 1] = p;
      for (int r2 = 0; r2 < 3; ++r2) {
        float t = z[r2][i - 1]; z[r2][i - 1] = z[r2][k - 1]; z[r2][k - 1] = t;
      }
    }
  }
}

// full ssyevd replica for 3x3 symmetric (lower entries), eigenvectors only
__device__ void eigh3_(float a00, float a10, float a11, float a20, float a21,
                       float a22, float V[3][3]) {
#pragma clang fp contract(off)
  float d0, d1, d2, e0, e1, tau1 = 0.f, v2 = 0.f;
  {
    float alpha = a10;
    float xnorm = fabsf(a20);
    if (xnorm == 0.f) {
      tau1 = 0.f; v2 = 0.f;
      e0 = alpha; d0 = a00; d1 = a11; d2 = a22; e1 = a21;
    } else {
      float beta = -f_sign(slapy2_(alpha, xnorm), alpha);
      tau1 = (beta - alpha) / beta;
      float inv = 1.0f / (alpha - beta);
      v2 = a20 * inv;
      float y0 = tau1 * a11;
      float y1v = tau1 * a21;
      float temp2 = a21 * v2;
      y0 = y0 + tau1 * temp2;
      y1v = y1v + (tau1 * v2) * a22;
      float dotyv = y0 * 1.f + y1v * v2;
      float al = (-0.5f * tau1) * dotyv;
      float w0 = y0 + al * 1.f;
      float w1 = y1v + al * v2;
      a11 = (a11 + 1.f * (-w0)) + w0 * (-1.f);
      a21 = (a21 + v2 * (-w0)) + w1 * (-1.f);
      a22 = (a22 + v2 * (-w1)) + w1 * (-v2);
      e0 = beta; d0 = a00; d1 = a11; d2 = a22; e1 = a21;
    }
  }
  float dd[3] = { d0, d1, d2 };
  float ee[2] = { e0, e1 };
  float z[3][3] = { {1.f,0.f,0.f},{0.f,1.f,0.f},{0.f,0.f,1.f} };
  ssteqr3_(dd, ee, z);
  if (tau1 != 0.f) {
    for (int j = 0; j < 3; ++j) {
      float wj = z[1][j] * 1.f + z[2][j] * v2;
      float temp = -tau1 * wj;
      z[1][j] = z[1][j] + 1.f * temp;
      z[2][j] = z[2][j] + v2 * temp;
    }
  }
  for (int r = 0; r < 3; ++r)
    for (int cix = 0; cix < 3; ++cix)
      V[r][cix] = z[r][cix];
}

// ---------------- kernels ----------------

// zero the BN1-3 stat buckets (doubles) and y1key
__global__ void zero_kernel(double* sb, int nd, u32* p2, int n2) {
  int t = blockIdx.x * blockDim.x + threadIdx.x;
  if (t < nd) sb[t] = 0.0;
  if (t < n2) p2[t] = 0u;
}

// exact KNN top-20 per point: threshold-select + wave bitonic sort.
__global__ __launch_bounds__(256) void knn_kernel(const float* __restrict__ pos,
                                                  int* __restrict__ idx) {
#pragma clang fp contract(off)
  __shared__ u64 cke[4][128];
  int w = threadIdx.x >> 6;
  int lane = threadIdx.x & 63;
  int wid = blockIdx.x * 4 + w;
  int b = wid >> 11;
  int n = wid & 2047;
  const float* pc = pos + (size_t)b * NNp * 3;
  float qx = pc[n * 3 + 0], qy = pc[n * 3 + 1], qz = pc[n * 3 + 2];
  float d2n = (qx * qx + qy * qy) + qz * qz;

  // pass A: 32 keys per lane, in registers; track wave-min
  u32 kreg[32];
  u32 mk = 0xFFFFFFFFu;
#pragma unroll
  for (int t = 0; t < 32; ++t) {
    int m = lane + 64 * t;
    float x = pc[m * 3 + 0], y = pc[m * 3 + 1], zc = pc[m * 3 + 2];
    float d2m = (x * x + y * y) + zc * zc;
    float dot = (qx * x + qy * y) + qz * zc;
    float dist = (d2n + d2m) - 2.0f * dot;
    u32 key = fkey(dist);
    if (m == n) key = 0xFFFFFFFFu;   // self-exclusion (== +1e10 diag in ref)
    kreg[t] = key;
    mk = key < mk ? key : mk;
  }
#pragma unroll
  for (int off = 32; off; off >>= 1) {
    u32 o = __shfl_xor(mk, off);
    mk = o < mk ? o : mk;
  }

  // threshold search: find hi with 20 <= count(key<=hi) <= 128
  u32 lo_b = mk - 1u, hi_b = 0xFFFFFFFEu;
  int c_hi = 2047;
  float tf = funkey(mk) * 7.368f;     // count ~ T^1.5 => rank-20 guess
  u32 T = fkey(tf);
  if (T < mk) T = mk;
  if (T > 0xFFFFFFFEu) T = 0xFFFFFFFEu;
  for (int it = 0; it < 48; ++it) {
    int cnt = 0;
#pragma unroll
    for (int t = 0; t < 32; ++t) cnt += (kreg[t] <= T) ? 1 : 0;
#pragma unroll
    for (int off = 32; off; off >>= 1) cnt += __shfl_xor(cnt, off);
    if (cnt >= 20) {
      hi_b = T; c_hi = cnt;
      if (cnt <= 128) break;
    } else {
      lo_b = T;
    }
    if (hi_b <= lo_b + 1u) break;
    u32 Tn;
    if (it < 12) {
      float tfc = funkey(T);
      int cc = cnt < 1 ? 1 : cnt;
      float guess = tfc * __builtin_exp2f(0.66667f * __builtin_log2f(45.0f / (float)cc));
      Tn = fkey(guess);
      if (!(Tn > lo_b && Tn < hi_b)) Tn = lo_b + ((hi_b - lo_b) >> 1);
    } else {
      Tn = lo_b + ((hi_b - lo_b) >> 1);   // pure bisection
    }
    T = Tn;
  }

  // collect survivors (key <= hi_b) in m-ascending order via ballot prefix
  u64* ck = cke[w];
  u32 base = 0;
#pragma unroll
  for (int t = 0; t < 32; ++t) {
    bool pass = kreg[t] <= hi_b;
    u64 ball = __ballot(pass);
    if (pass) {
      u32 posn = base + (u32)__popcll(ball & ((1ull << lane) - 1ull));
      if (posn < 128u)
        ck[posn] = ((u64)kreg[t] << 32) | (u32)(lane + 64 * t);
    }
    base += (u32)__popcll(ball);
  }
  if (base > 128u) {
    base = 0;
#pragma unroll
    for (int t = 0; t < 32; ++t) {
      bool pass = kreg[t] <= lo_b;
      u64 ball = __ballot(pass);
      if (pass) {
        u32 posn = base + (u32)__popcll(ball & ((1ull << lane) - 1ull));
        ck[posn] = ((u64)kreg[t] << 32) | (u32)(lane + 64 * t);
      }
      base += (u32)__popcll(ball);
    }
#pragma unroll
    for (int t = 0; t < 32; ++t) {
      bool pass = (kreg[t] > lo_b) && (kreg[t] <= hi_b);
      u64 ball = __ballot(pass);
      if (pass) {
        u32 posn = base + (u32)__popcll(ball & ((1ull << lane) - 1ull));
        if (posn < 128u)
          ck[posn] = ((u64)kreg[t] << 32) | (u32)(lane + 64 * t);
      }
      base += (u32)__popcll(ball);
    }
  }
  u32 ctot = base < 128u ? base : 128u;

  // sort survivors ascending by (key, m); take first 20
  u64 e0 = (lane < (int)ctot) ? ck[lane] : ~0ull;
  bsort64(e0, lane);
  if (ctot > 64u) {
    u64 e1 = (lane + 64 < (int)ctot) ? ck[lane + 64] : ~0ull;
    bsort64(e1, lane);
    u64 r = sidx64(e1, 63 - lane);          // reverse second run
    u64 mn = r < e0 ? r : e0;               // bitonic
#pragma unroll
    for (int j = 32; j > 0; j >>= 1) {      // clean
      u64 pv = sxor64(mn, j);
      bool lower2 = ((lane & j) == 0);
      bool take = lower2 ? (pv < mn) : (pv > mn);
      mn = take ? pv : mn;
    }
    e0 = mn;
  }
  if (lane < 20)
    idx[(size_t)wid * 20 + lane] = (int)(u32)(e0 & 0xFFFFFFFFull);
}

// per-point: covariance, LAPACK-replica eigh, loc = rel @ V
__global__ __launch_bounds__(64) void prep_kernel(const float* __restrict__ pos,
                                                  const int* __restrict__ idx,
                                                  float* __restrict__ loc,
                                                  float* __restrict__ Vout) {
#pragma clang fp contract(off)
  int p = blockIdx.x * 64 + threadIdx.x;
  int b = p >> 11, n = p & 2047;
  const float* pc = pos + (size_t)b * NNp * 3;
  float qx = pc[n * 3 + 0], qy = pc[n * 3 + 1], qz = pc[n * 3 + 2];
  const int* ip = idx + (size_t)p * 20;
  float c00 = 0, c01 = 0, c02 = 0, c11 = 0, c12 = 0, c22 = 0;
  for (int k = 0; k < 20; ++k) {
    int j = ip[k];
    float rx = pc[j * 3 + 0] - qx, ry = pc[j * 3 + 1] - qy, rz = pc[j * 3 + 2] - qz;
    c00 += rx * rx; c01 += rx * ry; c02 += rx * rz;
    c11 += ry * ry; c12 += ry * rz; c22 += rz * rz;
  }
  float Vm[3][3];
  eigh3_(c00, c01, c11, c02, c12, c22, Vm);
  float* vp = Vout + (size_t)p * 9;
  for (int d = 0; d < 3; ++d)
    for (int e = 0; e < 3; ++e) vp[d * 3 + e] = Vm[d][e];
  for (int k = 0; k < 20; ++k) {
    int j = ip[k];
    float rx = pc[j * 3 + 0] - qx, ry = pc[j * 3 + 1] - qy, rz = pc[j * 3 + 2] - qz;
    float l0 = rx * Vm[0][0] + ry * Vm[1][0] + rz * Vm[2][0];
    float l1 = rx * Vm[0][1] + ry * Vm[1][1] + rz * Vm[2][1];
    float l2 = rx * Vm[0][2] + ry * Vm[1][2] + rz * Vm[2][2];
    size_t e = ((size_t)p * 20 + k) * 3;
    loc[e + 0] = l0; loc[e + 1] = l1; loc[e + 2] = l2;
  }
}

// layer1: [E,3]@[3,64]+b, relu, store fp32; fused per-channel stats
__global__ __launch_bounds__(256) void l1_kernel(const float* __restrict__ loc,
                                                 const float* __restrict__ W,
                                                 const float* __restrict__ bias,
                                                 float* __restrict__ h1,
                                                 double* __restrict__ sb) {
  __shared__ float sW[192];
  __shared__ float sB[64];
  __shared__ float red[512];
  int t = threadIdx.x;
  if (t < 192) sW[t] = W[t];
  if (t < 64) sB[t] = bias[t];
  __syncthreads();
  int w = t >> 6, c = t & 63;
  size_t e0 = (size_t)blockIdx.x * 256 + w * 64;
  float wc0 = sW[c], wc1 = sW[64 + c], wc2 = sW[128 + c], bc = sB[c];
  float s = 0.f, q = 0.f;
  for (int e = 0; e < 64; ++e) {
    float x0 = loc[(e0 + e) * 3 + 0];
    float x1 = loc[(e0 + e) * 3 + 1];
    float x2 = loc[(e0 + e) * 3 + 2];
    float z = fmaxf(bc + x0 * wc0 + x1 * wc1 + x2 * wc2, 0.f);
    h1[(e0 + e) * 64 + c] = z;
    s += z; q += z * z;
  }
  red[w * 64 + c] = s;
  red[256 + w * 64 + c] = q;
  __syncthreads();
  if (t < 64) {
    float S = red[t] + red[64 + t] + red[128 + t] + red[192 + t];
    float Q = red[256 + t] + red[320 + t] + red[384 + t] + red[448 + t];
    atomicAdd(&sb[((int)blockIdx.x & 63) * 128 + t], (double)S);
    atomicAdd(&sb[((int)blockIdx.x & 63) * 128 + 64 + t], (double)Q);
  }
}

// 64-bucket stats (64 ch) -> per-channel BN affine (fixed-order reduce)
__global__ void finalizeB_kernel(const double* __restrict__ sb,
                                 const float* __restrict__ g,
                                 const float* __restrict__ be,
                                 float* __restrict__ outp) {
  int c = threadIdx.x;   // 64 threads
  if (c >= 64) return;
  double s = 0.0, q = 0.0;
  for (int buk = 0; buk < 64; ++buk) {
    s += sb[buk * 128 + c];
    q += sb[buk * 128 + 64 + c];
  }
  double m = s / (double)EE;
  double var = q / (double)EE - m * m;
  double inv = 1.0 / sqrt(var + 1e-5);
  double sc = (double)g[c] * inv;
  outp[c] = (float)sc;
  outp[64 + c] = (float)((double)be[c] - m * sc);
}

// 64-bucket stats (128 ch) -> BN4 affine (fixed-order bucket reduce)
__global__ void finalize64_kernel(const double* __restrict__ s4b,
                                  const float* __restrict__ g,
                                  const float* __restrict__ be,
                                  float* __restrict__ outp) {
  int c = threadIdx.x;   // 128 threads
  double s = 0.0, q = 0.0;
  for (int buk = 0; buk < 64; ++buk) {
    s += s4b[buk * 256 + c];
    q += s4b[buk * 256 + 128 + c];
  }
  double m = s / (double)EE;
  double var = q / (double)EE - m * m;
  double inv = 1.0 / sqrt(var + 1e-5);
  double sc = (double)g[c] * inv;
  outp[c] = (float)sc;
  outp[128 + c] = (float)((double)be[c] - m * sc);
}

// W12/W13 [64][64] fp32 -> split bf16 hi/lo, n-major [n][k]
// layout: wsp + layer*8192: whi[4096], wlo[4096]
__global__ __launch_bounds__(256) void wsplit_kernel(const float* __restrict__ w12,
                                                     const float* __restrict__ w13,
                                                     u16* __restrict__ wsp) {
  int id = blockIdx.x * 256 + threadIdx.x;  // 0..8191
  if (id >= 8192) return;
  int layer = id >> 12;
  int nk = id & 4095;
  int n = nk >> 6, k = nk & 63;
  const float* W = layer ? w13 : w12;
  float v = W[(size_t)k * 64 + n];
  u16 hi = f2bf(v);
  float rem = v - __uint_as_float(((u32)hi) << 16);
  u16 lo = f2bf(rem);
  wsp[layer * 8192 + n * 64 + k] = hi;
  wsp[layer * 8192 + 4096 + n * 64 + k] = lo;
}

// layers 2/3 via split-bf16 MFMA: z = relu(BN(x) @ W + b), fp32-grade
// accuracy (acc += Ahi*Bhi + Alo*Bhi + Ahi*Blo). 128 edges x 64 outs per
// block; B-frags in registers; IN-PLACE safe (reads staged before barrier);
// fused bias+relu+store+bucketed stats epilogue.
__global__ __launch_bounds__(256) void l23_kernel(const float* __restrict__ hin,
                                                  const float* __restrict__ ss,
                                                  const u16* __restrict__ whi,
                                                  const u16* __restrict__ wlo,
                                                  const float* __restrict__ bias,
                                                  float* __restrict__ hout,
                                                  double* __restrict__ sb) {
  __shared__ u16 sHI[128 * 72];   // [edge][chan] bf16 hi, row pad 72
  __shared__ u16 sLO[128 * 72];   // bf16 lo
  int t = threadIdx.x;
  size_t e0 = (size_t)blockIdx.x * 128;
  int w = t >> 6, l = t & 63;
  int lr = l & 15, lg = l >> 4;

  // B fragments: lane holds col = nt*16+lr, k-octet lg*8 (+ks*32)
  short8 bhi[4][2], blo[4][2];
#pragma unroll
  for (int nt = 0; nt < 4; ++nt)
#pragma unroll
    for (int ks = 0; ks < 2; ++ks) {
      int off = (nt * 16 + lr) * 64 + ks * 32 + lg * 8;
      bhi[nt][ks] = *(const short8*)&whi[off];
      blo[nt][ks] = *(const short8*)&wlo[off];
    }

  // stage X: BN affine in fp32, split to bf16 hi/lo
  for (int v = t; v < 128 * 16; v += 256) {
    int el = v >> 4, cq = v & 15;
    float4 x4 = *(const float4*)&hin[(e0 + el) * 64 + cq * 4];
    float4 sc4 = *(const float4*)&ss[cq * 4];
    float4 sh4 = *(const float4*)&ss[64 + cq * 4];
    float vv[4];
    vv[0] = x4.x * sc4.x + sh4.x;
    vv[1] = x4.y * sc4.y + sh4.y;
    vv[2] = x4.z * sc4.z + sh4.z;
    vv[3] = x4.w * sc4.w + sh4.w;
    u16 hi[4], lo[4];
#pragma unroll
    for (int j = 0; j < 4; ++j) {
      hi[j] = f2bf(vv[j]);
      float rem = vv[j] - __uint_as_float(((u32)hi[j]) << 16);
      lo[j] = f2bf(rem);
    }
    u32* ph = (u32*)&sHI[el * 72 + cq * 4];
    ph[0] = (u32)hi[0] | ((u32)hi[1] << 16);
    ph[1] = (u32)hi[2] | ((u32)hi[3] << 16);
    u32* pl = (u32*)&sLO[el * 72 + cq * 4];
    pl[0] = (u32)lo[0] | ((u32)lo[1] << 16);
    pl[1] = (u32)lo[2] | ((u32)lo[3] << 16);
  }
  __syncthreads();

  f32x4 acc[2][4];
#pragma unroll
  for (int mt = 0; mt < 2; ++mt)
#pragma unroll
    for (int nt = 0; nt < 4; ++nt) acc[mt][nt] = (f32x4)(0.f);

#pragma unroll
  for (int ks = 0; ks < 2; ++ks) {
    const int kb = ks * 32 + lg * 8;
#pragma unroll
    for (int mt = 0; mt < 2; ++mt) {
      int row = w * 32 + mt * 16 + lr;
      short8 ah = *(const short8*)&sHI[row * 72 + kb];
      short8 al = *(const short8*)&sLO[row * 72 + kb];
#pragma unroll
      for (int nt = 0; nt < 4; ++nt) {
        acc[mt][nt] = __builtin_amdgcn_mfma_f32_16x16x32_bf16(ah, bhi[nt][ks], acc[mt][nt], 0, 0, 0);
        acc[mt][nt] = __builtin_amdgcn_mfma_f32_16x16x32_bf16(al, bhi[nt][ks], acc[mt][nt], 0, 0, 0);
        acc[mt][nt] = __builtin_amdgcn_mfma_f32_16x16x32_bf16(ah, blo[nt][ks], acc[mt][nt], 0, 0, 0);
      }
    }
  }

  // epilogue: bias+relu, store, per-channel stats (wave-local + atomics)
#pragma unroll
  for (int nt = 0; nt < 4; ++nt) {
    int o = nt * 16 + lr;
    float bs = bias[o];
    float s = 0.f, q = 0.f;
#pragma unroll
    for (int mt = 0; mt < 2; ++mt) {
#pragma unroll
      for (int r = 0; r < 4; ++r) {
        float z = fmaxf(acc[mt][nt][r] + bs, 0.f);
        size_t e = e0 + w * 32 + mt * 16 + lg * 4 + r;
        hout[e * 64 + o] = z;
        s += z; q += z * z;
      }
    }
    s += __shfl_xor(s, 16); s += __shfl_xor(s, 32);
    q += __shfl_xor(q, 16); q += __shfl_xor(q, 32);
    if (l < 16) {
      atomicAdd(&sb[((int)blockIdx.x & 63) * 128 + o], (double)s);
      atomicAdd(&sb[((int)blockIdx.x & 63) * 128 + 64 + o], (double)q);
    }
  }
}

// f3d[p][c][d] = max_k h3n[p,k,c] * loc[p,k,d]
__global__ __launch_bounds__(256) void f3d_kernel(const float* __restrict__ h3,
                                                  const float* __restrict__ ss3,
                                                  const float* __restrict__ loc,
                                                  float* __restrict__ f3d) {
  int t = threadIdx.x;
  int p = blockIdx.x * 4 + (t >> 6);
  int c = t & 63;
  float sc = ss3[c], sh = ss3[64 + c];
  float m0 = -__builtin_inff(), m1 = m0, m2 = m0;
  size_t eb = (size_t)p * 20;
  for (int k = 0; k < 20; ++k) {
    size_t e = eb + k;
    float h = h3[e * 64 + c] * sc + sh;
    float l0 = loc[e * 3 + 0], l1 = loc[e * 3 + 1], l2 = loc[e * 3 + 2];
    m0 = fmaxf(m0, h * l0);
    m1 = fmaxf(m1, h * l1);
    m2 = fmaxf(m2, h * l2);
  }
  size_t o = (size_t)p * 192 + c * 3;
  f3d[o + 0] = m0; f3d[o + 1] = m1; f3d[o + 2] = m2;
}

// W21 [192][128] fp32 -> WT bf16 [128][192]; also zeroes the s4b buckets
__global__ __launch_bounds__(256) void wtcvt_kernel(const float* __restrict__ W,
                                                    u16* __restrict__ wt,
                                                    double* __restrict__ s4b) {
  int id = blockIdx.x * 256 + threadIdx.x;
  if (id < 192 * 128) {
    int n = id / 192, k = id - n * 192;
    wt[id] = f2bf(W[(size_t)k * 128 + n]);
  }
  if (id < 64 * 256) s4b[id] = 0.0;
}

// DD2 via bf16 MFMA: cloud->XCD swizzle; gather f3d[idx], rotate by V ->
// X bf16 LDS [80][200]; W-fragments in registers; GEMM [80,192]@[192,128];
// bias+relu+maxpool+stats fused; OUTPUT TRANSPOSED: fdd2T[128][16384].
__global__ __launch_bounds__(256) void dd2_kernel(const float* __restrict__ f3d,
                                                  const float* __restrict__ Vmat,
                                                  const int* __restrict__ idx,
                                                  const u16* __restrict__ wt,
                                                  const float* __restrict__ bias,
                                                  float* __restrict__ fdd2T,
                                                  double* __restrict__ s4b) {
  __shared__ u16 sX[80 * 200];     // X bf16, row stride 200 (400B, 16B aligned)
  __shared__ float sV[36];
  __shared__ int sJ[80];
  int t = threadIdx.x;
  int wk = (blockIdx.x & 7) * 512 + (blockIdx.x >> 3);
  int p0 = wk * 4;
  int bcl = p0 >> 11;              // cloud (4 points never straddle clouds)
  int buk = ((int)blockIdx.x & 63) << 8;   // stats bucket base

  int w = t >> 6, l = t & 63;
  int lr = l & 15, lg = l >> 4;

  // preload B fragments: lane holds cols (w*32+nt*16+lr), k-slices lg*8+...
  short8 breg[2][6];
#pragma unroll
  for (int nt = 0; nt < 2; ++nt)
#pragma unroll
    for (int s = 0; s < 6; ++s) {
      const int kk = (s / 3) * 96 + (s % 3) * 32 + lg * 8;
      breg[nt][s] = *(const short8*)&wt[(w * 32 + nt * 16 + lr) * 192 + kk];
    }

  if (t < 36) sV[t] = Vmat[(size_t)p0 * 9 + t];
  if (t < 80) sJ[t] = ((bcl << 11) + idx[(size_t)p0 * 20 + t]) * 192;
  __syncthreads();

  // build X: el = edge 0..79, c2 = channel-pair 0..31
  for (int v = t; v < 80 * 32; v += 256) {
    int el = v >> 5, c2 = v & 31;
    int pp = el / 20;
    const float* fp = f3d + (size_t)sJ[el] + 6 * c2;
    float f0 = fp[0], f1 = fp[1], f2 = fp[2];
    float f3 = fp[3], f4 = fp[4], f5 = fp[5];
    const float* Vp = &sV[pp * 9];
    float x0 = f0 * Vp[0] + f1 * Vp[3] + f2 * Vp[6];
    float x1 = f0 * Vp[1] + f1 * Vp[4] + f2 * Vp[7];
    float x2 = f0 * Vp[2] + f1 * Vp[5] + f2 * Vp[8];
    float y0 = f3 * Vp[0] + f4 * Vp[3] + f5 * Vp[6];
    float y1 = f3 * Vp[1] + f4 * Vp[4] + f5 * Vp[7];
    float y2 = f3 * Vp[2] + f4 * Vp[5] + f5 * Vp[8];
    u32* xp = (u32*)&sX[el * 200 + 6 * c2];
    xp[0] = (u32)f2bf(x0) | ((u32)f2bf(x1) << 16);
    xp[1] = (u32)f2bf(x2) | ((u32)f2bf(y0) << 16);
    xp[2] = (u32)f2bf(y1) | ((u32)f2bf(y2) << 16);
  }
  __syncthreads();

  f32x4 acc[5][2];
#pragma unroll
  for (int mt = 0; mt < 5; ++mt) {
    acc[mt][0] = (f32x4)(0.f);
    acc[mt][1] = (f32x4)(0.f);
  }

#pragma unroll
  for (int s = 0; s < 6; ++s) {
    const int kbase = (s / 3) * 96 + (s % 3) * 32 + lg * 8;
#pragma unroll
    for (int mt = 0; mt < 5; ++mt) {
      short8 a = *(const short8*)&sX[(mt * 16 + lr) * 200 + kbase];
      acc[mt][0] = __builtin_amdgcn_mfma_f32_16x16x32_bf16(a, breg[0][s], acc[mt][0], 0, 0, 0);
      acc[mt][1] = __builtin_amdgcn_mfma_f32_16x16x32_bf16(a, breg[1][s], acc[mt][1], 0, 0, 0);
    }
  }

  // epilogue: z = relu(acc+bias); maxpool over k per point; per-channel stats
#pragma unroll
  for (int nt = 0; nt < 2; ++nt) {
    int col = w * 32 + nt * 16 + lr;
    float bs = bias[col];
    float pm0 = 0.f, pm1 = 0.f, pm2 = 0.f, pm3 = 0.f;
    float s = 0.f, q = 0.f;
#pragma unroll
    for (int mt = 0; mt < 5; ++mt) {
#pragma unroll
      for (int r = 0; r < 4; ++r) {
        int edge = mt * 16 + lg * 4 + r;   // 0..79, exact (no padding)
        float z = fmaxf(acc[mt][nt][r] + bs, 0.f);
        pm0 = fmaxf(pm0, (edge < 20) ? z : 0.f);
        pm1 = fmaxf(pm1, (edge >= 20 && edge < 40) ? z : 0.f);
        pm2 = fmaxf(pm2, (edge >= 40 && edge < 60) ? z : 0.f);
        pm3 = fmaxf(pm3, (edge >= 60) ? z : 0.f);
        s += z; q += z * z;
      }
    }
#pragma unroll
    for (int off = 16; off < 64; off <<= 1) {
      pm0 = fmaxf(pm0, __shfl_xor(pm0, off));
      pm1 = fmaxf(pm1, __shfl_xor(pm1, off));
      pm2 = fmaxf(pm2, __shfl_xor(pm2, off));
      pm3 = fmaxf(pm3, __shfl_xor(pm3, off));
      s += __shfl_xor(s, off);
      q += __shfl_xor(q, off);
    }
    if (l < 16) {
      float4 pv;
      pv.x = pm0; pv.y = pm1; pv.z = pm2; pv.w = pm3;
      *(float4*)&fdd2T[(size_t)col * NP + p0] = pv;
      atomicAdd(&s4b[buk + col], (double)s);
      atomicAdd(&s4b[buk + 128 + col], (double)q);
    }
  }
}

// y1: fp32 GEMM [16384,128]@[128,1024] with fused max over n.
__global__ __launch_bounds__(256) void y1_kernel(const float* __restrict__ fdd2T,
                                                 const float* __restrict__ ss4,
                                                 const float* __restrict__ wh1,
                                                 u32* __restrict__ y1key) {
  __shared__ float sX[64][128];   // [k][point]
  __shared__ float sW[64][128];   // [k][chan]
  int t = threadIdx.x;
  int mtile = blockIdx.x & 127;
  int ntile = blockIdx.x >> 7;
  int cl = mtile >> 4;                  // 16 mtiles per cloud
  size_t pbase = (size_t)mtile * 128;
  int c0 = ntile * 128;
  int mg = t >> 4, ng = t & 15;

  float acc[8][8];
#pragma unroll
  for (int i = 0; i < 8; ++i)
#pragma unroll
    for (int j = 0; j < 8; ++j) acc[i][j] = 0.f;

  for (int ks = 0; ks < 2; ++ks) {
    int rr = t >> 5, mq = t & 31;
#pragma unroll
    for (int i = 0; i < 8; ++i) {
      int r = rr + i * 8;
      int k = ks * 64 + r;
      float4 x4 = *(const float4*)&fdd2T[(size_t)k * NP + pbase + mq * 4];
      float sc = ss4[k], sh = ss4[128 + k];
      float4 st;
      st.x = x4.x * sc + sh;
      st.y = x4.y * sc + sh;
      st.z = x4.z * sc + sh;
      st.w = x4.w * sc + sh;
      *(float4*)&sX[r][mq * 4] = st;
      float4 w4 = *(const float4*)&wh1[(size_t)k * 1024 + c0 + mq * 4];
      *(float4*)&sW[r][mq * 4] = w4;
    }
    __syncthreads();
#pragma unroll 8
    for (int kk = 0; kk < 64; ++kk) {
      float4 xa = *(const float4*)&sX[kk][mg * 4];
      float4 xb = *(const float4*)&sX[kk][64 + mg * 4];
      float4 wa = *(const float4*)&sW[kk][ng * 4];
      float4 wb = *(const float4*)&sW[kk][64 + ng * 4];
      float xr[8] = { xa.x, xa.y, xa.z, xa.w, xb.x, xb.y, xb.z, xb.w };
      float wc[8] = { wa.x, wa.y, wa.z, wa.w, wb.x, wb.y, wb.z, wb.w };
#pragma unroll
      for (int i = 0; i < 8; ++i)
#pragma unroll
        for (int j = 0; j < 8; ++j) acc[i][j] += xr[i] * wc[j];
    }
    __syncthreads();
  }

  float colmax[8];
#pragma unroll
  for (int j = 0; j < 8; ++j) {
    float v = acc[0][j];
#pragma unroll
    for (int i = 1; i < 8; ++i) v = fmaxf(v, acc[i][j]);
    colmax[j] = v;
  }
  float* red = &sX[0][0];
#pragma unroll
  for (int j = 0; j < 8; ++j) {
    int col = (j < 4) ? (ng * 4 + j) : (64 + ng * 4 + (j - 4));
    red[col * 16 + mg] = colmax[j];
  }
  __syncthreads();
  if (t < 128) {
    float m = red[t * 16];
#pragma unroll
    for (int i = 1; i < 16; ++i) m = fmaxf(m, red[t * 16 + i]);
    atomicMax(&y1key[(size_t)cl * 1024 + c0 + t], fkey(m));
  }
}

// y1 decode + bias + relu + BN over 8 clouds
__global__ void y1bn_kernel(const u32* __restrict__ y1key,
                            const float* __restrict__ bh1,
                            const float* __restrict__ g,
                            const float* __restrict__ be,
                            float* __restrict__ y1n) {
  int c = blockIdx.x * 256 + threadIdx.x;
  if (c >= 1024) return;
  float bs = bh1[c];
  float v[8]; double s = 0.0;
#pragma unroll
  for (int b = 0; b < 8; ++b) {
    v[b] = fmaxf(funkey(y1key[b * 1024 + c]) + bs, 0.f);
    s += (double)v[b];
  }
  double m = s / 8.0, q = 0.0;
#pragma unroll
  for (int b = 0; b < 8; ++b) { double d = (double)v[b] - m; q += d * d; }
  q /= 8.0;
  double inv = 1.0 / sqrt(q + 1e-5);
  double sg = (double)g[c] * inv;
#pragma unroll
  for (int b = 0; b < 8; ++b)
    y1n[b * 1024 + c] = (float)(((double)v[b] - m) * sg + (double)be[c]);
}

// head GEMM, K-split: grid = notile*8; block 256 = 64 outs x 4 k-subs.
__global__ __launch_bounds__(256) void hgemm_kernel(const float* __restrict__ yin,
                                                    const float* __restrict__ W,
                                                    float* __restrict__ part,
                                                    int INn, int OUTn, int notile) {
  __shared__ float sx[8 * 128];
  __shared__ float red[4][8][64];
  int t = threadIdx.x;
  int og = blockIdx.x % notile;
  int ks = blockIdx.x / notile;
  int KC = INn >> 3;                 // IN/8
  int k0 = ks * KC;
  for (int v = t; v < 8 * KC; v += 256) {
    int b = v / KC, i = v - b * KC;
    sx[b * KC + i] = yin[(size_t)b * INn + k0 + i];
  }
  __syncthreads();
  int o = og * 64 + (t & 63);
  int kq = t >> 6;
  int sub = KC >> 2;
  float acc[8];
#pragma unroll
  for (int b = 0; b < 8; ++b) acc[b] = 0.f;
  if (o < OUTn) {
    for (int i = kq * sub; i < kq * sub + sub; ++i) {
      float w = W[(size_t)(k0 + i) * OUTn + o];
#pragma unroll
      for (int b = 0; b < 8; ++b) acc[b] += sx[b * KC + i] * w;
    }
  }
#pragma unroll
  for (int b = 0; b < 8; ++b) red[kq][b][t & 63] = acc[b];
  __syncthreads();
  if (kq == 0 && o < OUTn) {
#pragma unroll
    for (int b = 0; b < 8; ++b) {
      float s = ((red[0][b][t] + red[1][b][t]) + red[2][b][t]) + red[3][b][t];
      part[(size_t)(ks * 8 + b) * 512 + o] = s;
    }
  }
}

// head reduce: sum 8 K-chunks in fixed order + bias + relu + BN over 8
__global__ void hreduce_kernel(const float* __restrict__ part,
                               const float* __restrict__ bias,
                               const float* __restrict__ g,
                               const float* __restrict__ be,
                               float* __restrict__ yout, int OUTn) {
  int o = blockIdx.x * 256 + threadIdx.x;
  if (o >= OUTn) return;
  float bs = bias[o];
  float v[8]; double s = 0.0;
#pragma unroll
  for (int b = 0; b < 8; ++b) {
    float p = 0.f;
#pragma unroll
    for (int ks = 0; ks < 8; ++ks) p += part[(size_t)(ks * 8 + b) * 512 + o];
    v[b] = fmaxf(p + bs, 0.f);
    s += (double)v[b];
  }
  double m = s / 8.0, q = 0.0;
#pragma unroll
  for (int b = 0; b < 8; ++b) { double d = (double)v[b] - m; q += d * d; }
  q /= 8.0;
  double inv = 1.0 / sqrt(q + 1e-5);
  double sg = (double)g[o] * inv;
#pragma unroll
  for (int b = 0; b < 8; ++b)
    yout[(size_t)b * OUTn + o] = (float)(((double)v[b] - m) * sg + (double)be[o]);
}

// final linear [8,265]@[265,40]+b then log_softmax per row
__global__ __launch_bounds__(384) void logits_kernel(const float* __restrict__ y3n,
                                                     const float* __restrict__ W,
                                                     const float* __restrict__ bias,
                                                     float* __restrict__ out) {
  __shared__ float sy[8 * 265];
  __shared__ float slog[320];
  __shared__ float sm[8], sl[8];
  int t = threadIdx.x;
  for (int v = t; v < 8 * 265; v += 384) sy[v] = y3n[v];
  __syncthreads();
  if (t < 320) {
    int b = t / 40, o = t % 40;
    float acc = 0.f;
    for (int i = 0; i < 265; ++i) acc += sy[b * 265 + i] * W[i * 40 + o];
    slog[t] = acc + bias[o];
  }
  __syncthreads();
  if (t < 8) {
    float m = slog[t * 40];
    for (int o = 1; o < 40; ++o) m = fmaxf(m, slog[t * 40 + o]);
    float s = 0.f;
    for (int o = 0; o < 40; ++o) s += expf(slog[t * 40 + o] - m);
    sm[t] = m; sl[t] = logf(s);
  }
  __syncthreads();
  if (t < 320) {
    int b = t / 40;
    out[t] = slog[t] - sm[b] - sl[b];
  }
}

// ---------------- launcher ----------------
extern "C" void kernel_launch(void* const* d_in, const int* in_sizes, int n_in,
                              void* d_out, int out_size, void* d_ws, size_t ws_size,
                              hipStream_t stream) {
  (void)in_sizes; (void)n_in; (void)out_size; (void)ws_size;
  const float* pos  = (const float*)d_in[0];
  const float* w11  = (const float*)d_in[1];
  const float* b11  = (const float*)d_in[2];
  const float* g11  = (const float*)d_in[3];
  const float* be11 = (const float*)d_in[4];
  const float* w12  = (const float*)d_in[5];
  const float* b12  = (const float*)d_in[6];
  const float* g12  = (const float*)d_in[7];
  const float* be12 = (const float*)d_in[8];
  const float* w13  = (const float*)d_in[9];
  const float* b13  = (const float*)d_in[10];
  const float* g13  = (const float*)d_in[11];
  const float* be13 = (const float*)d_in[12];
  const float* w21  = (const float*)d_in[13];
  const float* b21  = (const float*)d_in[14];
  const float* g21  = (const float*)d_in[15];
  const float* be21 = (const float*)d_in[16];
  const float* wh1  = (const float*)d_in[17];
  const float* bh1  = (const float*)d_in[18];
  const float* gh1  = (const float*)d_in[19];
  const float* beh1 = (const float*)d_in[20];
  const float* wh2  = (const float*)d_in[21];
  const float* bh2  = (const float*)d_in[22];
  const float* gh2  = (const float*)d_in[23];
  const float* beh2 = (const float*)d_in[24];
  const float* wh3  = (const float*)d_in[25];
  const float* bh3  = (const float*)d_in[26];
  const float* gh3  = (const float*)d_in[27];
  const float* beh3 = (const float*)d_in[28];
  const float* wh4  = (const float*)d_in[29];
  const float* bh4  = (const float*)d_in[30];

  char* ws = (char*)d_ws;
  int*    idx   = (int*)(ws + 0);                 // 1,310,720 B
  float*  loc   = (float*)(ws + 1310720);         // 3,932,160 B
  float*  V     = (float*)(ws + 5242880);         //   589,824 B
  float*  h     = (float*)(ws + 5832704);         // 83,886,080 B (fp32, in-place)
  u16*    wt    = (u16*)(ws + 5832704);           // 49,152 B (overlays h AFTER f3d)
  double* s4b   = (double*)(ws + 5898240);        // 131,072 B (h + 64KB)
  float*  hpart = (float*)(ws + 6881280);         // 131,072 B (h + 1MB)
  float*  f3d   = (float*)(ws + 89718784);        // 12,582,912 B
  double* sbkt  = (double*)(ws + 89718784);       // 196,608 B (BN1-3 buckets,
                                                  //   consumed before f3d writes)
  u16*    wsp   = (u16*)(ws + 89718784 + 196608); // 32,768 B (split W12/W13,
                                                  //   consumed before f3d writes)
  float*  fdd2T = (float*)(ws + 102301696);       //  8,388,608 B ([128][16384])
  u32*    y1k   = (u32*)(ws + 110690304);         //     32,768 B
  float*  y1n   = (float*)(ws + 110723072);       //     32,768 B
  float*  y2n   = (float*)(ws + 110755840);       //     16,384 B
  float*  y3n   = (float*)(ws + 110772224);       //      8,512 B
  float*  param = (float*)(ws + 110785856);       // 640 floats
  float*  out   = (float*)d_out;

  double* sbL1 = sbkt;
  double* sbL2 = sbkt + 8192;
  double* sbL3 = sbkt + 16384;

  zero_kernel<<<96, 256, 0, stream>>>(sbkt, 24576, y1k, 8192);
  wsplit_kernel<<<32, 256, 0, stream>>>(w12, w13, wsp);
  knn_kernel<<<4096, 256, 0, stream>>>(pos, idx);
  prep_kernel<<<256, 64, 0, stream>>>(pos, idx, loc, V);

  l1_kernel<<<1280, 256, 0, stream>>>(loc, w11, b11, h, sbL1);
  finalizeB_kernel<<<1, 64, 0, stream>>>(sbL1, g11, be11, param);

  l23_kernel<<<2560, 256, 0, stream>>>(h, param, wsp, wsp + 4096, b12, h, sbL2);
  finalizeB_kernel<<<1, 64, 0, stream>>>(sbL2, g12, be12, param + 128);

  l23_kernel<<<2560, 256, 0, stream>>>(h, param + 128, wsp + 8192, wsp + 12288, b13, h, sbL3);
  finalizeB_kernel<<<1, 64, 0, stream>>>(sbL3, g13, be13, param + 256);

  f3d_kernel<<<4096, 256, 0, stream>>>(h, param + 256, loc, f3d);
  // h is dead now; wt + s4b + hpart overlay it
  wtcvt_kernel<<<96, 256, 0, stream>>>(w21, wt, s4b);
  dd2_kernel<<<4096, 256, 0, stream>>>(f3d, V, idx, wt, b21, fdd2T, s4b);
  finalize64_kernel<<<1, 128, 0, stream>>>(s4b, g21, be21, param + 384);

  y1_kernel<<<1024, 256, 0, stream>>>(fdd2T, param + 384, wh1, y1k);
  y1bn_kernel<<<4, 256, 0, stream>>>(y1k, bh1, gh1, beh1, y1n);

  hgemm_kernel<<<64, 256, 0, stream>>>(y1n, wh2, hpart, 1024, 512, 8);
  hreduce_kernel<<<2, 256, 0, stream>>>(hpart, bh2, gh2, beh2, y2n, 512);
  hgemm_kernel<<<40, 256, 0, stream>>>(y2n, wh3, hpart, 512, 265, 5);
  hreduce_kernel<<<2, 256, 0, stream>>>(hpart, bh3, gh3, beh3, y3n, 265);
  logits_kernel<<<1, 384, 0, stream>>>(y3n, wh4, bh4, out);
}

// Round 11
// 352.327 us; speedup vs baseline: 3.3424x; 1.0502x over previous
//
#include <hip/hip_runtime.h>

// ---------------------------------------------------------------------------
// Net_3152505995976: point-cloud classifier forward pass on MI355X.
// Round 11: bit-identical efficiency pass.
//   - y1: K staged in 4x32 rows (LDS 64KB->32KB, 2->4+ blocks/CU)
//   - dd2: quad-aligned maxpool epilogue + float2 gather loads
//   - launch fusion: init(zero+wsplit+y1k), y1bn->hgemm1, hreduce->hgemm2,
//     hreduce->logits  (21 -> 17 dispatches), exact fp64 BN math preserved
//   - everything else identical to the passing R10 kernel.
// ---------------------------------------------------------------------------

#define NEW_SLARTG 1

typedef unsigned short u16;
typedef unsigned int u32;
typedef unsigned long long u64;
typedef __attribute__((ext_vector_type(8))) short short8;
typedef __attribute__((ext_vector_type(4))) float f32x4;

#define BB 8
#define NNp 2048
#define KKn 20
#define NP 16384      // BB*NNp
#define EE 327680     // NP*KKn

// ---------------- small helpers ----------------
__device__ __forceinline__ u32 fkey(float f) {
  u32 u = __float_as_uint(f);
  return (u & 0x80000000u) ? ~u : (u | 0x80000000u);
}
__device__ __forceinline__ float funkey(u32 k) {
  u32 u = (k & 0x80000000u) ? (k ^ 0x80000000u) : ~k;
  return __uint_as_float(u);
}
__device__ __forceinline__ float f_sign(float a, float b) {
  return (b >= 0.f) ? fabsf(a) : -fabsf(a);
}
__device__ __forceinline__ u16 f2bf(float f) {
  u32 u = __float_as_uint(f);
  u32 r = (u + 0x7fffu + ((u >> 16) & 1u)) >> 16;
  return (u16)r;
}

__device__ __forceinline__ u64 sxor64(u64 v, int m) {
  union { u64 q; u32 d[2]; } a; a.q = v;
  a.d[0] = __shfl_xor(a.d[0], m);
  a.d[1] = __shfl_xor(a.d[1], m);
  return a.q;
}
__device__ __forceinline__ u64 sidx64(u64 v, int src) {
  union { u64 q; u32 d[2]; } a; a.q = v;
  a.d[0] = __shfl(a.d[0], src);
  a.d[1] = __shfl(a.d[1], src);
  return a.q;
}
// wave-wide bitonic sort, 64 u64 elements (1/lane), ascending
__device__ __forceinline__ void bsort64(u64& v, int lane) {
#pragma unroll
  for (int k = 2; k <= 64; k <<= 1) {
#pragma unroll
    for (int j = k >> 1; j > 0; j >>= 1) {
      u64 pv = sxor64(v, j);
      bool up = ((lane & k) == 0);
      bool lower = ((lane & j) == 0);
      bool keepmin = (lower == up);
      bool take = keepmin ? (pv < v) : (pv > v);
      v = take ? pv : v;
    }
  }
}

// ---------------- LAPACK fp32 replicas ----------------
__device__ float slapy2_(float x, float y) {
#pragma clang fp contract(off)
  float xa = fabsf(x), ya = fabsf(y);
  float w = fmaxf(xa, ya), z = fminf(xa, ya);
  if (z == 0.f) return w;
  float t = z / w;
  return w * sqrtf(1.0f + t * t);
}

__device__ void slartg_(float f, float g, float& c, float& s, float& r) {
#pragma clang fp contract(off)
#if NEW_SLARTG
  const float safmin = 1.17549435e-38f;
  const float safmax = 8.50705917e+37f;
  const float rtmin = 1.08420217e-19f;   // sqrt(safmin)
  const float rtmax = 6.52221171e+18f;   // sqrt(safmax/2)
  float f1 = fabsf(f), g1 = fabsf(g);
  if (g == 0.f) { c = 1.f; s = 0.f; r = f; }
  else if (f == 0.f) { c = 0.f; s = (g >= 0.f) ? 1.f : -1.f; r = g1; }
  else {
    float d;
    if (f1 > rtmin && f1 < rtmax && g1 > rtmin && g1 < rtmax) {
      d = sqrtf(f * f + g * g);
      c = f1 / d;
      r = (f >= 0.f) ? d : -d;
    } else {
      float uu = fminf(safmax, fmaxf(safmin, fmaxf(f1, g1)));
      float fs = f / uu, gs = g / uu;
      d = sqrtf(fs * fs + gs * gs);
      c = fabsf(fs) / d;
      r = ((f >= 0.f) ? d : -d) * uu;
    }
    s = g / r;
  }
#else
  if (g == 0.f) { c = 1.f; s = 0.f; r = f; }
  else if (f == 0.f) { c = 0.f; s = 1.f; r = g; }
  else {
    float f1 = f, g1 = g;
    r = sqrtf(f1 * f1 + g1 * g1);
    c = f1 / r;
    s = g1 / r;
    if (fabsf(f) > fabsf(g) && c < 0.f) { c = -c; s = -s; r = -r; }
  }
#endif
}

__device__ void slaev2_(float a, float b, float c, float& rt1, float& rt2,
                        float& cs1, float& sn1) {
#pragma clang fp contract(off)
  float sm = a + c;
  float df = a - c;
  float adf = fabsf(df);
  float tb = b + b;
  float ab = fabsf(tb);
  float acmx, acmn;
  if (fabsf(a) > fabsf(c)) { acmx = a; acmn = c; } else { acmx = c; acmn = a; }
  float rt;
  if (adf > ab) { float t = ab / adf; rt = adf * sqrtf(1.f + t * t); }
  else if (adf < ab) { float t = adf / ab; rt = ab * sqrtf(1.f + t * t); }
  else { rt = ab * sqrtf(2.f); }
  int sgn1;
  if (sm < 0.f) {
    rt1 = 0.5f * (sm - rt); sgn1 = -1;
    rt2 = (acmx / rt1) * acmn - (b / rt1) * b;
  } else if (sm > 0.f) {
    rt1 = 0.5f * (sm + rt); sgn1 = 1;
    rt2 = (acmx / rt1) * acmn - (b / rt1) * b;
  } else {
    rt1 = 0.5f * rt; rt2 = -0.5f * rt; sgn1 = 1;
  }
  float cs; int sgn2;
  if (df >= 0.f) { cs = df + rt; sgn2 = 1; } else { cs = df - rt; sgn2 = -1; }
  float acs = fabsf(cs);
  if (acs > ab) {
    float ct = -tb / cs;
    sn1 = 1.f / sqrtf(1.f + ct * ct);
    cs1 = ct * sn1;
  } else {
    if (ab == 0.f) { cs1 = 1.f; sn1 = 0.f; }
    else {
      float tn = -cs / tb;
      cs1 = 1.f / sqrtf(1.f + tn * tn);
      sn1 = tn * cs1;
    }
  }
  if (sgn1 == sgn2) { float tn = cs1; cs1 = -sn1; sn1 = tn; }
}

// ssteqr for n=3, compz='I' (z must be identity on entry)
__device__ void ssteqr3_(float* d, float* e, float z[3][3]) {
#pragma clang fp contract(off)
  const float eps = 5.9604645e-08f;
  const float eps2 = 3.5527137e-15f;
  const float safmin = 1.17549435e-38f;
  const int n = 3;
  const int nmaxit = 90;
  int jtot = 0;
  int l1 = 1;

  while (1) {
    if (l1 > n) break;
    if (l1 > 1) e[l1 - 2] = 0.f;
    int m = n;
    if (l1 <= n - 1) {
      for (int mm = l1; mm <= n - 1; ++mm) {
        float tst = fabsf(e[mm - 1]);
        if (tst == 0.f) { m = mm; break; }
        if (tst <= (sqrtf(fabsf(d[mm - 1])) * sqrtf(fabsf(d[mm]))) * eps) {
          e[mm - 1] = 0.f; m = mm; break;
        }
      }
    }
    int l = l1, lsv = l, lend = m, lendsv = lend;
    (void)lsv; (void)lendsv;
    l1 = m + 1;
    if (lend == l) continue;

    float anorm = 0.f;
    for (int i = l; i <= lend; ++i) anorm = fmaxf(anorm, fabsf(d[i - 1]));
    for (int i = l; i <= lend - 1; ++i) anorm = fmaxf(anorm, fabsf(e[i - 1]));
    if (anorm == 0.f) continue;

    if (fabsf(d[lend - 1]) < fabsf(d[l - 1])) { lend = lsv; l = lendsv; }

    if (lend > l) {
      // --- QL iteration ---
      while (1) {
        int m2 = lend;
        if (l != lend) {
          for (int mm = l; mm <= lend - 1; ++mm) {
            float tst = fabsf(e[mm - 1]); tst = tst * tst;
            if (tst <= (eps2 * fabsf(d[mm - 1])) * fabsf(d[mm]) + safmin) { m2 = mm; break; }
          }
        }
        if (m2 < lend) e[m2 - 1] = 0.f;
        float p = d[l - 1];
        if (m2 == l) {
          d[l - 1] = p; l += 1;
          if (l <= lend) continue;
          break;
        }
        if (m2 == l + 1) {
          float rt1, rt2, cc, ss;
          slaev2_(d[l - 1], e[l - 1], d[l], rt1, rt2, cc, ss);
          for (int i = 0; i < 3; ++i) {
            float temp = z[i][l];
            z[i][l] = cc * temp - ss * z[i][l - 1];
            z[i][l - 1] = ss * temp + cc * z[i][l - 1];
          }
          d[l - 1] = rt1; d[l] = rt2; e[l - 1] = 0.f;
          l += 2;
          if (l <= lend) continue;
          break;
        }
        if (jtot == nmaxit) break;
        jtot++;
        float g = (d[l] - p) / (2.f * e[l - 1]);
        float r = slapy2_(g, 1.f);
        g = d[m2 - 1] - p + (e[l - 1] / (g + f_sign(r, g)));
        float s = 1.f, c = 1.f;
        p = 0.f;
        float csv[2], snv[2];
        for (int i = m2 - 1; i >= l; --i) {
          float f = s * e[i - 1];
          float b = c * e[i - 1];
          slartg_(g, f, c, s, r);
          if (i != m2 - 1) e[i] = r;
          g = d[i] - p;
          r = (d[i - 1] - g) * s + (2.f * c) * b;
          p = s * r;
          d[i] = g + p;
          g = c * r - b;
          csv[i - l] = c; snv[i - l] = -s;
        }
        int cnt = m2 - l;
        for (int j = cnt; j >= 1; --j) {       // slasr 'R','V','B'
          float cj = csv[j - 1], sj = snv[j - 1];
          int c0 = (l - 1) + (j - 1);
          for (int i = 0; i < 3; ++i) {
            float temp = z[i][c0 + 1];
            z[i][c0 + 1] = cj * temp - sj * z[i][c0];
            z[i][c0] = sj * temp + cj * z[i][c0];
          }
        }
        d[l - 1] = d[l - 1] - p;
        e[l - 1] = g;
      }
    } else {
      // --- QR iteration ---
      while (1) {
        int m2 = lend;
        if (l != lend) {
          for (int mm = l; mm >= lend + 1; --mm) {
            float tst = fabsf(e[mm - 2]); tst = tst * tst;
            if (tst <= (eps2 * fabsf(d[mm - 1])) * fabsf(d[mm - 2]) + safmin) { m2 = mm; break; }
          }
        }
        if (m2 > lend) e[m2 - 2] = 0.f;
        float p = d[l - 1];
        if (m2 == l) {
          d[l - 1] = p; l -= 1;
          if (l >= lend) continue;
          break;
        }
        if (m2 == l - 1) {
          float rt1, rt2, cc, ss;
          slaev2_(d[l - 2], e[l - 2], d[l - 1], rt1, rt2, cc, ss);
          for (int i = 0; i < 3; ++i) {
            float temp = z[i][l - 1];
            z[i][l - 1] = cc * temp - ss * z[i][l - 2];
            z[i][l - 2] = ss * temp + cc * z[i][l - 2];
          }
          d[l - 2] = rt1; d[l - 1] = rt2; e[l - 2] = 0.f;
          l -= 2;
          if (l >= lend) continue;
          break;
        }
        if (jtot == nmaxit) break;
        jtot++;
        float g = (d[l - 2] - p) / (2.f * e[l - 2]);
        float r = slapy2_(g, 1.f);
        g = d[m2 - 1] - p + (e[l - 2] / (g + f_sign(r, g)));
        float s = 1.f, c = 1.f;
        p = 0.f;
        float csv[2], snv[2];
        for (int i = m2; i <= l - 1; ++i) {
          float f = s * e[i - 1];
          float b = c * e[i - 1];
          slartg_(g, f, c, s, r);
          if (i != m2) e[i - 2] = r;
          g = d[i - 1] - p;
          r = (d[i] - g) * s + (2.f * c) * b;
          p = s * r;
          d[i - 1] = g + p;
          g = c * r - b;
          csv[i - m2] = c; snv[i - m2] = s;
        }
        int cnt = l - m2;
        for (int j = 1; j <= cnt; ++j) {       // slasr 'R','V','F'
          float cj = csv[j - 1], sj = snv[j - 1];
          int c0 = (m2 - 1) + (j - 1);
          for (int i = 0; i < 3; ++i) {
            float temp = z[i][c0 + 1];
            z[i][c0 + 1] = cj * temp - sj * z[i][c0];
            z[i][c0] = sj * temp + cj * z[i][c0];
          }
        }
        d[l - 1] = d[l - 1] - p;
        e[l - 2] = g;
      }
    }
  }

  // selection sort ascending, swap eigenvector columns (LAPACK exact)
  for (int ii = 2; ii <= n; ++ii) {
    int i = ii - 1, k = i;
    float p = d[i - 1];
    for (int j = ii; j <= n; ++j)
      if (d[j - 1] < p) { k = j; p = d[j - 1]; }
    if (k != i) {
      d[k - 1] = d[i - 1]; d[i - 1] = p;
      for (int r2 = 0; r2 < 3; ++r2) {
        float t = z[r2][i - 1]; z[r2][i - 1] = z[r2][k - 1]; z[r2][k - 1] = t;
      }
    }
  }
}

// full ssyevd replica for 3x3 symmetric (lower entries), eigenvectors only
__device__ void eigh3_(float a00, float a10, float a11, float a20, float a21,
                       float a22, float V[3][3]) {
#pragma clang fp contract(off)
  float d0, d1, d2, e0, e1, tau1 = 0.f, v2 = 0.f;
  {
    float alpha = a10;
    float xnorm = fabsf(a20);
    if (xnorm == 0.f) {
      tau1 = 0.f; v2 = 0.f;
      e0 = alpha; d0 = a00; d1 = a11; d2 = a22; e1 = a21;
    } else {
      float beta = -f_sign(slapy2_(alpha, xnorm), alpha);
      tau1 = (beta - alpha) / beta;
      float inv = 1.0f / (alpha - beta);
      v2 = a20 * inv;
      float y0 = tau1 * a11;
      float y1v = tau1 * a21;
      float temp2 = a21 * v2;
      y0 = y0 + tau1 * temp2;
      y1v = y1v + (tau1 * v2) * a22;
      float dotyv = y0 * 1.f + y1v * v2;
      float al = (-0.5f * tau1) * dotyv;
      float w0 = y0 + al * 1.f;
      float w1 = y1v + al * v2;
      a11 = (a11 + 1.f * (-w0)) + w0 * (-1.f);
      a21 = (a21 + v2 * (-w0)) + w1 * (-1.f);
      a22 = (a22 + v2 * (-w1)) + w1 * (-v2);
      e0 = beta; d0 = a00; d1 = a11; d2 = a22; e1 = a21;
    }
  }
  float dd[3] = { d0, d1, d2 };
  float ee[2] = { e0, e1 };
  float z[3][3] = { {1.f,0.f,0.f},{0.f,1.f,0.f},{0.f,0.f,1.f} };
  ssteqr3_(dd, ee, z);
  if (tau1 != 0.f) {
    for (int j = 0; j < 3; ++j) {
      float wj = z[1][j] * 1.f + z[2][j] * v2;
      float temp = -tau1 * wj;
      z[1][j] = z[1][j] + 1.f * temp;
      z[2][j] = z[2][j] + v2 * temp;
    }
  }
  for (int r = 0; r < 3; ++r)
    for (int cix = 0; cix < 3; ++cix)
      V[r][cix] = z[r][cix];
}

// ---------------- kernels ----------------

// init: zero BN1-3 buckets + y1key, split W12/W13 to bf16 hi/lo
__global__ __launch_bounds__(256) void init_kernel(double* __restrict__ sb,
                                                   u32* __restrict__ y1k,
                                                   const float* __restrict__ w12,
                                                   const float* __restrict__ w13,
                                                   u16* __restrict__ wsp) {
  int id = blockIdx.x * 256 + threadIdx.x;
  if (id < 24576) sb[id] = 0.0;
  if (id < 8192) {
    y1k[id] = 0u;
    int layer = id >> 12;
    int nk = id & 4095;
    int n = nk >> 6, k = nk & 63;
    const float* W = layer ? w13 : w12;
    float v = W[(size_t)k * 64 + n];
    u16 hi = f2bf(v);
    float rem = v - __uint_as_float(((u32)hi) << 16);
    u16 lo = f2bf(rem);
    wsp[layer * 8192 + n * 64 + k] = hi;
    wsp[layer * 8192 + 4096 + n * 64 + k] = lo;
  }
}

// exact KNN top-20 per point: threshold-select + wave bitonic sort.
__global__ __launch_bounds__(256) void knn_kernel(const float* __restrict__ pos,
                                                  int* __restrict__ idx) {
#pragma clang fp contract(off)
  __shared__ u64 cke[4][128];
  int w = threadIdx.x >> 6;
  int lane = threadIdx.x & 63;
  int wid = blockIdx.x * 4 + w;
  int b = wid >> 11;
  int n = wid & 2047;
  const float* pc = pos + (size_t)b * NNp * 3;
  float qx = pc[n * 3 + 0], qy = pc[n * 3 + 1], qz = pc[n * 3 + 2];
  float d2n = (qx * qx + qy * qy) + qz * qz;

  u32 kreg[32];
  u32 mk = 0xFFFFFFFFu;
#pragma unroll
  for (int t = 0; t < 32; ++t) {
    int m = lane + 64 * t;
    float x = pc[m * 3 + 0], y = pc[m * 3 + 1], zc = pc[m * 3 + 2];
    float d2m = (x * x + y * y) + zc * zc;
    float dot = (qx * x + qy * y) + qz * zc;
    float dist = (d2n + d2m) - 2.0f * dot;
    u32 key = fkey(dist);
    if (m == n) key = 0xFFFFFFFFu;
    kreg[t] = key;
    mk = key < mk ? key : mk;
  }
#pragma unroll
  for (int off = 32; off; off >>= 1) {
    u32 o = __shfl_xor(mk, off);
    mk = o < mk ? o : mk;
  }

  u32 lo_b = mk - 1u, hi_b = 0xFFFFFFFEu;
  int c_hi = 2047;
  float tf = funkey(mk) * 7.368f;
  u32 T = fkey(tf);
  if (T < mk) T = mk;
  if (T > 0xFFFFFFFEu) T = 0xFFFFFFFEu;
  for (int it = 0; it < 48; ++it) {
    int cnt = 0;
#pragma unroll
    for (int t = 0; t < 32; ++t) cnt += (kreg[t] <= T) ? 1 : 0;
#pragma unroll
    for (int off = 32; off; off >>= 1) cnt += __shfl_xor(cnt, off);
    if (cnt >= 20) {
      hi_b = T; c_hi = cnt;
      if (cnt <= 128) break;
    } else {
      lo_b = T;
    }
    if (hi_b <= lo_b + 1u) break;
    u32 Tn;
    if (it < 12) {
      float tfc = funkey(T);
      int cc = cnt < 1 ? 1 : cnt;
      float guess = tfc * __builtin_exp2f(0.66667f * __builtin_log2f(45.0f / (float)cc));
      Tn = fkey(guess);
      if (!(Tn > lo_b && Tn < hi_b)) Tn = lo_b + ((hi_b - lo_b) >> 1);
    } else {
      Tn = lo_b + ((hi_b - lo_b) >> 1);
    }
    T = Tn;
  }

  u64* ck = cke[w];
  u32 base = 0;
#pragma unroll
  for (int t = 0; t < 32; ++t) {
    bool pass = kreg[t] <= hi_b;
    u64 ball = __ballot(pass);
    if (pass) {
      u32 posn = base + (u32)__popcll(ball & ((1ull << lane) - 1ull));
      if (posn < 128u)
        ck[posn] = ((u64)kreg[t] << 32) | (u32)(lane + 64 * t);
    }
    base += (u32)__popcll(ball);
  }
  if (base > 128u) {
    base = 0;
#pragma unroll
    for (int t = 0; t < 32; ++t) {
      bool pass = kreg[t] <= lo_b;
      u64 ball = __ballot(pass);
      if (pass) {
        u32 posn = base + (u32)__popcll(ball & ((1ull << lane) - 1ull));
        ck[posn] = ((u64)kreg[t] << 32) | (u32)(lane + 64 * t);
      }
      base += (u32)__popcll(ball);
    }
#pragma unroll
    for (int t = 0; t < 32; ++t) {
      bool pass = (kreg[t] > lo_b) && (kreg[t] <= hi_b);
      u64 ball = __ballot(pass);
      if (pass) {
        u32 posn = base + (u32)__popcll(ball & ((1ull << lane) - 1ull));
        if (posn < 128u)
          ck[posn] = ((u64)kreg[t] << 32) | (u32)(lane + 64 * t);
      }
      base += (u32)__popcll(ball);
    }
  }
  u32 ctot = base < 128u ? base : 128u;

  u64 e0 = (lane < (int)ctot) ? ck[lane] : ~0ull;
  bsort64(e0, lane);
  if (ctot > 64u) {
    u64 e1 = (lane + 64 < (int)ctot) ? ck[lane + 64] : ~0ull;
    bsort64(e1, lane);
    u64 r = sidx64(e1, 63 - lane);
    u64 mn = r < e0 ? r : e0;
#pragma unroll
    for (int j = 32; j > 0; j >>= 1) {
      u64 pv = sxor64(mn, j);
      bool lower2 = ((lane & j) == 0);
      bool take = lower2 ? (pv < mn) : (pv > mn);
      mn = take ? pv : mn;
    }
    e0 = mn;
  }
  if (lane < 20)
    idx[(size_t)wid * 20 + lane] = (int)(u32)(e0 & 0xFFFFFFFFull);
}

// per-point: covariance, LAPACK-replica eigh, loc = rel @ V
__global__ __launch_bounds__(64) void prep_kernel(const float* __restrict__ pos,
                                                  const int* __restrict__ idx,
                                                  float* __restrict__ loc,
                                                  float* __restrict__ Vout) {
#pragma clang fp contract(off)
  int p = blockIdx.x * 64 + threadIdx.x;
  int b = p >> 11, n = p & 2047;
  const float* pc = pos + (size_t)b * NNp * 3;
  float qx = pc[n * 3 + 0], qy = pc[n * 3 + 1], qz = pc[n * 3 + 2];
  const int* ip = idx + (size_t)p * 20;
  float c00 = 0, c01 = 0, c02 = 0, c11 = 0, c12 = 0, c22 = 0;
  for (int k = 0; k < 20; ++k) {
    int j = ip[k];
    float rx = pc[j * 3 + 0] - qx, ry = pc[j * 3 + 1] - qy, rz = pc[j * 3 + 2] - qz;
    c00 += rx * rx; c01 += rx * ry; c02 += rx * rz;
    c11 += ry * ry; c12 += ry * rz; c22 += rz * rz;
  }
  float Vm[3][3];
  eigh3_(c00, c01, c11, c02, c12, c22, Vm);
  float* vp = Vout + (size_t)p * 9;
  for (int d = 0; d < 3; ++d)
    for (int e = 0; e < 3; ++e) vp[d * 3 + e] = Vm[d][e];
  for (int k = 0; k < 20; ++k) {
    int j = ip[k];
    float rx = pc[j * 3 + 0] - qx, ry = pc[j * 3 + 1] - qy, rz = pc[j * 3 + 2] - qz;
    float l0 = rx * Vm[0][0] + ry * Vm[1][0] + rz * Vm[2][0];
    float l1 = rx * Vm[0][1] + ry * Vm[1][1] + rz * Vm[2][1];
    float l2 = rx * Vm[0][2] + ry * Vm[1][2] + rz * Vm[2][2];
    size_t e = ((size_t)p * 20 + k) * 3;
    loc[e + 0] = l0; loc[e + 1] = l1; loc[e + 2] = l2;
  }
}

// layer1: [E,3]@[3,64]+b, relu, store fp32; fused per-channel stats
__global__ __launch_bounds__(256) void l1_kernel(const float* __restrict__ loc,
                                                 const float* __restrict__ W,
                                                 const float* __restrict__ bias,
                                                 float* __restrict__ h1,
                                                 double* __restrict__ sb) {
  __shared__ float sW[192];
  __shared__ float sB[64];
  __shared__ float red[512];
  int t = threadIdx.x;
  if (t < 192) sW[t] = W[t];
  if (t < 64) sB[t] = bias[t];
  __syncthreads();
  int w = t >> 6, c = t & 63;
  size_t e0 = (size_t)blockIdx.x * 256 + w * 64;
  float wc0 = sW[c], wc1 = sW[64 + c], wc2 = sW[128 + c], bc = sB[c];
  float s = 0.f, q = 0.f;
  for (int e = 0; e < 64; ++e) {
    float x0 = loc[(e0 + e) * 3 + 0];
    float x1 = loc[(e0 + e) * 3 + 1];
    float x2 = loc[(e0 + e) * 3 + 2];
    float z = fmaxf(bc + x0 * wc0 + x1 * wc1 + x2 * wc2, 0.f);
    h1[(e0 + e) * 64 + c] = z;
    s += z; q += z * z;
  }
  red[w * 64 + c] = s;
  red[256 + w * 64 + c] = q;
  __syncthreads();
  if (t < 64) {
    float S = red[t] + red[64 + t] + red[128 + t] + red[192 + t];
    float Q = red[256 + t] + red[320 + t] + red[384 + t] + red[448 + t];
    atomicAdd(&sb[((int)blockIdx.x & 63) * 128 + t], (double)S);
    atomicAdd(&sb[((int)blockIdx.x & 63) * 128 + 64 + t], (double)Q);
  }
}

// 64-bucket stats (64 ch) -> per-channel BN affine (fixed-order reduce)
__global__ void finalizeB_kernel(const double* __restrict__ sb,
                                 const float* __restrict__ g,
                                 const float* __restrict__ be,
                                 float* __restrict__ outp) {
  int c = threadIdx.x;
  if (c >= 64) return;
  double s = 0.0, q = 0.0;
  for (int buk = 0; buk < 64; ++buk) {
    s += sb[buk * 128 + c];
    q += sb[buk * 128 + 64 + c];
  }
  double m = s / (double)EE;
  double var = q / (double)EE - m * m;
  double inv = 1.0 / sqrt(var + 1e-5);
  double sc = (double)g[c] * inv;
  outp[c] = (float)sc;
  outp[64 + c] = (float)((double)be[c] - m * sc);
}

// 64-bucket stats (128 ch) -> BN4 affine (fixed-order bucket reduce)
__global__ void finalize64_kernel(const double* __restrict__ s4b,
                                  const float* __restrict__ g,
                                  const float* __restrict__ be,
                                  float* __restrict__ outp) {
  int c = threadIdx.x;
  double s = 0.0, q = 0.0;
  for (int buk = 0; buk < 64; ++buk) {
    s += s4b[buk * 256 + c];
    q += s4b[buk * 256 + 128 + c];
  }
  double m = s / (double)EE;
  double var = q / (double)EE - m * m;
  double inv = 1.0 / sqrt(var + 1e-5);
  double sc = (double)g[c] * inv;
  outp[c] = (float)sc;
  outp[128 + c] = (float)((double)be[c] - m * sc);
}

// layers 2/3 via split-bf16 MFMA (fp32-grade accuracy); fused stats
__global__ __launch_bounds__(256) void l23_kernel(const float* __restrict__ hin,
                                                  const float* __restrict__ ss,
                                                  const u16* __restrict__ whi,
                                                  const u16* __restrict__ wlo,
                                                  const float* __restrict__ bias,
                                                  float* __restrict__ hout,
                                                  double* __restrict__ sb) {
  __shared__ u16 sHI[128 * 72];
  __shared__ u16 sLO[128 * 72];
  int t = threadIdx.x;
  size_t e0 = (size_t)blockIdx.x * 128;
  int w = t >> 6, l = t & 63;
  int lr = l & 15, lg = l >> 4;

  short8 bhi[4][2], blo[4][2];
#pragma unroll
  for (int nt = 0; nt < 4; ++nt)
#pragma unroll
    for (int ks = 0; ks < 2; ++ks) {
      int off = (nt * 16 + lr) * 64 + ks * 32 + lg * 8;
      bhi[nt][ks] = *(const short8*)&whi[off];
      blo[nt][ks] = *(const short8*)&wlo[off];
    }

  for (int v = t; v < 128 * 16; v += 256) {
    int el = v >> 4, cq = v & 15;
    float4 x4 = *(const float4*)&hin[(e0 + el) * 64 + cq * 4];
    float4 sc4 = *(const float4*)&ss[cq * 4];
    float4 sh4 = *(const float4*)&ss[64 + cq * 4];
    float vv[4];
    vv[0] = x4.x * sc4.x + sh4.x;
    vv[1] = x4.y * sc4.y + sh4.y;
    vv[2] = x4.z * sc4.z + sh4.z;
    vv[3] = x4.w * sc4.w + sh4.w;
    u16 hi[4], lo[4];
#pragma unroll
    for (int j = 0; j < 4; ++j) {
      hi[j] = f2bf(vv[j]);
      float rem = vv[j] - __uint_as_float(((u32)hi[j]) << 16);
      lo[j] = f2bf(rem);
    }
    u32* ph = (u32*)&sHI[el * 72 + cq * 4];
    ph[0] = (u32)hi[0] | ((u32)hi[1] << 16);
    ph[1] = (u32)hi[2] | ((u32)hi[3] << 16);
    u32* pl = (u32*)&sLO[el * 72 + cq * 4];
    pl[0] = (u32)lo[0] | ((u32)lo[1] << 16);
    pl[1] = (u32)lo[2] | ((u32)lo[3] << 16);
  }
  __syncthreads();

  f32x4 acc[2][4];
#pragma unroll
  for (int mt = 0; mt < 2; ++mt)
#pragma unroll
    for (int nt = 0; nt < 4; ++nt) acc[mt][nt] = (f32x4)(0.f);

#pragma unroll
  for (int ks = 0; ks < 2; ++ks) {
    const int kb = ks * 32 + lg * 8;
#pragma unroll
    for (int mt = 0; mt < 2; ++mt) {
      int row = w * 32 + mt * 16 + lr;
      short8 ah = *(const short8*)&sHI[row * 72 + kb];
      short8 al = *(const short8*)&sLO[row * 72 + kb];
#pragma unroll
      for (int nt = 0; nt < 4; ++nt) {
        acc[mt][nt] = __builtin_amdgcn_mfma_f32_16x16x32_bf16(ah, bhi[nt][ks], acc[mt][nt], 0, 0, 0);
        acc[mt][nt] = __builtin_amdgcn_mfma_f32_16x16x32_bf16(al, bhi[nt][ks], acc[mt][nt], 0, 0, 0);
        acc[mt][nt] = __builtin_amdgcn_mfma_f32_16x16x32_bf16(ah, blo[nt][ks], acc[mt][nt], 0, 0, 0);
      }
    }
  }

#pragma unroll
  for (int nt = 0; nt < 4; ++nt) {
    int o = nt * 16 + lr;
    float bs = bias[o];
    float s = 0.f, q = 0.f;
#pragma unroll
    for (int mt = 0; mt < 2; ++mt) {
#pragma unroll
      for (int r = 0; r < 4; ++r) {
        float z = fmaxf(acc[mt][nt][r] + bs, 0.f);
        size_t e = e0 + w * 32 + mt * 16 + lg * 4 + r;
        hout[e * 64 + o] = z;
        s += z; q += z * z;
      }
    }
    s += __shfl_xor(s, 16); s += __shfl_xor(s, 32);
    q += __shfl_xor(q, 16); q += __shfl_xor(q, 32);
    if (l < 16) {
      atomicAdd(&sb[((int)blockIdx.x & 63) * 128 + o], (double)s);
      atomicAdd(&sb[((int)blockIdx.x & 63) * 128 + 64 + o], (double)q);
    }
  }
}

// f3d[p][c][d] = max_k h3n[p,k,c] * loc[p,k,d]
__global__ __launch_bounds__(256) void f3d_kernel(const float* __restrict__ h3,
                                                  const float* __restrict__ ss3,
                                                  const float* __restrict__ loc,
                                                  float* __restrict__ f3d) {
  int t = threadIdx.x;
  int p = blockIdx.x * 4 + (t >> 6);
  int c = t & 63;
  float sc = ss3[c], sh = ss3[64 + c];
  float m0 = -__builtin_inff(), m1 = m0, m2 = m0;
  size_t eb = (size_t)p * 20;
  for (int k = 0; k < 20; ++k) {
    size_t e = eb + k;
    float h = h3[e * 64 + c] * sc + sh;
    float l0 = loc[e * 3 + 0], l1 = loc[e * 3 + 1], l2 = loc[e * 3 + 2];
    m0 = fmaxf(m0, h * l0);
    m1 = fmaxf(m1, h * l1);
    m2 = fmaxf(m2, h * l2);
  }
  size_t o = (size_t)p * 192 + c * 3;
  f3d[o + 0] = m0; f3d[o + 1] = m1; f3d[o + 2] = m2;
}

// W21 [192][128] fp32 -> WT bf16 [128][192]; also zeroes the s4b buckets
__global__ __launch_bounds__(256) void wtcvt_kernel(const float* __restrict__ W,
                                                    u16* __restrict__ wt,
                                                    double* __restrict__ s4b) {
  int id = blockIdx.x * 256 + threadIdx.x;
  if (id < 192 * 128) {
    int n = id / 192, k = id - n * 192;
    wt[id] = f2bf(W[(size_t)k * 128 + n]);
  }
  if (id < 64 * 256) s4b[id] = 0.0;
}

// DD2 via bf16 MFMA: cloud->XCD swizzle; gather+rotate to LDS bf16;
// W-frags in registers; quad-aligned maxpool epilogue; bucketed stats.
// OUTPUT TRANSPOSED: fdd2T[128][16384].
__global__ __launch_bounds__(256) void dd2_kernel(const float* __restrict__ f3d,
                                                  const float* __restrict__ Vmat,
                                                  const int* __restrict__ idx,
                                                  const u16* __restrict__ wt,
                                                  const float* __restrict__ bias,
                                                  float* __restrict__ fdd2T,
                                                  double* __restrict__ s4b) {
  __shared__ u16 sX[80 * 200];
  __shared__ float sV[36];
  __shared__ int sJ[80];
  int t = threadIdx.x;
  int wk = (blockIdx.x & 7) * 512 + (blockIdx.x >> 3);
  int p0 = wk * 4;
  int bcl = p0 >> 11;
  int buk = ((int)blockIdx.x & 63) << 8;

  int w = t >> 6, l = t & 63;
  int lr = l & 15, lg = l >> 4;

  short8 breg[2][6];
#pragma unroll
  for (int nt = 0; nt < 2; ++nt)
#pragma unroll
    for (int s = 0; s < 6; ++s) {
      const int kk = (s / 3) * 96 + (s % 3) * 32 + lg * 8;
      breg[nt][s] = *(const short8*)&wt[(w * 32 + nt * 16 + lr) * 192 + kk];
    }

  if (t < 36) sV[t] = Vmat[(size_t)p0 * 9 + t];
  if (t < 80) sJ[t] = ((bcl << 11) + idx[(size_t)p0 * 20 + t]) * 192;
  __syncthreads();

  for (int v = t; v < 80 * 32; v += 256) {
    int el = v >> 5, c2 = v & 31;
    int pp = el / 20;
    const float* fp = f3d + (size_t)sJ[el] + 6 * c2;
    float2 f01 = *(const float2*)(fp);
    float2 f23 = *(const float2*)(fp + 2);
    float2 f45 = *(const float2*)(fp + 4);
    float f0 = f01.x, f1 = f01.y, f2 = f23.x;
    float f3 = f23.y, f4 = f45.x, f5 = f45.y;
    const float* Vp = &sV[pp * 9];
    float x0 = f0 * Vp[0] + f1 * Vp[3] + f2 * Vp[6];
    float x1 = f0 * Vp[1] + f1 * Vp[4] + f2 * Vp[7];
    float x2 = f0 * Vp[2] + f1 * Vp[5] + f2 * Vp[8];
    float y0 = f3 * Vp[0] + f4 * Vp[3] + f5 * Vp[6];
    float y1 = f3 * Vp[1] + f4 * Vp[4] + f5 * Vp[7];
    float y2 = f3 * Vp[2] + f4 * Vp[5] + f5 * Vp[8];
    u32* xp = (u32*)&sX[el * 200 + 6 * c2];
    xp[0] = (u32)f2bf(x0) | ((u32)f2bf(x1) << 16);
    xp[1] = (u32)f2bf(x2) | ((u32)f2bf(y0) << 16);
    xp[2] = (u32)f2bf(y1) | ((u32)f2bf(y2) << 16);
  }
  __syncthreads();

  f32x4 acc[5][2];
#pragma unroll
  for (int mt = 0; mt < 5; ++mt) {
    acc[mt][0] = (f32x4)(0.f);
    acc[mt][1] = (f32x4)(0.f);
  }

#pragma unroll
  for (int s = 0; s < 6; ++s) {
    const int kbase = (s / 3) * 96 + (s % 3) * 32 + lg * 8;
#pragma unroll
    for (int mt = 0; mt < 5; ++mt) {
      short8 a = *(const short8*)&sX[(mt * 16 + lr) * 200 + kbase];
      acc[mt][0] = __builtin_amdgcn_mfma_f32_16x16x32_bf16(a, breg[0][s], acc[mt][0], 0, 0, 0);
      acc[mt][1] = __builtin_amdgcn_mfma_f32_16x16x32_bf16(a, breg[1][s], acc[mt][1], 0, 0, 0);
    }
  }

  // epilogue: quad-aligned maxpool (each r-quad lies in exactly one point)
#pragma unroll
  for (int nt = 0; nt < 2; ++nt) {
    int col = w * 32 + nt * 16 + lr;
    float bs = bias[col];
    float pm0 = 0.f, pm1 = 0.f, pm2 = 0.f, pm3 = 0.f;
    float s = 0.f, q = 0.f;
#pragma unroll
    for (int mt = 0; mt < 5; ++mt) {
      int qs = mt * 16 + lg * 4;     // quad start edge (multiple of 4)
      int qp = qs / 20;              // owning point 0..3
      float z0 = fmaxf(acc[mt][nt][0] + bs, 0.f);
      float z1 = fmaxf(acc[mt][nt][1] + bs, 0.f);
      float z2 = fmaxf(acc[mt][nt][2] + bs, 0.f);
      float z3 = fmaxf(acc[mt][nt][3] + bs, 0.f);
      s += z0; q += z0 * z0;
      s += z1; q += z1 * z1;
      s += z2; q += z2 * z2;
      s += z3; q += z3 * z3;
      float qm = fmaxf(fmaxf(z0, z1), fmaxf(z2, z3));
      pm0 = fmaxf(pm0, (qp == 0) ? qm : 0.f);
      pm1 = fmaxf(pm1, (qp == 1) ? qm : 0.f);
      pm2 = fmaxf(pm2, (qp == 2) ? qm : 0.f);
      pm3 = fmaxf(pm3, (qp == 3) ? qm : 0.f);
    }
#pragma unroll
    for (int off = 16; off < 64; off <<= 1) {
      pm0 = fmaxf(pm0, __shfl_xor(pm0, off));
      pm1 = fmaxf(pm1, __shfl_xor(pm1, off));
      pm2 = fmaxf(pm2, __shfl_xor(pm2, off));
      pm3 = fmaxf(pm3, __shfl_xor(pm3, off));
      s += __shfl_xor(s, off);
      q += __shfl_xor(q, off);
    }
    if (l < 16) {
      float4 pv;
      pv.x = pm0; pv.y = pm1; pv.z = pm2; pv.w = pm3;
      *(float4*)&fdd2T[(size_t)col * NP + p0] = pv;
      atomicAdd(&s4b[buk + col], (double)s);
      atomicAdd(&s4b[buk + 128 + col], (double)q);
    }
  }
}

// y1: fp32 GEMM [16384,128]@[128,1024] with fused max over n.
// 128Mx128N tile, 8x8 acc/thread; K in FOUR 32-deep LDS stages (32KB).
// k-order sequential 0..127 -> outputs bit-identical.
__global__ __launch_bounds__(256) void y1_kernel(const float* __restrict__ fdd2T,
                                                 const float* __restrict__ ss4,
                                                 const float* __restrict__ wh1,
                                                 u32* __restrict__ y1key) {
  __shared__ float sX[32][128];
  __shared__ float sW[32][128];
  int t = threadIdx.x;
  int mtile = blockIdx.x & 127;
  int ntile = blockIdx.x >> 7;
  int cl = mtile >> 4;
  size_t pbase = (size_t)mtile * 128;
  int c0 = ntile * 128;
  int mg = t >> 4, ng = t & 15;

  float acc[8][8];
#pragma unroll
  for (int i = 0; i < 8; ++i)
#pragma unroll
    for (int j = 0; j < 8; ++j) acc[i][j] = 0.f;

  for (int ks = 0; ks < 4; ++ks) {
    int rr = t >> 5, mq = t & 31;
#pragma unroll
    for (int i = 0; i < 4; ++i) {
      int r = rr + i * 8;
      int k = ks * 32 + r;
      float4 x4 = *(const float4*)&fdd2T[(size_t)k * NP + pbase + mq * 4];
      float sc = ss4[k], sh = ss4[128 + k];
      float4 st;
      st.x = x4.x * sc + sh;
      st.y = x4.y * sc + sh;
      st.z = x4.z * sc + sh;
      st.w = x4.w * sc + sh;
      *(float4*)&sX[r][mq * 4] = st;
      float4 w4 = *(const float4*)&wh1[(size_t)k * 1024 + c0 + mq * 4];
      *(float4*)&sW[r][mq * 4] = w4;
    }
    __syncthreads();
#pragma unroll 8
    for (int kk = 0; kk < 32; ++kk) {
      float4 xa = *(const float4*)&sX[kk][mg * 4];
      float4 xb = *(const float4*)&sX[kk][64 + mg * 4];
      float4 wa = *(const float4*)&sW[kk][ng * 4];
      float4 wb = *(const float4*)&sW[kk][64 + ng * 4];
      float xr[8] = { xa.x, xa.y, xa.z, xa.w, xb.x, xb.y, xb.z, xb.w };
      float wc[8] = { wa.x, wa.y, wa.z, wa.w, wb.x, wb.y, wb.z, wb.w };
#pragma unroll
      for (int i = 0; i < 8; ++i)
#pragma unroll
        for (int j = 0; j < 8; ++j) acc[i][j] += xr[i] * wc[j];
    }
    __syncthreads();
  }

  float colmax[8];
#pragma unroll
  for (int j = 0; j < 8; ++j) {
    float v = acc[0][j];
#pragma unroll
    for (int i = 1; i < 8; ++i) v = fmaxf(v, acc[i][j]);
    colmax[j] = v;
  }
  float* red = &sX[0][0];   // 2048 floats needed; sX has 4096
#pragma unroll
  for (int j = 0; j < 8; ++j) {
    int col = (j < 4) ? (ng * 4 + j) : (64 + ng * 4 + (j - 4));
    red[col * 16 + mg] = colmax[j];
  }
  __syncthreads();
  if (t < 128) {
    float m = red[t * 16];
#pragma unroll
    for (int i = 1; i < 16; ++i) m = fmaxf(m, red[t * 16 + i]);
    atomicMax(&y1key[(size_t)cl * 1024 + c0 + t], fkey(m));
  }
}

// head GEMM layer 1 (1024->512) with FUSED y1 decode+bias+relu+BN staging.
// grid = 8 og x 8 ks; KC=128.
__global__ __launch_bounds__(256) void hgemm1_kernel(const u32* __restrict__ y1k,
                                                     const float* __restrict__ bh1,
                                                     const float* __restrict__ gh1,
                                                     const float* __restrict__ beh1,
                                                     const float* __restrict__ W,
                                                     float* __restrict__ part) {
  __shared__ float sx[8 * 128];
  __shared__ float red[4][8][64];
  int t = threadIdx.x;
  int og = blockIdx.x & 7;
  int ks = blockIdx.x >> 3;
  int k0 = ks * 128;
  if (t < 128) {
    int c = k0 + t;
    float bs = bh1[c];
    float v[8]; double s = 0.0;
#pragma unroll
    for (int b = 0; b < 8; ++b) {
      v[b] = fmaxf(funkey(y1k[b * 1024 + c]) + bs, 0.f);
      s += (double)v[b];
    }
    double m = s / 8.0, q = 0.0;
#pragma unroll
    for (int b = 0; b < 8; ++b) { double d = (double)v[b] - m; q += d * d; }
    q /= 8.0;
    double inv = 1.0 / sqrt(q + 1e-5);
    double sg = (double)gh1[c] * inv;
#pragma unroll
    for (int b = 0; b < 8; ++b)
      sx[b * 128 + t] = (float)(((double)v[b] - m) * sg + (double)beh1[c]);
  }
  __syncthreads();
  int o = og * 64 + (t & 63);
  int kq = t >> 6;
  float acc[8];
#pragma unroll
  for (int b = 0; b < 8; ++b) acc[b] = 0.f;
  for (int i = kq * 32; i < kq * 32 + 32; ++i) {
    float w = W[(size_t)(k0 + i) * 512 + o];
#pragma unroll
    for (int b = 0; b < 8; ++b) acc[b] += sx[b * 128 + i] * w;
  }
#pragma unroll
  for (int b = 0; b < 8; ++b) red[kq][b][t & 63] = acc[b];
  __syncthreads();
  if (kq == 0) {
#pragma unroll
    for (int b = 0; b < 8; ++b) {
      float s = ((red[0][b][t] + red[1][b][t]) + red[2][b][t]) + red[3][b][t];
      part[(size_t)(ks * 8 + b) * 512 + o] = s;
    }
  }
}

// head GEMM layer 2 (512->265) with FUSED chunk-sum+bias+relu+BN staging.
// grid = 5 og x 8 ks; KC=64.
__global__ __launch_bounds__(256) void hgemm2_kernel(const float* __restrict__ part,
                                                     const float* __restrict__ bh2,
                                                     const float* __restrict__ gh2,
                                                     const float* __restrict__ beh2,
                                                     const float* __restrict__ W,
                                                     float* __restrict__ part2) {
  __shared__ float sx[8 * 64];
  __shared__ float red[4][8][64];
  int t = threadIdx.x;
  int og = blockIdx.x % 5;
  int ks = blockIdx.x / 5;
  int k0 = ks * 64;
  if (t < 64) {
    int c = k0 + t;
    float bs = bh2[c];
    float v[8]; double s = 0.0;
#pragma unroll
    for (int b = 0; b < 8; ++b) {
      float p = 0.f;
#pragma unroll
      for (int c2 = 0; c2 < 8; ++c2) p += part[(size_t)(c2 * 8 + b) * 512 + c];
      v[b] = fmaxf(p + bs, 0.f);
      s += (double)v[b];
    }
    double m = s / 8.0, q = 0.0;
#pragma unroll
    for (int b = 0; b < 8; ++b) { double d = (double)v[b] - m; q += d * d; }
    q /= 8.0;
    double inv = 1.0 / sqrt(q + 1e-5);
    double sg = (double)gh2[c] * inv;
#pragma unroll
    for (int b = 0; b < 8; ++b)
      sx[b * 64 + t] = (float)(((double)v[b] - m) * sg + (double)beh2[c]);
  }
  __syncthreads();
  int o = og * 64 + (t & 63);
  int kq = t >> 6;
  float acc[8];
#pragma unroll
  for (int b = 0; b < 8; ++b) acc[b] = 0.f;
  if (o < 265) {
    for (int i = kq * 16; i < kq * 16 + 16; ++i) {
      float w = W[(size_t)(k0 + i) * 265 + o];
#pragma unroll
      for (int b = 0; b < 8; ++b) acc[b] += sx[b * 64 + i] * w;
    }
  }
#pragma unroll
  for (int b = 0; b < 8; ++b) red[kq][b][t & 63] = acc[b];
  __syncthreads();
  if (kq == 0 && o < 265) {
#pragma unroll
    for (int b = 0; b < 8; ++b) {
      float s = ((red[0][b][t] + red[1][b][t]) + red[2][b][t]) + red[3][b][t];
      part2[(size_t)(ks * 8 + b) * 512 + o] = s;
    }
  }
}

// final: fused y3 reduce+BN, then [8,265]@[265,40]+b and log_softmax
__global__ __launch_bounds__(384) void logits_kernel(const float* __restrict__ part2,
                                                     const float* __restrict__ bh3,
                                                     const float* __restrict__ gh3,
                                                     const float* __restrict__ beh3,
                                                     const float* __restrict__ W,
                                                     const float* __restrict__ bias,
                                                     float* __restrict__ out) {
  __shared__ float sy[8 * 265];
  __shared__ float slog[320];
  __shared__ float sm[8], sl[8];
  int t = threadIdx.x;
  if (t < 265) {
    float bs = bh3[t];
    float v[8]; double s = 0.0;
#pragma unroll
    for (int b = 0; b < 8; ++b) {
      float p = 0.f;
#pragma unroll
      for (int c2 = 0; c2 < 8; ++c2) p += part2[(size_t)(c2 * 8 + b) * 512 + t];
      v[b] = fmaxf(p + bs, 0.f);
      s += (double)v[b];
    }
    double m = s / 8.0, q = 0.0;
#pragma unroll
    for (int b = 0; b < 8; ++b) { double d = (double)v[b] - m; q += d * d; }
    q /= 8.0;
    double inv = 1.0 / sqrt(q + 1e-5);
    double sg = (double)gh3[t] * inv;
#pragma unroll
    for (int b = 0; b < 8; ++b)
      sy[b * 265 + t] = (float)(((double)v[b] - m) * sg + (double)beh3[t]);
  }
  __syncthreads();
  if (t < 320) {
    int b = t / 40, o = t % 40;
    float acc = 0.f;
    for (int i = 0; i < 265; ++i) acc += sy[b * 265 + i] * W[i * 40 + o];
    slog[t] = acc + bias[o];
  }
  __syncthreads();
  if (t < 8) {
    float m = slog[t * 40];
    for (int o = 1; o < 40; ++o) m = fmaxf(m, slog[t * 40 + o]);
    float s = 0.f;
    for (int o = 0; o < 40; ++o) s += expf(slog[t * 40 + o] - m);
    sm[t] = m; sl[t] = logf(s);
  }
  __syncthreads();
  if (t < 320) {
    int b = t / 40;
    out[t] = slog[t] - sm[b] - sl[b];
  }
}

// ---------------- launcher ----------------
extern "C" void kernel_launch(void* const* d_in, const int* in_sizes, int n_in,
                              void* d_out, int out_size, void* d_ws, size_t ws_size,
                              hipStream_t stream) {
  (void)in_sizes; (void)n_in; (void)out_size; (void)ws_size;
  const float* pos  = (const float*)d_in[0];
  const float* w11  = (const float*)d_in[1];
  const float* b11  = (const float*)d_in[2];
  const float* g11  = (const float*)d_in[3];
  const float* be11 = (const float*)d_in[4];
  const float* w12  = (const float*)d_in[5];
  const float* b12  = (const float*)d_in[6];
  const float* g12  = (const float*)d_in[7];
  const float* be12 = (const float*)d_in[8];
  const float* w13  = (const float*)d_in[9];
  const float* b13  = (const float*)d_in[10];
  const float* g13  = (const float*)d_in[11];
  const float* be13 = (const float*)d_in[12];
  const float* w21  = (const float*)d_in[13];
  const float* b21  = (const float*)d_in[14];
  const float* g21  = (const float*)d_in[15];
  const float* be21 = (const float*)d_in[16];
  const float* wh1  = (const float*)d_in[17];
  const float* bh1  = (const float*)d_in[18];
  const float* gh1  = (const float*)d_in[19];
  const float* beh1 = (const float*)d_in[20];
  const float* wh2  = (const float*)d_in[21];
  const float* bh2  = (const float*)d_in[22];
  const float* gh2  = (const float*)d_in[23];
  const float* beh2 = (const float*)d_in[24];
  const float* wh3  = (const float*)d_in[25];
  const float* bh3  = (const float*)d_in[26];
  const float* gh3  = (const float*)d_in[27];
  const float* beh3 = (const float*)d_in[28];
  const float* wh4  = (const float*)d_in[29];
  const float* bh4  = (const float*)d_in[30];

  char* ws = (char*)d_ws;
  int*    idx   = (int*)(ws + 0);                 // 1,310,720 B
  float*  loc   = (float*)(ws + 1310720);         // 3,932,160 B
  float*  V     = (float*)(ws + 5242880);         //   589,824 B
  float*  h     = (float*)(ws + 5832704);         // 83,886,080 B (fp32, in-place)
  u16*    wt    = (u16*)(ws + 5832704);           // 49,152 B (overlays h AFTER f3d)
  double* s4b   = (double*)(ws + 5898240);        // 131,072 B (h + 64KB)
  float*  hpart = (float*)(ws + 6881280);         // 131,072 B (h + 1MB)
  float*  hpart2= (float*)(ws + 7012352);         // 131,072 B
  float*  f3d   = (float*)(ws + 89718784);        // 12,582,912 B
  double* sbkt  = (double*)(ws + 89718784);       // 196,608 B (BN1-3 buckets,
                                                  //   consumed before f3d writes)
  u16*    wsp   = (u16*)(ws + 89718784 + 196608); // 32,768 B (split W12/W13,
                                                  //   consumed before f3d writes)
  float*  fdd2T = (float*)(ws + 102301696);       //  8,388,608 B ([128][16384])
  u32*    y1k   = (u32*)(ws + 110690304);         //     32,768 B
  float*  param = (float*)(ws + 110785856);       // 640 floats
  float*  out   = (float*)d_out;

  double* sbL1 = sbkt;
  double* sbL2 = sbkt + 8192;
  double* sbL3 = sbkt + 16384;

  init_kernel<<<96, 256, 0, stream>>>(sbkt, y1k, w12, w13, wsp);
  knn_kernel<<<4096, 256, 0, stream>>>(pos, idx);
  prep_kernel<<<256, 64, 0, stream>>>(pos, idx, loc, V);

  l1_kernel<<<1280, 256, 0, stream>>>(loc, w11, b11, h, sbL1);
  finalizeB_kernel<<<1, 64, 0, stream>>>(sbL1, g11, be11, param);

  l23_kernel<<<2560, 256, 0, stream>>>(h, param, wsp, wsp + 4096, b12, h, sbL2);
  finalizeB_kernel<<<1, 64, 0, stream>>>(sbL2, g12, be12, param + 128);

  l23_kernel<<<2560, 256, 0, stream>>>(h, param + 128, wsp + 8192, wsp + 12288, b13, h, sbL3);
  finalizeB_kernel<<<1, 64, 0, stream>>>(sbL3, g13, be13, param + 256);

  f3d_kernel<<<4096, 256, 0, stream>>>(h, param + 256, loc, f3d);
  // h is dead now; wt + s4b + hpart overlay it
  wtcvt_kernel<<<96, 256, 0, stream>>>(w21, wt, s4b);
  dd2_kernel<<<4096, 256, 0, stream>>>(f3d, V, idx, wt, b21, fdd2T, s4b);
  finalize64_kernel<<<1, 128, 0, stream>>>(s4b, g21, be21, param + 384);

  y1_kernel<<<1024, 256, 0, stream>>>(fdd2T, param + 384, wh1, y1k);

  hgemm1_kernel<<<64, 256, 0, stream>>>(y1k, bh1, gh1, beh1, wh2, hpart);
  hgemm2_kernel<<<40, 256, 0, stream>>>(hpart, bh2, gh2, beh2, wh3, hpart2);
  logits_kernel<<<1, 384, 0, stream>>>(hpart2, bh3, gh3, beh3, wh4, bh4, out);
}